// Round 1
// baseline (3852.559 us; speedup 1.0000x reference)
//
#include <hip/hip_runtime.h>
#include <math.h>

// Problem constants (from reference)
#define BB 2
#define SS 2048
#define DD 512
#define HH 8         // attn heads, dh=64
#define LL 6
#define WW 64        // window
#define MHH 4        // memory heads, dh=128
#define CHH 64       // chunk
#define NCC 32       // num chunks
#define BS (BB*SS)   // 4096 rows

// ---------------- LayerNorm (one block per row, D=512) ----------------
__global__ __launch_bounds__(256) void ln_kernel(
    const float* __restrict__ x, const float* __restrict__ w,
    const float* __restrict__ b, float* __restrict__ y)
{
  const int row = blockIdx.x;
  const int tid = threadIdx.x;
  const float2 v = reinterpret_cast<const float2*>(x + (size_t)row * DD)[tid];
  float s = v.x + v.y;
  float sq = v.x * v.x + v.y * v.y;
#pragma unroll
  for (int off = 32; off; off >>= 1) {
    s += __shfl_xor(s, off);
    sq += __shfl_xor(sq, off);
  }
  __shared__ float ss[4], ssq[4];
  if ((tid & 63) == 0) { ss[tid >> 6] = s; ssq[tid >> 6] = sq; }
  __syncthreads();
  s = ss[0] + ss[1] + ss[2] + ss[3];
  sq = ssq[0] + ssq[1] + ssq[2] + ssq[3];
  const float mean = s * (1.f / DD);
  const float var = sq * (1.f / DD) - mean * mean;
  const float inv = rsqrtf(var + 1e-5f);
  const float2 wv = reinterpret_cast<const float2*>(w)[tid];
  const float2 bv = reinterpret_cast<const float2*>(b)[tid];
  float2 o;
  o.x = (v.x - mean) * inv * wv.x + bv.x;
  o.y = (v.y - mean) * inv * wv.y + bv.y;
  reinterpret_cast<float2*>(y + (size_t)row * DD)[tid] = o;
}

// ---------------- Generic tiled fp32 GEMM with fused epilogues ----------------
// C[M,N] = A[M,K] @ B[K,N] + bias(+epilogue)
// EPI: 0=bias, 1=bias+gelu(tanh approx), 2=bias+add1, 3=bias+add1+add2
__device__ inline float gelu_tanh(float v) {
  float u = 0.7978845608f * (v + 0.044715f * v * v * v);
  u = fminf(fmaxf(u, -20.f), 20.f);
  float e2 = __expf(2.f * u);
  return 0.5f * v * (1.f + (e2 - 1.f) / (e2 + 1.f));
}

template <int EPI>
__global__ __launch_bounds__(256) void gemm_f32(
    const float* __restrict__ A, const float* __restrict__ B,
    const float* __restrict__ bias, const float* __restrict__ add1,
    const float* __restrict__ add2, float* __restrict__ C,
    int M, int N, int K)
{
  __shared__ float As[16][64];
  __shared__ float Bs[16][64];
  const int tid = threadIdx.x;
  const int bm = blockIdx.y * 64;
  const int bn = blockIdx.x * 64;
  const int tx = tid & 15, ty = tid >> 4;
  const int ar = tid & 63, ak = (tid >> 6) * 4;     // A tile load coords
  const int bk = tid >> 4, bn4 = (tid & 15) * 4;    // B tile load coords
  float acc[4][4] = {};

  for (int k0 = 0; k0 < K; k0 += 16) {
    const float4 av = *reinterpret_cast<const float4*>(&A[(size_t)(bm + ar) * K + k0 + ak]);
    const float4 bv = *reinterpret_cast<const float4*>(&B[(size_t)(k0 + bk) * N + bn + bn4]);
    __syncthreads();
    As[ak + 0][ar] = av.x;
    As[ak + 1][ar] = av.y;
    As[ak + 2][ar] = av.z;
    As[ak + 3][ar] = av.w;
    *reinterpret_cast<float4*>(&Bs[bk][bn4]) = bv;
    __syncthreads();
#pragma unroll
    for (int kk = 0; kk < 16; ++kk) {
      const float4 a = *reinterpret_cast<const float4*>(&As[kk][ty * 4]);
      const float4 b = *reinterpret_cast<const float4*>(&Bs[kk][tx * 4]);
      const float aa[4] = {a.x, a.y, a.z, a.w};
      const float bb2[4] = {b.x, b.y, b.z, b.w};
#pragma unroll
      for (int i = 0; i < 4; ++i)
#pragma unroll
        for (int j = 0; j < 4; ++j) acc[i][j] += aa[i] * bb2[j];
    }
  }

#pragma unroll
  for (int i = 0; i < 4; ++i) {
    const size_t row = bm + ty * 4 + i;
    const size_t base = row * (size_t)N + bn + tx * 4;
#pragma unroll
    for (int j = 0; j < 4; ++j) {
      const int col = bn + tx * 4 + j;
      float v = acc[i][j] + (bias ? bias[col] : 0.f);
      if (EPI == 1) v = gelu_tanh(v);
      if (EPI == 2 || EPI == 3) v += add1[base + j];
      if (EPI == 3) v += add2[base + j];
      C[base + j] = v;
    }
  }
}

// ---------------- Sliding-window attention (wave per query, online softmax) ----
__global__ __launch_bounds__(256) void swa_kernel(
    const float* __restrict__ qkv, float* __restrict__ out)
{
  const int wave = threadIdx.x >> 6;
  const int lane = threadIdx.x & 63;
  const int qidx = blockIdx.x * 4 + wave;       // (b*H + h)*S + s
  const int s = qidx & (SS - 1);
  const int bh = qidx >> 11;                    // log2(S)=11
  const int h = bh & (HH - 1);
  const int b = bh >> 3;
  const size_t rowq = (size_t)(b * SS + s) * 1536;
  const float qd = qkv[rowq + h * 64 + lane];
  float m = -INFINITY, l = 0.f, acc = 0.f;
  for (int w = 0; w <= WW; ++w) {
    const int j = s - WW / 2 + w;
    if (j < 0 || j >= SS) continue;
    const size_t rowk = (size_t)(b * SS + j) * 1536;
    const float kd = qkv[rowk + 512 + h * 64 + lane];
    float p = qd * kd;
#pragma unroll
    for (int off = 32; off; off >>= 1) p += __shfl_xor(p, off);
    const float score = p * 0.125f;  // dh^-0.5
    const float vd = qkv[rowk + 1024 + h * 64 + lane];
    const float mn = fmaxf(m, score);
    const float c = __expf(m - mn);
    const float pe = __expf(score - mn);
    l = l * c + pe;
    acc = acc * c + pe * vd;
    m = mn;
  }
  out[(size_t)(b * SS + s) * 512 + h * 64 + lane] = acc / l;
}

// ---------------- Neural memory scan (column-parallel) ----------------
// grid: 8 chains (b,mh) x 32 column-blocks of EC=4 columns = 256 blocks
#define EC 4
__global__ __launch_bounds__(256) void mem_scan_kernel(
    const float* __restrict__ qb, const float* __restrict__ kb,
    const float* __restrict__ vb, float* __restrict__ mem)
{
  const int chain = blockIdx.x >> 5;
  const int colblk = blockIdx.x & 31;
  const int b = chain >> 2;
  const int mh = chain & 3;
  const int ecol = mh * 128 + colblk * EC;   // column base within 512-wide buffer

  __shared__ float Ml[128][EC];
  __shared__ float Moml[128][EC];
  __shared__ float stg[64][132];   // qi then ki, padded row stride
  __shared__ float pvl[64][EC];

  const int tid = threadIdx.x;
  for (int i = tid; i < 128 * EC; i += 256) {
    (&Ml[0][0])[i] = 0.f;
    (&Moml[0][0])[i] = 0.f;
  }
  __syncthreads();

  const int r_o = tid >> 2, e_o = tid & 3;  // out/pred mapping (64x4)
  const int d_g = tid >> 1;                 // grad row owner
  const int e0 = (tid & 1) * 2;             // grad col pair

  for (int c = 0; c < NCC; ++c) {
    const size_t rowbase = (size_t)(b * SS + c * CHH);
    // stage qi
#pragma unroll
    for (int j = 0; j < 8; ++j) {
      const int i4 = tid + 256 * j;
      const int r = i4 >> 5, d4 = (i4 & 31) * 4;
      const float4 v = *reinterpret_cast<const float4*>(&qb[(rowbase + r) * 512 + mh * 128 + d4]);
      *reinterpret_cast<float4*>(&stg[r][d4]) = v;
    }
    __syncthreads();
    // out = qi @ M  (pre-update M)
    {
      float o = 0.f;
#pragma unroll 4
      for (int d = 0; d < 128; ++d) o += stg[r_o][d] * Ml[d][e_o];
      mem[(rowbase + r_o) * 512 + ecol + e_o] = o;
    }
    __syncthreads();
    // stage ki (overwrite)
#pragma unroll
    for (int j = 0; j < 8; ++j) {
      const int i4 = tid + 256 * j;
      const int r = i4 >> 5, d4 = (i4 & 31) * 4;
      const float4 v = *reinterpret_cast<const float4*>(&kb[(rowbase + r) * 512 + mh * 128 + d4]);
      *reinterpret_cast<float4*>(&stg[r][d4]) = v;
    }
    __syncthreads();
    // pv = ki @ M - vi
    {
      float pv = 0.f;
#pragma unroll 4
      for (int d = 0; d < 128; ++d) pv += stg[r_o][d] * Ml[d][e_o];
      pv -= vb[(rowbase + r_o) * 512 + ecol + e_o];
      pvl[r_o][e_o] = pv;
    }
    __syncthreads();
    // grad = ki^T @ pv / CH ; Mom = .9 Mom - .1 grad ; M = .99 M + Mom
    {
      float g0 = 0.f, g1 = 0.f;
      for (int r = 0; r < 64; ++r) {
        const float kv = stg[r][d_g];
        g0 += kv * pvl[r][e0];
        g1 += kv * pvl[r][e0 + 1];
      }
      g0 *= (1.f / 64.f);
      g1 *= (1.f / 64.f);
      const float mom0 = 0.9f * Moml[d_g][e0] - 0.1f * g0;
      const float mom1 = 0.9f * Moml[d_g][e0 + 1] - 0.1f * g1;
      Moml[d_g][e0] = mom0;
      Moml[d_g][e0 + 1] = mom1;
      Ml[d_g][e0] = 0.99f * Ml[d_g][e0] + mom0;
      Ml[d_g][e0 + 1] = 0.99f * Ml[d_g][e0 + 1] + mom1;
    }
    __syncthreads();
  }
}

// ---------------- small vec helpers ----------------
__global__ __launch_bounds__(256) void mean_tokens_kernel(
    const float* __restrict__ pm, float* __restrict__ mvec)
{
  const int d = blockIdx.x * 256 + threadIdx.x;
  if (d < 512) {
    float s = 0.f;
    for (int t = 0; t < 16; ++t) s += pm[t * 512 + d];
    mvec[d] = s * (1.f / 16.f);
  }
}

// out[e] = sum_d a[d]*W[d,e] (+bias)
__global__ __launch_bounds__(256) void matvec512_kernel(
    const float* __restrict__ a, const float* __restrict__ W,
    const float* __restrict__ bias, float* __restrict__ out)
{
  const int e = blockIdx.x * 256 + threadIdx.x;
  float s = bias ? bias[e] : 0.f;
  for (int d = 0; d < 512; ++d) s += a[d] * W[d * 512 + e];
  out[e] = s;
}

// ---------------- host side ----------------
static void launch_gemm(int epi, const float* A, const float* B, const float* bias,
                        const float* add1, const float* add2, float* C,
                        int M, int N, int K, hipStream_t stream)
{
  dim3 grid(N / 64, M / 64);
  switch (epi) {
    case 0: gemm_f32<0><<<grid, 256, 0, stream>>>(A, B, bias, add1, add2, C, M, N, K); break;
    case 1: gemm_f32<1><<<grid, 256, 0, stream>>>(A, B, bias, add1, add2, C, M, N, K); break;
    case 2: gemm_f32<2><<<grid, 256, 0, stream>>>(A, B, bias, add1, add2, C, M, N, K); break;
    case 3: gemm_f32<3><<<grid, 256, 0, stream>>>(A, B, bias, add1, add2, C, M, N, K); break;
  }
}

extern "C" void kernel_launch(void* const* d_in, const int* in_sizes, int n_in,
                              void* d_out, int out_size, void* d_ws, size_t ws_size,
                              hipStream_t stream)
{
  const float* x         = (const float*)d_in[0];
  const float* n1w       = (const float*)d_in[1];
  const float* n1b       = (const float*)d_in[2];
  const float* qkvw      = (const float*)d_in[3];
  const float* qkvb      = (const float*)d_in[4];
  const float* projw     = (const float*)d_in[5];
  const float* projb     = (const float*)d_in[6];
  const float* n2w       = (const float*)d_in[7];
  const float* n2b       = (const float*)d_in[8];
  const float* fc1w      = (const float*)d_in[9];
  const float* fc1b      = (const float*)d_in[10];
  const float* fc2w      = (const float*)d_in[11];
  const float* fc2b      = (const float*)d_in[12];
  const float* mlnw      = (const float*)d_in[13];
  const float* mlnb      = (const float*)d_in[14];
  const float* mwq       = (const float*)d_in[15];
  const float* mwk       = (const float*)d_in[16];
  const float* mwv       = (const float*)d_in[17];
  const float* mprojw    = (const float*)d_in[18];
  const float* mprojb    = (const float*)d_in[19];
  const float* pm_tokens = (const float*)d_in[20];
  const float* pmw       = (const float*)d_in[21];
  const float* pmb       = (const float*)d_in[22];
  const float* fw        = (const float*)d_in[23];
  const float* fb        = (const float*)d_in[24];
  float* out = (float*)d_out;

  // workspace layout (needs ~76 MB)
  char* w8 = (char*)d_ws;
  const size_t SZ = (size_t)BS * DD * sizeof(float);       // 8 MiB
  float* buf_h    = (float*)(w8 + 0 * SZ);
  float* buf_ln   = (float*)(w8 + 1 * SZ);
  float* buf_attn = (float*)(w8 + 2 * SZ);
  float* buf_b    = (float*)(w8 + 3 * SZ);
  float* buf_c    = (float*)(w8 + 4 * SZ);
  float* buf_big  = (float*)(w8 + 5 * SZ);                 // 32 MiB (qkv / ff1 / mem)
  float* t0       = (float*)(w8 + 5 * SZ + (size_t)BS * 2048 * sizeof(float));
  float* t1       = t0 + 512;
  float* t2       = t1 + 512;

  // ---- persistent path (tiny) ----
  mean_tokens_kernel<<<2, 256, 0, stream>>>(pm_tokens, t0);
  matvec512_kernel<<<2, 256, 0, stream>>>(t0, pmw, pmb, t1);            // pooled
  matvec512_kernel<<<2, 256, 0, stream>>>(t1, fw + (size_t)1024 * 512, fb, t2); // persistent contrib + fusion bias

  // ---- neural memory path (on original x) ----
  ln_kernel<<<BS, 256, 0, stream>>>(x, mlnw, mlnb, buf_c);              // nx
  launch_gemm(0, buf_c, mwq, nullptr, nullptr, nullptr, buf_ln,   BS, 512, 512, stream);
  launch_gemm(0, buf_c, mwk, nullptr, nullptr, nullptr, buf_attn, BS, 512, 512, stream);
  launch_gemm(0, buf_c, mwv, nullptr, nullptr, nullptr, buf_b,    BS, 512, 512, stream);
  mem_scan_kernel<<<256, 256, 0, stream>>>(buf_ln, buf_attn, buf_b, buf_big);
  // long_term = x + mem @ mproj + b  -> buf_c
  launch_gemm(2, buf_big, mprojw, mprojb, x, nullptr, buf_c, BS, 512, 512, stream);

  // ---- layer stack ----
  hipMemcpyAsync(buf_h, x, SZ, hipMemcpyDeviceToDevice, stream);
  for (int l = 0; l < LL; ++l) {
    ln_kernel<<<BS, 256, 0, stream>>>(buf_h, n1w + l * 512, n1b + l * 512, buf_ln);
    launch_gemm(0, buf_ln, qkvw + (size_t)l * 512 * 1536, qkvb + l * 1536,
                nullptr, nullptr, buf_big, BS, 1536, 512, stream);
    swa_kernel<<<(BB * HH * SS) / 4, 256, 0, stream>>>(buf_big, buf_attn);
    launch_gemm(2, buf_attn, projw + (size_t)l * 512 * 512, projb + l * 512,
                buf_h, nullptr, buf_h, BS, 512, 512, stream);
    ln_kernel<<<BS, 256, 0, stream>>>(buf_h, n2w + l * 512, n2b + l * 512, buf_ln);
    launch_gemm(1, buf_ln, fc1w + (size_t)l * 512 * 2048, fc1b + l * 2048,
                nullptr, nullptr, buf_big, BS, 2048, 512, stream);
    launch_gemm(3, buf_big, fc2w + (size_t)l * 2048 * 512, fc2b + l * 512,
                buf_ln, buf_h, buf_h, BS, 512, 2048, stream);
  }

  // ---- fusion: out = ST@W0 + LT@W1 + (persistent contrib incl. bias) ----
  launch_gemm(0, buf_h, fw, t2, nullptr, nullptr, out, BS, 512, 512, stream);
  launch_gemm(2, buf_c, fw + (size_t)512 * 512, nullptr, out, nullptr, out, BS, 512, 512, stream);
}

// Round 2
// 2128.248 us; speedup vs baseline: 1.8102x; 1.8102x over previous
//
#include <hip/hip_runtime.h>
#include <math.h>

// Problem constants
#define BB 2
#define SS 2048
#define DD 512
#define HH 8
#define LL 6
#define WW 64
#define CHH 64
#define NCC 32
#define BS (BB*SS)   // 4096 rows

typedef __attribute__((ext_vector_type(8))) short short8;
typedef __attribute__((ext_vector_type(4))) short short4v;
typedef __attribute__((ext_vector_type(4))) float f32x4;

__device__ inline float b2f(short s) {
  unsigned u = ((unsigned)(unsigned short)s) << 16;
  float f; __builtin_memcpy(&f, &u, 4); return f;
}
__device__ inline short f2b(float f) {
  unsigned u; __builtin_memcpy(&u, &f, 4);
  unsigned r = (u + 0x7FFFu + ((u >> 16) & 1u)) >> 16;
  return (short)r;
}
__device__ inline float gelu_tanh(float v) {
  float u = 0.7978845608f * (v + 0.044715f * v * v * v);
  u = fminf(fmaxf(u, -20.f), 20.f);
  float e2 = __expf(2.f * u);
  return 0.5f * v * (1.f + (e2 - 1.f) / (e2 + 1.f));
}

#define AS1(p) ((const __attribute__((address_space(1))) void*)(p))
#define AS3(p) ((__attribute__((address_space(3))) void*)(p))

// ---------------- LayerNorm: fp32 in -> bf16 out ----------------
__global__ __launch_bounds__(256) void ln_kernel(
    const float* __restrict__ x, const float* __restrict__ w,
    const float* __restrict__ b, short* __restrict__ y)
{
  const int row = blockIdx.x;
  const int tid = threadIdx.x;
  const float2 v = reinterpret_cast<const float2*>(x + (size_t)row * DD)[tid];
  float s = v.x + v.y;
  float sq = v.x * v.x + v.y * v.y;
#pragma unroll
  for (int off = 32; off; off >>= 1) {
    s += __shfl_xor(s, off);
    sq += __shfl_xor(sq, off);
  }
  __shared__ float ss[4], ssq[4];
  if ((tid & 63) == 0) { ss[tid >> 6] = s; ssq[tid >> 6] = sq; }
  __syncthreads();
  s = ss[0] + ss[1] + ss[2] + ss[3];
  sq = ssq[0] + ssq[1] + ssq[2] + ssq[3];
  const float mean = s * (1.f / DD);
  const float var = sq * (1.f / DD) - mean * mean;
  const float inv = rsqrtf(var + 1e-5f);
  const float2 wv = reinterpret_cast<const float2*>(w)[tid];
  const float2 bv = reinterpret_cast<const float2*>(b)[tid];
  const float ox = (v.x - mean) * inv * wv.x + bv.x;
  const float oy = (v.y - mean) * inv * wv.y + bv.y;
  unsigned pk = ((unsigned)(unsigned short)f2b(oy) << 16) | (unsigned short)f2b(ox);
  reinterpret_cast<unsigned*>(y + (size_t)row * DD)[tid] = pk;
}

// ---------------- bf16 MFMA GEMM ----------------
// C[M,N] = A[M,K](bf16) @ B(via BT[N,K] bf16) with epilogue.
// EPI: 0 = +bias(opt); 1 = gelu(+bias); 2 = +bias(opt)+add1(f32); 3 = +bias+add1(f32)+add2(bf16)
// OBF: 0 = fp32 out, 1 = bf16 out
template<int EPI, int OBF>
__global__ __launch_bounds__(256) void gemm_bf16(
    const short* __restrict__ A, const short* __restrict__ BT,
    const float* __restrict__ bias, const float* __restrict__ add1,
    const short* __restrict__ add2, void* __restrict__ C,
    int M, int N, int K)
{
  // 128x128 tile, 4 waves (2x2), per-wave 64x64 = 4x4 frags of 16x16x32
  __shared__ __align__(16) short As[128 * 32];
  __shared__ __align__(16) short Bs[128 * 32];
  const int tid = threadIdx.x;
  const int wave = tid >> 6, lane = tid & 63;
  const int wr = wave >> 1, wc = wave & 1;
  const int bm = blockIdx.y * 128, bn = blockIdx.x * 128;

  const int l4r = lane >> 2;        // 0..15: row within 16-row chunk
  const int l4c = (lane & 3) * 8;   // k element offset (16B quarters)

  const short* sA[2]; const short* sB[2];
  int ldsA[2], ldsB[2];
#pragma unroll
  for (int r = 0; r < 2; ++r) {
    const int chunk = r * 4 + wave;
    sA[r] = A + (size_t)(bm + chunk * 16 + l4r) * K + l4c;
    sB[r] = BT + (size_t)(bn + chunk * 16 + l4r) * K + l4c;
    ldsA[r] = chunk * 1024;   // bytes
    ldsB[r] = chunk * 1024;
  }

  f32x4 acc[4][4] = {};

  for (int k0 = 0; k0 < K; k0 += 32) {
#pragma unroll
    for (int r = 0; r < 2; ++r) {
      __builtin_amdgcn_global_load_lds(AS1(sA[r]), AS3((char*)As + ldsA[r]), 16, 0, 0);
      __builtin_amdgcn_global_load_lds(AS1(sB[r]), AS3((char*)Bs + ldsB[r]), 16, 0, 0);
      sA[r] += 32; sB[r] += 32;
    }
    __syncthreads();
    short8 af[4], bf[4];
#pragma unroll
    for (int m = 0; m < 4; ++m)
      af[m] = *(const short8*)&As[(wr * 64 + m * 16 + (lane & 15)) * 32 + (lane >> 4) * 8];
#pragma unroll
    for (int n = 0; n < 4; ++n)
      bf[n] = *(const short8*)&Bs[(wc * 64 + n * 16 + (lane & 15)) * 32 + (lane >> 4) * 8];
#pragma unroll
    for (int m = 0; m < 4; ++m)
#pragma unroll
      for (int n = 0; n < 4; ++n)
        acc[m][n] = __builtin_amdgcn_mfma_f32_16x16x32_bf16(af[m], bf[n], acc[m][n], 0, 0, 0);
    __syncthreads();
  }

#pragma unroll
  for (int m = 0; m < 4; ++m) {
#pragma unroll
    for (int n = 0; n < 4; ++n) {
      const int col = bn + wc * 64 + n * 16 + (lane & 15);
      const float bb = (EPI == 1 || EPI == 3) ? bias[col] : (bias ? bias[col] : 0.f);
#pragma unroll
      for (int r = 0; r < 4; ++r) {
        const int row = bm + wr * 64 + m * 16 + (lane >> 4) * 4 + r;
        const size_t idx = (size_t)row * N + col;
        float v = acc[m][n][r] + bb;
        if (EPI == 1) v = gelu_tanh(v);
        if (EPI == 2 || EPI == 3) v += add1[idx];
        if (EPI == 3) v += b2f(add2[idx]);
        if (OBF) ((short*)C)[idx] = f2b(v);
        else ((float*)C)[idx] = v;
      }
    }
  }
}

// ---------------- Sliding-window attention (f32 qkv in, bf16 out) ----------
__global__ __launch_bounds__(256) void swa_kernel(
    const float* __restrict__ qkv, short* __restrict__ out)
{
  const int wave = threadIdx.x >> 6;
  const int lane = threadIdx.x & 63;
  const int qidx = blockIdx.x * 4 + wave;
  const int s = qidx & (SS - 1);
  const int bh = qidx >> 11;
  const int h = bh & (HH - 1);
  const int b = bh >> 3;
  const size_t rowq = (size_t)(b * SS + s) * 1536;
  const float qd = qkv[rowq + h * 64 + lane];
  float m = -INFINITY, l = 0.f, acc = 0.f;
  for (int w = 0; w <= WW; ++w) {
    const int j = s - WW / 2 + w;
    if (j < 0 || j >= SS) continue;
    const size_t rowk = (size_t)(b * SS + j) * 1536;
    const float kd = qkv[rowk + 512 + h * 64 + lane];
    float p = qd * kd;
#pragma unroll
    for (int off = 32; off; off >>= 1) p += __shfl_xor(p, off);
    const float score = p * 0.125f;
    const float vd = qkv[rowk + 1024 + h * 64 + lane];
    const float mn = fmaxf(m, score);
    const float c = __expf(m - mn);
    const float pe = __expf(score - mn);
    l = l * c + pe;
    acc = acc * c + pe * vd;
    m = mn;
  }
  out[(size_t)(b * SS + s) * 512 + h * 64 + lane] = f2b(acc / l);
}

// ---------------- Neural memory scan (f32 q/k/v in, stride st; bf16 mem out) ---
#define EC 4
__global__ __launch_bounds__(256) void mem_scan_kernel(
    const float* __restrict__ qb, const float* __restrict__ kb,
    const float* __restrict__ vb, short* __restrict__ mem, int st)
{
  const int chain = blockIdx.x >> 5;
  const int colblk = blockIdx.x & 31;
  const int b = chain >> 2;
  const int mh = chain & 3;
  const int ecol = mh * 128 + colblk * EC;

  __shared__ float Ml[128][EC];
  __shared__ float Moml[128][EC];
  __shared__ float stg[64][132];
  __shared__ float pvl[64][EC];

  const int tid = threadIdx.x;
  for (int i = tid; i < 128 * EC; i += 256) {
    (&Ml[0][0])[i] = 0.f;
    (&Moml[0][0])[i] = 0.f;
  }
  __syncthreads();

  const int r_o = tid >> 2, e_o = tid & 3;
  const int d_g = tid >> 1;
  const int e0 = (tid & 1) * 2;

  for (int c = 0; c < NCC; ++c) {
    const size_t rowbase = (size_t)(b * SS + c * CHH);
#pragma unroll
    for (int j = 0; j < 8; ++j) {
      const int i4 = tid + 256 * j;
      const int r = i4 >> 5, d4 = (i4 & 31) * 4;
      const float4 v = *reinterpret_cast<const float4*>(&qb[(rowbase + r) * st + mh * 128 + d4]);
      *reinterpret_cast<float4*>(&stg[r][d4]) = v;
    }
    __syncthreads();
    {
      float o = 0.f;
#pragma unroll 4
      for (int d = 0; d < 128; ++d) o += stg[r_o][d] * Ml[d][e_o];
      mem[(rowbase + r_o) * 512 + ecol + e_o] = f2b(o);
    }
    __syncthreads();
#pragma unroll
    for (int j = 0; j < 8; ++j) {
      const int i4 = tid + 256 * j;
      const int r = i4 >> 5, d4 = (i4 & 31) * 4;
      const float4 v = *reinterpret_cast<const float4*>(&kb[(rowbase + r) * st + mh * 128 + d4]);
      *reinterpret_cast<float4*>(&stg[r][d4]) = v;
    }
    __syncthreads();
    {
      float pv = 0.f;
#pragma unroll 4
      for (int d = 0; d < 128; ++d) pv += stg[r_o][d] * Ml[d][e_o];
      pv -= vb[(rowbase + r_o) * st + ecol + e_o];
      pvl[r_o][e_o] = pv;
    }
    __syncthreads();
    {
      float g0 = 0.f, g1 = 0.f;
      for (int r = 0; r < 64; ++r) {
        const float kv = stg[r][d_g];
        g0 += kv * pvl[r][e0];
        g1 += kv * pvl[r][e0 + 1];
      }
      g0 *= (1.f / 64.f);
      g1 *= (1.f / 64.f);
      const float mom0 = 0.9f * Moml[d_g][e0] - 0.1f * g0;
      const float mom1 = 0.9f * Moml[d_g][e0 + 1] - 0.1f * g1;
      Moml[d_g][e0] = mom0;
      Moml[d_g][e0 + 1] = mom1;
      Ml[d_g][e0] = 0.99f * Ml[d_g][e0] + mom0;
      Ml[d_g][e0 + 1] = 0.99f * Ml[d_g][e0 + 1] + mom1;
    }
    __syncthreads();
  }
}

// ---------------- transpose + f32->bf16 convert: src[K,N] -> dst[N,K] -------
__global__ __launch_bounds__(256) void tcvt_kernel(
    const float* __restrict__ src, short* __restrict__ dst, int K, int N)
{
  __shared__ float t[32][33];
  const int k0 = blockIdx.y * 32, n0 = blockIdx.x * 32;
  const size_t zoff = (size_t)blockIdx.z * K * N;
  src += zoff; dst += zoff;
  const int tx = threadIdx.x & 31, ty = threadIdx.x >> 5;
#pragma unroll
  for (int i = 0; i < 4; ++i)
    t[ty + i * 8][tx] = src[(size_t)(k0 + ty + i * 8) * N + n0 + tx];
  __syncthreads();
#pragma unroll
  for (int i = 0; i < 4; ++i)
    dst[(size_t)(n0 + ty + i * 8) * K + k0 + tx] = f2b(t[tx][ty + i * 8]);
}

// ---------------- f32 -> bf16 convert ----------------
__global__ __launch_bounds__(256) void cvt_kernel(
    const float* __restrict__ in, short* __restrict__ out, int n4)
{
  const int i = blockIdx.x * 256 + threadIdx.x;
  if (i >= n4) return;
  const float4 v = reinterpret_cast<const float4*>(in)[i];
  short4v o;
  o.x = f2b(v.x); o.y = f2b(v.y); o.z = f2b(v.z); o.w = f2b(v.w);
  reinterpret_cast<short4v*>(out)[i] = o;
}

// ---------------- small vec helpers ----------------
__global__ __launch_bounds__(256) void mean_tokens_kernel(
    const float* __restrict__ pm, float* __restrict__ mvec)
{
  const int d = blockIdx.x * 256 + threadIdx.x;
  if (d < 512) {
    float s = 0.f;
    for (int t = 0; t < 16; ++t) s += pm[t * 512 + d];
    mvec[d] = s * (1.f / 16.f);
  }
}

__global__ __launch_bounds__(256) void matvec512_kernel(
    const float* __restrict__ a, const float* __restrict__ W,
    const float* __restrict__ bias, float* __restrict__ out)
{
  const int e = blockIdx.x * 256 + threadIdx.x;
  float s = bias ? bias[e] : 0.f;
  for (int d = 0; d < 512; ++d) s += a[d] * W[d * 512 + e];
  out[e] = s;
}

// ---------------- host side ----------------
extern "C" void kernel_launch(void* const* d_in, const int* in_sizes, int n_in,
                              void* d_out, int out_size, void* d_ws, size_t ws_size,
                              hipStream_t stream)
{
  const float* x         = (const float*)d_in[0];
  const float* n1w       = (const float*)d_in[1];
  const float* n1b       = (const float*)d_in[2];
  const float* qkvw      = (const float*)d_in[3];
  const float* qkvb      = (const float*)d_in[4];
  const float* projw     = (const float*)d_in[5];
  const float* projb     = (const float*)d_in[6];
  const float* n2w       = (const float*)d_in[7];
  const float* n2b       = (const float*)d_in[8];
  const float* fc1w      = (const float*)d_in[9];
  const float* fc1b      = (const float*)d_in[10];
  const float* fc2w      = (const float*)d_in[11];
  const float* fc2b      = (const float*)d_in[12];
  const float* mlnw      = (const float*)d_in[13];
  const float* mlnb      = (const float*)d_in[14];
  const float* mwq       = (const float*)d_in[15];
  const float* mwk       = (const float*)d_in[16];
  const float* mwv       = (const float*)d_in[17];
  const float* mprojw    = (const float*)d_in[18];
  const float* mprojb    = (const float*)d_in[19];
  const float* pm_tokens = (const float*)d_in[20];
  const float* pmw       = (const float*)d_in[21];
  const float* pmb       = (const float*)d_in[22];
  const float* fw        = (const float*)d_in[23];
  const float* fb        = (const float*)d_in[24];
  float* out = (float*)d_out;

  // ---- workspace bump allocator ----
  char* p = (char*)d_ws;
  auto alloc = [&](size_t bytes) {
    char* r = p;
    p += (bytes + 255) & ~(size_t)255;
    return r;
  };
  // bf16 transposed weights
  short* qkvwT  = (short*)alloc(6ull * 1536 * 512 * 2);
  short* projwT = (short*)alloc(6ull * 512 * 512 * 2);
  short* fc1wT  = (short*)alloc(6ull * 2048 * 512 * 2);
  short* fc2wT  = (short*)alloc(6ull * 512 * 2048 * 2);
  short* mqkvT  = (short*)alloc(3ull * 512 * 512 * 2);   // wq|wk|wv packed
  short* mprojT = (short*)alloc(512ull * 512 * 2);
  short* fw0T   = (short*)alloc(512ull * 512 * 2);
  short* fw1T   = (short*)alloc(512ull * 512 * 2);
  // fp32 buffers
  float* bigf = (float*)alloc((size_t)BS * 1536 * 4);    // qkv out / mem q|k|v
  float* hbuf = (float*)alloc((size_t)BS * 512 * 4);
  float* t0   = (float*)alloc(3 * 512 * 4);
  float* t1 = t0 + 512; float* t2 = t1 + 512;
  // bf16 activations
  short* actA  = (short*)alloc((size_t)BS * 512 * 2);    // ln outs / h_bf
  short* attnb = (short*)alloc((size_t)BS * 512 * 2);
  short* ff1b  = (short*)alloc((size_t)BS * 2048 * 2);   // also mem_bf pre-loop
  short* ltb   = (short*)alloc((size_t)BS * 512 * 2);

  // ---- weight transpose/convert ----
  tcvt_kernel<<<dim3(1536 / 32, 512 / 32, 6), 256, 0, stream>>>(qkvw, qkvwT, 512, 1536);
  tcvt_kernel<<<dim3(512 / 32, 512 / 32, 6), 256, 0, stream>>>(projw, projwT, 512, 512);
  tcvt_kernel<<<dim3(2048 / 32, 512 / 32, 6), 256, 0, stream>>>(fc1w, fc1wT, 512, 2048);
  tcvt_kernel<<<dim3(512 / 32, 2048 / 32, 6), 256, 0, stream>>>(fc2w, fc2wT, 2048, 512);
  tcvt_kernel<<<dim3(16, 16, 1), 256, 0, stream>>>(mwq, mqkvT, 512, 512);
  tcvt_kernel<<<dim3(16, 16, 1), 256, 0, stream>>>(mwk, mqkvT + 512 * 512, 512, 512);
  tcvt_kernel<<<dim3(16, 16, 1), 256, 0, stream>>>(mwv, mqkvT + 2 * 512 * 512, 512, 512);
  tcvt_kernel<<<dim3(16, 16, 1), 256, 0, stream>>>(mprojw, mprojT, 512, 512);
  tcvt_kernel<<<dim3(16, 16, 1), 256, 0, stream>>>(fw, fw0T, 512, 512);
  tcvt_kernel<<<dim3(16, 16, 1), 256, 0, stream>>>(fw + 512 * 512, fw1T, 512, 512);

  // ---- persistent path ----
  mean_tokens_kernel<<<2, 256, 0, stream>>>(pm_tokens, t0);
  matvec512_kernel<<<2, 256, 0, stream>>>(t0, pmw, pmb, t1);
  matvec512_kernel<<<2, 256, 0, stream>>>(t1, fw + (size_t)1024 * 512, fb, t2);

  // ---- neural memory path ----
  ln_kernel<<<BS, 256, 0, stream>>>(x, mlnw, mlnb, actA);
  gemm_bf16<0, 0><<<dim3(12, 32), 256, 0, stream>>>(
      actA, mqkvT, nullptr, nullptr, nullptr, bigf, BS, 1536, 512);
  mem_scan_kernel<<<256, 256, 0, stream>>>(bigf, bigf + 512, bigf + 1024, ff1b, 1536);
  gemm_bf16<2, 1><<<dim3(4, 32), 256, 0, stream>>>(
      ff1b, mprojT, mprojb, x, nullptr, ltb, BS, 512, 512);

  // ---- layer stack ----
  hipMemcpyAsync(hbuf, x, (size_t)BS * 512 * 4, hipMemcpyDeviceToDevice, stream);
  for (int l = 0; l < LL; ++l) {
    ln_kernel<<<BS, 256, 0, stream>>>(hbuf, n1w + l * 512, n1b + l * 512, actA);
    gemm_bf16<0, 0><<<dim3(12, 32), 256, 0, stream>>>(
        actA, qkvwT + (size_t)l * 1536 * 512, qkvb + l * 1536,
        nullptr, nullptr, bigf, BS, 1536, 512);
    swa_kernel<<<(BB * HH * SS) / 4, 256, 0, stream>>>(bigf, attnb);
    gemm_bf16<2, 0><<<dim3(4, 32), 256, 0, stream>>>(
        attnb, projwT + (size_t)l * 512 * 512, projb + l * 512,
        hbuf, nullptr, hbuf, BS, 512, 512);
    ln_kernel<<<BS, 256, 0, stream>>>(hbuf, n2w + l * 512, n2b + l * 512, actA);
    gemm_bf16<1, 1><<<dim3(16, 32), 256, 0, stream>>>(
        actA, fc1wT + (size_t)l * 2048 * 512, fc1b + l * 2048,
        nullptr, nullptr, ff1b, BS, 2048, 512);
    gemm_bf16<3, 0><<<dim3(4, 32), 256, 0, stream>>>(
        ff1b, fc2wT + (size_t)l * 512 * 2048, fc2b + l * 512,
        hbuf, actA, hbuf, BS, 512, 2048);
  }

  // ---- fusion ----
  cvt_kernel<<<(BS * 512 / 4 + 255) / 256, 256, 0, stream>>>(hbuf, actA, BS * 512 / 4);
  gemm_bf16<0, 0><<<dim3(4, 32), 256, 0, stream>>>(
      actA, fw0T, t2, nullptr, nullptr, out, BS, 512, 512);
  gemm_bf16<2, 0><<<dim3(4, 32), 256, 0, stream>>>(
      ltb, fw1T, nullptr, out, nullptr, out, BS, 512, 512);
}

// Round 3
// 1143.478 us; speedup vs baseline: 3.3692x; 1.8612x over previous
//
#include <hip/hip_runtime.h>
#include <math.h>

// Problem constants
#define BB 2
#define SS 2048
#define DD 512
#define HH 8
#define LL 6
#define WW 64
#define CHH 64
#define NCC 32
#define BS (BB*SS)   // 4096 rows

typedef __attribute__((ext_vector_type(8))) short short8;
typedef __attribute__((ext_vector_type(4))) short short4v;
typedef __attribute__((ext_vector_type(4))) float f32x4;

__device__ inline float b2f(short s) {
  unsigned u = ((unsigned)(unsigned short)s) << 16;
  float f; __builtin_memcpy(&f, &u, 4); return f;
}
__device__ inline short f2b(float f) {
  unsigned u; __builtin_memcpy(&u, &f, 4);
  unsigned r = (u + 0x7FFFu + ((u >> 16) & 1u)) >> 16;
  return (short)r;
}
__device__ inline float gelu_tanh(float v) {
  float u = 0.7978845608f * (v + 0.044715f * v * v * v);
  u = fminf(fmaxf(u, -20.f), 20.f);
  float e2 = __expf(2.f * u);
  return 0.5f * v * (1.f + (e2 - 1.f) / (e2 + 1.f));
}

#define AS1(p) ((const __attribute__((address_space(1))) void*)(p))
#define AS3(p) ((__attribute__((address_space(3))) void*)(p))

// ---------------- LayerNorm: fp32 in -> bf16 out ----------------
__global__ __launch_bounds__(256) void ln_kernel(
    const float* __restrict__ x, const float* __restrict__ w,
    const float* __restrict__ b, short* __restrict__ y)
{
  const int row = blockIdx.x;
  const int tid = threadIdx.x;
  const float2 v = reinterpret_cast<const float2*>(x + (size_t)row * DD)[tid];
  float s = v.x + v.y;
  float sq = v.x * v.x + v.y * v.y;
#pragma unroll
  for (int off = 32; off; off >>= 1) {
    s += __shfl_xor(s, off);
    sq += __shfl_xor(sq, off);
  }
  __shared__ float ss[4], ssq[4];
  if ((tid & 63) == 0) { ss[tid >> 6] = s; ssq[tid >> 6] = sq; }
  __syncthreads();
  s = ss[0] + ss[1] + ss[2] + ss[3];
  sq = ssq[0] + ssq[1] + ssq[2] + ssq[3];
  const float mean = s * (1.f / DD);
  const float var = sq * (1.f / DD) - mean * mean;
  const float inv = rsqrtf(var + 1e-5f);
  const float2 wv = reinterpret_cast<const float2*>(w)[tid];
  const float2 bv = reinterpret_cast<const float2*>(b)[tid];
  const float ox = (v.x - mean) * inv * wv.x + bv.x;
  const float oy = (v.y - mean) * inv * wv.y + bv.y;
  unsigned pk = ((unsigned)(unsigned short)f2b(oy) << 16) | (unsigned short)f2b(ox);
  reinterpret_cast<unsigned*>(y + (size_t)row * DD)[tid] = pk;
}

// ---------------- bf16 MFMA GEMM ----------------
template<int EPI, int OBF>
__global__ __launch_bounds__(256) void gemm_bf16(
    const short* __restrict__ A, const short* __restrict__ BT,
    const float* __restrict__ bias, const float* __restrict__ add1,
    const short* __restrict__ add2, void* __restrict__ C,
    int M, int N, int K)
{
  __shared__ __align__(16) short As[128 * 32];
  __shared__ __align__(16) short Bs[128 * 32];
  const int tid = threadIdx.x;
  const int wave = tid >> 6, lane = tid & 63;
  const int wr = wave >> 1, wc = wave & 1;
  const int bm = blockIdx.y * 128, bn = blockIdx.x * 128;

  const int l4r = lane >> 2;
  const int l4c = (lane & 3) * 8;

  const short* sA[2]; const short* sB[2];
  int ldsA[2], ldsB[2];
#pragma unroll
  for (int r = 0; r < 2; ++r) {
    const int chunk = r * 4 + wave;
    sA[r] = A + (size_t)(bm + chunk * 16 + l4r) * K + l4c;
    sB[r] = BT + (size_t)(bn + chunk * 16 + l4r) * K + l4c;
    ldsA[r] = chunk * 1024;
    ldsB[r] = chunk * 1024;
  }

  f32x4 acc[4][4] = {};

  for (int k0 = 0; k0 < K; k0 += 32) {
#pragma unroll
    for (int r = 0; r < 2; ++r) {
      __builtin_amdgcn_global_load_lds(AS1(sA[r]), AS3((char*)As + ldsA[r]), 16, 0, 0);
      __builtin_amdgcn_global_load_lds(AS1(sB[r]), AS3((char*)Bs + ldsB[r]), 16, 0, 0);
      sA[r] += 32; sB[r] += 32;
    }
    __syncthreads();
    short8 af[4], bf[4];
#pragma unroll
    for (int m = 0; m < 4; ++m)
      af[m] = *(const short8*)&As[(wr * 64 + m * 16 + (lane & 15)) * 32 + (lane >> 4) * 8];
#pragma unroll
    for (int n = 0; n < 4; ++n)
      bf[n] = *(const short8*)&Bs[(wc * 64 + n * 16 + (lane & 15)) * 32 + (lane >> 4) * 8];
#pragma unroll
    for (int m = 0; m < 4; ++m)
#pragma unroll
      for (int n = 0; n < 4; ++n)
        acc[m][n] = __builtin_amdgcn_mfma_f32_16x16x32_bf16(af[m], bf[n], acc[m][n], 0, 0, 0);
    __syncthreads();
  }

#pragma unroll
  for (int m = 0; m < 4; ++m) {
#pragma unroll
    for (int n = 0; n < 4; ++n) {
      const int col = bn + wc * 64 + n * 16 + (lane & 15);
      const float bb = (EPI == 1 || EPI == 3) ? bias[col] : (bias ? bias[col] : 0.f);
#pragma unroll
      for (int r = 0; r < 4; ++r) {
        const int row = bm + wr * 64 + m * 16 + (lane >> 4) * 4 + r;
        const size_t idx = (size_t)row * N + col;
        float v = acc[m][n][r] + bb;
        if (EPI == 1) v = gelu_tanh(v);
        if (EPI == 2 || EPI == 3) v += add1[idx];
        if (EPI == 3) v += b2f(add2[idx]);
        if (OBF) ((short*)C)[idx] = f2b(v);
        else ((float*)C)[idx] = v;
      }
    }
  }
}

// ---------------- Sliding-window attention, MFMA flash-style ----------------
// Block = one (b, h, 64-query tile). 4 waves, each owns 16 queries.
// S^T = mfma(K, Q)  ->  per-lane softmax over 32 j's + 2 shfls
// P -> LDS (bf16) -> A-frags ; O = mfma(P, V^T)
__global__ __launch_bounds__(256) void swa_kernel(
    const float* __restrict__ qkv, short* __restrict__ out)
{
  __shared__ __align__(16) short ks[128 * 72];      // K rows, stride 72
  __shared__ __align__(16) short vt[64 * 136];      // V^T [d][j], stride 136
  __shared__ __align__(16) short ps[4][16 * 136];   // per-wave P [q][j], stride 136
  __shared__ float lsum[64];

  const int tid = threadIdx.x;
  const int w = tid >> 6, l = tid & 63;
  const int tile = blockIdx.x & 31;
  const int h = (blockIdx.x >> 5) & 7;
  const int b = blockIdx.x >> 8;
  const int s0 = tile * 64;
  const size_t base = (size_t)b * SS;

  // ---- stage K (row-major) and V^T (transposed) as bf16 ----
#pragma unroll
  for (int u = 0; u < 16; ++u) {
    const int id = u * 256 + tid;
    const int row = id >> 5, dp = id & 31;     // row 0..127, dim-pair 0..31
    int jp = s0 - 32 + row;
    jp = min(max(jp, 0), SS - 1);
    const size_t g = (base + jp) * 1536 + h * 64 + dp * 2;
    const float2 kv = *(const float2*)&qkv[g + 512];
    const float2 vv = *(const float2*)&qkv[g + 1024];
    unsigned pk = ((unsigned)(unsigned short)f2b(kv.y) << 16) | (unsigned short)f2b(kv.x);
    *(unsigned*)&ks[row * 72 + dp * 2] = pk;
    vt[(dp * 2) * 136 + row] = f2b(vv.x);
    vt[(dp * 2 + 1) * 136 + row] = f2b(vv.y);
  }

  // ---- Q fragments straight from global (B-operand of S^T) ----
  const int qi = w * 16 + (l & 15);            // this lane's query column 0..63
  short8 qf[2];
#pragma unroll
  for (int kf = 0; kf < 2; ++kf) {
    const float* qp = &qkv[(base + s0 + qi) * 1536 + h * 64 + kf * 32 + (l >> 4) * 8];
    const float4 a = *(const float4*)qp;
    const float4 c = *(const float4*)(qp + 4);
    short8 q8;
    q8[0] = f2b(a.x); q8[1] = f2b(a.y); q8[2] = f2b(a.z); q8[3] = f2b(a.w);
    q8[4] = f2b(c.x); q8[5] = f2b(c.y); q8[6] = f2b(c.z); q8[7] = f2b(c.w);
    qf[kf] = q8;
  }
  __syncthreads();

  // ---- S^T[128 j][16 q] for this wave's 16 queries ----
  f32x4 sa[8] = {};
#pragma unroll
  for (int mf = 0; mf < 8; ++mf)
#pragma unroll
    for (int kf = 0; kf < 2; ++kf) {
      const short8 af = *(const short8*)&ks[(mf * 16 + (l & 15)) * 72 + kf * 32 + (l >> 4) * 8];
      sa[mf] = __builtin_amdgcn_mfma_f32_16x16x32_bf16(af, qf[kf], sa[mf], 0, 0, 0);
    }

  // ---- mask + softmax (per lane: 32 j's of one query; 4 lanes/query) ----
  float sv[8][4];
  float mx = -INFINITY;
#pragma unroll
  for (int mf = 0; mf < 8; ++mf)
#pragma unroll
    for (int r = 0; r < 4; ++r) {
      const int j = mf * 16 + (l >> 4) * 4 + r;
      const int jpos = s0 - 32 + j;
      const bool ok = (j >= qi) && (j <= qi + 64) && (jpos >= 0) && (jpos < SS);
      const float s = ok ? sa[mf][r] * 0.125f : -INFINITY;
      sv[mf][r] = s;
      mx = fmaxf(mx, s);
    }
  mx = fmaxf(mx, __shfl_xor(mx, 16));
  mx = fmaxf(mx, __shfl_xor(mx, 32));
  float ls = 0.f;
#pragma unroll
  for (int mf = 0; mf < 8; ++mf)
#pragma unroll
    for (int r = 0; r < 4; ++r) {
      const float p = __expf(sv[mf][r] - mx);
      sv[mf][r] = p;
      ls += p;
    }
  ls += __shfl_xor(ls, 16);
  ls += __shfl_xor(ls, 32);
  if (l < 16) lsum[w * 16 + l] = ls;

  // ---- P -> LDS (per-wave region, [q][j] bf16) ----
#pragma unroll
  for (int mf = 0; mf < 8; ++mf) {
    short4v p4;
    p4.x = f2b(sv[mf][0]); p4.y = f2b(sv[mf][1]);
    p4.z = f2b(sv[mf][2]); p4.w = f2b(sv[mf][3]);
    *(short4v*)&ps[w][(l & 15) * 136 + mf * 16 + (l >> 4) * 4] = p4;
  }

  // ---- O[16 q][64 d] = P @ V ----
  f32x4 oa[4] = {};
#pragma unroll
  for (int kf = 0; kf < 4; ++kf) {
    const short8 pf = *(const short8*)&ps[w][(l & 15) * 136 + kf * 32 + (l >> 4) * 8];
#pragma unroll
    for (int nf = 0; nf < 4; ++nf) {
      const short8 vf = *(const short8*)&vt[(nf * 16 + (l & 15)) * 136 + kf * 32 + (l >> 4) * 8];
      oa[nf] = __builtin_amdgcn_mfma_f32_16x16x32_bf16(pf, vf, oa[nf], 0, 0, 0);
    }
  }

  // ---- normalize + store bf16 ----
  float rl[4];
#pragma unroll
  for (int r = 0; r < 4; ++r) rl[r] = 1.f / lsum[w * 16 + (l >> 4) * 4 + r];
#pragma unroll
  for (int nf = 0; nf < 4; ++nf)
#pragma unroll
    for (int r = 0; r < 4; ++r) {
      const int q = (l >> 4) * 4 + r;
      const int d = nf * 16 + (l & 15);
      out[(base + s0 + w * 16 + q) * 512 + h * 64 + d] = f2b(oa[nf][r] * rl[r]);
    }
}

// ---------------- Neural memory scan (f32 q/k/v in, stride st; bf16 mem out) ---
#define EC 4
__global__ __launch_bounds__(256) void mem_scan_kernel(
    const float* __restrict__ qb, const float* __restrict__ kb,
    const float* __restrict__ vb, short* __restrict__ mem, int st)
{
  const int chain = blockIdx.x >> 5;
  const int colblk = blockIdx.x & 31;
  const int b = chain >> 2;
  const int mh = chain & 3;
  const int ecol = mh * 128 + colblk * EC;

  __shared__ float Ml[128][EC];
  __shared__ float Moml[128][EC];
  __shared__ float stg[64][132];
  __shared__ float pvl[64][EC];

  const int tid = threadIdx.x;
  for (int i = tid; i < 128 * EC; i += 256) {
    (&Ml[0][0])[i] = 0.f;
    (&Moml[0][0])[i] = 0.f;
  }
  __syncthreads();

  const int r_o = tid >> 2, e_o = tid & 3;
  const int d_g = tid >> 1;
  const int e0 = (tid & 1) * 2;

  for (int c = 0; c < NCC; ++c) {
    const size_t rowbase = (size_t)(b * SS + c * CHH);
#pragma unroll
    for (int j = 0; j < 8; ++j) {
      const int i4 = tid + 256 * j;
      const int r = i4 >> 5, d4 = (i4 & 31) * 4;
      const float4 v = *reinterpret_cast<const float4*>(&qb[(rowbase + r) * st + mh * 128 + d4]);
      *reinterpret_cast<float4*>(&stg[r][d4]) = v;
    }
    __syncthreads();
    {
      float o = 0.f;
#pragma unroll 4
      for (int d = 0; d < 128; ++d) o += stg[r_o][d] * Ml[d][e_o];
      mem[(rowbase + r_o) * 512 + ecol + e_o] = f2b(o);
    }
    __syncthreads();
#pragma unroll
    for (int j = 0; j < 8; ++j) {
      const int i4 = tid + 256 * j;
      const int r = i4 >> 5, d4 = (i4 & 31) * 4;
      const float4 v = *reinterpret_cast<const float4*>(&kb[(rowbase + r) * st + mh * 128 + d4]);
      *reinterpret_cast<float4*>(&stg[r][d4]) = v;
    }
    __syncthreads();
    {
      float pv = 0.f;
#pragma unroll 4
      for (int d = 0; d < 128; ++d) pv += stg[r_o][d] * Ml[d][e_o];
      pv -= vb[(rowbase + r_o) * st + ecol + e_o];
      pvl[r_o][e_o] = pv;
    }
    __syncthreads();
    {
      float g0 = 0.f, g1 = 0.f;
      for (int r = 0; r < 64; ++r) {
        const float kv = stg[r][d_g];
        g0 += kv * pvl[r][e0];
        g1 += kv * pvl[r][e0 + 1];
      }
      g0 *= (1.f / 64.f);
      g1 *= (1.f / 64.f);
      const float mom0 = 0.9f * Moml[d_g][e0] - 0.1f * g0;
      const float mom1 = 0.9f * Moml[d_g][e0 + 1] - 0.1f * g1;
      Moml[d_g][e0] = mom0;
      Moml[d_g][e0 + 1] = mom1;
      Ml[d_g][e0] = 0.99f * Ml[d_g][e0] + mom0;
      Ml[d_g][e0 + 1] = 0.99f * Ml[d_g][e0 + 1] + mom1;
    }
    __syncthreads();
  }
}

// ---------------- transpose + f32->bf16 convert: src[K,N] -> dst[N,K] -------
__global__ __launch_bounds__(256) void tcvt_kernel(
    const float* __restrict__ src, short* __restrict__ dst, int K, int N)
{
  __shared__ float t[32][33];
  const int k0 = blockIdx.y * 32, n0 = blockIdx.x * 32;
  const size_t zoff = (size_t)blockIdx.z * K * N;
  src += zoff; dst += zoff;
  const int tx = threadIdx.x & 31, ty = threadIdx.x >> 5;
#pragma unroll
  for (int i = 0; i < 4; ++i)
    t[ty + i * 8][tx] = src[(size_t)(k0 + ty + i * 8) * N + n0 + tx];
  __syncthreads();
#pragma unroll
  for (int i = 0; i < 4; ++i)
    dst[(size_t)(n0 + ty + i * 8) * K + k0 + tx] = f2b(t[tx][ty + i * 8]);
}

// ---------------- f32 -> bf16 convert ----------------
__global__ __launch_bounds__(256) void cvt_kernel(
    const float* __restrict__ in, short* __restrict__ out, int n4)
{
  const int i = blockIdx.x * 256 + threadIdx.x;
  if (i >= n4) return;
  const float4 v = reinterpret_cast<const float4*>(in)[i];
  short4v o;
  o.x = f2b(v.x); o.y = f2b(v.y); o.z = f2b(v.z); o.w = f2b(v.w);
  reinterpret_cast<short4v*>(out)[i] = o;
}

// ---------------- small vec helpers ----------------
__global__ __launch_bounds__(256) void mean_tokens_kernel(
    const float* __restrict__ pm, float* __restrict__ mvec)
{
  const int d = blockIdx.x * 256 + threadIdx.x;
  if (d < 512) {
    float s = 0.f;
    for (int t = 0; t < 16; ++t) s += pm[t * 512 + d];
    mvec[d] = s * (1.f / 16.f);
  }
}

__global__ __launch_bounds__(256) void matvec512_kernel(
    const float* __restrict__ a, const float* __restrict__ W,
    const float* __restrict__ bias, float* __restrict__ out)
{
  const int e = blockIdx.x * 256 + threadIdx.x;
  float s = bias ? bias[e] : 0.f;
  for (int d = 0; d < 512; ++d) s += a[d] * W[d * 512 + e];
  out[e] = s;
}

// ---------------- host side ----------------
extern "C" void kernel_launch(void* const* d_in, const int* in_sizes, int n_in,
                              void* d_out, int out_size, void* d_ws, size_t ws_size,
                              hipStream_t stream)
{
  const float* x         = (const float*)d_in[0];
  const float* n1w       = (const float*)d_in[1];
  const float* n1b       = (const float*)d_in[2];
  const float* qkvw      = (const float*)d_in[3];
  const float* qkvb      = (const float*)d_in[4];
  const float* projw     = (const float*)d_in[5];
  const float* projb     = (const float*)d_in[6];
  const float* n2w       = (const float*)d_in[7];
  const float* n2b       = (const float*)d_in[8];
  const float* fc1w      = (const float*)d_in[9];
  const float* fc1b      = (const float*)d_in[10];
  const float* fc2w      = (const float*)d_in[11];
  const float* fc2b      = (const float*)d_in[12];
  const float* mlnw      = (const float*)d_in[13];
  const float* mlnb      = (const float*)d_in[14];
  const float* mwq       = (const float*)d_in[15];
  const float* mwk       = (const float*)d_in[16];
  const float* mwv       = (const float*)d_in[17];
  const float* mprojw    = (const float*)d_in[18];
  const float* mprojb    = (const float*)d_in[19];
  const float* pm_tokens = (const float*)d_in[20];
  const float* pmw       = (const float*)d_in[21];
  const float* pmb       = (const float*)d_in[22];
  const float* fw        = (const float*)d_in[23];
  const float* fb        = (const float*)d_in[24];
  float* out = (float*)d_out;

  char* p = (char*)d_ws;
  auto alloc = [&](size_t bytes) {
    char* r = p;
    p += (bytes + 255) & ~(size_t)255;
    return r;
  };
  short* qkvwT  = (short*)alloc(6ull * 1536 * 512 * 2);
  short* projwT = (short*)alloc(6ull * 512 * 512 * 2);
  short* fc1wT  = (short*)alloc(6ull * 2048 * 512 * 2);
  short* fc2wT  = (short*)alloc(6ull * 512 * 2048 * 2);
  short* mqkvT  = (short*)alloc(3ull * 512 * 512 * 2);
  short* mprojT = (short*)alloc(512ull * 512 * 2);
  short* fw0T   = (short*)alloc(512ull * 512 * 2);
  short* fw1T   = (short*)alloc(512ull * 512 * 2);
  float* bigf = (float*)alloc((size_t)BS * 1536 * 4);
  float* hbuf = (float*)alloc((size_t)BS * 512 * 4);
  float* t0   = (float*)alloc(3 * 512 * 4);
  float* t1 = t0 + 512; float* t2 = t1 + 512;
  short* actA  = (short*)alloc((size_t)BS * 512 * 2);
  short* attnb = (short*)alloc((size_t)BS * 512 * 2);
  short* ff1b  = (short*)alloc((size_t)BS * 2048 * 2);
  short* ltb   = (short*)alloc((size_t)BS * 512 * 2);

  tcvt_kernel<<<dim3(1536 / 32, 512 / 32, 6), 256, 0, stream>>>(qkvw, qkvwT, 512, 1536);
  tcvt_kernel<<<dim3(512 / 32, 512 / 32, 6), 256, 0, stream>>>(projw, projwT, 512, 512);
  tcvt_kernel<<<dim3(2048 / 32, 512 / 32, 6), 256, 0, stream>>>(fc1w, fc1wT, 512, 2048);
  tcvt_kernel<<<dim3(512 / 32, 2048 / 32, 6), 256, 0, stream>>>(fc2w, fc2wT, 2048, 512);
  tcvt_kernel<<<dim3(16, 16, 1), 256, 0, stream>>>(mwq, mqkvT, 512, 512);
  tcvt_kernel<<<dim3(16, 16, 1), 256, 0, stream>>>(mwk, mqkvT + 512 * 512, 512, 512);
  tcvt_kernel<<<dim3(16, 16, 1), 256, 0, stream>>>(mwv, mqkvT + 2 * 512 * 512, 512, 512);
  tcvt_kernel<<<dim3(16, 16, 1), 256, 0, stream>>>(mprojw, mprojT, 512, 512);
  tcvt_kernel<<<dim3(16, 16, 1), 256, 0, stream>>>(fw, fw0T, 512, 512);
  tcvt_kernel<<<dim3(16, 16, 1), 256, 0, stream>>>(fw + 512 * 512, fw1T, 512, 512);

  mean_tokens_kernel<<<2, 256, 0, stream>>>(pm_tokens, t0);
  matvec512_kernel<<<2, 256, 0, stream>>>(t0, pmw, pmb, t1);
  matvec512_kernel<<<2, 256, 0, stream>>>(t1, fw + (size_t)1024 * 512, fb, t2);

  ln_kernel<<<BS, 256, 0, stream>>>(x, mlnw, mlnb, actA);
  gemm_bf16<0, 0><<<dim3(12, 32), 256, 0, stream>>>(
      actA, mqkvT, nullptr, nullptr, nullptr, bigf, BS, 1536, 512);
  mem_scan_kernel<<<256, 256, 0, stream>>>(bigf, bigf + 512, bigf + 1024, ff1b, 1536);
  gemm_bf16<2, 1><<<dim3(4, 32), 256, 0, stream>>>(
      ff1b, mprojT, mprojb, x, nullptr, ltb, BS, 512, 512);

  hipMemcpyAsync(hbuf, x, (size_t)BS * 512 * 4, hipMemcpyDeviceToDevice, stream);
  for (int l = 0; l < LL; ++l) {
    ln_kernel<<<BS, 256, 0, stream>>>(hbuf, n1w + l * 512, n1b + l * 512, actA);
    gemm_bf16<0, 0><<<dim3(12, 32), 256, 0, stream>>>(
        actA, qkvwT + (size_t)l * 1536 * 512, qkvb + l * 1536,
        nullptr, nullptr, bigf, BS, 1536, 512);
    swa_kernel<<<512, 256, 0, stream>>>(bigf, attnb);
    gemm_bf16<2, 0><<<dim3(4, 32), 256, 0, stream>>>(
        attnb, projwT + (size_t)l * 512 * 512, projb + l * 512,
        hbuf, nullptr, hbuf, BS, 512, 512);
    ln_kernel<<<BS, 256, 0, stream>>>(hbuf, n2w + l * 512, n2b + l * 512, actA);
    gemm_bf16<1, 1><<<dim3(16, 32), 256, 0, stream>>>(
        actA, fc1wT + (size_t)l * 2048 * 512, fc1b + l * 2048,
        nullptr, nullptr, ff1b, BS, 2048, 512);
    gemm_bf16<3, 0><<<dim3(4, 32), 256, 0, stream>>>(
        ff1b, fc2wT + (size_t)l * 512 * 2048, fc2b + l * 512,
        hbuf, actA, hbuf, BS, 512, 2048);
  }

  cvt_kernel<<<(BS * 512 / 4 + 255) / 256, 256, 0, stream>>>(hbuf, actA, BS * 512 / 4);
  gemm_bf16<0, 0><<<dim3(4, 32), 256, 0, stream>>>(
      actA, fw0T, t2, nullptr, nullptr, out, BS, 512, 512);
  gemm_bf16<2, 0><<<dim3(4, 32), 256, 0, stream>>>(
      ltb, fw1T, nullptr, out, nullptr, out, BS, 512, 512);
}

// Round 4
// 1072.228 us; speedup vs baseline: 3.5930x; 1.0665x over previous
//
#include <hip/hip_runtime.h>
#include <math.h>

// Problem constants
#define BB 2
#define SS 2048
#define DD 512
#define HH 8
#define LL 6
#define WW 64
#define CHH 64
#define NCC 32
#define BS (BB*SS)   // 4096 rows

typedef __attribute__((ext_vector_type(8))) short short8;
typedef __attribute__((ext_vector_type(4))) short short4v;
typedef __attribute__((ext_vector_type(4))) float f32x4;

__device__ inline float b2f(short s) {
  unsigned u = ((unsigned)(unsigned short)s) << 16;
  float f; __builtin_memcpy(&f, &u, 4); return f;
}
__device__ inline short f2b(float f) {
  unsigned u; __builtin_memcpy(&u, &f, 4);
  unsigned r = (u + 0x7FFFu + ((u >> 16) & 1u)) >> 16;
  return (short)r;
}
__device__ inline float gelu_tanh(float v) {
  float u = 0.7978845608f * (v + 0.044715f * v * v * v);
  u = fminf(fmaxf(u, -20.f), 20.f);
  float e2 = __expf(2.f * u);
  return 0.5f * v * (1.f + (e2 - 1.f) / (e2 + 1.f));
}

#define AS1(p) ((const __attribute__((address_space(1))) void*)(p))
#define AS3(p) ((__attribute__((address_space(3))) void*)(p))

// ---------------- LayerNorm: fp32 in -> bf16 out ----------------
__global__ __launch_bounds__(256) void ln_kernel(
    const float* __restrict__ x, const float* __restrict__ w,
    const float* __restrict__ b, short* __restrict__ y)
{
  const int row = blockIdx.x;
  const int tid = threadIdx.x;
  const float2 v = reinterpret_cast<const float2*>(x + (size_t)row * DD)[tid];
  float s = v.x + v.y;
  float sq = v.x * v.x + v.y * v.y;
#pragma unroll
  for (int off = 32; off; off >>= 1) {
    s += __shfl_xor(s, off);
    sq += __shfl_xor(sq, off);
  }
  __shared__ float ss[4], ssq[4];
  if ((tid & 63) == 0) { ss[tid >> 6] = s; ssq[tid >> 6] = sq; }
  __syncthreads();
  s = ss[0] + ss[1] + ss[2] + ss[3];
  sq = ssq[0] + ssq[1] + ssq[2] + ssq[3];
  const float mean = s * (1.f / DD);
  const float var = sq * (1.f / DD) - mean * mean;
  const float inv = rsqrtf(var + 1e-5f);
  const float2 wv = reinterpret_cast<const float2*>(w)[tid];
  const float2 bv = reinterpret_cast<const float2*>(b)[tid];
  const float ox = (v.x - mean) * inv * wv.x + bv.x;
  const float oy = (v.y - mean) * inv * wv.y + bv.y;
  unsigned pk = ((unsigned)(unsigned short)f2b(oy) << 16) | (unsigned short)f2b(ox);
  reinterpret_cast<unsigned*>(y + (size_t)row * DD)[tid] = pk;
}

// ---------------- bf16 MFMA GEMM (BM=128 or 64, BN=128) ----------------
// EPI: 0 = +bias(opt); 1 = gelu(+bias); 2 = +bias(opt)+add1(f32); 3 = +bias+add1(f32)+add2(bf16)
// OBF: 0 = fp32 out, 1 = bf16 out
template<int EPI, int OBF, int BM>
__global__ __launch_bounds__(256) void gemm_bf16(
    const short* __restrict__ A, const short* __restrict__ BT,
    const float* __restrict__ bias, const float* __restrict__ add1,
    const short* __restrict__ add2, void* __restrict__ C,
    int M, int N, int K)
{
  constexpr int MF = BM / 32;      // per-wave M fragments (wave tile = BM/2 x 64)
  constexpr int CA = BM / 64;      // A staging rounds
  __shared__ __align__(16) short As[BM * 32];
  __shared__ __align__(16) short Bs[128 * 32];
  const int tid = threadIdx.x;
  const int wave = tid >> 6, lane = tid & 63;
  const int wr = wave >> 1, wc = wave & 1;
  const int bm = blockIdx.y * BM, bn = blockIdx.x * 128;

  const int l4r = lane >> 2;
  const int l4c = (lane & 3) * 8;

  const short* sA[CA]; const short* sB[2];
  int ldsA[CA], ldsB[2];
#pragma unroll
  for (int r = 0; r < CA; ++r) {
    const int chunk = r * 4 + wave;
    sA[r] = A + (size_t)(bm + chunk * 16 + l4r) * K + l4c;
    ldsA[r] = chunk * 1024;
  }
#pragma unroll
  for (int r = 0; r < 2; ++r) {
    const int chunk = r * 4 + wave;
    sB[r] = BT + (size_t)(bn + chunk * 16 + l4r) * K + l4c;
    ldsB[r] = chunk * 1024;
  }

  f32x4 acc[MF][4] = {};

  for (int k0 = 0; k0 < K; k0 += 32) {
#pragma unroll
    for (int r = 0; r < CA; ++r) {
      __builtin_amdgcn_global_load_lds(AS1(sA[r]), AS3((char*)As + ldsA[r]), 16, 0, 0);
      sA[r] += 32;
    }
#pragma unroll
    for (int r = 0; r < 2; ++r) {
      __builtin_amdgcn_global_load_lds(AS1(sB[r]), AS3((char*)Bs + ldsB[r]), 16, 0, 0);
      sB[r] += 32;
    }
    __syncthreads();
    short8 af[MF], bf[4];
#pragma unroll
    for (int m = 0; m < MF; ++m)
      af[m] = *(const short8*)&As[(wr * (BM / 2) + m * 16 + (lane & 15)) * 32 + (lane >> 4) * 8];
#pragma unroll
    for (int n = 0; n < 4; ++n)
      bf[n] = *(const short8*)&Bs[(wc * 64 + n * 16 + (lane & 15)) * 32 + (lane >> 4) * 8];
#pragma unroll
    for (int m = 0; m < MF; ++m)
#pragma unroll
      for (int n = 0; n < 4; ++n)
        acc[m][n] = __builtin_amdgcn_mfma_f32_16x16x32_bf16(af[m], bf[n], acc[m][n], 0, 0, 0);
    __syncthreads();
  }

#pragma unroll
  for (int m = 0; m < MF; ++m) {
#pragma unroll
    for (int n = 0; n < 4; ++n) {
      const int col = bn + wc * 64 + n * 16 + (lane & 15);
      const float bb = (EPI == 1 || EPI == 3) ? bias[col] : (bias ? bias[col] : 0.f);
#pragma unroll
      for (int r = 0; r < 4; ++r) {
        const int row = bm + wr * (BM / 2) + m * 16 + (lane >> 4) * 4 + r;
        const size_t idx = (size_t)row * N + col;
        float v = acc[m][n][r] + bb;
        if (EPI == 1) v = gelu_tanh(v);
        if (EPI == 2 || EPI == 3) v += add1[idx];
        if (EPI == 3) v += b2f(add2[idx]);
        if (OBF) ((short*)C)[idx] = f2b(v);
        else ((float*)C)[idx] = v;
      }
    }
  }
}

// ---------------- Sliding-window attention, MFMA flash-style ----------------
__global__ __launch_bounds__(256) void swa_kernel(
    const float* __restrict__ qkv, short* __restrict__ out)
{
  __shared__ __align__(16) short ks[128 * 72];
  __shared__ __align__(16) short vt[64 * 136];
  __shared__ __align__(16) short ps[4][16 * 136];
  __shared__ float lsum[64];

  const int tid = threadIdx.x;
  const int w = tid >> 6, l = tid & 63;
  const int tile = blockIdx.x & 31;
  const int h = (blockIdx.x >> 5) & 7;
  const int b = blockIdx.x >> 8;
  const int s0 = tile * 64;
  const size_t base = (size_t)b * SS;

#pragma unroll
  for (int u = 0; u < 16; ++u) {
    const int id = u * 256 + tid;
    const int row = id >> 5, dp = id & 31;
    int jp = s0 - 32 + row;
    jp = min(max(jp, 0), SS - 1);
    const size_t g = (base + jp) * 1536 + h * 64 + dp * 2;
    const float2 kv = *(const float2*)&qkv[g + 512];
    const float2 vv = *(const float2*)&qkv[g + 1024];
    unsigned pk = ((unsigned)(unsigned short)f2b(kv.y) << 16) | (unsigned short)f2b(kv.x);
    *(unsigned*)&ks[row * 72 + dp * 2] = pk;
    vt[(dp * 2) * 136 + row] = f2b(vv.x);
    vt[(dp * 2 + 1) * 136 + row] = f2b(vv.y);
  }

  const int qi = w * 16 + (l & 15);
  short8 qf[2];
#pragma unroll
  for (int kf = 0; kf < 2; ++kf) {
    const float* qp = &qkv[(base + s0 + qi) * 1536 + h * 64 + kf * 32 + (l >> 4) * 8];
    const float4 a = *(const float4*)qp;
    const float4 c = *(const float4*)(qp + 4);
    short8 q8;
    q8[0] = f2b(a.x); q8[1] = f2b(a.y); q8[2] = f2b(a.z); q8[3] = f2b(a.w);
    q8[4] = f2b(c.x); q8[5] = f2b(c.y); q8[6] = f2b(c.z); q8[7] = f2b(c.w);
    qf[kf] = q8;
  }
  __syncthreads();

  f32x4 sa[8] = {};
#pragma unroll
  for (int mf = 0; mf < 8; ++mf)
#pragma unroll
    for (int kf = 0; kf < 2; ++kf) {
      const short8 af = *(const short8*)&ks[(mf * 16 + (l & 15)) * 72 + kf * 32 + (l >> 4) * 8];
      sa[mf] = __builtin_amdgcn_mfma_f32_16x16x32_bf16(af, qf[kf], sa[mf], 0, 0, 0);
    }

  float sv[8][4];
  float mx = -INFINITY;
#pragma unroll
  for (int mf = 0; mf < 8; ++mf)
#pragma unroll
    for (int r = 0; r < 4; ++r) {
      const int j = mf * 16 + (l >> 4) * 4 + r;
      const int jpos = s0 - 32 + j;
      const bool ok = (j >= qi) && (j <= qi + 64) && (jpos >= 0) && (jpos < SS);
      const float s = ok ? sa[mf][r] * 0.125f : -INFINITY;
      sv[mf][r] = s;
      mx = fmaxf(mx, s);
    }
  mx = fmaxf(mx, __shfl_xor(mx, 16));
  mx = fmaxf(mx, __shfl_xor(mx, 32));
  float ls = 0.f;
#pragma unroll
  for (int mf = 0; mf < 8; ++mf)
#pragma unroll
    for (int r = 0; r < 4; ++r) {
      const float p = __expf(sv[mf][r] - mx);
      sv[mf][r] = p;
      ls += p;
    }
  ls += __shfl_xor(ls, 16);
  ls += __shfl_xor(ls, 32);
  if (l < 16) lsum[w * 16 + l] = ls;

#pragma unroll
  for (int mf = 0; mf < 8; ++mf) {
    short4v p4;
    p4.x = f2b(sv[mf][0]); p4.y = f2b(sv[mf][1]);
    p4.z = f2b(sv[mf][2]); p4.w = f2b(sv[mf][3]);
    *(short4v*)&ps[w][(l & 15) * 136 + mf * 16 + (l >> 4) * 4] = p4;
  }

  f32x4 oa[4] = {};
#pragma unroll
  for (int kf = 0; kf < 4; ++kf) {
    const short8 pf = *(const short8*)&ps[w][(l & 15) * 136 + kf * 32 + (l >> 4) * 8];
#pragma unroll
    for (int nf = 0; nf < 4; ++nf) {
      const short8 vf = *(const short8*)&vt[(nf * 16 + (l & 15)) * 136 + kf * 32 + (l >> 4) * 8];
      oa[nf] = __builtin_amdgcn_mfma_f32_16x16x32_bf16(pf, vf, oa[nf], 0, 0, 0);
    }
  }

  float rl[4];
#pragma unroll
  for (int r = 0; r < 4; ++r) rl[r] = 1.f / lsum[w * 16 + (l >> 4) * 4 + r];
#pragma unroll
  for (int nf = 0; nf < 4; ++nf)
#pragma unroll
    for (int r = 0; r < 4; ++r) {
      const int q = (l >> 4) * 4 + r;
      const int d = nf * 16 + (l & 15);
      out[(base + s0 + w * 16 + q) * 512 + h * 64 + d] = f2b(oa[nf][r] * rl[r]);
    }
}

// ---------------- Neural memory scan: 1 column per block, 1024 blocks -------
__global__ __launch_bounds__(256) void mem_scan_kernel(
    const float* __restrict__ qb, const float* __restrict__ kb,
    const float* __restrict__ vb, short* __restrict__ mem, int st)
{
  const int chain = blockIdx.x >> 7;    // 0..7 = (b, mh)
  const int col   = blockIdx.x & 127;   // column within head matrix
  const int b = chain >> 2;
  const int mh = chain & 3;
  const int ecol = mh * 128 + col;

  __shared__ float Ml[128];
  __shared__ float Mom[128];
  __shared__ float stg[64][132];
  __shared__ float pvl[64];

  const int tid = threadIdx.x;
  if (tid < 128) { Ml[tid] = 0.f; Mom[tid] = 0.f; }
  __syncthreads();

  const int q4 = tid & 3;
  const int r_o = tid >> 2;     // 0..63 (row owner, 4 threads per row)
  const int d_g = tid >> 1;     // 0..127 (grad dim owner, 2 threads per dim)
  const int half = tid & 1;

  for (int c = 0; c < NCC; ++c) {
    const size_t rowbase = (size_t)(b * SS + c * CHH);
    // stage q (f32)
#pragma unroll
    for (int j = 0; j < 8; ++j) {
      const int i4 = tid + 256 * j;
      const int r = i4 >> 5, d4 = (i4 & 31) * 4;
      const float4 v = *reinterpret_cast<const float4*>(&qb[(rowbase + r) * st + mh * 128 + d4]);
      *reinterpret_cast<float4*>(&stg[r][d4]) = v;
    }
    __syncthreads();
    // out = q @ M[:,col]
    {
      float o = 0.f;
#pragma unroll
      for (int i = 0; i < 32; ++i) o += stg[r_o][q4 + 4 * i] * Ml[q4 + 4 * i];
      o += __shfl_xor(o, 1);
      o += __shfl_xor(o, 2);
      if (q4 == 0) mem[(rowbase + r_o) * 512 + ecol] = f2b(o);
    }
    __syncthreads();
    // stage k
#pragma unroll
    for (int j = 0; j < 8; ++j) {
      const int i4 = tid + 256 * j;
      const int r = i4 >> 5, d4 = (i4 & 31) * 4;
      const float4 v = *reinterpret_cast<const float4*>(&kb[(rowbase + r) * st + mh * 128 + d4]);
      *reinterpret_cast<float4*>(&stg[r][d4]) = v;
    }
    __syncthreads();
    // pv = k @ M[:,col] - v
    {
      float o = 0.f;
#pragma unroll
      for (int i = 0; i < 32; ++i) o += stg[r_o][q4 + 4 * i] * Ml[q4 + 4 * i];
      o += __shfl_xor(o, 1);
      o += __shfl_xor(o, 2);
      if (q4 == 0) pvl[r_o] = o - vb[(rowbase + r_o) * st + ecol];
    }
    __syncthreads();
    // grad[d] = sum_r k[r][d]*pv[r] / 64 ; Mom/M update
    {
      float g = 0.f;
#pragma unroll
      for (int rr = 0; rr < 32; ++rr) {
        const int r = half * 32 + rr;
        g += stg[r][d_g] * pvl[r];
      }
      g += __shfl_xor(g, 1);
      if (half == 0) {
        const float gg = g * (1.f / 64.f);
        const float mom = 0.9f * Mom[d_g] - 0.1f * gg;
        Mom[d_g] = mom;
        Ml[d_g] = 0.99f * Ml[d_g] + mom;
      }
    }
    __syncthreads();
  }
}

// ---------------- transpose + f32->bf16 convert: src[K,N] -> dst[N,K] -------
__global__ __launch_bounds__(256) void tcvt_kernel(
    const float* __restrict__ src, short* __restrict__ dst, int K, int N)
{
  __shared__ float t[32][33];
  const int k0 = blockIdx.y * 32, n0 = blockIdx.x * 32;
  const size_t zoff = (size_t)blockIdx.z * K * N;
  src += zoff; dst += zoff;
  const int tx = threadIdx.x & 31, ty = threadIdx.x >> 5;
#pragma unroll
  for (int i = 0; i < 4; ++i)
    t[ty + i * 8][tx] = src[(size_t)(k0 + ty + i * 8) * N + n0 + tx];
  __syncthreads();
#pragma unroll
  for (int i = 0; i < 4; ++i)
    dst[(size_t)(n0 + ty + i * 8) * K + k0 + tx] = f2b(t[tx][ty + i * 8]);
}

// ---------------- f32 -> bf16 convert ----------------
__global__ __launch_bounds__(256) void cvt_kernel(
    const float* __restrict__ in, short* __restrict__ out, int n4)
{
  const int i = blockIdx.x * 256 + threadIdx.x;
  if (i >= n4) return;
  const float4 v = reinterpret_cast<const float4*>(in)[i];
  short4v o;
  o.x = f2b(v.x); o.y = f2b(v.y); o.z = f2b(v.z); o.w = f2b(v.w);
  reinterpret_cast<short4v*>(out)[i] = o;
}

// ---------------- small vec helpers ----------------
__global__ __launch_bounds__(256) void mean_tokens_kernel(
    const float* __restrict__ pm, float* __restrict__ mvec)
{
  const int d = blockIdx.x * 256 + threadIdx.x;
  if (d < 512) {
    float s = 0.f;
    for (int t = 0; t < 16; ++t) s += pm[t * 512 + d];
    mvec[d] = s * (1.f / 16.f);
  }
}

__global__ __launch_bounds__(256) void matvec512_kernel(
    const float* __restrict__ a, const float* __restrict__ W,
    const float* __restrict__ bias, float* __restrict__ out)
{
  const int e = blockIdx.x * 256 + threadIdx.x;
  float s = bias ? bias[e] : 0.f;
  for (int d = 0; d < 512; ++d) s += a[d] * W[d * 512 + e];
  out[e] = s;
}

// ---------------- host side ----------------
extern "C" void kernel_launch(void* const* d_in, const int* in_sizes, int n_in,
                              void* d_out, int out_size, void* d_ws, size_t ws_size,
                              hipStream_t stream)
{
  const float* x         = (const float*)d_in[0];
  const float* n1w       = (const float*)d_in[1];
  const float* n1b       = (const float*)d_in[2];
  const float* qkvw      = (const float*)d_in[3];
  const float* qkvb      = (const float*)d_in[4];
  const float* projw     = (const float*)d_in[5];
  const float* projb     = (const float*)d_in[6];
  const float* n2w       = (const float*)d_in[7];
  const float* n2b       = (const float*)d_in[8];
  const float* fc1w      = (const float*)d_in[9];
  const float* fc1b      = (const float*)d_in[10];
  const float* fc2w      = (const float*)d_in[11];
  const float* fc2b      = (const float*)d_in[12];
  const float* mlnw      = (const float*)d_in[13];
  const float* mlnb      = (const float*)d_in[14];
  const float* mwq       = (const float*)d_in[15];
  const float* mwk       = (const float*)d_in[16];
  const float* mwv       = (const float*)d_in[17];
  const float* mprojw    = (const float*)d_in[18];
  const float* mprojb    = (const float*)d_in[19];
  const float* pm_tokens = (const float*)d_in[20];
  const float* pmw       = (const float*)d_in[21];
  const float* pmb       = (const float*)d_in[22];
  const float* fw        = (const float*)d_in[23];
  const float* fb        = (const float*)d_in[24];
  float* out = (float*)d_out;

  char* p = (char*)d_ws;
  auto alloc = [&](size_t bytes) {
    char* r = p;
    p += (bytes + 255) & ~(size_t)255;
    return r;
  };
  short* qkvwT  = (short*)alloc(6ull * 1536 * 512 * 2);
  short* projwT = (short*)alloc(6ull * 512 * 512 * 2);
  short* fc1wT  = (short*)alloc(6ull * 2048 * 512 * 2);
  short* fc2wT  = (short*)alloc(6ull * 512 * 2048 * 2);
  short* mqkvT  = (short*)alloc(3ull * 512 * 512 * 2);
  short* mprojT = (short*)alloc(512ull * 512 * 2);
  short* fw0T   = (short*)alloc(512ull * 512 * 2);
  short* fw1T   = (short*)alloc(512ull * 512 * 2);
  float* bigf = (float*)alloc((size_t)BS * 1536 * 4);
  float* hbuf = (float*)alloc((size_t)BS * 512 * 4);
  float* t0   = (float*)alloc(3 * 512 * 4);
  float* t1 = t0 + 512; float* t2 = t1 + 512;
  short* actA  = (short*)alloc((size_t)BS * 512 * 2);
  short* attnb = (short*)alloc((size_t)BS * 512 * 2);
  short* ff1b  = (short*)alloc((size_t)BS * 2048 * 2);
  short* ltb   = (short*)alloc((size_t)BS * 512 * 2);

  tcvt_kernel<<<dim3(1536 / 32, 512 / 32, 6), 256, 0, stream>>>(qkvw, qkvwT, 512, 1536);
  tcvt_kernel<<<dim3(512 / 32, 512 / 32, 6), 256, 0, stream>>>(projw, projwT, 512, 512);
  tcvt_kernel<<<dim3(2048 / 32, 512 / 32, 6), 256, 0, stream>>>(fc1w, fc1wT, 512, 2048);
  tcvt_kernel<<<dim3(512 / 32, 2048 / 32, 6), 256, 0, stream>>>(fc2w, fc2wT, 2048, 512);
  tcvt_kernel<<<dim3(16, 16, 1), 256, 0, stream>>>(mwq, mqkvT, 512, 512);
  tcvt_kernel<<<dim3(16, 16, 1), 256, 0, stream>>>(mwk, mqkvT + 512 * 512, 512, 512);
  tcvt_kernel<<<dim3(16, 16, 1), 256, 0, stream>>>(mwv, mqkvT + 2 * 512 * 512, 512, 512);
  tcvt_kernel<<<dim3(16, 16, 1), 256, 0, stream>>>(mprojw, mprojT, 512, 512);
  tcvt_kernel<<<dim3(16, 16, 1), 256, 0, stream>>>(fw, fw0T, 512, 512);
  tcvt_kernel<<<dim3(16, 16, 1), 256, 0, stream>>>(fw + 512 * 512, fw1T, 512, 512);

  mean_tokens_kernel<<<2, 256, 0, stream>>>(pm_tokens, t0);
  matvec512_kernel<<<2, 256, 0, stream>>>(t0, pmw, pmb, t1);
  matvec512_kernel<<<2, 256, 0, stream>>>(t1, fw + (size_t)1024 * 512, fb, t2);

  ln_kernel<<<BS, 256, 0, stream>>>(x, mlnw, mlnb, actA);
  gemm_bf16<0, 0, 128><<<dim3(12, 32), 256, 0, stream>>>(
      actA, mqkvT, nullptr, nullptr, nullptr, bigf, BS, 1536, 512);
  mem_scan_kernel<<<1024, 256, 0, stream>>>(bigf, bigf + 512, bigf + 1024, ff1b, 1536);
  gemm_bf16<2, 1, 64><<<dim3(4, 64), 256, 0, stream>>>(
      ff1b, mprojT, mprojb, x, nullptr, ltb, BS, 512, 512);

  hipMemcpyAsync(hbuf, x, (size_t)BS * 512 * 4, hipMemcpyDeviceToDevice, stream);
  for (int l = 0; l < LL; ++l) {
    ln_kernel<<<BS, 256, 0, stream>>>(hbuf, n1w + l * 512, n1b + l * 512, actA);
    gemm_bf16<0, 0, 128><<<dim3(12, 32), 256, 0, stream>>>(
        actA, qkvwT + (size_t)l * 1536 * 512, qkvb + l * 1536,
        nullptr, nullptr, bigf, BS, 1536, 512);
    swa_kernel<<<512, 256, 0, stream>>>(bigf, attnb);
    gemm_bf16<2, 0, 64><<<dim3(4, 64), 256, 0, stream>>>(
        attnb, projwT + (size_t)l * 512 * 512, projb + l * 512,
        hbuf, nullptr, hbuf, BS, 512, 512);
    ln_kernel<<<BS, 256, 0, stream>>>(hbuf, n2w + l * 512, n2b + l * 512, actA);
    gemm_bf16<1, 1, 128><<<dim3(16, 32), 256, 0, stream>>>(
        actA, fc1wT + (size_t)l * 2048 * 512, fc1b + l * 2048,
        nullptr, nullptr, ff1b, BS, 2048, 512);
    gemm_bf16<3, 0, 64><<<dim3(4, 64), 256, 0, stream>>>(
        ff1b, fc2wT + (size_t)l * 512 * 2048, fc2b + l * 512,
        hbuf, actA, hbuf, BS, 512, 2048);
  }

  cvt_kernel<<<(BS * 512 / 4 + 255) / 256, 256, 0, stream>>>(hbuf, actA, BS * 512 / 4);
  gemm_bf16<0, 0, 64><<<dim3(4, 64), 256, 0, stream>>>(
      actA, fw0T, t2, nullptr, nullptr, out, BS, 512, 512);
  gemm_bf16<2, 0, 64><<<dim3(4, 64), 256, 0, stream>>>(
      ltb, fw1T, nullptr, out, nullptr, out, BS, 512, 512);
}

// Round 5
// 980.024 us; speedup vs baseline: 3.9311x; 1.0941x over previous
//
#include <hip/hip_runtime.h>
#include <math.h>

// Problem constants
#define BB 2
#define SS 2048
#define DD 512
#define HH 8
#define LL 6
#define WW 64
#define CHH 64
#define NCC 32
#define BS (BB*SS)   // 4096 rows

typedef __attribute__((ext_vector_type(8))) short short8;
typedef __attribute__((ext_vector_type(4))) short short4v;
typedef __attribute__((ext_vector_type(4))) float f32x4;

__device__ inline float b2f(short s) {
  unsigned u = ((unsigned)(unsigned short)s) << 16;
  float f; __builtin_memcpy(&f, &u, 4); return f;
}
__device__ inline short f2b(float f) {
  unsigned u; __builtin_memcpy(&u, &f, 4);
  unsigned r = (u + 0x7FFFu + ((u >> 16) & 1u)) >> 16;
  return (short)r;
}
__device__ inline float gelu_tanh(float v) {
  float u = 0.7978845608f * (v + 0.044715f * v * v * v);
  u = fminf(fmaxf(u, -20.f), 20.f);
  float e2 = __expf(2.f * u);
  return 0.5f * v * (1.f + (e2 - 1.f) / (e2 + 1.f));
}

#define AS1(p) ((const __attribute__((address_space(1))) void*)(p))
#define AS3(p) ((__attribute__((address_space(3))) void*)(p))

// ---------------- LayerNorm: fp32 in -> bf16 out ----------------
__global__ __launch_bounds__(256) void ln_kernel(
    const float* __restrict__ x, const float* __restrict__ w,
    const float* __restrict__ b, short* __restrict__ y)
{
  const int row = blockIdx.x;
  const int tid = threadIdx.x;
  const float2 v = reinterpret_cast<const float2*>(x + (size_t)row * DD)[tid];
  float s = v.x + v.y;
  float sq = v.x * v.x + v.y * v.y;
#pragma unroll
  for (int off = 32; off; off >>= 1) {
    s += __shfl_xor(s, off);
    sq += __shfl_xor(sq, off);
  }
  __shared__ float ss[4], ssq[4];
  if ((tid & 63) == 0) { ss[tid >> 6] = s; ssq[tid >> 6] = sq; }
  __syncthreads();
  s = ss[0] + ss[1] + ss[2] + ss[3];
  sq = ssq[0] + ssq[1] + ssq[2] + ssq[3];
  const float mean = s * (1.f / DD);
  const float var = sq * (1.f / DD) - mean * mean;
  const float inv = rsqrtf(var + 1e-5f);
  const float2 wv = reinterpret_cast<const float2*>(w)[tid];
  const float2 bv = reinterpret_cast<const float2*>(b)[tid];
  const float ox = (v.x - mean) * inv * wv.x + bv.x;
  const float oy = (v.y - mean) * inv * wv.y + bv.y;
  unsigned pk = ((unsigned)(unsigned short)f2b(oy) << 16) | (unsigned short)f2b(ox);
  reinterpret_cast<unsigned*>(y + (size_t)row * DD)[tid] = pk;
}

// ---------------- bf16 MFMA GEMM (BM=128 or 64, BN=128) ----------------
template<int EPI, int OBF, int BM>
__global__ __launch_bounds__(256) void gemm_bf16(
    const short* __restrict__ A, const short* __restrict__ BT,
    const float* __restrict__ bias, const float* __restrict__ add1,
    const short* __restrict__ add2, void* __restrict__ C,
    int M, int N, int K)
{
  constexpr int MF = BM / 32;
  constexpr int CA = BM / 64;
  __shared__ __align__(16) short As[BM * 32];
  __shared__ __align__(16) short Bs[128 * 32];
  const int tid = threadIdx.x;
  const int wave = tid >> 6, lane = tid & 63;
  const int wr = wave >> 1, wc = wave & 1;
  const int bm = blockIdx.y * BM, bn = blockIdx.x * 128;

  const int l4r = lane >> 2;
  const int l4c = (lane & 3) * 8;

  const short* sA[CA]; const short* sB[2];
  int ldsA[CA], ldsB[2];
#pragma unroll
  for (int r = 0; r < CA; ++r) {
    const int chunk = r * 4 + wave;
    sA[r] = A + (size_t)(bm + chunk * 16 + l4r) * K + l4c;
    ldsA[r] = chunk * 1024;
  }
#pragma unroll
  for (int r = 0; r < 2; ++r) {
    const int chunk = r * 4 + wave;
    sB[r] = BT + (size_t)(bn + chunk * 16 + l4r) * K + l4c;
    ldsB[r] = chunk * 1024;
  }

  f32x4 acc[MF][4] = {};

  for (int k0 = 0; k0 < K; k0 += 32) {
#pragma unroll
    for (int r = 0; r < CA; ++r) {
      __builtin_amdgcn_global_load_lds(AS1(sA[r]), AS3((char*)As + ldsA[r]), 16, 0, 0);
      sA[r] += 32;
    }
#pragma unroll
    for (int r = 0; r < 2; ++r) {
      __builtin_amdgcn_global_load_lds(AS1(sB[r]), AS3((char*)Bs + ldsB[r]), 16, 0, 0);
      sB[r] += 32;
    }
    __syncthreads();
    short8 af[MF], bf[4];
#pragma unroll
    for (int m = 0; m < MF; ++m)
      af[m] = *(const short8*)&As[(wr * (BM / 2) + m * 16 + (lane & 15)) * 32 + (lane >> 4) * 8];
#pragma unroll
    for (int n = 0; n < 4; ++n)
      bf[n] = *(const short8*)&Bs[(wc * 64 + n * 16 + (lane & 15)) * 32 + (lane >> 4) * 8];
#pragma unroll
    for (int m = 0; m < MF; ++m)
#pragma unroll
      for (int n = 0; n < 4; ++n)
        acc[m][n] = __builtin_amdgcn_mfma_f32_16x16x32_bf16(af[m], bf[n], acc[m][n], 0, 0, 0);
    __syncthreads();
  }

#pragma unroll
  for (int m = 0; m < MF; ++m) {
#pragma unroll
    for (int n = 0; n < 4; ++n) {
      const int col = bn + wc * 64 + n * 16 + (lane & 15);
      const float bb = (EPI == 1 || EPI == 3) ? bias[col] : (bias ? bias[col] : 0.f);
#pragma unroll
      for (int r = 0; r < 4; ++r) {
        const int row = bm + wr * (BM / 2) + m * 16 + (lane >> 4) * 4 + r;
        const size_t idx = (size_t)row * N + col;
        float v = acc[m][n][r] + bb;
        if (EPI == 1) v = gelu_tanh(v);
        if (EPI == 2 || EPI == 3) v += add1[idx];
        if (EPI == 3) v += b2f(add2[idx]);
        if (OBF) ((short*)C)[idx] = f2b(v);
        else ((float*)C)[idx] = v;
      }
    }
  }
}

// ---------------- Sliding-window attention, MFMA flash-style ----------------
__global__ __launch_bounds__(256) void swa_kernel(
    const float* __restrict__ qkv, short* __restrict__ out)
{
  __shared__ __align__(16) short ks[128 * 72];
  __shared__ __align__(16) short vt[64 * 136];
  __shared__ __align__(16) short ps[4][16 * 136];
  __shared__ float lsum[64];

  const int tid = threadIdx.x;
  const int w = tid >> 6, l = tid & 63;
  const int tile = blockIdx.x & 31;
  const int h = (blockIdx.x >> 5) & 7;
  const int b = blockIdx.x >> 8;
  const int s0 = tile * 64;
  const size_t base = (size_t)b * SS;

#pragma unroll
  for (int u = 0; u < 16; ++u) {
    const int id = u * 256 + tid;
    const int row = id >> 5, dp = id & 31;
    int jp = s0 - 32 + row;
    jp = min(max(jp, 0), SS - 1);
    const size_t g = (base + jp) * 1536 + h * 64 + dp * 2;
    const float2 kv = *(const float2*)&qkv[g + 512];
    const float2 vv = *(const float2*)&qkv[g + 1024];
    unsigned pk = ((unsigned)(unsigned short)f2b(kv.y) << 16) | (unsigned short)f2b(kv.x);
    *(unsigned*)&ks[row * 72 + dp * 2] = pk;
    vt[(dp * 2) * 136 + row] = f2b(vv.x);
    vt[(dp * 2 + 1) * 136 + row] = f2b(vv.y);
  }

  const int qi = w * 16 + (l & 15);
  short8 qf[2];
#pragma unroll
  for (int kf = 0; kf < 2; ++kf) {
    const float* qp = &qkv[(base + s0 + qi) * 1536 + h * 64 + kf * 32 + (l >> 4) * 8];
    const float4 a = *(const float4*)qp;
    const float4 c = *(const float4*)(qp + 4);
    short8 q8;
    q8[0] = f2b(a.x); q8[1] = f2b(a.y); q8[2] = f2b(a.z); q8[3] = f2b(a.w);
    q8[4] = f2b(c.x); q8[5] = f2b(c.y); q8[6] = f2b(c.z); q8[7] = f2b(c.w);
    qf[kf] = q8;
  }
  __syncthreads();

  f32x4 sa[8] = {};
#pragma unroll
  for (int mf = 0; mf < 8; ++mf)
#pragma unroll
    for (int kf = 0; kf < 2; ++kf) {
      const short8 af = *(const short8*)&ks[(mf * 16 + (l & 15)) * 72 + kf * 32 + (l >> 4) * 8];
      sa[mf] = __builtin_amdgcn_mfma_f32_16x16x32_bf16(af, qf[kf], sa[mf], 0, 0, 0);
    }

  float sv[8][4];
  float mx = -INFINITY;
#pragma unroll
  for (int mf = 0; mf < 8; ++mf)
#pragma unroll
    for (int r = 0; r < 4; ++r) {
      const int j = mf * 16 + (l >> 4) * 4 + r;
      const int jpos = s0 - 32 + j;
      const bool ok = (j >= qi) && (j <= qi + 64) && (jpos >= 0) && (jpos < SS);
      const float s = ok ? sa[mf][r] * 0.125f : -INFINITY;
      sv[mf][r] = s;
      mx = fmaxf(mx, s);
    }
  mx = fmaxf(mx, __shfl_xor(mx, 16));
  mx = fmaxf(mx, __shfl_xor(mx, 32));
  float ls = 0.f;
#pragma unroll
  for (int mf = 0; mf < 8; ++mf)
#pragma unroll
    for (int r = 0; r < 4; ++r) {
      const float p = __expf(sv[mf][r] - mx);
      sv[mf][r] = p;
      ls += p;
    }
  ls += __shfl_xor(ls, 16);
  ls += __shfl_xor(ls, 32);
  if (l < 16) lsum[w * 16 + l] = ls;

#pragma unroll
  for (int mf = 0; mf < 8; ++mf) {
    short4v p4;
    p4.x = f2b(sv[mf][0]); p4.y = f2b(sv[mf][1]);
    p4.z = f2b(sv[mf][2]); p4.w = f2b(sv[mf][3]);
    *(short4v*)&ps[w][(l & 15) * 136 + mf * 16 + (l >> 4) * 4] = p4;
  }

  f32x4 oa[4] = {};
#pragma unroll
  for (int kf = 0; kf < 4; ++kf) {
    const short8 pf = *(const short8*)&ps[w][(l & 15) * 136 + kf * 32 + (l >> 4) * 8];
#pragma unroll
    for (int nf = 0; nf < 4; ++nf) {
      const short8 vf = *(const short8*)&vt[(nf * 16 + (l & 15)) * 136 + kf * 32 + (l >> 4) * 8];
      oa[nf] = __builtin_amdgcn_mfma_f32_16x16x32_bf16(pf, vf, oa[nf], 0, 0, 0);
    }
  }

  float rl[4];
#pragma unroll
  for (int r = 0; r < 4; ++r) rl[r] = 1.f / lsum[w * 16 + (l >> 4) * 4 + r];
#pragma unroll
  for (int nf = 0; nf < 4; ++nf)
#pragma unroll
    for (int r = 0; r < 4; ++r) {
      const int q = (l >> 4) * 4 + r;
      const int d = nf * 16 + (l & 15);
      out[(base + s0 + w * 16 + q) * 512 + h * 64 + d] = f2b(oa[nf][r] * rl[r]);
    }
}

// ========== Neural memory, linear-scan formulation ==========
// grad_c = A_c M_{c-1} - B_c,  A_c = k^T k/64 (bf16), B_c = k^T v/64 (bf16)

// ---- P1: per (chain, chunk) compute A_c, B_c via MFMA ----
__global__ __launch_bounds__(256) void mem_prep(
    const float* __restrict__ kb, const float* __restrict__ vb,
    short* __restrict__ Aq, short* __restrict__ Bq)
{
  __shared__ __align__(16) short kn[64 * 136];   // natural staging
  __shared__ __align__(16) char kT[128 * 128];   // bf16 [d][r], XOR swizzled
  __shared__ __align__(16) char vT[128 * 128];
  const int bid = blockIdx.x;
  const int chain = bid >> 5, c = bid & 31;
  const int b = chain >> 2, mh = chain & 3;
  const size_t rowbase = (size_t)(b * SS + c * 64);
  const int tid = threadIdx.x, w = tid >> 6, l = tid & 63;
  const int td = tid & 127, rh = tid >> 7;

#pragma unroll
  for (int pass = 0; pass < 2; ++pass) {
    const float* src = pass ? vb : kb;
    char* dT = pass ? vT : kT;
#pragma unroll
    for (int j = 0; j < 8; ++j) {
      const int i4 = tid + 256 * j;
      const int r = i4 >> 5, d4 = (i4 & 31) * 4;
      const float4 vv = *(const float4*)&src[(rowbase + r) * 1536 + mh * 128 + d4];
      short4v s4;
      s4.x = f2b(vv.x); s4.y = f2b(vv.y); s4.z = f2b(vv.z); s4.w = f2b(vv.w);
      *(short4v*)&kn[r * 136 + d4] = s4;
    }
    __syncthreads();
#pragma unroll
    for (int j = 0; j < 4; ++j) {
      const int r0 = rh * 8 + 16 * j;
      short8 g8;
#pragma unroll
      for (int t = 0; t < 8; ++t) g8[t] = kn[(r0 + t) * 136 + td];
      *(short8*)&dT[(td * 128 + r0 * 2) ^ ((td & 7) << 4)] = g8;
    }
    __syncthreads();
  }

  const int wr = w >> 1, wc = w & 1;
  // A = kT @ kT(BT) / 64
  {
    f32x4 acc[4][4] = {};
#pragma unroll
    for (int kf = 0; kf < 2; ++kf) {
      short8 af[4];
#pragma unroll
      for (int m = 0; m < 4; ++m) {
        const int d = wr * 64 + m * 16 + (l & 15);
        af[m] = *(const short8*)&kT[(d * 128 + kf * 64 + (l >> 4) * 16) ^ ((d & 7) << 4)];
      }
#pragma unroll
      for (int n = 0; n < 4; ++n) {
        const int dp = wc * 64 + n * 16 + (l & 15);
        const short8 bf = *(const short8*)&kT[(dp * 128 + kf * 64 + (l >> 4) * 16) ^ ((dp & 7) << 4)];
#pragma unroll
        for (int m = 0; m < 4; ++m)
          acc[m][n] = __builtin_amdgcn_mfma_f32_16x16x32_bf16(af[m], bf, acc[m][n], 0, 0, 0);
      }
    }
    short* Ad = Aq + (size_t)bid * 16384;
#pragma unroll
    for (int m = 0; m < 4; ++m)
#pragma unroll
      for (int n = 0; n < 4; ++n)
#pragma unroll
        for (int i = 0; i < 4; ++i) {
          const int d = wr * 64 + m * 16 + (l >> 4) * 4 + i;
          const int dp = wc * 64 + n * 16 + (l & 15);
          Ad[d * 128 + dp] = f2b(acc[m][n][i] * 0.015625f);
        }
  }
  // B = kT @ vT(BT) / 64
  {
    f32x4 acc[4][4] = {};
#pragma unroll
    for (int kf = 0; kf < 2; ++kf) {
      short8 af[4];
#pragma unroll
      for (int m = 0; m < 4; ++m) {
        const int d = wr * 64 + m * 16 + (l & 15);
        af[m] = *(const short8*)&kT[(d * 128 + kf * 64 + (l >> 4) * 16) ^ ((d & 7) << 4)];
      }
#pragma unroll
      for (int n = 0; n < 4; ++n) {
        const int e = wc * 64 + n * 16 + (l & 15);
        const short8 bf = *(const short8*)&vT[(e * 128 + kf * 64 + (l >> 4) * 16) ^ ((e & 7) << 4)];
#pragma unroll
        for (int m = 0; m < 4; ++m)
          acc[m][n] = __builtin_amdgcn_mfma_f32_16x16x32_bf16(af[m], bf, acc[m][n], 0, 0, 0);
      }
    }
    short* Bd = Bq + (size_t)bid * 16384;
#pragma unroll
    for (int m = 0; m < 4; ++m)
#pragma unroll
      for (int n = 0; n < 4; ++n)
#pragma unroll
        for (int i = 0; i < 4; ++i) {
          const int d = wr * 64 + m * 16 + (l >> 4) * 4 + i;
          const int e = wc * 64 + n * 16 + (l & 15);
          Bd[d * 128 + e] = f2b(acc[m][n][i] * 0.015625f);
        }
  }
}

// ---- P2: serial scan. 32 blocks = 8 chains x 4 column-quarters (32 cols) ----
// M, Mom in registers; M^T bf16 (XOR swizzled) in LDS for MFMA B-operand.
// Snapshots M^T_{c-1} -> MTg[chain][c].
__global__ __launch_bounds__(256) void mem_scan2(
    const short* __restrict__ Aq, const short* __restrict__ Bq,
    short* __restrict__ MTg)
{
  __shared__ __align__(16) char MT[32 * 256];
  const int bid = blockIdx.x;
  const int chain = bid >> 2, ch = bid & 3;
  const int tid = threadIdx.x;
  const int w = tid >> 6, l = tid & 63;
  const int wr = w >> 1, wc = w & 1;

  for (int i = tid; i < 32 * 256 / 16; i += 256)
    *(short8*)&MT[i * 16] = short8{0, 0, 0, 0, 0, 0, 0, 0};
  float Mreg[16] = {}, Momreg[16] = {};
  __syncthreads();

  const short* Ab = Aq + (size_t)chain * 32 * 16384;
  const short* Bb = Bq + (size_t)chain * 32 * 16384;
  short* MTb = MTg + (size_t)chain * 32 * 16384 + (size_t)ch * 32 * 128;
  const int se = tid & 31, sdb = tid >> 5;

  for (int c = 0; c < NCC; ++c) {
    // snapshot M_{c-1}^T (this block's 32 e-rows) to global, un-swizzled
#pragma unroll
    for (int j = 0; j < 2; ++j) {
      const int db = sdb + 8 * j;
      const short8 vv = *(const short8*)&MT[(se * 256 + db * 16) ^ ((se & 7) << 4)];
      *(short8*)&MTb[(size_t)c * 16384 + se * 128 + db * 8] = vv;
    }
    // G = A_c @ M  (output 128 x 32)
    const short* Ac = Ab + (size_t)c * 16384;
    f32x4 acc[4] = {};
#pragma unroll
    for (int kf = 0; kf < 4; ++kf) {
      const int e = wc * 16 + (l & 15);
      const short8 bf = *(const short8*)&MT[(e * 256 + kf * 64 + (l >> 4) * 16) ^ ((e & 7) << 4)];
#pragma unroll
      for (int m = 0; m < 4; ++m) {
        const int d = wr * 64 + m * 16 + (l & 15);
        const short8 af = *(const short8*)&Ac[d * 128 + kf * 32 + (l >> 4) * 8];
        acc[m] = __builtin_amdgcn_mfma_f32_16x16x32_bf16(af, bf, acc[m], 0, 0, 0);
      }
    }
    __syncthreads();   // all MT reads (frags + snapshot) complete
    // update M, Mom (registers) + rewrite MT
    const short* Bc = Bb + (size_t)c * 16384;
    const int e = wc * 16 + (l & 15);
#pragma unroll
    for (int m = 0; m < 4; ++m)
#pragma unroll
      for (int i = 0; i < 4; ++i) {
        const int d = wr * 64 + m * 16 + (l >> 4) * 4 + i;
        const int idx = m * 4 + i;
        const float g = acc[m][i] - b2f(Bc[d * 128 + ch * 32 + e]);
        Momreg[idx] = 0.9f * Momreg[idx] - 0.1f * g;
        Mreg[idx] = 0.99f * Mreg[idx] + Momreg[idx];
        *(short*)&MT[(e * 256 + d * 2) ^ ((e & 7) << 4)] = f2b(Mreg[idx]);
      }
    __syncthreads();
  }
}

// ---- P3: out_c = q_c @ M_{c-1}, batched over 256 (chain, chunk) blocks ----
__global__ __launch_bounds__(256) void mem_out(
    const float* __restrict__ qb, const short* __restrict__ MTg,
    short* __restrict__ mem)
{
  const int bid = blockIdx.x;
  const int chain = bid >> 5, c = bid & 31;
  const int b = chain >> 2, mh = chain & 3;
  const size_t rowbase = (size_t)(b * SS + c * 64);
  const int tid = threadIdx.x, w = tid >> 6, l = tid & 63;
  const int wr = w >> 1, wc = w & 1;
  const short* MTc = MTg + (size_t)chain * 32 * 16384 + (size_t)c * 16384;

  f32x4 acc[2][4] = {};
#pragma unroll
  for (int kf = 0; kf < 4; ++kf) {
    short8 af[2];
#pragma unroll
    for (int m = 0; m < 2; ++m) {
      const int r = wr * 32 + m * 16 + (l & 15);
      const float* qp = &qb[(rowbase + r) * 1536 + mh * 128 + kf * 32 + (l >> 4) * 8];
      const float4 a = *(const float4*)qp;
      const float4 cc = *(const float4*)(qp + 4);
      short8 q8;
      q8[0] = f2b(a.x); q8[1] = f2b(a.y); q8[2] = f2b(a.z); q8[3] = f2b(a.w);
      q8[4] = f2b(cc.x); q8[5] = f2b(cc.y); q8[6] = f2b(cc.z); q8[7] = f2b(cc.w);
      af[m] = q8;
    }
#pragma unroll
    for (int n = 0; n < 4; ++n) {
      const int e = wc * 64 + n * 16 + (l & 15);
      const short8 bf = *(const short8*)&MTc[e * 128 + kf * 32 + (l >> 4) * 8];
#pragma unroll
      for (int m = 0; m < 2; ++m)
        acc[m][n] = __builtin_amdgcn_mfma_f32_16x16x32_bf16(af[m], bf, acc[m][n], 0, 0, 0);
    }
  }
#pragma unroll
  for (int m = 0; m < 2; ++m)
#pragma unroll
    for (int n = 0; n < 4; ++n)
#pragma unroll
      for (int i = 0; i < 4; ++i) {
        const int r = wr * 32 + m * 16 + (l >> 4) * 4 + i;
        const int e = wc * 64 + n * 16 + (l & 15);
        mem[(rowbase + r) * 512 + mh * 128 + e] = f2b(acc[m][n][i]);
      }
}

// ---------------- transpose + f32->bf16 convert: src[K,N] -> dst[N,K] -------
__global__ __launch_bounds__(256) void tcvt_kernel(
    const float* __restrict__ src, short* __restrict__ dst, int K, int N)
{
  __shared__ float t[32][33];
  const int k0 = blockIdx.y * 32, n0 = blockIdx.x * 32;
  const size_t zoff = (size_t)blockIdx.z * K * N;
  src += zoff; dst += zoff;
  const int tx = threadIdx.x & 31, ty = threadIdx.x >> 5;
#pragma unroll
  for (int i = 0; i < 4; ++i)
    t[ty + i * 8][tx] = src[(size_t)(k0 + ty + i * 8) * N + n0 + tx];
  __syncthreads();
#pragma unroll
  for (int i = 0; i < 4; ++i)
    dst[(size_t)(n0 + ty + i * 8) * K + k0 + tx] = f2b(t[tx][ty + i * 8]);
}

// ---------------- f32 -> bf16 convert ----------------
__global__ __launch_bounds__(256) void cvt_kernel(
    const float* __restrict__ in, short* __restrict__ out, int n4)
{
  const int i = blockIdx.x * 256 + threadIdx.x;
  if (i >= n4) return;
  const float4 v = reinterpret_cast<const float4*>(in)[i];
  short4v o;
  o.x = f2b(v.x); o.y = f2b(v.y); o.z = f2b(v.z); o.w = f2b(v.w);
  reinterpret_cast<short4v*>(out)[i] = o;
}

// ---------------- small vec helpers ----------------
__global__ __launch_bounds__(256) void mean_tokens_kernel(
    const float* __restrict__ pm, float* __restrict__ mvec)
{
  const int d = blockIdx.x * 256 + threadIdx.x;
  if (d < 512) {
    float s = 0.f;
    for (int t = 0; t < 16; ++t) s += pm[t * 512 + d];
    mvec[d] = s * (1.f / 16.f);
  }
}

__global__ __launch_bounds__(256) void matvec512_kernel(
    const float* __restrict__ a, const float* __restrict__ W,
    const float* __restrict__ bias, float* __restrict__ out)
{
  const int e = blockIdx.x * 256 + threadIdx.x;
  float s = bias ? bias[e] : 0.f;
  for (int d = 0; d < 512; ++d) s += a[d] * W[d * 512 + e];
  out[e] = s;
}

// ---------------- host side ----------------
extern "C" void kernel_launch(void* const* d_in, const int* in_sizes, int n_in,
                              void* d_out, int out_size, void* d_ws, size_t ws_size,
                              hipStream_t stream)
{
  const float* x         = (const float*)d_in[0];
  const float* n1w       = (const float*)d_in[1];
  const float* n1b       = (const float*)d_in[2];
  const float* qkvw      = (const float*)d_in[3];
  const float* qkvb      = (const float*)d_in[4];
  const float* projw     = (const float*)d_in[5];
  const float* projb     = (const float*)d_in[6];
  const float* n2w       = (const float*)d_in[7];
  const float* n2b       = (const float*)d_in[8];
  const float* fc1w      = (const float*)d_in[9];
  const float* fc1b      = (const float*)d_in[10];
  const float* fc2w      = (const float*)d_in[11];
  const float* fc2b      = (const float*)d_in[12];
  const float* mlnw      = (const float*)d_in[13];
  const float* mlnb      = (const float*)d_in[14];
  const float* mwq       = (const float*)d_in[15];
  const float* mwk       = (const float*)d_in[16];
  const float* mwv       = (const float*)d_in[17];
  const float* mprojw    = (const float*)d_in[18];
  const float* mprojb    = (const float*)d_in[19];
  const float* pm_tokens = (const float*)d_in[20];
  const float* pmw       = (const float*)d_in[21];
  const float* pmb       = (const float*)d_in[22];
  const float* fw        = (const float*)d_in[23];
  const float* fb        = (const float*)d_in[24];
  float* out = (float*)d_out;

  char* p = (char*)d_ws;
  auto alloc = [&](size_t bytes) {
    char* r = p;
    p += (bytes + 255) & ~(size_t)255;
    return r;
  };
  short* qkvwT  = (short*)alloc(6ull * 1536 * 512 * 2);
  short* projwT = (short*)alloc(6ull * 512 * 512 * 2);
  short* fc1wT  = (short*)alloc(6ull * 2048 * 512 * 2);
  short* fc2wT  = (short*)alloc(6ull * 512 * 2048 * 2);
  short* mqkvT  = (short*)alloc(3ull * 512 * 512 * 2);
  short* mprojT = (short*)alloc(512ull * 512 * 2);
  short* fw0T   = (short*)alloc(512ull * 512 * 2);
  short* fw1T   = (short*)alloc(512ull * 512 * 2);
  float* bigf = (float*)alloc((size_t)BS * 1536 * 4);
  float* hbuf = (float*)alloc((size_t)BS * 512 * 4);
  float* t0   = (float*)alloc(3 * 512 * 4);
  float* t1 = t0 + 512; float* t2 = t1 + 512;
  short* actA  = (short*)alloc((size_t)BS * 512 * 2);
  short* attnb = (short*)alloc((size_t)BS * 512 * 2);
  short* ff1b  = (short*)alloc((size_t)BS * 2048 * 2);
  short* ltb   = (short*)alloc((size_t)BS * 512 * 2);
  short* Aq    = (short*)alloc(256ull * 16384 * 2);   // A_c bf16
  short* Bq    = (short*)alloc(256ull * 16384 * 2);   // B_c bf16
  short* MTg   = (short*)alloc(256ull * 16384 * 2);   // M^T snapshots bf16

  tcvt_kernel<<<dim3(1536 / 32, 512 / 32, 6), 256, 0, stream>>>(qkvw, qkvwT, 512, 1536);
  tcvt_kernel<<<dim3(512 / 32, 512 / 32, 6), 256, 0, stream>>>(projw, projwT, 512, 512);
  tcvt_kernel<<<dim3(2048 / 32, 512 / 32, 6), 256, 0, stream>>>(fc1w, fc1wT, 512, 2048);
  tcvt_kernel<<<dim3(512 / 32, 2048 / 32, 6), 256, 0, stream>>>(fc2w, fc2wT, 2048, 512);
  tcvt_kernel<<<dim3(16, 16, 1), 256, 0, stream>>>(mwq, mqkvT, 512, 512);
  tcvt_kernel<<<dim3(16, 16, 1), 256, 0, stream>>>(mwk, mqkvT + 512 * 512, 512, 512);
  tcvt_kernel<<<dim3(16, 16, 1), 256, 0, stream>>>(mwv, mqkvT + 2 * 512 * 512, 512, 512);
  tcvt_kernel<<<dim3(16, 16, 1), 256, 0, stream>>>(mprojw, mprojT, 512, 512);
  tcvt_kernel<<<dim3(16, 16, 1), 256, 0, stream>>>(fw, fw0T, 512, 512);
  tcvt_kernel<<<dim3(16, 16, 1), 256, 0, stream>>>(fw + 512 * 512, fw1T, 512, 512);

  mean_tokens_kernel<<<2, 256, 0, stream>>>(pm_tokens, t0);
  matvec512_kernel<<<2, 256, 0, stream>>>(t0, pmw, pmb, t1);
  matvec512_kernel<<<2, 256, 0, stream>>>(t1, fw + (size_t)1024 * 512, fb, t2);

  // ---- neural memory path (linear-scan formulation) ----
  ln_kernel<<<BS, 256, 0, stream>>>(x, mlnw, mlnb, actA);
  gemm_bf16<0, 0, 128><<<dim3(12, 32), 256, 0, stream>>>(
      actA, mqkvT, nullptr, nullptr, nullptr, bigf, BS, 1536, 512);
  mem_prep<<<256, 256, 0, stream>>>(bigf + 512, bigf + 1024, Aq, Bq);
  mem_scan2<<<32, 256, 0, stream>>>(Aq, Bq, MTg);
  mem_out<<<256, 256, 0, stream>>>(bigf, MTg, ff1b);
  gemm_bf16<2, 1, 64><<<dim3(4, 64), 256, 0, stream>>>(
      ff1b, mprojT, mprojb, x, nullptr, ltb, BS, 512, 512);

  // ---- layer stack ----
  hipMemcpyAsync(hbuf, x, (size_t)BS * 512 * 4, hipMemcpyDeviceToDevice, stream);
  for (int l = 0; l < LL; ++l) {
    ln_kernel<<<BS, 256, 0, stream>>>(hbuf, n1w + l * 512, n1b + l * 512, actA);
    gemm_bf16<0, 0, 128><<<dim3(12, 32), 256, 0, stream>>>(
        actA, qkvwT + (size_t)l * 1536 * 512, qkvb + l * 1536,
        nullptr, nullptr, bigf, BS, 1536, 512);
    swa_kernel<<<512, 256, 0, stream>>>(bigf, attnb);
    gemm_bf16<2, 0, 64><<<dim3(4, 64), 256, 0, stream>>>(
        attnb, projwT + (size_t)l * 512 * 512, projb + l * 512,
        hbuf, nullptr, hbuf, BS, 512, 512);
    ln_kernel<<<BS, 256, 0, stream>>>(hbuf, n2w + l * 512, n2b + l * 512, actA);
    gemm_bf16<1, 1, 128><<<dim3(16, 32), 256, 0, stream>>>(
        actA, fc1wT + (size_t)l * 2048 * 512, fc1b + l * 2048,
        nullptr, nullptr, ff1b, BS, 2048, 512);
    gemm_bf16<3, 0, 64><<<dim3(4, 64), 256, 0, stream>>>(
        ff1b, fc2wT + (size_t)l * 512 * 2048, fc2b + l * 512,
        hbuf, actA, hbuf, BS, 512, 2048);
  }

  // ---- fusion ----
  cvt_kernel<<<(BS * 512 / 4 + 255) / 256, 256, 0, stream>>>(hbuf, actA, BS * 512 / 4);
  gemm_bf16<0, 0, 64><<<dim3(4, 64), 256, 0, stream>>>(
      actA, fw0T, t2, nullptr, nullptr, out, BS, 512, 512);
  gemm_bf16<2, 0, 64><<<dim3(4, 64), 256, 0, stream>>>(
      ltb, fw1T, nullptr, out, nullptr, out, BS, 512, 512);
}

// Round 6
// 906.382 us; speedup vs baseline: 4.2505x; 1.0812x over previous
//
#include <hip/hip_runtime.h>
#include <math.h>

// Problem constants
#define BB 2
#define SS 2048
#define DD 512
#define HH 8
#define LL 6
#define WW 64
#define CHH 64
#define NCC 32
#define BS (BB*SS)   // 4096 rows

typedef __attribute__((ext_vector_type(8))) short short8;
typedef __attribute__((ext_vector_type(4))) short short4v;
typedef __attribute__((ext_vector_type(4))) float f32x4;

__device__ inline float b2f(short s) {
  unsigned u = ((unsigned)(unsigned short)s) << 16;
  float f; __builtin_memcpy(&f, &u, 4); return f;
}
__device__ inline short f2b(float f) {
  unsigned u; __builtin_memcpy(&u, &f, 4);
  unsigned r = (u + 0x7FFFu + ((u >> 16) & 1u)) >> 16;
  return (short)r;
}
__device__ inline float gelu_tanh(float v) {
  float u = 0.7978845608f * (v + 0.044715f * v * v * v);
  u = fminf(fmaxf(u, -20.f), 20.f);
  float e2 = __expf(2.f * u);
  return 0.5f * v * (1.f + (e2 - 1.f) / (e2 + 1.f));
}

#define AS1(p) ((const __attribute__((address_space(1))) void*)(p))
#define AS3(p) ((__attribute__((address_space(3))) void*)(p))

// ---------------- LayerNorm: fp32 in -> bf16 out ----------------
__global__ __launch_bounds__(256) void ln_kernel(
    const float* __restrict__ x, const float* __restrict__ w,
    const float* __restrict__ b, short* __restrict__ y)
{
  const int row = blockIdx.x;
  const int tid = threadIdx.x;
  const float2 v = reinterpret_cast<const float2*>(x + (size_t)row * DD)[tid];
  float s = v.x + v.y;
  float sq = v.x * v.x + v.y * v.y;
#pragma unroll
  for (int off = 32; off; off >>= 1) {
    s += __shfl_xor(s, off);
    sq += __shfl_xor(sq, off);
  }
  __shared__ float ss[4], ssq[4];
  if ((tid & 63) == 0) { ss[tid >> 6] = s; ssq[tid >> 6] = sq; }
  __syncthreads();
  s = ss[0] + ss[1] + ss[2] + ss[3];
  sq = ssq[0] + ssq[1] + ssq[2] + ssq[3];
  const float mean = s * (1.f / DD);
  const float var = sq * (1.f / DD) - mean * mean;
  const float inv = rsqrtf(var + 1e-5f);
  const float2 wv = reinterpret_cast<const float2*>(w)[tid];
  const float2 bv = reinterpret_cast<const float2*>(b)[tid];
  const float ox = (v.x - mean) * inv * wv.x + bv.x;
  const float oy = (v.y - mean) * inv * wv.y + bv.y;
  unsigned pk = ((unsigned)(unsigned short)f2b(oy) << 16) | (unsigned short)f2b(ox);
  reinterpret_cast<unsigned*>(y + (size_t)row * DD)[tid] = pk;
}

// ---------------- bf16 MFMA GEMM (BM=128 or 64, BN=128) ----------------
template<int EPI, int OBF, int BM>
__global__ __launch_bounds__(256) void gemm_bf16(
    const short* __restrict__ A, const short* __restrict__ BT,
    const float* __restrict__ bias, const float* __restrict__ add1,
    const short* __restrict__ add2, void* __restrict__ C,
    int M, int N, int K)
{
  constexpr int MF = BM / 32;
  constexpr int CA = BM / 64;
  __shared__ __align__(16) short As[BM * 32];
  __shared__ __align__(16) short Bs[128 * 32];
  const int tid = threadIdx.x;
  const int wave = tid >> 6, lane = tid & 63;
  const int wr = wave >> 1, wc = wave & 1;
  const int bm = blockIdx.y * BM, bn = blockIdx.x * 128;

  const int l4r = lane >> 2;
  const int l4c = (lane & 3) * 8;

  const short* sA[CA]; const short* sB[2];
  int ldsA[CA], ldsB[2];
#pragma unroll
  for (int r = 0; r < CA; ++r) {
    const int chunk = r * 4 + wave;
    sA[r] = A + (size_t)(bm + chunk * 16 + l4r) * K + l4c;
    ldsA[r] = chunk * 1024;
  }
#pragma unroll
  for (int r = 0; r < 2; ++r) {
    const int chunk = r * 4 + wave;
    sB[r] = BT + (size_t)(bn + chunk * 16 + l4r) * K + l4c;
    ldsB[r] = chunk * 1024;
  }

  f32x4 acc[MF][4] = {};

  for (int k0 = 0; k0 < K; k0 += 32) {
#pragma unroll
    for (int r = 0; r < CA; ++r) {
      __builtin_amdgcn_global_load_lds(AS1(sA[r]), AS3((char*)As + ldsA[r]), 16, 0, 0);
      sA[r] += 32;
    }
#pragma unroll
    for (int r = 0; r < 2; ++r) {
      __builtin_amdgcn_global_load_lds(AS1(sB[r]), AS3((char*)Bs + ldsB[r]), 16, 0, 0);
      sB[r] += 32;
    }
    __syncthreads();
    short8 af[MF], bf[4];
#pragma unroll
    for (int m = 0; m < MF; ++m)
      af[m] = *(const short8*)&As[(wr * (BM / 2) + m * 16 + (lane & 15)) * 32 + (lane >> 4) * 8];
#pragma unroll
    for (int n = 0; n < 4; ++n)
      bf[n] = *(const short8*)&Bs[(wc * 64 + n * 16 + (lane & 15)) * 32 + (lane >> 4) * 8];
#pragma unroll
    for (int m = 0; m < MF; ++m)
#pragma unroll
      for (int n = 0; n < 4; ++n)
        acc[m][n] = __builtin_amdgcn_mfma_f32_16x16x32_bf16(af[m], bf[n], acc[m][n], 0, 0, 0);
    __syncthreads();
  }

#pragma unroll
  for (int m = 0; m < MF; ++m) {
#pragma unroll
    for (int n = 0; n < 4; ++n) {
      const int col = bn + wc * 64 + n * 16 + (lane & 15);
      const float bb = (EPI == 1 || EPI == 3) ? bias[col] : (bias ? bias[col] : 0.f);
#pragma unroll
      for (int r = 0; r < 4; ++r) {
        const int row = bm + wr * (BM / 2) + m * 16 + (lane >> 4) * 4 + r;
        const size_t idx = (size_t)row * N + col;
        float v = acc[m][n][r] + bb;
        if (EPI == 1) v = gelu_tanh(v);
        if (EPI == 2 || EPI == 3) v += add1[idx];
        if (EPI == 3) v += b2f(add2[idx]);
        if (OBF) ((short*)C)[idx] = f2b(v);
        else ((float*)C)[idx] = v;
      }
    }
  }
}

// ---------------- Sliding-window attention, MFMA flash-style ----------------
__global__ __launch_bounds__(256) void swa_kernel(
    const float* __restrict__ qkv, short* __restrict__ out)
{
  __shared__ __align__(16) short ks[128 * 72];
  __shared__ __align__(16) short vt[64 * 136];
  __shared__ __align__(16) short ps[4][16 * 136];
  __shared__ float lsum[64];

  const int tid = threadIdx.x;
  const int w = tid >> 6, l = tid & 63;
  const int tile = blockIdx.x & 31;
  const int h = (blockIdx.x >> 5) & 7;
  const int b = blockIdx.x >> 8;
  const int s0 = tile * 64;
  const size_t base = (size_t)b * SS;

#pragma unroll
  for (int u = 0; u < 16; ++u) {
    const int id = u * 256 + tid;
    const int row = id >> 5, dp = id & 31;
    int jp = s0 - 32 + row;
    jp = min(max(jp, 0), SS - 1);
    const size_t g = (base + jp) * 1536 + h * 64 + dp * 2;
    const float2 kv = *(const float2*)&qkv[g + 512];
    const float2 vv = *(const float2*)&qkv[g + 1024];
    unsigned pk = ((unsigned)(unsigned short)f2b(kv.y) << 16) | (unsigned short)f2b(kv.x);
    *(unsigned*)&ks[row * 72 + dp * 2] = pk;
    vt[(dp * 2) * 136 + row] = f2b(vv.x);
    vt[(dp * 2 + 1) * 136 + row] = f2b(vv.y);
  }

  const int qi = w * 16 + (l & 15);
  short8 qf[2];
#pragma unroll
  for (int kf = 0; kf < 2; ++kf) {
    const float* qp = &qkv[(base + s0 + qi) * 1536 + h * 64 + kf * 32 + (l >> 4) * 8];
    const float4 a = *(const float4*)qp;
    const float4 c = *(const float4*)(qp + 4);
    short8 q8;
    q8[0] = f2b(a.x); q8[1] = f2b(a.y); q8[2] = f2b(a.z); q8[3] = f2b(a.w);
    q8[4] = f2b(c.x); q8[5] = f2b(c.y); q8[6] = f2b(c.z); q8[7] = f2b(c.w);
    qf[kf] = q8;
  }
  __syncthreads();

  f32x4 sa[8] = {};
#pragma unroll
  for (int mf = 0; mf < 8; ++mf)
#pragma unroll
    for (int kf = 0; kf < 2; ++kf) {
      const short8 af = *(const short8*)&ks[(mf * 16 + (l & 15)) * 72 + kf * 32 + (l >> 4) * 8];
      sa[mf] = __builtin_amdgcn_mfma_f32_16x16x32_bf16(af, qf[kf], sa[mf], 0, 0, 0);
    }

  float sv[8][4];
  float mx = -INFINITY;
#pragma unroll
  for (int mf = 0; mf < 8; ++mf)
#pragma unroll
    for (int r = 0; r < 4; ++r) {
      const int j = mf * 16 + (l >> 4) * 4 + r;
      const int jpos = s0 - 32 + j;
      const bool ok = (j >= qi) && (j <= qi + 64) && (jpos >= 0) && (jpos < SS);
      const float s = ok ? sa[mf][r] * 0.125f : -INFINITY;
      sv[mf][r] = s;
      mx = fmaxf(mx, s);
    }
  mx = fmaxf(mx, __shfl_xor(mx, 16));
  mx = fmaxf(mx, __shfl_xor(mx, 32));
  float ls = 0.f;
#pragma unroll
  for (int mf = 0; mf < 8; ++mf)
#pragma unroll
    for (int r = 0; r < 4; ++r) {
      const float p = __expf(sv[mf][r] - mx);
      sv[mf][r] = p;
      ls += p;
    }
  ls += __shfl_xor(ls, 16);
  ls += __shfl_xor(ls, 32);
  if (l < 16) lsum[w * 16 + l] = ls;

#pragma unroll
  for (int mf = 0; mf < 8; ++mf) {
    short4v p4;
    p4.x = f2b(sv[mf][0]); p4.y = f2b(sv[mf][1]);
    p4.z = f2b(sv[mf][2]); p4.w = f2b(sv[mf][3]);
    *(short4v*)&ps[w][(l & 15) * 136 + mf * 16 + (l >> 4) * 4] = p4;
  }

  f32x4 oa[4] = {};
#pragma unroll
  for (int kf = 0; kf < 4; ++kf) {
    const short8 pf = *(const short8*)&ps[w][(l & 15) * 136 + kf * 32 + (l >> 4) * 8];
#pragma unroll
    for (int nf = 0; nf < 4; ++nf) {
      const short8 vf = *(const short8*)&vt[(nf * 16 + (l & 15)) * 136 + kf * 32 + (l >> 4) * 8];
      oa[nf] = __builtin_amdgcn_mfma_f32_16x16x32_bf16(pf, vf, oa[nf], 0, 0, 0);
    }
  }

  float rl[4];
#pragma unroll
  for (int r = 0; r < 4; ++r) rl[r] = 1.f / lsum[w * 16 + (l >> 4) * 4 + r];
#pragma unroll
  for (int nf = 0; nf < 4; ++nf)
#pragma unroll
    for (int r = 0; r < 4; ++r) {
      const int q = (l >> 4) * 4 + r;
      const int d = nf * 16 + (l & 15);
      out[(base + s0 + w * 16 + q) * 512 + h * 64 + d] = f2b(oa[nf][r] * rl[r]);
    }
}

// ========== Neural memory, linear-scan formulation ==========
// grad_c = A_c M_{c-1} - B_c,  A_c = k^T k/64 (bf16, stored XOR-swizzled),
// B_c = k^T v/64 (bf16, natural layout)

// ---- P1: per (chain, chunk) compute A_c, B_c via MFMA ----
__global__ __launch_bounds__(256) void mem_prep(
    const float* __restrict__ kb, const float* __restrict__ vb,
    short* __restrict__ Aq, short* __restrict__ Bq)
{
  __shared__ __align__(16) short kn[64 * 136];   // natural staging
  __shared__ __align__(16) char kT[128 * 128];   // bf16 [d][r], XOR swizzled
  __shared__ __align__(16) char vT[128 * 128];
  const int bid = blockIdx.x;
  const int chain = bid >> 5, c = bid & 31;
  const int b = chain >> 2, mh = chain & 3;
  const size_t rowbase = (size_t)(b * SS + c * 64);
  const int tid = threadIdx.x, w = tid >> 6, l = tid & 63;
  const int td = tid & 127, rh = tid >> 7;

#pragma unroll
  for (int pass = 0; pass < 2; ++pass) {
    const float* src = pass ? vb : kb;
    char* dT = pass ? vT : kT;
#pragma unroll
    for (int j = 0; j < 8; ++j) {
      const int i4 = tid + 256 * j;
      const int r = i4 >> 5, d4 = (i4 & 31) * 4;
      const float4 vv = *(const float4*)&src[(rowbase + r) * 1536 + mh * 128 + d4];
      short4v s4;
      s4.x = f2b(vv.x); s4.y = f2b(vv.y); s4.z = f2b(vv.z); s4.w = f2b(vv.w);
      *(short4v*)&kn[r * 136 + d4] = s4;
    }
    __syncthreads();
#pragma unroll
    for (int j = 0; j < 4; ++j) {
      const int r0 = rh * 8 + 16 * j;
      short8 g8;
#pragma unroll
      for (int t = 0; t < 8; ++t) g8[t] = kn[(r0 + t) * 136 + td];
      *(short8*)&dT[(td * 128 + r0 * 2) ^ ((td & 7) << 4)] = g8;
    }
    __syncthreads();
  }

  const int wr = w >> 1, wc = w & 1;
  // A = kT @ kT(BT) / 64  (write swizzled: byte (d*256+dp*2) ^ ((d&7)<<4))
  {
    f32x4 acc[4][4] = {};
#pragma unroll
    for (int kf = 0; kf < 2; ++kf) {
      short8 af[4];
#pragma unroll
      for (int m = 0; m < 4; ++m) {
        const int d = wr * 64 + m * 16 + (l & 15);
        af[m] = *(const short8*)&kT[(d * 128 + kf * 64 + (l >> 4) * 16) ^ ((d & 7) << 4)];
      }
#pragma unroll
      for (int n = 0; n < 4; ++n) {
        const int dp = wc * 64 + n * 16 + (l & 15);
        const short8 bf = *(const short8*)&kT[(dp * 128 + kf * 64 + (l >> 4) * 16) ^ ((dp & 7) << 4)];
#pragma unroll
        for (int m = 0; m < 4; ++m)
          acc[m][n] = __builtin_amdgcn_mfma_f32_16x16x32_bf16(af[m], bf, acc[m][n], 0, 0, 0);
      }
    }
    char* Ad = (char*)(Aq + (size_t)bid * 16384);
#pragma unroll
    for (int m = 0; m < 4; ++m)
#pragma unroll
      for (int n = 0; n < 4; ++n)
#pragma unroll
        for (int i = 0; i < 4; ++i) {
          const int d = wr * 64 + m * 16 + (l >> 4) * 4 + i;
          const int dp = wc * 64 + n * 16 + (l & 15);
          *(short*)&Ad[(d * 256 + dp * 2) ^ ((d & 7) << 4)] = f2b(acc[m][n][i] * 0.015625f);
        }
  }
  // B = kT @ vT(BT) / 64  (natural layout)
  {
    f32x4 acc[4][4] = {};
#pragma unroll
    for (int kf = 0; kf < 2; ++kf) {
      short8 af[4];
#pragma unroll
      for (int m = 0; m < 4; ++m) {
        const int d = wr * 64 + m * 16 + (l & 15);
        af[m] = *(const short8*)&kT[(d * 128 + kf * 64 + (l >> 4) * 16) ^ ((d & 7) << 4)];
      }
#pragma unroll
      for (int n = 0; n < 4; ++n) {
        const int e = wc * 64 + n * 16 + (l & 15);
        const short8 bf = *(const short8*)&vT[(e * 128 + kf * 64 + (l >> 4) * 16) ^ ((e & 7) << 4)];
#pragma unroll
        for (int m = 0; m < 4; ++m)
          acc[m][n] = __builtin_amdgcn_mfma_f32_16x16x32_bf16(af[m], bf, acc[m][n], 0, 0, 0);
      }
    }
    short* Bd = Bq + (size_t)bid * 16384;
#pragma unroll
    for (int m = 0; m < 4; ++m)
#pragma unroll
      for (int n = 0; n < 4; ++n)
#pragma unroll
        for (int i = 0; i < 4; ++i) {
          const int d = wr * 64 + m * 16 + (l >> 4) * 4 + i;
          const int e = wc * 64 + n * 16 + (l & 15);
          Bd[d * 128 + e] = f2b(acc[m][n][i] * 0.015625f);
        }
  }
}

// ---- P2: serial scan, software-pipelined. 32 blocks = 8 chains x 4 quarters ----
// A_{c+1} prefetched into LDS via global_load_lds while chunk c computes.
// B_c loaded to registers (plain loads, overlap MFMA). MT double-buffered.
__global__ __launch_bounds__(256) void mem_scan2(
    const short* __restrict__ Aq, const short* __restrict__ Bq,
    short* __restrict__ MTg)
{
  __shared__ __align__(16) char AcL[2][32768];
  __shared__ __align__(16) char MT[2][8192];
  const int bid = blockIdx.x;
  const int chain = bid >> 2, ch = bid & 3;
  const int tid = threadIdx.x;
  const int w = tid >> 6, l = tid & 63;
  const int wr = w >> 1, wc = w & 1;
  const int e = wc * 16 + (l & 15);

  {
    const short8 z = {0, 0, 0, 0, 0, 0, 0, 0};
    for (int i = tid; i < 1024; i += 256)
      *(short8*)((char*)MT + i * 16) = z;
  }
  float Mreg[16] = {}, Momreg[16] = {};

  const short* Ab = Aq + (size_t)chain * 32 * 16384;
  const short* Bb = Bq + (size_t)chain * 32 * 16384;
  short* MTb = MTg + (size_t)chain * 32 * 16384 + (size_t)ch * 32 * 128;
  const int se = tid & 31, sdb = tid >> 5;

  // prologue: stage chunk 0 (syncthreads below drains vmcnt)
#pragma unroll
  for (int j = 0; j < 8; ++j) {
    const int byte = tid * 16 + j * 4096;
    __builtin_amdgcn_global_load_lds(AS1((const char*)Ab + byte),
                                     AS3(AcL[0] + byte), 16, 0, 0);
  }
  __syncthreads();

  int buf = 0, cur = 0;
  for (int c = 0; c < NCC; ++c) {
    // issue prefetch of A_{c+1}
    if (c + 1 < NCC) {
      const char* src = (const char*)(Ab + (size_t)(c + 1) * 16384);
#pragma unroll
      for (int j = 0; j < 8; ++j) {
        const int byte = tid * 16 + j * 4096;
        __builtin_amdgcn_global_load_lds(AS1(src + byte),
                                         AS3(AcL[buf ^ 1] + byte), 16, 0, 0);
      }
    }
    // B_c -> registers (use is after MFMA; latency overlaps)
    unsigned short breg[16];
    const unsigned short* Bc = (const unsigned short*)(Bb + (size_t)c * 16384);
#pragma unroll
    for (int m = 0; m < 4; ++m)
#pragma unroll
      for (int i = 0; i < 4; ++i) {
        const int d = wr * 64 + m * 16 + (l >> 4) * 4 + i;
        breg[m * 4 + i] = Bc[d * 128 + ch * 32 + e];
      }
    // snapshot M^T_{c-1} -> global (natural layout)
#pragma unroll
    for (int j = 0; j < 2; ++j) {
      const int db = sdb + 8 * j;
      const short8 vv = *(const short8*)&MT[cur][(se * 256 + db * 16) ^ ((se & 7) << 4)];
      *(short8*)&MTb[(size_t)c * 16384 + se * 128 + db * 8] = vv;
    }
    // G = A_c @ M
    f32x4 acc[4] = {};
#pragma unroll
    for (int kf = 0; kf < 4; ++kf) {
      const short8 bf = *(const short8*)&MT[cur][(e * 256 + kf * 64 + (l >> 4) * 16) ^ ((e & 7) << 4)];
#pragma unroll
      for (int m = 0; m < 4; ++m) {
        const int d = wr * 64 + m * 16 + (l & 15);
        const short8 af = *(const short8*)&AcL[buf][(d * 256 + kf * 64 + (l >> 4) * 16) ^ ((d & 7) << 4)];
        acc[m] = __builtin_amdgcn_mfma_f32_16x16x32_bf16(af, bf, acc[m], 0, 0, 0);
      }
    }
    // update M, Mom (registers); write M^T_c into the other MT buffer
#pragma unroll
    for (int m = 0; m < 4; ++m)
#pragma unroll
      for (int i = 0; i < 4; ++i) {
        const int d = wr * 64 + m * 16 + (l >> 4) * 4 + i;
        const int idx = m * 4 + i;
        const float g = acc[m][i] - b2f((short)breg[idx]);
        Momreg[idx] = 0.9f * Momreg[idx] - 0.1f * g;
        Mreg[idx] = 0.99f * Mreg[idx] + Momreg[idx];
        *(short*)&MT[cur ^ 1][(e * 256 + d * 2) ^ ((e & 7) << 4)] = f2b(Mreg[idx]);
      }
    __syncthreads();   // MT writes visible + A-prefetch (vmcnt drain) complete
    buf ^= 1; cur ^= 1;
  }
}

// ---- P3: out_c = q_c @ M_{c-1}, batched over 256 (chain, chunk) blocks ----
__global__ __launch_bounds__(256) void mem_out(
    const float* __restrict__ qb, const short* __restrict__ MTg,
    short* __restrict__ mem)
{
  const int bid = blockIdx.x;
  const int chain = bid >> 5, c = bid & 31;
  const int b = chain >> 2, mh = chain & 3;
  const size_t rowbase = (size_t)(b * SS + c * 64);
  const int tid = threadIdx.x, w = tid >> 6, l = tid & 63;
  const int wr = w >> 1, wc = w & 1;
  const short* MTc = MTg + (size_t)chain * 32 * 16384 + (size_t)c * 16384;

  f32x4 acc[2][4] = {};
#pragma unroll
  for (int kf = 0; kf < 4; ++kf) {
    short8 af[2];
#pragma unroll
    for (int m = 0; m < 2; ++m) {
      const int r = wr * 32 + m * 16 + (l & 15);
      const float* qp = &qb[(rowbase + r) * 1536 + mh * 128 + kf * 32 + (l >> 4) * 8];
      const float4 a = *(const float4*)qp;
      const float4 cc = *(const float4*)(qp + 4);
      short8 q8;
      q8[0] = f2b(a.x); q8[1] = f2b(a.y); q8[2] = f2b(a.z); q8[3] = f2b(a.w);
      q8[4] = f2b(cc.x); q8[5] = f2b(cc.y); q8[6] = f2b(cc.z); q8[7] = f2b(cc.w);
      af[m] = q8;
    }
#pragma unroll
    for (int n = 0; n < 4; ++n) {
      const int e = wc * 64 + n * 16 + (l & 15);
      const short8 bf = *(const short8*)&MTc[e * 128 + kf * 32 + (l >> 4) * 8];
#pragma unroll
      for (int m = 0; m < 2; ++m)
        acc[m][n] = __builtin_amdgcn_mfma_f32_16x16x32_bf16(af[m], bf, acc[m][n], 0, 0, 0);
    }
  }
#pragma unroll
  for (int m = 0; m < 2; ++m)
#pragma unroll
    for (int n = 0; n < 4; ++n)
#pragma unroll
      for (int i = 0; i < 4; ++i) {
        const int r = wr * 32 + m * 16 + (l >> 4) * 4 + i;
        const int e = wc * 64 + n * 16 + (l & 15);
        mem[(rowbase + r) * 512 + mh * 128 + e] = f2b(acc[m][n][i]);
      }
}

// ---------------- transpose + f32->bf16 convert: src[K,N] -> dst[N,K] -------
__global__ __launch_bounds__(256) void tcvt_kernel(
    const float* __restrict__ src, short* __restrict__ dst, int K, int N)
{
  __shared__ float t[32][33];
  const int k0 = blockIdx.y * 32, n0 = blockIdx.x * 32;
  const size_t zoff = (size_t)blockIdx.z * K * N;
  src += zoff; dst += zoff;
  const int tx = threadIdx.x & 31, ty = threadIdx.x >> 5;
#pragma unroll
  for (int i = 0; i < 4; ++i)
    t[ty + i * 8][tx] = src[(size_t)(k0 + ty + i * 8) * N + n0 + tx];
  __syncthreads();
#pragma unroll
  for (int i = 0; i < 4; ++i)
    dst[(size_t)(n0 + ty + i * 8) * K + k0 + tx] = f2b(t[tx][ty + i * 8]);
}

// ---------------- f32 -> bf16 convert ----------------
__global__ __launch_bounds__(256) void cvt_kernel(
    const float* __restrict__ in, short* __restrict__ out, int n4)
{
  const int i = blockIdx.x * 256 + threadIdx.x;
  if (i >= n4) return;
  const float4 v = reinterpret_cast<const float4*>(in)[i];
  short4v o;
  o.x = f2b(v.x); o.y = f2b(v.y); o.z = f2b(v.z); o.w = f2b(v.w);
  reinterpret_cast<short4v*>(out)[i] = o;
}

// ---------------- small vec helpers ----------------
__global__ __launch_bounds__(256) void mean_tokens_kernel(
    const float* __restrict__ pm, float* __restrict__ mvec)
{
  const int d = blockIdx.x * 256 + threadIdx.x;
  if (d < 512) {
    float s = 0.f;
    for (int t = 0; t < 16; ++t) s += pm[t * 512 + d];
    mvec[d] = s * (1.f / 16.f);
  }
}

__global__ __launch_bounds__(256) void matvec512_kernel(
    const float* __restrict__ a, const float* __restrict__ W,
    const float* __restrict__ bias, float* __restrict__ out)
{
  const int e = blockIdx.x * 256 + threadIdx.x;
  float s = bias ? bias[e] : 0.f;
  for (int d = 0; d < 512; ++d) s += a[d] * W[d * 512 + e];
  out[e] = s;
}

// ---------------- host side ----------------
extern "C" void kernel_launch(void* const* d_in, const int* in_sizes, int n_in,
                              void* d_out, int out_size, void* d_ws, size_t ws_size,
                              hipStream_t stream)
{
  const float* x         = (const float*)d_in[0];
  const float* n1w       = (const float*)d_in[1];
  const float* n1b       = (const float*)d_in[2];
  const float* qkvw      = (const float*)d_in[3];
  const float* qkvb      = (const float*)d_in[4];
  const float* projw     = (const float*)d_in[5];
  const float* projb     = (const float*)d_in[6];
  const float* n2w       = (const float*)d_in[7];
  const float* n2b       = (const float*)d_in[8];
  const float* fc1w      = (const float*)d_in[9];
  const float* fc1b      = (const float*)d_in[10];
  const float* fc2w      = (const float*)d_in[11];
  const float* fc2b      = (const float*)d_in[12];
  const float* mlnw      = (const float*)d_in[13];
  const float* mlnb      = (const float*)d_in[14];
  const float* mwq       = (const float*)d_in[15];
  const float* mwk       = (const float*)d_in[16];
  const float* mwv       = (const float*)d_in[17];
  const float* mprojw    = (const float*)d_in[18];
  const float* mprojb    = (const float*)d_in[19];
  const float* pm_tokens = (const float*)d_in[20];
  const float* pmw       = (const float*)d_in[21];
  const float* pmb       = (const float*)d_in[22];
  const float* fw        = (const float*)d_in[23];
  const float* fb        = (const float*)d_in[24];
  float* out = (float*)d_out;

  char* p = (char*)d_ws;
  auto alloc = [&](size_t bytes) {
    char* r = p;
    p += (bytes + 255) & ~(size_t)255;
    return r;
  };
  short* qkvwT  = (short*)alloc(6ull * 1536 * 512 * 2);
  short* projwT = (short*)alloc(6ull * 512 * 512 * 2);
  short* fc1wT  = (short*)alloc(6ull * 2048 * 512 * 2);
  short* fc2wT  = (short*)alloc(6ull * 512 * 2048 * 2);
  short* mqkvT  = (short*)alloc(3ull * 512 * 512 * 2);
  short* mprojT = (short*)alloc(512ull * 512 * 2);
  short* fw0T   = (short*)alloc(512ull * 512 * 2);
  short* fw1T   = (short*)alloc(512ull * 512 * 2);
  float* bigf = (float*)alloc((size_t)BS * 1536 * 4);
  float* hbuf = (float*)alloc((size_t)BS * 512 * 4);
  float* t0   = (float*)alloc(3 * 512 * 4);
  float* t1 = t0 + 512; float* t2 = t1 + 512;
  short* actA  = (short*)alloc((size_t)BS * 512 * 2);
  short* attnb = (short*)alloc((size_t)BS * 512 * 2);
  short* ff1b  = (short*)alloc((size_t)BS * 2048 * 2);
  short* ltb   = (short*)alloc((size_t)BS * 512 * 2);
  short* Aq    = (short*)alloc(256ull * 16384 * 2);   // A_c bf16 (swizzled)
  short* Bq    = (short*)alloc(256ull * 16384 * 2);   // B_c bf16
  short* MTg   = (short*)alloc(256ull * 16384 * 2);   // M^T snapshots bf16

  tcvt_kernel<<<dim3(1536 / 32, 512 / 32, 6), 256, 0, stream>>>(qkvw, qkvwT, 512, 1536);
  tcvt_kernel<<<dim3(512 / 32, 512 / 32, 6), 256, 0, stream>>>(projw, projwT, 512, 512);
  tcvt_kernel<<<dim3(2048 / 32, 512 / 32, 6), 256, 0, stream>>>(fc1w, fc1wT, 512, 2048);
  tcvt_kernel<<<dim3(512 / 32, 2048 / 32, 6), 256, 0, stream>>>(fc2w, fc2wT, 2048, 512);
  tcvt_kernel<<<dim3(16, 16, 1), 256, 0, stream>>>(mwq, mqkvT, 512, 512);
  tcvt_kernel<<<dim3(16, 16, 1), 256, 0, stream>>>(mwk, mqkvT + 512 * 512, 512, 512);
  tcvt_kernel<<<dim3(16, 16, 1), 256, 0, stream>>>(mwv, mqkvT + 2 * 512 * 512, 512, 512);
  tcvt_kernel<<<dim3(16, 16, 1), 256, 0, stream>>>(mprojw, mprojT, 512, 512);
  tcvt_kernel<<<dim3(16, 16, 1), 256, 0, stream>>>(fw, fw0T, 512, 512);
  tcvt_kernel<<<dim3(16, 16, 1), 256, 0, stream>>>(fw + 512 * 512, fw1T, 512, 512);

  mean_tokens_kernel<<<2, 256, 0, stream>>>(pm_tokens, t0);
  matvec512_kernel<<<2, 256, 0, stream>>>(t0, pmw, pmb, t1);
  matvec512_kernel<<<2, 256, 0, stream>>>(t1, fw + (size_t)1024 * 512, fb, t2);

  // ---- neural memory path (linear-scan formulation) ----
  ln_kernel<<<BS, 256, 0, stream>>>(x, mlnw, mlnb, actA);
  gemm_bf16<0, 0, 128><<<dim3(12, 32), 256, 0, stream>>>(
      actA, mqkvT, nullptr, nullptr, nullptr, bigf, BS, 1536, 512);
  mem_prep<<<256, 256, 0, stream>>>(bigf + 512, bigf + 1024, Aq, Bq);
  mem_scan2<<<32, 256, 0, stream>>>(Aq, Bq, MTg);
  mem_out<<<256, 256, 0, stream>>>(bigf, MTg, ff1b);
  gemm_bf16<2, 1, 64><<<dim3(4, 64), 256, 0, stream>>>(
      ff1b, mprojT, mprojb, x, nullptr, ltb, BS, 512, 512);

  // ---- layer stack ----
  hipMemcpyAsync(hbuf, x, (size_t)BS * 512 * 4, hipMemcpyDeviceToDevice, stream);
  for (int l = 0; l < LL; ++l) {
    ln_kernel<<<BS, 256, 0, stream>>>(hbuf, n1w + l * 512, n1b + l * 512, actA);
    gemm_bf16<0, 0, 128><<<dim3(12, 32), 256, 0, stream>>>(
        actA, qkvwT + (size_t)l * 1536 * 512, qkvb + l * 1536,
        nullptr, nullptr, bigf, BS, 1536, 512);
    swa_kernel<<<512, 256, 0, stream>>>(bigf, attnb);
    gemm_bf16<2, 0, 64><<<dim3(4, 64), 256, 0, stream>>>(
        attnb, projwT + (size_t)l * 512 * 512, projb + l * 512,
        hbuf, nullptr, hbuf, BS, 512, 512);
    ln_kernel<<<BS, 256, 0, stream>>>(hbuf, n2w + l * 512, n2b + l * 512, actA);
    gemm_bf16<1, 1, 128><<<dim3(16, 32), 256, 0, stream>>>(
        actA, fc1wT + (size_t)l * 2048 * 512, fc1b + l * 2048,
        nullptr, nullptr, ff1b, BS, 2048, 512);
    gemm_bf16<3, 0, 64><<<dim3(4, 64), 256, 0, stream>>>(
        ff1b, fc2wT + (size_t)l * 512 * 2048, fc2b + l * 512,
        hbuf, actA, hbuf, BS, 512, 2048);
  }

  // ---- fusion ----
  cvt_kernel<<<(BS * 512 / 4 + 255) / 256, 256, 0, stream>>>(hbuf, actA, BS * 512 / 4);
  gemm_bf16<0, 0, 64><<<dim3(4, 64), 256, 0, stream>>>(
      actA, fw0T, t2, nullptr, nullptr, out, BS, 512, 512);
  gemm_bf16<2, 0, 64><<<dim3(4, 64), 256, 0, stream>>>(
      ltb, fw1T, nullptr, out, nullptr, out, BS, 512, 512);
}

// Round 7
// 851.355 us; speedup vs baseline: 4.5252x; 1.0646x over previous
//
#include <hip/hip_runtime.h>
#include <math.h>

// Problem constants
#define BB 2
#define SS 2048
#define DD 512
#define HH 8
#define LL 6
#define WW 64
#define CHH 64
#define NCC 32
#define BS (BB*SS)   // 4096 rows

typedef __attribute__((ext_vector_type(8))) short short8;
typedef __attribute__((ext_vector_type(4))) short short4v;
typedef __attribute__((ext_vector_type(4))) float f32x4;

__device__ inline float b2f(short s) {
  unsigned u = ((unsigned)(unsigned short)s) << 16;
  float f; __builtin_memcpy(&f, &u, 4); return f;
}
__device__ inline short f2b(float f) {
  unsigned u; __builtin_memcpy(&u, &f, 4);
  unsigned r = (u + 0x7FFFu + ((u >> 16) & 1u)) >> 16;
  return (short)r;
}
__device__ inline float gelu_tanh(float v) {
  float u = 0.7978845608f * (v + 0.044715f * v * v * v);
  u = fminf(fmaxf(u, -20.f), 20.f);
  float e2 = __expf(2.f * u);
  return 0.5f * v * (1.f + (e2 - 1.f) / (e2 + 1.f));
}

#define AS1(p) ((const __attribute__((address_space(1))) void*)(p))
#define AS3(p) ((__attribute__((address_space(3))) void*)(p))

// ---------------- LayerNorm: wave-per-row, 4 rows/block ----------------
__global__ __launch_bounds__(256) void ln_kernel(
    const float* __restrict__ x, const float* __restrict__ w,
    const float* __restrict__ b, short* __restrict__ y)
{
  const int row = blockIdx.x * 4 + (threadIdx.x >> 6);
  const int l = threadIdx.x & 63;
  const float* xr = x + (size_t)row * DD + l * 8;
  const float4 a = *(const float4*)xr;
  const float4 c = *(const float4*)(xr + 4);
  float s = a.x + a.y + a.z + a.w + c.x + c.y + c.z + c.w;
  float sq = a.x * a.x + a.y * a.y + a.z * a.z + a.w * a.w
           + c.x * c.x + c.y * c.y + c.z * c.z + c.w * c.w;
#pragma unroll
  for (int off = 1; off < 64; off <<= 1) {
    s += __shfl_xor(s, off);
    sq += __shfl_xor(sq, off);
  }
  const float mean = s * (1.f / DD);
  const float var = sq * (1.f / DD) - mean * mean;
  const float inv = rsqrtf(var + 1e-5f);
  const float4 w0 = *(const float4*)(w + l * 8);
  const float4 w1 = *(const float4*)(w + l * 8 + 4);
  const float4 b0 = *(const float4*)(b + l * 8);
  const float4 b1 = *(const float4*)(b + l * 8 + 4);
  short8 o;
  o[0] = f2b((a.x - mean) * inv * w0.x + b0.x);
  o[1] = f2b((a.y - mean) * inv * w0.y + b0.y);
  o[2] = f2b((a.z - mean) * inv * w0.z + b0.z);
  o[3] = f2b((a.w - mean) * inv * w0.w + b0.w);
  o[4] = f2b((c.x - mean) * inv * w1.x + b1.x);
  o[5] = f2b((c.y - mean) * inv * w1.y + b1.y);
  o[6] = f2b((c.z - mean) * inv * w1.z + b1.z);
  o[7] = f2b((c.w - mean) * inv * w1.w + b1.w);
  *(short8*)(y + (size_t)row * DD + l * 8) = o;
}

// ---------------- bf16 MFMA GEMM (BM=128 or 64, BN=128) ----------------
// EPI: 0=+bias(opt); 1=gelu(+bias); 2=+bias(opt)+add1(f32); 3=+bias+add1(f32)+add2(bf16)
// OBF: 0=f32 out; 1=bf16 out; 2=f32 out + bf16 copy to C2
template<int EPI, int OBF, int BM>
__global__ __launch_bounds__(256) void gemm_bf16(
    const short* __restrict__ A, const short* __restrict__ BT,
    const float* __restrict__ bias, const float* __restrict__ add1,
    const short* __restrict__ add2, void* __restrict__ C,
    short* __restrict__ C2, int M, int N, int K)
{
  constexpr int MF = BM / 32;
  constexpr int CA = BM / 64;
  __shared__ __align__(16) short As[BM * 32];
  __shared__ __align__(16) short Bs[128 * 32];
  const int tid = threadIdx.x;
  const int wave = tid >> 6, lane = tid & 63;
  const int wr = wave >> 1, wc = wave & 1;
  const int bm = blockIdx.y * BM, bn = blockIdx.x * 128;

  const int l4r = lane >> 2;
  const int l4c = (lane & 3) * 8;

  const short* sA[CA]; const short* sB[2];
  int ldsA[CA], ldsB[2];
#pragma unroll
  for (int r = 0; r < CA; ++r) {
    const int chunk = r * 4 + wave;
    sA[r] = A + (size_t)(bm + chunk * 16 + l4r) * K + l4c;
    ldsA[r] = chunk * 1024;
  }
#pragma unroll
  for (int r = 0; r < 2; ++r) {
    const int chunk = r * 4 + wave;
    sB[r] = BT + (size_t)(bn + chunk * 16 + l4r) * K + l4c;
    ldsB[r] = chunk * 1024;
  }

  f32x4 acc[MF][4] = {};

  for (int k0 = 0; k0 < K; k0 += 32) {
#pragma unroll
    for (int r = 0; r < CA; ++r) {
      __builtin_amdgcn_global_load_lds(AS1(sA[r]), AS3((char*)As + ldsA[r]), 16, 0, 0);
      sA[r] += 32;
    }
#pragma unroll
    for (int r = 0; r < 2; ++r) {
      __builtin_amdgcn_global_load_lds(AS1(sB[r]), AS3((char*)Bs + ldsB[r]), 16, 0, 0);
      sB[r] += 32;
    }
    __syncthreads();
    short8 af[MF], bf[4];
#pragma unroll
    for (int m = 0; m < MF; ++m)
      af[m] = *(const short8*)&As[(wr * (BM / 2) + m * 16 + (lane & 15)) * 32 + (lane >> 4) * 8];
#pragma unroll
    for (int n = 0; n < 4; ++n)
      bf[n] = *(const short8*)&Bs[(wc * 64 + n * 16 + (lane & 15)) * 32 + (lane >> 4) * 8];
#pragma unroll
    for (int m = 0; m < MF; ++m)
#pragma unroll
      for (int n = 0; n < 4; ++n)
        acc[m][n] = __builtin_amdgcn_mfma_f32_16x16x32_bf16(af[m], bf[n], acc[m][n], 0, 0, 0);
    __syncthreads();
  }

#pragma unroll
  for (int m = 0; m < MF; ++m) {
#pragma unroll
    for (int n = 0; n < 4; ++n) {
      const int col = bn + wc * 64 + n * 16 + (lane & 15);
      const float bb = (EPI == 1 || EPI == 3) ? bias[col] : (bias ? bias[col] : 0.f);
#pragma unroll
      for (int r = 0; r < 4; ++r) {
        const int row = bm + wr * (BM / 2) + m * 16 + (lane >> 4) * 4 + r;
        const size_t idx = (size_t)row * N + col;
        float v = acc[m][n][r] + bb;
        if (EPI == 1) v = gelu_tanh(v);
        if (EPI == 2 || EPI == 3) v += add1[idx];
        if (EPI == 3) v += b2f(add2[idx]);
        if (OBF == 1) ((short*)C)[idx] = f2b(v);
        else {
          ((float*)C)[idx] = v;
          if (OBF == 2) C2[idx] = f2b(v);
        }
      }
    }
  }
}

// ---------------- Sliding-window attention, MFMA flash-style ----------------
__global__ __launch_bounds__(256) void swa_kernel(
    const float* __restrict__ qkv, short* __restrict__ out)
{
  __shared__ __align__(16) short ks[128 * 72];
  __shared__ __align__(16) short vt[64 * 136];
  __shared__ __align__(16) short ps[4][16 * 136];
  __shared__ float lsum[64];

  const int tid = threadIdx.x;
  const int w = tid >> 6, l = tid & 63;
  const int tile = blockIdx.x & 31;
  const int h = (blockIdx.x >> 5) & 7;
  const int b = blockIdx.x >> 8;
  const int s0 = tile * 64;
  const size_t base = (size_t)b * SS;

#pragma unroll
  for (int u = 0; u < 16; ++u) {
    const int id = u * 256 + tid;
    const int row = id >> 5, dp = id & 31;
    int jp = s0 - 32 + row;
    jp = min(max(jp, 0), SS - 1);
    const size_t g = (base + jp) * 1536 + h * 64 + dp * 2;
    const float2 kv = *(const float2*)&qkv[g + 512];
    const float2 vv = *(const float2*)&qkv[g + 1024];
    unsigned pk = ((unsigned)(unsigned short)f2b(kv.y) << 16) | (unsigned short)f2b(kv.x);
    *(unsigned*)&ks[row * 72 + dp * 2] = pk;
    vt[(dp * 2) * 136 + row] = f2b(vv.x);
    vt[(dp * 2 + 1) * 136 + row] = f2b(vv.y);
  }

  const int qi = w * 16 + (l & 15);
  short8 qf[2];
#pragma unroll
  for (int kf = 0; kf < 2; ++kf) {
    const float* qp = &qkv[(base + s0 + qi) * 1536 + h * 64 + kf * 32 + (l >> 4) * 8];
    const float4 a = *(const float4*)qp;
    const float4 c = *(const float4*)(qp + 4);
    short8 q8;
    q8[0] = f2b(a.x); q8[1] = f2b(a.y); q8[2] = f2b(a.z); q8[3] = f2b(a.w);
    q8[4] = f2b(c.x); q8[5] = f2b(c.y); q8[6] = f2b(c.z); q8[7] = f2b(c.w);
    qf[kf] = q8;
  }
  __syncthreads();

  f32x4 sa[8] = {};
#pragma unroll
  for (int mf = 0; mf < 8; ++mf)
#pragma unroll
    for (int kf = 0; kf < 2; ++kf) {
      const short8 af = *(const short8*)&ks[(mf * 16 + (l & 15)) * 72 + kf * 32 + (l >> 4) * 8];
      sa[mf] = __builtin_amdgcn_mfma_f32_16x16x32_bf16(af, qf[kf], sa[mf], 0, 0, 0);
    }

  float sv[8][4];
  float mx = -INFINITY;
#pragma unroll
  for (int mf = 0; mf < 8; ++mf)
#pragma unroll
    for (int r = 0; r < 4; ++r) {
      const int j = mf * 16 + (l >> 4) * 4 + r;
      const int jpos = s0 - 32 + j;
      const bool ok = (j >= qi) && (j <= qi + 64) && (jpos >= 0) && (jpos < SS);
      const float s = ok ? sa[mf][r] * 0.125f : -INFINITY;
      sv[mf][r] = s;
      mx = fmaxf(mx, s);
    }
  mx = fmaxf(mx, __shfl_xor(mx, 16));
  mx = fmaxf(mx, __shfl_xor(mx, 32));
  float ls = 0.f;
#pragma unroll
  for (int mf = 0; mf < 8; ++mf)
#pragma unroll
    for (int r = 0; r < 4; ++r) {
      const float p = __expf(sv[mf][r] - mx);
      sv[mf][r] = p;
      ls += p;
    }
  ls += __shfl_xor(ls, 16);
  ls += __shfl_xor(ls, 32);
  if (l < 16) lsum[w * 16 + l] = ls;

#pragma unroll
  for (int mf = 0; mf < 8; ++mf) {
    short4v p4;
    p4.x = f2b(sv[mf][0]); p4.y = f2b(sv[mf][1]);
    p4.z = f2b(sv[mf][2]); p4.w = f2b(sv[mf][3]);
    *(short4v*)&ps[w][(l & 15) * 136 + mf * 16 + (l >> 4) * 4] = p4;
  }

  f32x4 oa[4] = {};
#pragma unroll
  for (int kf = 0; kf < 4; ++kf) {
    const short8 pf = *(const short8*)&ps[w][(l & 15) * 136 + kf * 32 + (l >> 4) * 8];
#pragma unroll
    for (int nf = 0; nf < 4; ++nf) {
      const short8 vf = *(const short8*)&vt[(nf * 16 + (l & 15)) * 136 + kf * 32 + (l >> 4) * 8];
      oa[nf] = __builtin_amdgcn_mfma_f32_16x16x32_bf16(pf, vf, oa[nf], 0, 0, 0);
    }
  }

  float rl[4];
#pragma unroll
  for (int r = 0; r < 4; ++r) rl[r] = 1.f / lsum[w * 16 + (l >> 4) * 4 + r];
#pragma unroll
  for (int nf = 0; nf < 4; ++nf)
#pragma unroll
    for (int r = 0; r < 4; ++r) {
      const int q = (l >> 4) * 4 + r;
      const int d = nf * 16 + (l & 15);
      out[(base + s0 + w * 16 + q) * 512 + h * 64 + d] = f2b(oa[nf][r] * rl[r]);
    }
}

// ========== Neural memory, linear-scan formulation ==========
// grad_c = A_c M_{c-1} - B_c,  A_c = k^T k/64 (bf16, XOR-swizzled, symmetric),
// B_c = k^T v/64 (bf16, stored TRANSPOSED [e][d])

// ---- P1: per (chain, chunk) compute A_c, B_c via MFMA ----
__global__ __launch_bounds__(256) void mem_prep(
    const float* __restrict__ kb, const float* __restrict__ vb,
    short* __restrict__ Aq, short* __restrict__ Bq)
{
  __shared__ __align__(16) short kn[64 * 136];
  __shared__ __align__(16) char kT[128 * 128];
  __shared__ __align__(16) char vT[128 * 128];
  const int bid = blockIdx.x;
  const int chain = bid >> 5, c = bid & 31;
  const int b = chain >> 2, mh = chain & 3;
  const size_t rowbase = (size_t)(b * SS + c * 64);
  const int tid = threadIdx.x, w = tid >> 6, l = tid & 63;
  const int td = tid & 127, rh = tid >> 7;

#pragma unroll
  for (int pass = 0; pass < 2; ++pass) {
    const float* src = pass ? vb : kb;
    char* dT = pass ? vT : kT;
#pragma unroll
    for (int j = 0; j < 8; ++j) {
      const int i4 = tid + 256 * j;
      const int r = i4 >> 5, d4 = (i4 & 31) * 4;
      const float4 vv = *(const float4*)&src[(rowbase + r) * 1536 + mh * 128 + d4];
      short4v s4;
      s4.x = f2b(vv.x); s4.y = f2b(vv.y); s4.z = f2b(vv.z); s4.w = f2b(vv.w);
      *(short4v*)&kn[r * 136 + d4] = s4;
    }
    __syncthreads();
#pragma unroll
    for (int j = 0; j < 4; ++j) {
      const int r0 = rh * 8 + 16 * j;
      short8 g8;
#pragma unroll
      for (int t = 0; t < 8; ++t) g8[t] = kn[(r0 + t) * 136 + td];
      *(short8*)&dT[(td * 128 + r0 * 2) ^ ((td & 7) << 4)] = g8;
    }
    __syncthreads();
  }

  const int wr = w >> 1, wc = w & 1;
  // A = kT @ kT(BT)/64 — symmetric, so store transposed with short4 vectors,
  // swizzled: byte (dp*256 + d*2) ^ ((dp&7)<<4)
  {
    f32x4 acc[4][4] = {};
#pragma unroll
    for (int kf = 0; kf < 2; ++kf) {
      short8 af[4];
#pragma unroll
      for (int m = 0; m < 4; ++m) {
        const int d = wr * 64 + m * 16 + (l & 15);
        af[m] = *(const short8*)&kT[(d * 128 + kf * 64 + (l >> 4) * 16) ^ ((d & 7) << 4)];
      }
#pragma unroll
      for (int n = 0; n < 4; ++n) {
        const int dp = wc * 64 + n * 16 + (l & 15);
        const short8 bf = *(const short8*)&kT[(dp * 128 + kf * 64 + (l >> 4) * 16) ^ ((dp & 7) << 4)];
#pragma unroll
        for (int m = 0; m < 4; ++m)
          acc[m][n] = __builtin_amdgcn_mfma_f32_16x16x32_bf16(af[m], bf, acc[m][n], 0, 0, 0);
      }
    }
    char* Ad = (char*)(Aq + (size_t)bid * 16384);
#pragma unroll
    for (int m = 0; m < 4; ++m)
#pragma unroll
      for (int n = 0; n < 4; ++n) {
        const int dp = wc * 64 + n * 16 + (l & 15);
        const int d0 = wr * 64 + m * 16 + (l >> 4) * 4;
        short4v s4;
#pragma unroll
        for (int i = 0; i < 4; ++i) s4[i] = f2b(acc[m][n][i] * 0.015625f);
        *(short4v*)&Ad[(dp * 256 + d0 * 2) ^ ((dp & 7) << 4)] = s4;
      }
  }
  // B = kT @ vT(BT)/64 — store TRANSPOSED [e][d] with short4 vectors
  {
    f32x4 acc[4][4] = {};
#pragma unroll
    for (int kf = 0; kf < 2; ++kf) {
      short8 af[4];
#pragma unroll
      for (int m = 0; m < 4; ++m) {
        const int d = wr * 64 + m * 16 + (l & 15);
        af[m] = *(const short8*)&kT[(d * 128 + kf * 64 + (l >> 4) * 16) ^ ((d & 7) << 4)];
      }
#pragma unroll
      for (int n = 0; n < 4; ++n) {
        const int e = wc * 64 + n * 16 + (l & 15);
        const short8 bf = *(const short8*)&vT[(e * 128 + kf * 64 + (l >> 4) * 16) ^ ((e & 7) << 4)];
#pragma unroll
        for (int m = 0; m < 4; ++m)
          acc[m][n] = __builtin_amdgcn_mfma_f32_16x16x32_bf16(af[m], bf, acc[m][n], 0, 0, 0);
      }
    }
    short* Bd = Bq + (size_t)bid * 16384;
#pragma unroll
    for (int m = 0; m < 4; ++m)
#pragma unroll
      for (int n = 0; n < 4; ++n) {
        const int e = wc * 64 + n * 16 + (l & 15);
        const int d0 = wr * 64 + m * 16 + (l >> 4) * 4;
        short4v s4;
#pragma unroll
        for (int i = 0; i < 4; ++i) s4[i] = f2b(acc[m][n][i] * 0.015625f);
        *(short4v*)&Bd[e * 128 + d0] = s4;
      }
  }
}

// ---- P2: serial scan, software-pipelined ----
__global__ __launch_bounds__(256) void mem_scan2(
    const short* __restrict__ Aq, const short* __restrict__ Bq,
    short* __restrict__ MTg)
{
  __shared__ __align__(16) char AcL[2][32768];
  __shared__ __align__(16) char MT[2][8192];
  const int bid = blockIdx.x;
  const int chain = bid >> 2, ch = bid & 3;
  const int tid = threadIdx.x;
  const int w = tid >> 6, l = tid & 63;
  const int wr = w >> 1, wc = w & 1;
  const int e = wc * 16 + (l & 15);

  {
    const short8 z = {0, 0, 0, 0, 0, 0, 0, 0};
    for (int i = tid; i < 1024; i += 256)
      *(short8*)((char*)MT + i * 16) = z;
  }
  float Mreg[16] = {}, Momreg[16] = {};

  const short* Ab = Aq + (size_t)chain * 32 * 16384;
  const short* Bb = Bq + (size_t)chain * 32 * 16384;
  short* MTb = MTg + (size_t)chain * 32 * 16384 + (size_t)ch * 32 * 128;
  const int se = tid & 31, sdb = tid >> 5;

  // prologue: stage chunk 0
#pragma unroll
  for (int j = 0; j < 8; ++j) {
    const int byte = tid * 16 + j * 4096;
    __builtin_amdgcn_global_load_lds(AS1((const char*)Ab + byte),
                                     AS3(AcL[0] + byte), 16, 0, 0);
  }
  __syncthreads();

  int buf = 0, cur = 0;
  for (int c = 0; c < NCC; ++c) {
    // issue prefetch of A_{c+1}
    if (c + 1 < NCC) {
      const char* src = (const char*)(Ab + (size_t)(c + 1) * 16384);
#pragma unroll
      for (int j = 0; j < 8; ++j) {
        const int byte = tid * 16 + j * 4096;
        __builtin_amdgcn_global_load_lds(AS1(src + byte),
                                         AS3(AcL[buf ^ 1] + byte), 16, 0, 0);
      }
    }
    // B_c -> registers: transposed layout -> 4 contiguous 8B loads
    short4v bld[4];
    const short* Bc = Bb + (size_t)c * 16384;
#pragma unroll
    for (int m = 0; m < 4; ++m)
      bld[m] = *(const short4v*)&Bc[(ch * 32 + e) * 128 + wr * 64 + m * 16 + (l >> 4) * 4];
    // snapshot M^T_{c-1} -> global (natural layout)
#pragma unroll
    for (int j = 0; j < 2; ++j) {
      const int db = sdb + 8 * j;
      const short8 vv = *(const short8*)&MT[cur][(se * 256 + db * 16) ^ ((se & 7) << 4)];
      *(short8*)&MTb[(size_t)c * 16384 + se * 128 + db * 8] = vv;
    }
    // G = A_c @ M
    f32x4 acc[4] = {};
#pragma unroll
    for (int kf = 0; kf < 4; ++kf) {
      const short8 bf = *(const short8*)&MT[cur][(e * 256 + kf * 64 + (l >> 4) * 16) ^ ((e & 7) << 4)];
#pragma unroll
      for (int m = 0; m < 4; ++m) {
        const int d = wr * 64 + m * 16 + (l & 15);
        const short8 af = *(const short8*)&AcL[buf][(d * 256 + kf * 64 + (l >> 4) * 16) ^ ((d & 7) << 4)];
        acc[m] = __builtin_amdgcn_mfma_f32_16x16x32_bf16(af, bf, acc[m], 0, 0, 0);
      }
    }
    // update M, Mom; write M^T_c into the other MT buffer
#pragma unroll
    for (int m = 0; m < 4; ++m)
#pragma unroll
      for (int i = 0; i < 4; ++i) {
        const int d = wr * 64 + m * 16 + (l >> 4) * 4 + i;
        const int idx = m * 4 + i;
        const float g = acc[m][i] - b2f(bld[m][i]);
        Momreg[idx] = 0.9f * Momreg[idx] - 0.1f * g;
        Mreg[idx] = 0.99f * Mreg[idx] + Momreg[idx];
        *(short*)&MT[cur ^ 1][(e * 256 + d * 2) ^ ((e & 7) << 4)] = f2b(Mreg[idx]);
      }
    __syncthreads();
    buf ^= 1; cur ^= 1;
  }
}

// ---- P3: out_c = q_c @ M_{c-1} ----
__global__ __launch_bounds__(256) void mem_out(
    const float* __restrict__ qb, const short* __restrict__ MTg,
    short* __restrict__ mem)
{
  const int bid = blockIdx.x;
  const int chain = bid >> 5, c = bid & 31;
  const int b = chain >> 2, mh = chain & 3;
  const size_t rowbase = (size_t)(b * SS + c * 64);
  const int tid = threadIdx.x, w = tid >> 6, l = tid & 63;
  const int wr = w >> 1, wc = w & 1;
  const short* MTc = MTg + (size_t)chain * 32 * 16384 + (size_t)c * 16384;

  f32x4 acc[2][4] = {};
#pragma unroll
  for (int kf = 0; kf < 4; ++kf) {
    short8 af[2];
#pragma unroll
    for (int m = 0; m < 2; ++m) {
      const int r = wr * 32 + m * 16 + (l & 15);
      const float* qp = &qb[(rowbase + r) * 1536 + mh * 128 + kf * 32 + (l >> 4) * 8];
      const float4 a = *(const float4*)qp;
      const float4 cc = *(const float4*)(qp + 4);
      short8 q8;
      q8[0] = f2b(a.x); q8[1] = f2b(a.y); q8[2] = f2b(a.z); q8[3] = f2b(a.w);
      q8[4] = f2b(cc.x); q8[5] = f2b(cc.y); q8[6] = f2b(cc.z); q8[7] = f2b(cc.w);
      af[m] = q8;
    }
#pragma unroll
    for (int n = 0; n < 4; ++n) {
      const int e = wc * 64 + n * 16 + (l & 15);
      const short8 bf = *(const short8*)&MTc[e * 128 + kf * 32 + (l >> 4) * 8];
#pragma unroll
      for (int m = 0; m < 2; ++m)
        acc[m][n] = __builtin_amdgcn_mfma_f32_16x16x32_bf16(af[m], bf, acc[m][n], 0, 0, 0);
    }
  }
#pragma unroll
  for (int m = 0; m < 2; ++m)
#pragma unroll
    for (int n = 0; n < 4; ++n)
#pragma unroll
      for (int i = 0; i < 4; ++i) {
        const int r = wr * 32 + m * 16 + (l >> 4) * 4 + i;
        const int e = wc * 64 + n * 16 + (l & 15);
        mem[(rowbase + r) * 512 + mh * 128 + e] = f2b(acc[m][n][i]);
      }
}

// ---------------- merged weight transpose+convert (all matrices, 1 launch) ---
struct TcvtJob { const float* src; short* dst; int K; int N; int blks; };
struct TcvtArgs { TcvtJob j[10]; };

__global__ __launch_bounds__(256) void tcvt_all(TcvtArgs a)
{
  int bid = blockIdx.x;
  const float* src = nullptr; short* dst = nullptr; int K = 0, N = 0;
#pragma unroll
  for (int i = 0; i < 10; ++i) {
    if (!src) {
      if (bid < a.j[i].blks) { src = a.j[i].src; dst = a.j[i].dst; K = a.j[i].K; N = a.j[i].N; }
      else bid -= a.j[i].blks;
    }
  }
  const int nt = N >> 5, kt = K >> 5;
  const int z = bid / (nt * kt);
  const int rem = bid % (nt * kt);
  const int k0 = (rem / nt) * 32, n0 = (rem % nt) * 32;
  const size_t zoff = (size_t)z * K * N;
  src += zoff; dst += zoff;

  __shared__ float t[32][33];
  const int tx = threadIdx.x & 31, ty = threadIdx.x >> 5;
#pragma unroll
  for (int i = 0; i < 4; ++i)
    t[ty + i * 8][tx] = src[(size_t)(k0 + ty + i * 8) * N + n0 + tx];
  __syncthreads();
#pragma unroll
  for (int i = 0; i < 4; ++i)
    dst[(size_t)(n0 + ty + i * 8) * K + k0 + tx] = f2b(t[tx][ty + i * 8]);
}

// ---------------- persistent path: 1 block, 512 threads -------------------
__global__ __launch_bounds__(512) void persist_kernel(
    const float* __restrict__ pm, const float* __restrict__ pmw,
    const float* __restrict__ pmb, const float* __restrict__ fw2,
    const float* __restrict__ fb, float* __restrict__ t2)
{
  __shared__ float t0[512], t1[512];
  const int e = threadIdx.x;
  float s = 0.f;
#pragma unroll
  for (int t = 0; t < 16; ++t) s += pm[t * 512 + e];
  t0[e] = s * (1.f / 16.f);
  __syncthreads();
  float p = pmb[e];
  for (int d = 0; d < 512; ++d) p += t0[d] * pmw[d * 512 + e];
  t1[e] = p;
  __syncthreads();
  float q = fb[e];
  for (int d = 0; d < 512; ++d) q += t1[d] * fw2[d * 512 + e];
  t2[e] = q;
}

// ---------------- host side ----------------
extern "C" void kernel_launch(void* const* d_in, const int* in_sizes, int n_in,
                              void* d_out, int out_size, void* d_ws, size_t ws_size,
                              hipStream_t stream)
{
  const float* x         = (const float*)d_in[0];
  const float* n1w       = (const float*)d_in[1];
  const float* n1b       = (const float*)d_in[2];
  const float* qkvw      = (const float*)d_in[3];
  const float* qkvb      = (const float*)d_in[4];
  const float* projw     = (const float*)d_in[5];
  const float* projb     = (const float*)d_in[6];
  const float* n2w       = (const float*)d_in[7];
  const float* n2b       = (const float*)d_in[8];
  const float* fc1w      = (const float*)d_in[9];
  const float* fc1b      = (const float*)d_in[10];
  const float* fc2w      = (const float*)d_in[11];
  const float* fc2b      = (const float*)d_in[12];
  const float* mlnw      = (const float*)d_in[13];
  const float* mlnb      = (const float*)d_in[14];
  const float* mwq       = (const float*)d_in[15];
  const float* mwk       = (const float*)d_in[16];
  const float* mwv       = (const float*)d_in[17];
  const float* mprojw    = (const float*)d_in[18];
  const float* mprojb    = (const float*)d_in[19];
  const float* pm_tokens = (const float*)d_in[20];
  const float* pmw       = (const float*)d_in[21];
  const float* pmb       = (const float*)d_in[22];
  const float* fw        = (const float*)d_in[23];
  const float* fb        = (const float*)d_in[24];
  float* out = (float*)d_out;

  char* p = (char*)d_ws;
  auto alloc = [&](size_t bytes) {
    char* r = p;
    p += (bytes + 255) & ~(size_t)255;
    return r;
  };
  short* qkvwT  = (short*)alloc(6ull * 1536 * 512 * 2);
  short* projwT = (short*)alloc(6ull * 512 * 512 * 2);
  short* fc1wT  = (short*)alloc(6ull * 2048 * 512 * 2);
  short* fc2wT  = (short*)alloc(6ull * 512 * 2048 * 2);
  short* mqkvT  = (short*)alloc(3ull * 512 * 512 * 2);
  short* mprojT = (short*)alloc(512ull * 512 * 2);
  short* fw0T   = (short*)alloc(512ull * 512 * 2);
  short* fw1T   = (short*)alloc(512ull * 512 * 2);
  float* bigf = (float*)alloc((size_t)BS * 1536 * 4);
  float* hbuf = (float*)alloc((size_t)BS * 512 * 4);
  float* t2   = (float*)alloc(512 * 4);
  short* actA  = (short*)alloc((size_t)BS * 512 * 2);
  short* ln0b  = (short*)alloc((size_t)BS * 512 * 2);
  short* attnb = (short*)alloc((size_t)BS * 512 * 2);
  short* ff1b  = (short*)alloc((size_t)BS * 2048 * 2);
  short* ltb   = (short*)alloc((size_t)BS * 512 * 2);
  short* Aq    = (short*)alloc(256ull * 16384 * 2);
  short* Bq    = (short*)alloc(256ull * 16384 * 2);
  short* MTg   = (short*)alloc(256ull * 16384 * 2);

  // ---- all weight transposes in one launch ----
  TcvtArgs ta;
  ta.j[0] = {qkvw,  qkvwT,  512, 1536, 48 * 16 * 6};
  ta.j[1] = {projw, projwT, 512, 512,  16 * 16 * 6};
  ta.j[2] = {fc1w,  fc1wT,  512, 2048, 64 * 16 * 6};
  ta.j[3] = {fc2w,  fc2wT,  2048, 512, 16 * 64 * 6};
  ta.j[4] = {mwq, mqkvT,                512, 512, 256};
  ta.j[5] = {mwk, mqkvT + 512 * 512,    512, 512, 256};
  ta.j[6] = {mwv, mqkvT + 2 * 512 * 512, 512, 512, 256};
  ta.j[7] = {mprojw, mprojT, 512, 512, 256};
  ta.j[8] = {fw, fw0T, 512, 512, 256};
  ta.j[9] = {fw + 512 * 512, fw1T, 512, 512, 256};
  int total_blks = 0;
  for (int i = 0; i < 10; ++i) total_blks += ta.j[i].blks;
  tcvt_all<<<total_blks, 256, 0, stream>>>(ta);

  persist_kernel<<<1, 512, 0, stream>>>(pm_tokens, pmw, pmb,
                                        fw + (size_t)1024 * 512, fb, t2);

  // ---- neural memory path ----
  ln_kernel<<<BS / 4, 256, 0, stream>>>(x, mlnw, mlnb, actA);
  ln_kernel<<<BS / 4, 256, 0, stream>>>(x, n1w, n1b, ln0b);     // layer-0 ln1
  gemm_bf16<0, 0, 128><<<dim3(12, 32), 256, 0, stream>>>(
      actA, mqkvT, nullptr, nullptr, nullptr, bigf, nullptr, BS, 1536, 512);
  mem_prep<<<256, 256, 0, stream>>>(bigf + 512, bigf + 1024, Aq, Bq);
  mem_scan2<<<32, 256, 0, stream>>>(Aq, Bq, MTg);
  mem_out<<<256, 256, 0, stream>>>(bigf, MTg, ff1b);
  gemm_bf16<2, 1, 64><<<dim3(4, 64), 256, 0, stream>>>(
      ff1b, mprojT, mprojb, x, nullptr, ltb, nullptr, BS, 512, 512);

  // ---- layer stack (no memcpy: layer-0 residual comes straight from x) ----
  for (int l = 0; l < LL; ++l) {
    const short* lnin = (l == 0) ? ln0b : actA;
    if (l > 0)
      ln_kernel<<<BS / 4, 256, 0, stream>>>(hbuf, n1w + l * 512, n1b + l * 512, actA);
    gemm_bf16<0, 0, 128><<<dim3(12, 32), 256, 0, stream>>>(
        lnin, qkvwT + (size_t)l * 1536 * 512, qkvb + l * 1536,
        nullptr, nullptr, bigf, nullptr, BS, 1536, 512);
    swa_kernel<<<512, 256, 0, stream>>>(bigf, attnb);
    gemm_bf16<2, 0, 64><<<dim3(4, 64), 256, 0, stream>>>(
        attnb, projwT + (size_t)l * 512 * 512, projb + l * 512,
        (l == 0) ? x : hbuf, nullptr, hbuf, nullptr, BS, 512, 512);
    ln_kernel<<<BS / 4, 256, 0, stream>>>(hbuf, n2w + l * 512, n2b + l * 512, actA);
    gemm_bf16<1, 1, 128><<<dim3(16, 32), 256, 0, stream>>>(
        actA, fc1wT + (size_t)l * 2048 * 512, fc1b + l * 2048,
        nullptr, nullptr, ff1b, nullptr, BS, 2048, 512);
    if (l < LL - 1)
      gemm_bf16<3, 0, 64><<<dim3(4, 64), 256, 0, stream>>>(
          ff1b, fc2wT + (size_t)l * 512 * 2048, fc2b + l * 512,
          hbuf, actA, hbuf, nullptr, BS, 512, 2048);
    else
      gemm_bf16<3, 2, 64><<<dim3(4, 64), 256, 0, stream>>>(
          ff1b, fc2wT + (size_t)l * 512 * 2048, fc2b + l * 512,
          hbuf, actA, hbuf, actA, BS, 512, 2048);   // also emit bf16 h
  }

  // ---- fusion ----
  gemm_bf16<0, 0, 64><<<dim3(4, 64), 256, 0, stream>>>(
      actA, fw0T, t2, nullptr, nullptr, out, nullptr, BS, 512, 512);
  gemm_bf16<2, 0, 64><<<dim3(4, 64), 256, 0, stream>>>(
      ltb, fw1T, nullptr, out, nullptr, out, nullptr, BS, 512, 512);
}

// Round 8
// 834.670 us; speedup vs baseline: 4.6157x; 1.0200x over previous
//
#include <hip/hip_runtime.h>
#include <math.h>

// Problem constants
#define BB 2
#define SS 2048
#define DD 512
#define HH 8
#define LL 6
#define WW 64
#define CHH 64
#define NCC 32
#define BS (BB*SS)   // 4096 rows

typedef __attribute__((ext_vector_type(8))) short short8;
typedef __attribute__((ext_vector_type(4))) short short4v;
typedef __attribute__((ext_vector_type(4))) float f32x4;

__device__ inline float b2f(short s) {
  unsigned u = ((unsigned)(unsigned short)s) << 16;
  float f; __builtin_memcpy(&f, &u, 4); return f;
}
__device__ inline short f2b(float f) {
  unsigned u; __builtin_memcpy(&u, &f, 4);
  unsigned r = (u + 0x7FFFu + ((u >> 16) & 1u)) >> 16;
  return (short)r;
}
__device__ inline float gelu_tanh(float v) {
  float u = 0.7978845608f * (v + 0.044715f * v * v * v);
  u = fminf(fmaxf(u, -20.f), 20.f);
  float e2 = __expf(2.f * u);
  return 0.5f * v * (1.f + (e2 - 1.f) / (e2 + 1.f));
}

#define AS1(p) ((const __attribute__((address_space(1))) void*)(p))
#define AS3(p) ((__attribute__((address_space(3))) void*)(p))

// ---------------- LayerNorm: wave-per-row, 4 rows/block ----------------
__global__ __launch_bounds__(256) void ln_kernel(
    const float* __restrict__ x, const float* __restrict__ w,
    const float* __restrict__ b, short* __restrict__ y)
{
  const int row = blockIdx.x * 4 + (threadIdx.x >> 6);
  const int l = threadIdx.x & 63;
  const float* xr = x + (size_t)row * DD + l * 8;
  const float4 a = *(const float4*)xr;
  const float4 c = *(const float4*)(xr + 4);
  float s = a.x + a.y + a.z + a.w + c.x + c.y + c.z + c.w;
  float sq = a.x * a.x + a.y * a.y + a.z * a.z + a.w * a.w
           + c.x * c.x + c.y * c.y + c.z * c.z + c.w * c.w;
#pragma unroll
  for (int off = 1; off < 64; off <<= 1) {
    s += __shfl_xor(s, off);
    sq += __shfl_xor(sq, off);
  }
  const float mean = s * (1.f / DD);
  const float var = sq * (1.f / DD) - mean * mean;
  const float inv = rsqrtf(var + 1e-5f);
  const float4 w0 = *(const float4*)(w + l * 8);
  const float4 w1 = *(const float4*)(w + l * 8 + 4);
  const float4 b0 = *(const float4*)(b + l * 8);
  const float4 b1 = *(const float4*)(b + l * 8 + 4);
  short8 o;
  o[0] = f2b((a.x - mean) * inv * w0.x + b0.x);
  o[1] = f2b((a.y - mean) * inv * w0.y + b0.y);
  o[2] = f2b((a.z - mean) * inv * w0.z + b0.z);
  o[3] = f2b((a.w - mean) * inv * w0.w + b0.w);
  o[4] = f2b((c.x - mean) * inv * w1.x + b1.x);
  o[5] = f2b((c.y - mean) * inv * w1.y + b1.y);
  o[6] = f2b((c.z - mean) * inv * w1.z + b1.z);
  o[7] = f2b((c.w - mean) * inv * w1.w + b1.w);
  *(short8*)(y + (size_t)row * DD + l * 8) = o;
}

// ---------------- bf16 MFMA GEMM (BM=128 or 64, BN=128) ----------------
// EPI: 0=+bias(opt); 1=gelu(+bias); 2=+bias(opt)+add1(f32); 3=+bias+add1(f32)+add2(bf16)
// OBF: 0=f32 out (stride N); 1=bf16 out (stride NS)
template<int EPI, int OBF, int BM>
__global__ __launch_bounds__(256) void gemm_bf16(
    const short* __restrict__ A, const short* __restrict__ BT,
    const float* __restrict__ bias, const float* __restrict__ add1,
    const short* __restrict__ add2, void* __restrict__ C,
    int M, int N, int K, int NS)
{
  constexpr int MF = BM / 32;
  constexpr int CA = BM / 64;
  __shared__ __align__(16) short As[BM * 32];
  __shared__ __align__(16) short Bs[128 * 32];
  const int tid = threadIdx.x;
  const int wave = tid >> 6, lane = tid & 63;
  const int wr = wave >> 1, wc = wave & 1;
  const int bm = blockIdx.y * BM, bn = blockIdx.x * 128;

  const int l4r = lane >> 2;
  const int l4c = (lane & 3) * 8;

  const short* sA[CA]; const short* sB[2];
  int ldsA[CA], ldsB[2];
#pragma unroll
  for (int r = 0; r < CA; ++r) {
    const int chunk = r * 4 + wave;
    sA[r] = A + (size_t)(bm + chunk * 16 + l4r) * K + l4c;
    ldsA[r] = chunk * 1024;
  }
#pragma unroll
  for (int r = 0; r < 2; ++r) {
    const int chunk = r * 4 + wave;
    sB[r] = BT + (size_t)(bn + chunk * 16 + l4r) * K + l4c;
    ldsB[r] = chunk * 1024;
  }

  f32x4 acc[MF][4] = {};

  for (int k0 = 0; k0 < K; k0 += 32) {
#pragma unroll
    for (int r = 0; r < CA; ++r) {
      __builtin_amdgcn_global_load_lds(AS1(sA[r]), AS3((char*)As + ldsA[r]), 16, 0, 0);
      sA[r] += 32;
    }
#pragma unroll
    for (int r = 0; r < 2; ++r) {
      __builtin_amdgcn_global_load_lds(AS1(sB[r]), AS3((char*)Bs + ldsB[r]), 16, 0, 0);
      sB[r] += 32;
    }
    __syncthreads();
    short8 af[MF], bf[4];
#pragma unroll
    for (int m = 0; m < MF; ++m)
      af[m] = *(const short8*)&As[(wr * (BM / 2) + m * 16 + (lane & 15)) * 32 + (lane >> 4) * 8];
#pragma unroll
    for (int n = 0; n < 4; ++n)
      bf[n] = *(const short8*)&Bs[(wc * 64 + n * 16 + (lane & 15)) * 32 + (lane >> 4) * 8];
#pragma unroll
    for (int m = 0; m < MF; ++m)
#pragma unroll
      for (int n = 0; n < 4; ++n)
        acc[m][n] = __builtin_amdgcn_mfma_f32_16x16x32_bf16(af[m], bf[n], acc[m][n], 0, 0, 0);
    __syncthreads();
  }

#pragma unroll
  for (int m = 0; m < MF; ++m) {
#pragma unroll
    for (int n = 0; n < 4; ++n) {
      const int col = bn + wc * 64 + n * 16 + (lane & 15);
      const float bb = (EPI == 1 || EPI == 3) ? bias[col] : (bias ? bias[col] : 0.f);
#pragma unroll
      for (int r = 0; r < 4; ++r) {
        const int row = bm + wr * (BM / 2) + m * 16 + (lane >> 4) * 4 + r;
        const size_t idx = (size_t)row * N + col;
        float v = acc[m][n][r] + bb;
        if (EPI == 1) v = gelu_tanh(v);
        if (EPI == 2 || EPI == 3) v += add1[idx];
        if (EPI == 3) v += b2f(add2[idx]);
        if (OBF == 1) ((short*)C)[(size_t)row * NS + col] = f2b(v);
        else ((float*)C)[idx] = v;
      }
    }
  }
}

// ---------------- Sliding-window attention (bf16 qkv in, bf16 out) ----------
__global__ __launch_bounds__(256) void swa_kernel(
    const unsigned short* __restrict__ qkv, short* __restrict__ out)
{
  __shared__ __align__(16) short ks[128 * 72];
  __shared__ __align__(16) short vt[64 * 136];
  __shared__ __align__(16) short ps[4][16 * 136];
  __shared__ float lsum[64];

  const int tid = threadIdx.x;
  const int w = tid >> 6, l = tid & 63;
  const int tile = blockIdx.x & 31;
  const int h = (blockIdx.x >> 5) & 7;
  const int b = blockIdx.x >> 8;
  const int s0 = tile * 64;
  const size_t base = (size_t)b * SS;

#pragma unroll
  for (int u = 0; u < 16; ++u) {
    const int id = u * 256 + tid;
    const int row = id >> 5, dp = id & 31;
    int jp = s0 - 32 + row;
    jp = min(max(jp, 0), SS - 1);
    const size_t g = (base + jp) * 1536 + h * 64 + dp * 2;
    *(unsigned*)&ks[row * 72 + dp * 2] = *(const unsigned*)&qkv[g + 512];
    const unsigned vv = *(const unsigned*)&qkv[g + 1024];
    vt[(dp * 2) * 136 + row] = (short)(vv & 0xFFFF);
    vt[(dp * 2 + 1) * 136 + row] = (short)(vv >> 16);
  }

  const int qi = w * 16 + (l & 15);
  short8 qf[2];
#pragma unroll
  for (int kf = 0; kf < 2; ++kf)
    qf[kf] = *(const short8*)&qkv[(base + s0 + qi) * 1536 + h * 64 + kf * 32 + (l >> 4) * 8];
  __syncthreads();

  f32x4 sa[8] = {};
#pragma unroll
  for (int mf = 0; mf < 8; ++mf)
#pragma unroll
    for (int kf = 0; kf < 2; ++kf) {
      const short8 af = *(const short8*)&ks[(mf * 16 + (l & 15)) * 72 + kf * 32 + (l >> 4) * 8];
      sa[mf] = __builtin_amdgcn_mfma_f32_16x16x32_bf16(af, qf[kf], sa[mf], 0, 0, 0);
    }

  float sv[8][4];
  float mx = -INFINITY;
#pragma unroll
  for (int mf = 0; mf < 8; ++mf)
#pragma unroll
    for (int r = 0; r < 4; ++r) {
      const int j = mf * 16 + (l >> 4) * 4 + r;
      const int jpos = s0 - 32 + j;
      const bool ok = (j >= qi) && (j <= qi + 64) && (jpos >= 0) && (jpos < SS);
      const float s = ok ? sa[mf][r] * 0.125f : -INFINITY;
      sv[mf][r] = s;
      mx = fmaxf(mx, s);
    }
  mx = fmaxf(mx, __shfl_xor(mx, 16));
  mx = fmaxf(mx, __shfl_xor(mx, 32));
  float ls = 0.f;
#pragma unroll
  for (int mf = 0; mf < 8; ++mf)
#pragma unroll
    for (int r = 0; r < 4; ++r) {
      const float p = __expf(sv[mf][r] - mx);
      sv[mf][r] = p;
      ls += p;
    }
  ls += __shfl_xor(ls, 16);
  ls += __shfl_xor(ls, 32);
  if (l < 16) lsum[w * 16 + l] = ls;

#pragma unroll
  for (int mf = 0; mf < 8; ++mf) {
    short4v p4;
    p4.x = f2b(sv[mf][0]); p4.y = f2b(sv[mf][1]);
    p4.z = f2b(sv[mf][2]); p4.w = f2b(sv[mf][3]);
    *(short4v*)&ps[w][(l & 15) * 136 + mf * 16 + (l >> 4) * 4] = p4;
  }

  f32x4 oa[4] = {};
#pragma unroll
  for (int kf = 0; kf < 4; ++kf) {
    const short8 pf = *(const short8*)&ps[w][(l & 15) * 136 + kf * 32 + (l >> 4) * 8];
#pragma unroll
    for (int nf = 0; nf < 4; ++nf) {
      const short8 vf = *(const short8*)&vt[(nf * 16 + (l & 15)) * 136 + kf * 32 + (l >> 4) * 8];
      oa[nf] = __builtin_amdgcn_mfma_f32_16x16x32_bf16(pf, vf, oa[nf], 0, 0, 0);
    }
  }

  float rl[4];
#pragma unroll
  for (int r = 0; r < 4; ++r) rl[r] = 1.f / lsum[w * 16 + (l >> 4) * 4 + r];
#pragma unroll
  for (int nf = 0; nf < 4; ++nf)
#pragma unroll
    for (int r = 0; r < 4; ++r) {
      const int q = (l >> 4) * 4 + r;
      const int d = nf * 16 + (l & 15);
      out[(base + s0 + w * 16 + q) * 512 + h * 64 + d] = f2b(oa[nf][r] * rl[r]);
    }
}

// ========== Neural memory, linear-scan formulation ==========
// grad_c = A_c M_{c-1} - B_c,  A_c = k^T k/64 (bf16, XOR-swizzled, via symmetry),
// B_c = k^T v/64 (bf16, stored TRANSPOSED [e][d])

// ---- P1: per (chain, chunk) compute A_c, B_c via MFMA (bf16 k,v inputs) ----
__global__ __launch_bounds__(256) void mem_prep(
    const short* __restrict__ kb, const short* __restrict__ vb,
    short* __restrict__ Aq, short* __restrict__ Bq)
{
  __shared__ __align__(16) short kn[64 * 136];
  __shared__ __align__(16) char kT[128 * 128];
  __shared__ __align__(16) char vT[128 * 128];
  const int bid = blockIdx.x;
  const int chain = bid >> 5, c = bid & 31;
  const int b = chain >> 2, mh = chain & 3;
  const size_t rowbase = (size_t)(b * SS + c * 64);
  const int tid = threadIdx.x, w = tid >> 6, l = tid & 63;
  const int td = tid & 127, rh = tid >> 7;

#pragma unroll
  for (int pass = 0; pass < 2; ++pass) {
    const short* src = pass ? vb : kb;
    char* dT = pass ? vT : kT;
#pragma unroll
    for (int j = 0; j < 4; ++j) {
      const int i4 = tid + 256 * j;
      const int r = i4 >> 4, d8 = (i4 & 15) * 8;
      *(short8*)&kn[r * 136 + d8] = *(const short8*)&src[(rowbase + r) * 1536 + mh * 128 + d8];
    }
    __syncthreads();
#pragma unroll
    for (int j = 0; j < 4; ++j) {
      const int r0 = rh * 8 + 16 * j;
      short8 g8;
#pragma unroll
      for (int t = 0; t < 8; ++t) g8[t] = kn[(r0 + t) * 136 + td];
      *(short8*)&dT[(td * 128 + r0 * 2) ^ ((td & 7) << 4)] = g8;
    }
    __syncthreads();
  }

  const int wr = w >> 1, wc = w & 1;
  // A = kT @ kT(BT)/64 — symmetric; store transposed with short4 vectors,
  // swizzled: byte (dp*256 + d*2) ^ ((dp&7)<<4)
  {
    f32x4 acc[4][4] = {};
#pragma unroll
    for (int kf = 0; kf < 2; ++kf) {
      short8 af[4];
#pragma unroll
      for (int m = 0; m < 4; ++m) {
        const int d = wr * 64 + m * 16 + (l & 15);
        af[m] = *(const short8*)&kT[(d * 128 + kf * 64 + (l >> 4) * 16) ^ ((d & 7) << 4)];
      }
#pragma unroll
      for (int n = 0; n < 4; ++n) {
        const int dp = wc * 64 + n * 16 + (l & 15);
        const short8 bf = *(const short8*)&kT[(dp * 128 + kf * 64 + (l >> 4) * 16) ^ ((dp & 7) << 4)];
#pragma unroll
        for (int m = 0; m < 4; ++m)
          acc[m][n] = __builtin_amdgcn_mfma_f32_16x16x32_bf16(af[m], bf, acc[m][n], 0, 0, 0);
      }
    }
    char* Ad = (char*)(Aq + (size_t)bid * 16384);
#pragma unroll
    for (int m = 0; m < 4; ++m)
#pragma unroll
      for (int n = 0; n < 4; ++n) {
        const int dp = wc * 64 + n * 16 + (l & 15);
        const int d0 = wr * 64 + m * 16 + (l >> 4) * 4;
        short4v s4;
#pragma unroll
        for (int i = 0; i < 4; ++i) s4[i] = f2b(acc[m][n][i] * 0.015625f);
        *(short4v*)&Ad[(dp * 256 + d0 * 2) ^ ((dp & 7) << 4)] = s4;
      }
  }
  // B = kT @ vT(BT)/64 — store TRANSPOSED [e][d] with short4 vectors
  {
    f32x4 acc[4][4] = {};
#pragma unroll
    for (int kf = 0; kf < 2; ++kf) {
      short8 af[4];
#pragma unroll
      for (int m = 0; m < 4; ++m) {
        const int d = wr * 64 + m * 16 + (l & 15);
        af[m] = *(const short8*)&kT[(d * 128 + kf * 64 + (l >> 4) * 16) ^ ((d & 7) << 4)];
      }
#pragma unroll
      for (int n = 0; n < 4; ++n) {
        const int e = wc * 64 + n * 16 + (l & 15);
        const short8 bf = *(const short8*)&vT[(e * 128 + kf * 64 + (l >> 4) * 16) ^ ((e & 7) << 4)];
#pragma unroll
        for (int m = 0; m < 4; ++m)
          acc[m][n] = __builtin_amdgcn_mfma_f32_16x16x32_bf16(af[m], bf, acc[m][n], 0, 0, 0);
      }
    }
    short* Bd = Bq + (size_t)bid * 16384;
#pragma unroll
    for (int m = 0; m < 4; ++m)
#pragma unroll
      for (int n = 0; n < 4; ++n) {
        const int e = wc * 64 + n * 16 + (l & 15);
        const int d0 = wr * 64 + m * 16 + (l >> 4) * 4;
        short4v s4;
#pragma unroll
        for (int i = 0; i < 4; ++i) s4[i] = f2b(acc[m][n][i] * 0.015625f);
        *(short4v*)&Bd[e * 128 + d0] = s4;
      }
  }
}

// ---- P2: serial scan, software-pipelined; M_c written straight to global ----
__global__ __launch_bounds__(256) void mem_scan2(
    const short* __restrict__ Aq, const short* __restrict__ Bq,
    short* __restrict__ MTg)
{
  __shared__ __align__(16) char AcL[2][32768];
  __shared__ __align__(16) char MT[2][8192];
  const int bid = blockIdx.x;
  const int chain = bid >> 2, ch = bid & 3;
  const int tid = threadIdx.x;
  const int w = tid >> 6, l = tid & 63;
  const int wr = w >> 1, wc = w & 1;
  const int e = wc * 16 + (l & 15);

  const short* Ab = Aq + (size_t)chain * 32 * 16384;
  const short* Bb = Bq + (size_t)chain * 32 * 16384;
  short* MTb = MTg + (size_t)chain * 32 * 16384 + (size_t)ch * 32 * 128;
  const int se = tid & 31, sdb = tid >> 5;

  // prologue: zero MT[0] (LDS), zero global slot 0, stage chunk 0
  {
    const short8 z = {0, 0, 0, 0, 0, 0, 0, 0};
    for (int i = tid; i < 512; i += 256)
      *(short8*)(MT[0] + i * 16) = z;
#pragma unroll
    for (int j = 0; j < 2; ++j)
      *(short8*)&MTb[se * 128 + (sdb + 8 * j) * 8] = z;
  }
#pragma unroll
  for (int j = 0; j < 8; ++j) {
    const int byte = tid * 16 + j * 4096;
    __builtin_amdgcn_global_load_lds(AS1((const char*)Ab + byte),
                                     AS3(AcL[0] + byte), 16, 0, 0);
  }
  float Mreg[16] = {}, Momreg[16] = {};
  __syncthreads();

  int buf = 0, cur = 0;
  for (int c = 0; c < NCC; ++c) {
    // issue prefetch of A_{c+1}
    if (c + 1 < NCC) {
      const char* src = (const char*)(Ab + (size_t)(c + 1) * 16384);
#pragma unroll
      for (int j = 0; j < 8; ++j) {
        const int byte = tid * 16 + j * 4096;
        __builtin_amdgcn_global_load_lds(AS1(src + byte),
                                         AS3(AcL[buf ^ 1] + byte), 16, 0, 0);
      }
    }
    // B_c -> registers (transposed layout: 4 contiguous 8B loads)
    short4v bld[4];
    const short* Bc = Bb + (size_t)c * 16384;
#pragma unroll
    for (int m = 0; m < 4; ++m)
      bld[m] = *(const short4v*)&Bc[(ch * 32 + e) * 128 + wr * 64 + m * 16 + (l >> 4) * 4];
    // G = A_c @ M
    f32x4 acc[4] = {};
#pragma unroll
    for (int kf = 0; kf < 4; ++kf) {
      const short8 bf = *(const short8*)&MT[cur][(e * 256 + kf * 64 + (l >> 4) * 16) ^ ((e & 7) << 4)];
#pragma unroll
      for (int m = 0; m < 4; ++m) {
        const int d = wr * 64 + m * 16 + (l & 15);
        const short8 af = *(const short8*)&AcL[buf][(d * 256 + kf * 64 + (l >> 4) * 16) ^ ((d & 7) << 4)];
        acc[m] = __builtin_amdgcn_mfma_f32_16x16x32_bf16(af, bf, acc[m], 0, 0, 0);
      }
    }
    // update M, Mom; write M_c to LDS (other buffer) AND global slot c+1
    short* MTslot = MTb + (size_t)(c + 1) * 16384;
#pragma unroll
    for (int m = 0; m < 4; ++m) {
      const int d0 = wr * 64 + m * 16 + (l >> 4) * 4;
      short4v s4;
#pragma unroll
      for (int i = 0; i < 4; ++i) {
        const int d = d0 + i;
        const int idx = m * 4 + i;
        const float g = acc[m][i] - b2f(bld[m][i]);
        Momreg[idx] = 0.9f * Momreg[idx] - 0.1f * g;
        Mreg[idx] = 0.99f * Mreg[idx] + Momreg[idx];
        const short mv = f2b(Mreg[idx]);
        s4[i] = mv;
        *(short*)&MT[cur ^ 1][(e * 256 + d * 2) ^ ((e & 7) << 4)] = mv;
      }
      if (c + 1 < NCC) *(short4v*)&MTslot[e * 128 + d0] = s4;
    }
    __syncthreads();
    buf ^= 1; cur ^= 1;
  }
}

// ---- P3: out_c = q_c @ M_{c-1} (bf16 q input) ----
__global__ __launch_bounds__(256) void mem_out(
    const short* __restrict__ qb, const short* __restrict__ MTg,
    short* __restrict__ mem)
{
  const int bid = blockIdx.x;
  const int chain = bid >> 5, c = bid & 31;
  const int b = chain >> 2, mh = chain & 3;
  const size_t rowbase = (size_t)(b * SS + c * 64);
  const int tid = threadIdx.x, w = tid >> 6, l = tid & 63;
  const int wr = w >> 1, wc = w & 1;
  const short* MTc = MTg + (size_t)chain * 32 * 16384 + (size_t)c * 16384;

  f32x4 acc[2][4] = {};
#pragma unroll
  for (int kf = 0; kf < 4; ++kf) {
    short8 af[2];
#pragma unroll
    for (int m = 0; m < 2; ++m) {
      const int r = wr * 32 + m * 16 + (l & 15);
      af[m] = *(const short8*)&qb[(rowbase + r) * 1536 + mh * 128 + kf * 32 + (l >> 4) * 8];
    }
#pragma unroll
    for (int n = 0; n < 4; ++n) {
      const int e = wc * 64 + n * 16 + (l & 15);
      const short8 bf = *(const short8*)&MTc[e * 128 + kf * 32 + (l >> 4) * 8];
#pragma unroll
      for (int m = 0; m < 2; ++m)
        acc[m][n] = __builtin_amdgcn_mfma_f32_16x16x32_bf16(af[m], bf, acc[m][n], 0, 0, 0);
    }
  }
#pragma unroll
  for (int m = 0; m < 2; ++m)
#pragma unroll
    for (int n = 0; n < 4; ++n)
#pragma unroll
      for (int i = 0; i < 4; ++i) {
        const int r = wr * 32 + m * 16 + (l >> 4) * 4 + i;
        const int e = wc * 64 + n * 16 + (l & 15);
        mem[(rowbase + r) * 512 + mh * 128 + e] = f2b(acc[m][n][i]);
      }
}

// ---------------- merged weight transpose+convert (all matrices, 1 launch) ---
struct TcvtJob { const float* src; short* dst; int K; int N; int blks; };
struct TcvtArgs { TcvtJob j[10]; };

__global__ __launch_bounds__(256) void tcvt_all(TcvtArgs a)
{
  int bid = blockIdx.x;
  const float* src = nullptr; short* dst = nullptr; int K = 0, N = 0;
#pragma unroll
  for (int i = 0; i < 10; ++i) {
    if (!src) {
      if (bid < a.j[i].blks) { src = a.j[i].src; dst = a.j[i].dst; K = a.j[i].K; N = a.j[i].N; }
      else bid -= a.j[i].blks;
    }
  }
  const int nt = N >> 5, kt = K >> 5;
  const int z = bid / (nt * kt);
  const int rem = bid % (nt * kt);
  const int k0 = (rem / nt) * 32, n0 = (rem % nt) * 32;
  const size_t zoff = (size_t)z * K * N;
  src += zoff; dst += zoff;

  __shared__ float t[32][33];
  const int tx = threadIdx.x & 31, ty = threadIdx.x >> 5;
#pragma unroll
  for (int i = 0; i < 4; ++i)
    t[ty + i * 8][tx] = src[(size_t)(k0 + ty + i * 8) * N + n0 + tx];
  __syncthreads();
#pragma unroll
  for (int i = 0; i < 4; ++i)
    dst[(size_t)(n0 + ty + i * 8) * K + k0 + tx] = f2b(t[tx][ty + i * 8]);
}

// ---------------- persistent path: 1 block, 512 threads -------------------
__global__ __launch_bounds__(512) void persist_kernel(
    const float* __restrict__ pm, const float* __restrict__ pmw,
    const float* __restrict__ pmb, const float* __restrict__ fw2,
    const float* __restrict__ fb, float* __restrict__ t2)
{
  __shared__ float t0[512], t1[512];
  const int e = threadIdx.x;
  float s = 0.f;
#pragma unroll
  for (int t = 0; t < 16; ++t) s += pm[t * 512 + e];
  t0[e] = s * (1.f / 16.f);
  __syncthreads();
  float p = pmb[e];
  for (int d = 0; d < 512; ++d) p += t0[d] * pmw[d * 512 + e];
  t1[e] = p;
  __syncthreads();
  float q = fb[e];
  for (int d = 0; d < 512; ++d) q += t1[d] * fw2[d * 512 + e];
  t2[e] = q;
}

// ---------------- host side ----------------
extern "C" void kernel_launch(void* const* d_in, const int* in_sizes, int n_in,
                              void* d_out, int out_size, void* d_ws, size_t ws_size,
                              hipStream_t stream)
{
  const float* x         = (const float*)d_in[0];
  const float* n1w       = (const float*)d_in[1];
  const float* n1b       = (const float*)d_in[2];
  const float* qkvw      = (const float*)d_in[3];
  const float* qkvb      = (const float*)d_in[4];
  const float* projw     = (const float*)d_in[5];
  const float* projb     = (const float*)d_in[6];
  const float* n2w       = (const float*)d_in[7];
  const float* n2b       = (const float*)d_in[8];
  const float* fc1w      = (const float*)d_in[9];
  const float* fc1b      = (const float*)d_in[10];
  const float* fc2w      = (const float*)d_in[11];
  const float* fc2b      = (const float*)d_in[12];
  const float* mlnw      = (const float*)d_in[13];
  const float* mlnb      = (const float*)d_in[14];
  const float* mwq       = (const float*)d_in[15];
  const float* mwk       = (const float*)d_in[16];
  const float* mwv       = (const float*)d_in[17];
  const float* mprojw    = (const float*)d_in[18];
  const float* mprojb    = (const float*)d_in[19];
  const float* pm_tokens = (const float*)d_in[20];
  const float* pmw       = (const float*)d_in[21];
  const float* pmb       = (const float*)d_in[22];
  const float* fw        = (const float*)d_in[23];
  const float* fb        = (const float*)d_in[24];
  float* out = (float*)d_out;

  char* p = (char*)d_ws;
  auto alloc = [&](size_t bytes) {
    char* r = p;
    p += (bytes + 255) & ~(size_t)255;
    return r;
  };
  short* qkvwT  = (short*)alloc(6ull * 1536 * 512 * 2);
  short* projwT = (short*)alloc(6ull * 512 * 512 * 2);
  short* fc1wT  = (short*)alloc(6ull * 2048 * 512 * 2);
  short* fc2wT  = (short*)alloc(6ull * 512 * 2048 * 2);
  short* mqkvT  = (short*)alloc(3ull * 512 * 512 * 2);
  short* mprojT = (short*)alloc(512ull * 512 * 2);
  short* fwT    = (short*)alloc(512ull * 1024 * 2);
  short* bigb   = (short*)alloc((size_t)BS * 1536 * 2);
  float* hbuf   = (float*)alloc((size_t)BS * 512 * 4);
  float* t2     = (float*)alloc(512 * 4);
  short* actA   = (short*)alloc((size_t)BS * 512 * 2);
  short* ln0b   = (short*)alloc((size_t)BS * 512 * 2);
  short* attnb  = (short*)alloc((size_t)BS * 512 * 2);
  short* ff1b   = (short*)alloc((size_t)BS * 2048 * 2);
  short* stlt   = (short*)alloc((size_t)BS * 1024 * 2);
  short* Aq     = (short*)alloc(256ull * 16384 * 2);
  short* Bq     = (short*)alloc(256ull * 16384 * 2);
  short* MTg    = (short*)alloc(256ull * 16384 * 2);

  // ---- all weight transposes in one launch ----
  TcvtArgs ta;
  ta.j[0] = {qkvw,  qkvwT,  512, 1536, 48 * 16 * 6};
  ta.j[1] = {projw, projwT, 512, 512,  16 * 16 * 6};
  ta.j[2] = {fc1w,  fc1wT,  512, 2048, 64 * 16 * 6};
  ta.j[3] = {fc2w,  fc2wT,  2048, 512, 16 * 64 * 6};
  ta.j[4] = {mwq, mqkvT,                 512, 512, 256};
  ta.j[5] = {mwk, mqkvT + 512 * 512,     512, 512, 256};
  ta.j[6] = {mwv, mqkvT + 2 * 512 * 512, 512, 512, 256};
  ta.j[7] = {mprojw, mprojT, 512, 512, 256};
  ta.j[8] = {fw, fwT, 1024, 512, 512};
  ta.j[9] = {nullptr, nullptr, 32, 32, 0};
  int total_blks = 0;
  for (int i = 0; i < 10; ++i) total_blks += ta.j[i].blks;
  tcvt_all<<<total_blks, 256, 0, stream>>>(ta);

  persist_kernel<<<1, 512, 0, stream>>>(pm_tokens, pmw, pmb,
                                        fw + (size_t)1024 * 512, fb, t2);

  // ---- neural memory path ----
  ln_kernel<<<BS / 4, 256, 0, stream>>>(x, mlnw, mlnb, actA);
  ln_kernel<<<BS / 4, 256, 0, stream>>>(x, n1w, n1b, ln0b);     // layer-0 ln1
  gemm_bf16<0, 1, 128><<<dim3(12, 32), 256, 0, stream>>>(
      actA, mqkvT, nullptr, nullptr, nullptr, bigb, BS, 1536, 512, 1536);
  mem_prep<<<256, 256, 0, stream>>>(bigb + 512, bigb + 1024, Aq, Bq);
  mem_scan2<<<32, 256, 0, stream>>>(Aq, Bq, MTg);
  mem_out<<<256, 256, 0, stream>>>(bigb, MTg, ff1b);
  gemm_bf16<2, 1, 64><<<dim3(4, 64), 256, 0, stream>>>(
      ff1b, mprojT, mprojb, x, nullptr, stlt + 512, BS, 512, 512, 1024);

  // ---- layer stack ----
  for (int l = 0; l < LL; ++l) {
    const short* lnin = (l == 0) ? ln0b : actA;
    if (l > 0)
      ln_kernel<<<BS / 4, 256, 0, stream>>>(hbuf, n1w + l * 512, n1b + l * 512, actA);
    gemm_bf16<0, 1, 128><<<dim3(12, 32), 256, 0, stream>>>(
        lnin, qkvwT + (size_t)l * 1536 * 512, qkvb + l * 1536,
        nullptr, nullptr, bigb, BS, 1536, 512, 1536);
    swa_kernel<<<512, 256, 0, stream>>>((const unsigned short*)bigb, attnb);
    gemm_bf16<2, 0, 64><<<dim3(4, 64), 256, 0, stream>>>(
        attnb, projwT + (size_t)l * 512 * 512, projb + l * 512,
        (l == 0) ? x : hbuf, nullptr, hbuf, BS, 512, 512, 512);
    ln_kernel<<<BS / 4, 256, 0, stream>>>(hbuf, n2w + l * 512, n2b + l * 512, actA);
    gemm_bf16<1, 1, 128><<<dim3(16, 32), 256, 0, stream>>>(
        actA, fc1wT + (size_t)l * 2048 * 512, fc1b + l * 2048,
        nullptr, nullptr, ff1b, BS, 2048, 512, 2048);
    if (l < LL - 1)
      gemm_bf16<3, 0, 64><<<dim3(4, 64), 256, 0, stream>>>(
          ff1b, fc2wT + (size_t)l * 512 * 2048, fc2b + l * 512,
          hbuf, actA, hbuf, BS, 512, 2048, 512);
    else
      gemm_bf16<3, 1, 64><<<dim3(4, 64), 256, 0, stream>>>(
          ff1b, fc2wT + (size_t)l * 512 * 2048, fc2b + l * 512,
          hbuf, actA, stlt, BS, 512, 2048, 1024);   // ST -> stlt[:, 0:512]
  }

  // ---- fusion: out = [ST | LT] @ fwT + (persistent + fusion bias) ----
  gemm_bf16<0, 0, 64><<<dim3(4, 64), 256, 0, stream>>>(
      stlt, fwT, t2, nullptr, nullptr, out, BS, 512, 1024, 512);
}

// Round 9
// 816.898 us; speedup vs baseline: 4.7161x; 1.0218x over previous
//
#include <hip/hip_runtime.h>
#include <math.h>

// Problem constants
#define BB 2
#define SS 2048
#define DD 512
#define HH 8
#define LL 6
#define WW 64
#define CHH 64
#define NCC 32
#define BS (BB*SS)   // 4096 rows

typedef __attribute__((ext_vector_type(8))) short short8;
typedef __attribute__((ext_vector_type(4))) short short4v;
typedef __attribute__((ext_vector_type(4))) float f32x4;

__device__ inline float b2f(short s) {
  unsigned u = ((unsigned)(unsigned short)s) << 16;
  float f; __builtin_memcpy(&f, &u, 4); return f;
}
__device__ inline short f2b(float f) {
  unsigned u; __builtin_memcpy(&u, &f, 4);
  unsigned r = (u + 0x7FFFu + ((u >> 16) & 1u)) >> 16;
  return (short)r;
}
__device__ inline float gelu_tanh(float v) {
  float u = 0.7978845608f * (v + 0.044715f * v * v * v);
  u = fminf(fmaxf(u, -20.f), 20.f);
  float e2 = __expf(2.f * u);
  return 0.5f * v * (1.f + (e2 - 1.f) / (e2 + 1.f));
}

#define AS1(p) ((const __attribute__((address_space(1))) void*)(p))
#define AS3(p) ((__attribute__((address_space(3))) void*)(p))

// ---------------- LayerNorm: wave-per-row, 4 rows/block ----------------
__global__ __launch_bounds__(256) void ln_kernel(
    const float* __restrict__ x, const float* __restrict__ w,
    const float* __restrict__ b, short* __restrict__ y)
{
  const int row = blockIdx.x * 4 + (threadIdx.x >> 6);
  const int l = threadIdx.x & 63;
  const float* xr = x + (size_t)row * DD + l * 8;
  const float4 a = *(const float4*)xr;
  const float4 c = *(const float4*)(xr + 4);
  float s = a.x + a.y + a.z + a.w + c.x + c.y + c.z + c.w;
  float sq = a.x * a.x + a.y * a.y + a.z * a.z + a.w * a.w
           + c.x * c.x + c.y * c.y + c.z * c.z + c.w * c.w;
#pragma unroll
  for (int off = 1; off < 64; off <<= 1) {
    s += __shfl_xor(s, off);
    sq += __shfl_xor(sq, off);
  }
  const float mean = s * (1.f / DD);
  const float var = sq * (1.f / DD) - mean * mean;
  const float inv = rsqrtf(var + 1e-5f);
  const float4 w0 = *(const float4*)(w + l * 8);
  const float4 w1 = *(const float4*)(w + l * 8 + 4);
  const float4 b0 = *(const float4*)(b + l * 8);
  const float4 b1 = *(const float4*)(b + l * 8 + 4);
  short8 o;
  o[0] = f2b((a.x - mean) * inv * w0.x + b0.x);
  o[1] = f2b((a.y - mean) * inv * w0.y + b0.y);
  o[2] = f2b((a.z - mean) * inv * w0.z + b0.z);
  o[3] = f2b((a.w - mean) * inv * w0.w + b0.w);
  o[4] = f2b((c.x - mean) * inv * w1.x + b1.x);
  o[5] = f2b((c.y - mean) * inv * w1.y + b1.y);
  o[6] = f2b((c.z - mean) * inv * w1.z + b1.z);
  o[7] = f2b((c.w - mean) * inv * w1.w + b1.w);
  *(short8*)(y + (size_t)row * DD + l * 8) = o;
}

// ---------------- Dual LayerNorm: one read of x, two (w,b,y) ----------------
__global__ __launch_bounds__(256) void ln_dual_kernel(
    const float* __restrict__ x,
    const float* __restrict__ w1, const float* __restrict__ b1v, short* __restrict__ y1,
    const float* __restrict__ w2, const float* __restrict__ b2v, short* __restrict__ y2)
{
  const int row = blockIdx.x * 4 + (threadIdx.x >> 6);
  const int l = threadIdx.x & 63;
  const float* xr = x + (size_t)row * DD + l * 8;
  const float4 a = *(const float4*)xr;
  const float4 c = *(const float4*)(xr + 4);
  float s = a.x + a.y + a.z + a.w + c.x + c.y + c.z + c.w;
  float sq = a.x * a.x + a.y * a.y + a.z * a.z + a.w * a.w
           + c.x * c.x + c.y * c.y + c.z * c.z + c.w * c.w;
#pragma unroll
  for (int off = 1; off < 64; off <<= 1) {
    s += __shfl_xor(s, off);
    sq += __shfl_xor(sq, off);
  }
  const float mean = s * (1.f / DD);
  const float var = sq * (1.f / DD) - mean * mean;
  const float inv = rsqrtf(var + 1e-5f);
  const float n0 = (a.x - mean) * inv, n1 = (a.y - mean) * inv,
              n2 = (a.z - mean) * inv, n3 = (a.w - mean) * inv,
              n4 = (c.x - mean) * inv, n5 = (c.y - mean) * inv,
              n6 = (c.z - mean) * inv, n7 = (c.w - mean) * inv;
#pragma unroll
  for (int pass = 0; pass < 2; ++pass) {
    const float* w = pass ? w2 : w1;
    const float* b = pass ? b2v : b1v;
    short* y = pass ? y2 : y1;
    const float4 w0 = *(const float4*)(w + l * 8);
    const float4 w1_ = *(const float4*)(w + l * 8 + 4);
    const float4 bb0 = *(const float4*)(b + l * 8);
    const float4 bb1 = *(const float4*)(b + l * 8 + 4);
    short8 o;
    o[0] = f2b(n0 * w0.x + bb0.x);
    o[1] = f2b(n1 * w0.y + bb0.y);
    o[2] = f2b(n2 * w0.z + bb0.z);
    o[3] = f2b(n3 * w0.w + bb0.w);
    o[4] = f2b(n4 * w1_.x + bb1.x);
    o[5] = f2b(n5 * w1_.y + bb1.y);
    o[6] = f2b(n6 * w1_.z + bb1.z);
    o[7] = f2b(n7 * w1_.w + bb1.w);
    *(short8*)(y + (size_t)row * DD + l * 8) = o;
  }
}

// ---------------- bf16 MFMA GEMM (BM=128 or 64, BN=128) ----------------
// EPI: 0=+bias(opt); 1=gelu(+bias); 2=+bias(opt)+add1(f32); 3=+bias+add1(f32)+add2(bf16)
// OBF: 0=f32 out (stride N); 1=bf16 out (stride NS)
template<int EPI, int OBF, int BM>
__global__ __launch_bounds__(256) void gemm_bf16(
    const short* __restrict__ A, const short* __restrict__ BT,
    const float* __restrict__ bias, const float* __restrict__ add1,
    const short* __restrict__ add2, void* __restrict__ C,
    int M, int N, int K, int NS)
{
  constexpr int MF = BM / 32;
  constexpr int CA = BM / 64;
  __shared__ __align__(16) short As[BM * 32];
  __shared__ __align__(16) short Bs[128 * 32];
  const int tid = threadIdx.x;
  const int wave = tid >> 6, lane = tid & 63;
  const int wr = wave >> 1, wc = wave & 1;
  const int bm = blockIdx.y * BM, bn = blockIdx.x * 128;

  const int l4r = lane >> 2;
  const int l4c = (lane & 3) * 8;

  const short* sA[CA]; const short* sB[2];
  int ldsA[CA], ldsB[2];
#pragma unroll
  for (int r = 0; r < CA; ++r) {
    const int chunk = r * 4 + wave;
    sA[r] = A + (size_t)(bm + chunk * 16 + l4r) * K + l4c;
    ldsA[r] = chunk * 1024;
  }
#pragma unroll
  for (int r = 0; r < 2; ++r) {
    const int chunk = r * 4 + wave;
    sB[r] = BT + (size_t)(bn + chunk * 16 + l4r) * K + l4c;
    ldsB[r] = chunk * 1024;
  }

  f32x4 acc[MF][4] = {};

  for (int k0 = 0; k0 < K; k0 += 32) {
#pragma unroll
    for (int r = 0; r < CA; ++r) {
      __builtin_amdgcn_global_load_lds(AS1(sA[r]), AS3((char*)As + ldsA[r]), 16, 0, 0);
      sA[r] += 32;
    }
#pragma unroll
    for (int r = 0; r < 2; ++r) {
      __builtin_amdgcn_global_load_lds(AS1(sB[r]), AS3((char*)Bs + ldsB[r]), 16, 0, 0);
      sB[r] += 32;
    }
    __syncthreads();
    short8 af[MF], bf[4];
#pragma unroll
    for (int m = 0; m < MF; ++m)
      af[m] = *(const short8*)&As[(wr * (BM / 2) + m * 16 + (lane & 15)) * 32 + (lane >> 4) * 8];
#pragma unroll
    for (int n = 0; n < 4; ++n)
      bf[n] = *(const short8*)&Bs[(wc * 64 + n * 16 + (lane & 15)) * 32 + (lane >> 4) * 8];
#pragma unroll
    for (int m = 0; m < MF; ++m)
#pragma unroll
      for (int n = 0; n < 4; ++n)
        acc[m][n] = __builtin_amdgcn_mfma_f32_16x16x32_bf16(af[m], bf[n], acc[m][n], 0, 0, 0);
    __syncthreads();
  }

#pragma unroll
  for (int m = 0; m < MF; ++m) {
#pragma unroll
    for (int n = 0; n < 4; ++n) {
      const int col = bn + wc * 64 + n * 16 + (lane & 15);
      const float bb = (EPI == 1 || EPI == 3) ? bias[col] : (bias ? bias[col] : 0.f);
#pragma unroll
      for (int r = 0; r < 4; ++r) {
        const int row = bm + wr * (BM / 2) + m * 16 + (lane >> 4) * 4 + r;
        const size_t idx = (size_t)row * N + col;
        float v = acc[m][n][r] + bb;
        if (EPI == 1) v = gelu_tanh(v);
        if (EPI == 2 || EPI == 3) v += add1[idx];
        if (EPI == 3) v += b2f(add2[idx]);
        if (OBF == 1) ((short*)C)[(size_t)row * NS + col] = f2b(v);
        else ((float*)C)[idx] = v;
      }
    }
  }
}

// ---------------- Sliding-window attention (bf16 qkv in, bf16 out) ----------
__global__ __launch_bounds__(256) void swa_kernel(
    const unsigned short* __restrict__ qkv, short* __restrict__ out)
{
  __shared__ __align__(16) short ks[128 * 72];
  __shared__ __align__(16) short vt[64 * 136];
  __shared__ __align__(16) short ps[4][16 * 136];
  __shared__ float lsum[64];

  const int tid = threadIdx.x;
  const int w = tid >> 6, l = tid & 63;
  const int tile = blockIdx.x & 31;
  const int h = (blockIdx.x >> 5) & 7;
  const int b = blockIdx.x >> 8;
  const int s0 = tile * 64;
  const size_t base = (size_t)b * SS;

#pragma unroll
  for (int u = 0; u < 16; ++u) {
    const int id = u * 256 + tid;
    const int row = id >> 5, dp = id & 31;
    int jp = s0 - 32 + row;
    jp = min(max(jp, 0), SS - 1);
    const size_t g = (base + jp) * 1536 + h * 64 + dp * 2;
    *(unsigned*)&ks[row * 72 + dp * 2] = *(const unsigned*)&qkv[g + 512];
    const unsigned vv = *(const unsigned*)&qkv[g + 1024];
    vt[(dp * 2) * 136 + row] = (short)(vv & 0xFFFF);
    vt[(dp * 2 + 1) * 136 + row] = (short)(vv >> 16);
  }

  const int qi = w * 16 + (l & 15);
  short8 qf[2];
#pragma unroll
  for (int kf = 0; kf < 2; ++kf)
    qf[kf] = *(const short8*)&qkv[(base + s0 + qi) * 1536 + h * 64 + kf * 32 + (l >> 4) * 8];
  __syncthreads();

  f32x4 sa[8] = {};
#pragma unroll
  for (int mf = 0; mf < 8; ++mf)
#pragma unroll
    for (int kf = 0; kf < 2; ++kf) {
      const short8 af = *(const short8*)&ks[(mf * 16 + (l & 15)) * 72 + kf * 32 + (l >> 4) * 8];
      sa[mf] = __builtin_amdgcn_mfma_f32_16x16x32_bf16(af, qf[kf], sa[mf], 0, 0, 0);
    }

  float sv[8][4];
  float mx = -INFINITY;
#pragma unroll
  for (int mf = 0; mf < 8; ++mf)
#pragma unroll
    for (int r = 0; r < 4; ++r) {
      const int j = mf * 16 + (l >> 4) * 4 + r;
      const int jpos = s0 - 32 + j;
      const bool ok = (j >= qi) && (j <= qi + 64) && (jpos >= 0) && (jpos < SS);
      const float s = ok ? sa[mf][r] * 0.125f : -INFINITY;
      sv[mf][r] = s;
      mx = fmaxf(mx, s);
    }
  mx = fmaxf(mx, __shfl_xor(mx, 16));
  mx = fmaxf(mx, __shfl_xor(mx, 32));
  float ls = 0.f;
#pragma unroll
  for (int mf = 0; mf < 8; ++mf)
#pragma unroll
    for (int r = 0; r < 4; ++r) {
      const float p = __expf(sv[mf][r] - mx);
      sv[mf][r] = p;
      ls += p;
    }
  ls += __shfl_xor(ls, 16);
  ls += __shfl_xor(ls, 32);
  if (l < 16) lsum[w * 16 + l] = ls;

#pragma unroll
  for (int mf = 0; mf < 8; ++mf) {
    short4v p4;
    p4.x = f2b(sv[mf][0]); p4.y = f2b(sv[mf][1]);
    p4.z = f2b(sv[mf][2]); p4.w = f2b(sv[mf][3]);
    *(short4v*)&ps[w][(l & 15) * 136 + mf * 16 + (l >> 4) * 4] = p4;
  }

  f32x4 oa[4] = {};
#pragma unroll
  for (int kf = 0; kf < 4; ++kf) {
    const short8 pf = *(const short8*)&ps[w][(l & 15) * 136 + kf * 32 + (l >> 4) * 8];
#pragma unroll
    for (int nf = 0; nf < 4; ++nf) {
      const short8 vf = *(const short8*)&vt[(nf * 16 + (l & 15)) * 136 + kf * 32 + (l >> 4) * 8];
      oa[nf] = __builtin_amdgcn_mfma_f32_16x16x32_bf16(pf, vf, oa[nf], 0, 0, 0);
    }
  }

  float rl[4];
#pragma unroll
  for (int r = 0; r < 4; ++r) rl[r] = 1.f / lsum[w * 16 + (l >> 4) * 4 + r];
#pragma unroll
  for (int nf = 0; nf < 4; ++nf)
#pragma unroll
    for (int r = 0; r < 4; ++r) {
      const int q = (l >> 4) * 4 + r;
      const int d = nf * 16 + (l & 15);
      out[(base + s0 + w * 16 + q) * 512 + h * 64 + d] = f2b(oa[nf][r] * rl[r]);
    }
}

// ========== Neural memory, linear-scan formulation ==========
// grad_c = A_c M_{c-1} - B_c,  A_c = k^T k/64 (bf16, XOR-swizzled, via symmetry),
// B_c = k^T v/64 (bf16, stored TRANSPOSED [e][d])

// ---- P1: per (chain, chunk) compute A_c, B_c via MFMA (bf16 k,v inputs) ----
__global__ __launch_bounds__(256) void mem_prep(
    const short* __restrict__ kb, const short* __restrict__ vb,
    short* __restrict__ Aq, short* __restrict__ Bq)
{
  __shared__ __align__(16) short kn[64 * 136];
  __shared__ __align__(16) char kT[128 * 128];
  __shared__ __align__(16) char vT[128 * 128];
  const int bid = blockIdx.x;
  const int chain = bid >> 5, c = bid & 31;
  const int b = chain >> 2, mh = chain & 3;
  const size_t rowbase = (size_t)(b * SS + c * 64);
  const int tid = threadIdx.x, w = tid >> 6, l = tid & 63;
  const int td = tid & 127, rh = tid >> 7;

#pragma unroll
  for (int pass = 0; pass < 2; ++pass) {
    const short* src = pass ? vb : kb;
    char* dT = pass ? vT : kT;
#pragma unroll
    for (int j = 0; j < 4; ++j) {
      const int i4 = tid + 256 * j;
      const int r = i4 >> 4, d8 = (i4 & 15) * 8;
      *(short8*)&kn[r * 136 + d8] = *(const short8*)&src[(rowbase + r) * 1536 + mh * 128 + d8];
    }
    __syncthreads();
#pragma unroll
    for (int j = 0; j < 4; ++j) {
      const int r0 = rh * 8 + 16 * j;
      short8 g8;
#pragma unroll
      for (int t = 0; t < 8; ++t) g8[t] = kn[(r0 + t) * 136 + td];
      *(short8*)&dT[(td * 128 + r0 * 2) ^ ((td & 7) << 4)] = g8;
    }
    __syncthreads();
  }

  const int wr = w >> 1, wc = w & 1;
  {
    f32x4 acc[4][4] = {};
#pragma unroll
    for (int kf = 0; kf < 2; ++kf) {
      short8 af[4];
#pragma unroll
      for (int m = 0; m < 4; ++m) {
        const int d = wr * 64 + m * 16 + (l & 15);
        af[m] = *(const short8*)&kT[(d * 128 + kf * 64 + (l >> 4) * 16) ^ ((d & 7) << 4)];
      }
#pragma unroll
      for (int n = 0; n < 4; ++n) {
        const int dp = wc * 64 + n * 16 + (l & 15);
        const short8 bf = *(const short8*)&kT[(dp * 128 + kf * 64 + (l >> 4) * 16) ^ ((dp & 7) << 4)];
#pragma unroll
        for (int m = 0; m < 4; ++m)
          acc[m][n] = __builtin_amdgcn_mfma_f32_16x16x32_bf16(af[m], bf, acc[m][n], 0, 0, 0);
      }
    }
    char* Ad = (char*)(Aq + (size_t)bid * 16384);
#pragma unroll
    for (int m = 0; m < 4; ++m)
#pragma unroll
      for (int n = 0; n < 4; ++n) {
        const int dp = wc * 64 + n * 16 + (l & 15);
        const int d0 = wr * 64 + m * 16 + (l >> 4) * 4;
        short4v s4;
#pragma unroll
        for (int i = 0; i < 4; ++i) s4[i] = f2b(acc[m][n][i] * 0.015625f);
        *(short4v*)&Ad[(dp * 256 + d0 * 2) ^ ((dp & 7) << 4)] = s4;
      }
  }
  {
    f32x4 acc[4][4] = {};
#pragma unroll
    for (int kf = 0; kf < 2; ++kf) {
      short8 af[4];
#pragma unroll
      for (int m = 0; m < 4; ++m) {
        const int d = wr * 64 + m * 16 + (l & 15);
        af[m] = *(const short8*)&kT[(d * 128 + kf * 64 + (l >> 4) * 16) ^ ((d & 7) << 4)];
      }
#pragma unroll
      for (int n = 0; n < 4; ++n) {
        const int e = wc * 64 + n * 16 + (l & 15);
        const short8 bf = *(const short8*)&vT[(e * 128 + kf * 64 + (l >> 4) * 16) ^ ((e & 7) << 4)];
#pragma unroll
        for (int m = 0; m < 4; ++m)
          acc[m][n] = __builtin_amdgcn_mfma_f32_16x16x32_bf16(af[m], bf, acc[m][n], 0, 0, 0);
      }
    }
    short* Bd = Bq + (size_t)bid * 16384;
#pragma unroll
    for (int m = 0; m < 4; ++m)
#pragma unroll
      for (int n = 0; n < 4; ++n) {
        const int e = wc * 64 + n * 16 + (l & 15);
        const int d0 = wr * 64 + m * 16 + (l >> 4) * 4;
        short4v s4;
#pragma unroll
        for (int i = 0; i < 4; ++i) s4[i] = f2b(acc[m][n][i] * 0.015625f);
        *(short4v*)&Bd[e * 128 + d0] = s4;
      }
  }
}

// ---- P2: serial scan — raw s_barrier + counted vmcnt, depth-2 A prefetch ----
// Chunk c: store M_{c-1}->slot c; issue A(c+2)->AcL[(c+2)%3], B(c+2)->breg;
// MFMA G=A_c@M; update; lgkmcnt(0) vmcnt(N); s_barrier.
// N=20 = ops issued after A(c+1): B(c+1)x4 + st(c)x4 + A(c+2)x8 + B(c+2)x4.
__global__ __launch_bounds__(256) void mem_scan2(
    const short* __restrict__ Aq, const short* __restrict__ Bq,
    short* __restrict__ MTg)
{
  __shared__ __align__(16) char AcL[3][32768];
  __shared__ __align__(16) char MT[2][8192];
  const int bid = blockIdx.x;
  const int chain = bid >> 2, ch = bid & 3;
  const int tid = threadIdx.x;
  const int w = tid >> 6, l = tid & 63;
  const int wr = w >> 1, wc = w & 1;
  const int e = wc * 16 + (l & 15);

  const short* Ab = Aq + (size_t)chain * 32 * 16384;
  const short* Bb = Bq + (size_t)chain * 32 * 16384;
  short* MTb = MTg + (size_t)chain * 32 * 16384 + (size_t)ch * 32 * 128;
  const int brow = (ch * 32 + e) * 128;

  // prologue: zero MT[0]; stage A(0),A(1); load B(0),B(1); full sync
  {
    const short8 z = {0, 0, 0, 0, 0, 0, 0, 0};
    for (int i = tid; i < 512; i += 256) *(short8*)(MT[0] + i * 16) = z;
  }
#pragma unroll
  for (int cc = 0; cc < 2; ++cc) {
    const char* srcA = (const char*)(Ab + (size_t)cc * 16384);
#pragma unroll
    for (int j = 0; j < 8; ++j) {
      const int byte = tid * 16 + j * 4096;
      __builtin_amdgcn_global_load_lds(AS1(srcA + byte), AS3(AcL[cc] + byte), 16, 0, 0);
    }
  }
  short4v b0[4], b1[4], b2[4];
#pragma unroll
  for (int m = 0; m < 4; ++m) {
    b0[m] = *(const short4v*)&Bb[brow + wr * 64 + m * 16 + (l >> 4) * 4];
    b1[m] = *(const short4v*)&Bb[16384 + brow + wr * 64 + m * 16 + (l >> 4) * 4];
  }
  float Mreg[16] = {}, Momreg[16] = {};
  __syncthreads();

#define SCHUNK(C, AB, MR, BC, BN, DOI, WN)                                     \
  {                                                                            \
    short* slot = MTb + (size_t)(C) * 16384;                                   \
    _Pragma("unroll") for (int m = 0; m < 4; ++m) {                            \
      const int d0 = wr * 64 + m * 16 + (l >> 4) * 4;                          \
      short4v s4;                                                              \
      _Pragma("unroll") for (int i = 0; i < 4; ++i) s4[i] = f2b(Mreg[m * 4 + i]); \
      *(short4v*)&slot[e * 128 + d0] = s4;                                     \
    }                                                                          \
    if (DOI) {                                                                 \
      const char* srcA = (const char*)(Ab + (size_t)((C) + 2) * 16384);        \
      _Pragma("unroll") for (int j = 0; j < 8; ++j) {                          \
        const int byte = tid * 16 + j * 4096;                                  \
        __builtin_amdgcn_global_load_lds(AS1(srcA + byte),                     \
            AS3(AcL[((C) + 2) % 3] + byte), 16, 0, 0);                         \
      }                                                                        \
      const short* Bn = Bb + (size_t)((C) + 2) * 16384;                        \
      _Pragma("unroll") for (int m = 0; m < 4; ++m)                            \
        BN[m] = *(const short4v*)&Bn[brow + wr * 64 + m * 16 + (l >> 4) * 4];  \
    }                                                                          \
    {                                                                          \
      f32x4 acc[4] = {};                                                       \
      _Pragma("unroll") for (int kf = 0; kf < 4; ++kf) {                       \
        const short8 bf = *(const short8*)&MT[MR][(e * 256 + kf * 64 + (l >> 4) * 16) ^ ((e & 7) << 4)]; \
        _Pragma("unroll") for (int m = 0; m < 4; ++m) {                        \
          const int d = wr * 64 + m * 16 + (l & 15);                           \
          const short8 af = *(const short8*)&AcL[AB][(d * 256 + kf * 64 + (l >> 4) * 16) ^ ((d & 7) << 4)]; \
          acc[m] = __builtin_amdgcn_mfma_f32_16x16x32_bf16(af, bf, acc[m], 0, 0, 0); \
        }                                                                      \
      }                                                                        \
      _Pragma("unroll") for (int m = 0; m < 4; ++m) {                          \
        const int d0 = wr * 64 + m * 16 + (l >> 4) * 4;                        \
        short4v s4;                                                            \
        _Pragma("unroll") for (int i = 0; i < 4; ++i) {                        \
          const int idx = m * 4 + i;                                           \
          const float g = acc[m][i] - b2f(BC[m][i]);                           \
          Momreg[idx] = 0.9f * Momreg[idx] - 0.1f * g;                         \
          Mreg[idx] = 0.99f * Mreg[idx] + Momreg[idx];                         \
          s4[i] = f2b(Mreg[idx]);                                              \
        }                                                                      \
        *(short4v*)&MT[(MR) ^ 1][(e * 256 + d0 * 2) ^ ((e & 7) << 4)] = s4;    \
      }                                                                        \
    }                                                                          \
    asm volatile("s_waitcnt lgkmcnt(0) vmcnt(" #WN ")" ::: "memory");          \
    __builtin_amdgcn_sched_barrier(0);                                         \
    __builtin_amdgcn_s_barrier();                                              \
    __builtin_amdgcn_sched_barrier(0);                                         \
  }

  // chunks 0..30 (period-6 buffer pattern); chunk 31 degenerates to a store
  SCHUNK(0, 0, 0, b0, b2, 1, 20)  SCHUNK(1, 1, 1, b1, b0, 1, 20)
  SCHUNK(2, 2, 0, b2, b1, 1, 20)  SCHUNK(3, 0, 1, b0, b2, 1, 20)
  SCHUNK(4, 1, 0, b1, b0, 1, 20)  SCHUNK(5, 2, 1, b2, b1, 1, 20)
  SCHUNK(6, 0, 0, b0, b2, 1, 20)  SCHUNK(7, 1, 1, b1, b0, 1, 20)
  SCHUNK(8, 2, 0, b2, b1, 1, 20)  SCHUNK(9, 0, 1, b0, b2, 1, 20)
  SCHUNK(10, 1, 0, b1, b0, 1, 20) SCHUNK(11, 2, 1, b2, b1, 1, 20)
  SCHUNK(12, 0, 0, b0, b2, 1, 20) SCHUNK(13, 1, 1, b1, b0, 1, 20)
  SCHUNK(14, 2, 0, b2, b1, 1, 20) SCHUNK(15, 0, 1, b0, b2, 1, 20)
  SCHUNK(16, 1, 0, b1, b0, 1, 20) SCHUNK(17, 2, 1, b2, b1, 1, 20)
  SCHUNK(18, 0, 0, b0, b2, 1, 20) SCHUNK(19, 1, 1, b1, b0, 1, 20)
  SCHUNK(20, 2, 0, b2, b1, 1, 20) SCHUNK(21, 0, 1, b0, b2, 1, 20)
  SCHUNK(22, 1, 0, b1, b0, 1, 20) SCHUNK(23, 2, 1, b2, b1, 1, 20)
  SCHUNK(24, 0, 0, b0, b2, 1, 20) SCHUNK(25, 1, 1, b1, b0, 1, 20)
  SCHUNK(26, 2, 0, b2, b1, 1, 20) SCHUNK(27, 0, 1, b0, b2, 1, 20)
  SCHUNK(28, 1, 0, b1, b0, 1, 20) SCHUNK(29, 2, 1, b2, b1, 0, 8)
  SCHUNK(30, 0, 0, b0, b2, 0, 8)
#undef SCHUNK

  // epilogue: slot 31 = M_30
  {
    short* slot = MTb + (size_t)31 * 16384;
#pragma unroll
    for (int m = 0; m < 4; ++m) {
      const int d0 = wr * 64 + m * 16 + (l >> 4) * 4;
      short4v s4;
#pragma unroll
      for (int i = 0; i < 4; ++i) s4[i] = f2b(Mreg[m * 4 + i]);
      *(short4v*)&slot[e * 128 + d0] = s4;
    }
  }
}

// ---- P3: out_c = q_c @ M_{c-1} (bf16 q input) ----
__global__ __launch_bounds__(256) void mem_out(
    const short* __restrict__ qb, const short* __restrict__ MTg,
    short* __restrict__ mem)
{
  const int bid = blockIdx.x;
  const int chain = bid >> 5, c = bid & 31;
  const int b = chain >> 2, mh = chain & 3;
  const size_t rowbase = (size_t)(b * SS + c * 64);
  const int tid = threadIdx.x, w = tid >> 6, l = tid & 63;
  const int wr = w >> 1, wc = w & 1;
  const short* MTc = MTg + (size_t)chain * 32 * 16384 + (size_t)c * 16384;

  f32x4 acc[2][4] = {};
#pragma unroll
  for (int kf = 0; kf < 4; ++kf) {
    short8 af[2];
#pragma unroll
    for (int m = 0; m < 2; ++m) {
      const int r = wr * 32 + m * 16 + (l & 15);
      af[m] = *(const short8*)&qb[(rowbase + r) * 1536 + mh * 128 + kf * 32 + (l >> 4) * 8];
    }
#pragma unroll
    for (int n = 0; n < 4; ++n) {
      const int e = wc * 64 + n * 16 + (l & 15);
      const short8 bf = *(const short8*)&MTc[e * 128 + kf * 32 + (l >> 4) * 8];
#pragma unroll
      for (int m = 0; m < 2; ++m)
        acc[m][n] = __builtin_amdgcn_mfma_f32_16x16x32_bf16(af[m], bf, acc[m][n], 0, 0, 0);
    }
  }
#pragma unroll
  for (int m = 0; m < 2; ++m)
#pragma unroll
    for (int n = 0; n < 4; ++n)
#pragma unroll
      for (int i = 0; i < 4; ++i) {
        const int r = wr * 32 + m * 16 + (l >> 4) * 4 + i;
        const int e = wc * 64 + n * 16 + (l & 15);
        mem[(rowbase + r) * 512 + mh * 128 + e] = f2b(acc[m][n][i]);
      }
}

// ---------------- merged weight transpose+convert (all matrices, 1 launch) ---
struct TcvtJob { const float* src; short* dst; int K; int N; int blks; };
struct TcvtArgs { TcvtJob j[10]; };

__global__ __launch_bounds__(256) void tcvt_all(TcvtArgs a)
{
  int bid = blockIdx.x;
  const float* src = nullptr; short* dst = nullptr; int K = 0, N = 0;
#pragma unroll
  for (int i = 0; i < 10; ++i) {
    if (!src) {
      if (bid < a.j[i].blks) { src = a.j[i].src; dst = a.j[i].dst; K = a.j[i].K; N = a.j[i].N; }
      else bid -= a.j[i].blks;
    }
  }
  const int nt = N >> 5, kt = K >> 5;
  const int z = bid / (nt * kt);
  const int rem = bid % (nt * kt);
  const int k0 = (rem / nt) * 32, n0 = (rem % nt) * 32;
  const size_t zoff = (size_t)z * K * N;
  src += zoff; dst += zoff;

  __shared__ float t[32][33];
  const int tx = threadIdx.x & 31, ty = threadIdx.x >> 5;
#pragma unroll
  for (int i = 0; i < 4; ++i)
    t[ty + i * 8][tx] = src[(size_t)(k0 + ty + i * 8) * N + n0 + tx];
  __syncthreads();
#pragma unroll
  for (int i = 0; i < 4; ++i)
    dst[(size_t)(n0 + ty + i * 8) * K + k0 + tx] = f2b(t[tx][ty + i * 8]);
}

// ---------------- persistent path: 1 block, 512 threads -------------------
__global__ __launch_bounds__(512) void persist_kernel(
    const float* __restrict__ pm, const float* __restrict__ pmw,
    const float* __restrict__ pmb, const float* __restrict__ fw2,
    const float* __restrict__ fb, float* __restrict__ t2)
{
  __shared__ float t0[512], t1[512];
  const int e = threadIdx.x;
  float s = 0.f;
#pragma unroll
  for (int t = 0; t < 16; ++t) s += pm[t * 512 + e];
  t0[e] = s * (1.f / 16.f);
  __syncthreads();
  float p = pmb[e];
  for (int d = 0; d < 512; ++d) p += t0[d] * pmw[d * 512 + e];
  t1[e] = p;
  __syncthreads();
  float q = fb[e];
  for (int d = 0; d < 512; ++d) q += t1[d] * fw2[d * 512 + e];
  t2[e] = q;
}

// ---------------- host side ----------------
extern "C" void kernel_launch(void* const* d_in, const int* in_sizes, int n_in,
                              void* d_out, int out_size, void* d_ws, size_t ws_size,
                              hipStream_t stream)
{
  const float* x         = (const float*)d_in[0];
  const float* n1w       = (const float*)d_in[1];
  const float* n1b       = (const float*)d_in[2];
  const float* qkvw      = (const float*)d_in[3];
  const float* qkvb      = (const float*)d_in[4];
  const float* projw     = (const float*)d_in[5];
  const float* projb     = (const float*)d_in[6];
  const float* n2w       = (const float*)d_in[7];
  const float* n2b       = (const float*)d_in[8];
  const float* fc1w      = (const float*)d_in[9];
  const float* fc1b      = (const float*)d_in[10];
  const float* fc2w      = (const float*)d_in[11];
  const float* fc2b      = (const float*)d_in[12];
  const float* mlnw      = (const float*)d_in[13];
  const float* mlnb      = (const float*)d_in[14];
  const float* mwq       = (const float*)d_in[15];
  const float* mwk       = (const float*)d_in[16];
  const float* mwv       = (const float*)d_in[17];
  const float* mprojw    = (const float*)d_in[18];
  const float* mprojb    = (const float*)d_in[19];
  const float* pm_tokens = (const float*)d_in[20];
  const float* pmw       = (const float*)d_in[21];
  const float* pmb       = (const float*)d_in[22];
  const float* fw        = (const float*)d_in[23];
  const float* fb        = (const float*)d_in[24];
  float* out = (float*)d_out;

  char* p = (char*)d_ws;
  auto alloc = [&](size_t bytes) {
    char* r = p;
    p += (bytes + 255) & ~(size_t)255;
    return r;
  };
  short* qkvwT  = (short*)alloc(6ull * 1536 * 512 * 2);
  short* projwT = (short*)alloc(6ull * 512 * 512 * 2);
  short* fc1wT  = (short*)alloc(6ull * 2048 * 512 * 2);
  short* fc2wT  = (short*)alloc(6ull * 512 * 2048 * 2);
  short* mqkvT  = (short*)alloc(3ull * 512 * 512 * 2);
  short* mprojT = (short*)alloc(512ull * 512 * 2);
  short* fwT    = (short*)alloc(512ull * 1024 * 2);
  short* bigb   = (short*)alloc((size_t)BS * 1536 * 2);
  float* hbuf   = (float*)alloc((size_t)BS * 512 * 4);
  float* t2     = (float*)alloc(512 * 4);
  short* actA   = (short*)alloc((size_t)BS * 512 * 2);
  short* ln0b   = (short*)alloc((size_t)BS * 512 * 2);
  short* attnb  = (short*)alloc((size_t)BS * 512 * 2);
  short* ff1b   = (short*)alloc((size_t)BS * 2048 * 2);
  short* stlt   = (short*)alloc((size_t)BS * 1024 * 2);
  short* Aq     = (short*)alloc(256ull * 16384 * 2);
  short* Bq     = (short*)alloc(256ull * 16384 * 2);
  short* MTg    = (short*)alloc(256ull * 16384 * 2);

  // ---- all weight transposes in one launch ----
  TcvtArgs ta;
  ta.j[0] = {qkvw,  qkvwT,  512, 1536, 48 * 16 * 6};
  ta.j[1] = {projw, projwT, 512, 512,  16 * 16 * 6};
  ta.j[2] = {fc1w,  fc1wT,  512, 2048, 64 * 16 * 6};
  ta.j[3] = {fc2w,  fc2wT,  2048, 512, 16 * 64 * 6};
  ta.j[4] = {mwq, mqkvT,                 512, 512, 256};
  ta.j[5] = {mwk, mqkvT + 512 * 512,     512, 512, 256};
  ta.j[6] = {mwv, mqkvT + 2 * 512 * 512, 512, 512, 256};
  ta.j[7] = {mprojw, mprojT, 512, 512, 256};
  ta.j[8] = {fw, fwT, 1024, 512, 512};
  ta.j[9] = {nullptr, nullptr, 32, 32, 0};
  int total_blks = 0;
  for (int i = 0; i < 10; ++i) total_blks += ta.j[i].blks;
  tcvt_all<<<total_blks, 256, 0, stream>>>(ta);

  persist_kernel<<<1, 512, 0, stream>>>(pm_tokens, pmw, pmb,
                                        fw + (size_t)1024 * 512, fb, t2);

  // ---- neural memory path ----
  ln_dual_kernel<<<BS / 4, 256, 0, stream>>>(x, mlnw, mlnb, actA, n1w, n1b, ln0b);
  gemm_bf16<0, 1, 128><<<dim3(12, 32), 256, 0, stream>>>(
      actA, mqkvT, nullptr, nullptr, nullptr, bigb, BS, 1536, 512, 1536);
  mem_prep<<<256, 256, 0, stream>>>(bigb + 512, bigb + 1024, Aq, Bq);
  mem_scan2<<<32, 256, 0, stream>>>(Aq, Bq, MTg);
  mem_out<<<256, 256, 0, stream>>>(bigb, MTg, ff1b);
  gemm_bf16<2, 1, 64><<<dim3(4, 64), 256, 0, stream>>>(
      ff1b, mprojT, mprojb, x, nullptr, stlt + 512, BS, 512, 512, 1024);

  // ---- layer stack ----
  for (int l = 0; l < LL; ++l) {
    const short* lnin = (l == 0) ? ln0b : actA;
    if (l > 0)
      ln_kernel<<<BS / 4, 256, 0, stream>>>(hbuf, n1w + l * 512, n1b + l * 512, actA);
    gemm_bf16<0, 1, 128><<<dim3(12, 32), 256, 0, stream>>>(
        lnin, qkvwT + (size_t)l * 1536 * 512, qkvb + l * 1536,
        nullptr, nullptr, bigb, BS, 1536, 512, 1536);
    swa_kernel<<<512, 256, 0, stream>>>((const unsigned short*)bigb, attnb);
    gemm_bf16<2, 0, 64><<<dim3(4, 64), 256, 0, stream>>>(
        attnb, projwT + (size_t)l * 512 * 512, projb + l * 512,
        (l == 0) ? x : hbuf, nullptr, hbuf, BS, 512, 512, 512);
    ln_kernel<<<BS / 4, 256, 0, stream>>>(hbuf, n2w + l * 512, n2b + l * 512, actA);
    gemm_bf16<1, 1, 128><<<dim3(16, 32), 256, 0, stream>>>(
        actA, fc1wT + (size_t)l * 2048 * 512, fc1b + l * 2048,
        nullptr, nullptr, ff1b, BS, 2048, 512, 2048);
    if (l < LL - 1)
      gemm_bf16<3, 0, 64><<<dim3(4, 64), 256, 0, stream>>>(
          ff1b, fc2wT + (size_t)l * 512 * 2048, fc2b + l * 512,
          hbuf, actA, hbuf, BS, 512, 2048, 512);
    else
      gemm_bf16<3, 1, 64><<<dim3(4, 64), 256, 0, stream>>>(
          ff1b, fc2wT + (size_t)l * 512 * 2048, fc2b + l * 512,
          hbuf, actA, stlt, BS, 512, 2048, 1024);   // ST -> stlt[:, 0:512]
  }

  // ---- fusion: out = [ST | LT] @ fwT + (persistent + fusion bias) ----
  gemm_bf16<0, 0, 64><<<dim3(4, 64), 256, 0, stream>>>(
      stlt, fwT, t2, nullptr, nullptr, out, BS, 512, 1024, 512);
}

// Round 10
// 783.130 us; speedup vs baseline: 4.9194x; 1.0431x over previous
//
#include <hip/hip_runtime.h>
#include <math.h>

// Problem constants
#define BB 2
#define SS 2048
#define DD 512
#define HH 8
#define LL 6
#define WW 64
#define CHH 64
#define NCC 32
#define BS (BB*SS)   // 4096 rows

typedef __attribute__((ext_vector_type(8))) short short8;
typedef __attribute__((ext_vector_type(4))) short short4v;
typedef __attribute__((ext_vector_type(4))) float f32x4;

__device__ inline float b2f(short s) {
  unsigned u = ((unsigned)(unsigned short)s) << 16;
  float f; __builtin_memcpy(&f, &u, 4); return f;
}
__device__ inline short f2b(float f) {
  unsigned u; __builtin_memcpy(&u, &f, 4);
  unsigned r = (u + 0x7FFFu + ((u >> 16) & 1u)) >> 16;
  return (short)r;
}
__device__ inline float gelu_tanh(float v) {
  float u = 0.7978845608f * (v + 0.044715f * v * v * v);
  u = fminf(fmaxf(u, -20.f), 20.f);
  float e2 = __expf(2.f * u);
  return 0.5f * v * (1.f + (e2 - 1.f) / (e2 + 1.f));
}

#define AS1(p) ((const __attribute__((address_space(1))) void*)(p))
#define AS3(p) ((__attribute__((address_space(3))) void*)(p))

// ---------------- LayerNorm: wave-per-row, 4 rows/block ----------------
__global__ __launch_bounds__(256) void ln_kernel(
    const float* __restrict__ x, const float* __restrict__ w,
    const float* __restrict__ b, short* __restrict__ y)
{
  const int row = blockIdx.x * 4 + (threadIdx.x >> 6);
  const int l = threadIdx.x & 63;
  const float* xr = x + (size_t)row * DD + l * 8;
  const float4 a = *(const float4*)xr;
  const float4 c = *(const float4*)(xr + 4);
  float s = a.x + a.y + a.z + a.w + c.x + c.y + c.z + c.w;
  float sq = a.x * a.x + a.y * a.y + a.z * a.z + a.w * a.w
           + c.x * c.x + c.y * c.y + c.z * c.z + c.w * c.w;
#pragma unroll
  for (int off = 1; off < 64; off <<= 1) {
    s += __shfl_xor(s, off);
    sq += __shfl_xor(sq, off);
  }
  const float mean = s * (1.f / DD);
  const float var = sq * (1.f / DD) - mean * mean;
  const float inv = rsqrtf(var + 1e-5f);
  const float4 w0 = *(const float4*)(w + l * 8);
  const float4 w1 = *(const float4*)(w + l * 8 + 4);
  const float4 b0 = *(const float4*)(b + l * 8);
  const float4 b1 = *(const float4*)(b + l * 8 + 4);
  short8 o;
  o[0] = f2b((a.x - mean) * inv * w0.x + b0.x);
  o[1] = f2b((a.y - mean) * inv * w0.y + b0.y);
  o[2] = f2b((a.z - mean) * inv * w0.z + b0.z);
  o[3] = f2b((a.w - mean) * inv * w0.w + b0.w);
  o[4] = f2b((c.x - mean) * inv * w1.x + b1.x);
  o[5] = f2b((c.y - mean) * inv * w1.y + b1.y);
  o[6] = f2b((c.z - mean) * inv * w1.z + b1.z);
  o[7] = f2b((c.w - mean) * inv * w1.w + b1.w);
  *(short8*)(y + (size_t)row * DD + l * 8) = o;
}

// ---------------- Dual LayerNorm: one read of x, two (w,b,y) ----------------
__global__ __launch_bounds__(256) void ln_dual_kernel(
    const float* __restrict__ x,
    const float* __restrict__ w1, const float* __restrict__ b1v, short* __restrict__ y1,
    const float* __restrict__ w2, const float* __restrict__ b2v, short* __restrict__ y2)
{
  const int row = blockIdx.x * 4 + (threadIdx.x >> 6);
  const int l = threadIdx.x & 63;
  const float* xr = x + (size_t)row * DD + l * 8;
  const float4 a = *(const float4*)xr;
  const float4 c = *(const float4*)(xr + 4);
  float s = a.x + a.y + a.z + a.w + c.x + c.y + c.z + c.w;
  float sq = a.x * a.x + a.y * a.y + a.z * a.z + a.w * a.w
           + c.x * c.x + c.y * c.y + c.z * c.z + c.w * c.w;
#pragma unroll
  for (int off = 1; off < 64; off <<= 1) {
    s += __shfl_xor(s, off);
    sq += __shfl_xor(sq, off);
  }
  const float mean = s * (1.f / DD);
  const float var = sq * (1.f / DD) - mean * mean;
  const float inv = rsqrtf(var + 1e-5f);
  const float n0 = (a.x - mean) * inv, n1 = (a.y - mean) * inv,
              n2 = (a.z - mean) * inv, n3 = (a.w - mean) * inv,
              n4 = (c.x - mean) * inv, n5 = (c.y - mean) * inv,
              n6 = (c.z - mean) * inv, n7 = (c.w - mean) * inv;
#pragma unroll
  for (int pass = 0; pass < 2; ++pass) {
    const float* w = pass ? w2 : w1;
    const float* b = pass ? b2v : b1v;
    short* y = pass ? y2 : y1;
    const float4 w0 = *(const float4*)(w + l * 8);
    const float4 w1_ = *(const float4*)(w + l * 8 + 4);
    const float4 bb0 = *(const float4*)(b + l * 8);
    const float4 bb1 = *(const float4*)(b + l * 8 + 4);
    short8 o;
    o[0] = f2b(n0 * w0.x + bb0.x);
    o[1] = f2b(n1 * w0.y + bb0.y);
    o[2] = f2b(n2 * w0.z + bb0.z);
    o[3] = f2b(n3 * w0.w + bb0.w);
    o[4] = f2b(n4 * w1_.x + bb1.x);
    o[5] = f2b(n5 * w1_.y + bb1.y);
    o[6] = f2b(n6 * w1_.z + bb1.z);
    o[7] = f2b(n7 * w1_.w + bb1.w);
    *(short8*)(y + (size_t)row * DD + l * 8) = o;
  }
}

// ---------------- bf16 MFMA GEMM, BK=64, XOR-swizzled LDS ----------------
// EPI: 0=+bias(opt); 1=gelu(+bias); 2=+bias(opt)+add1(f32); 3=+bias+add1(f32)+add2(bf16)
// OBF: 0=f32 out (stride N); 1=bf16 out (stride NS)
// LDS tile [row][64] (128B rows); content at 16B-unit u holds data unit u^(row&7)
// (pre-swizzled global source piece); frag reads XOR with ((lane&7)<<4).
template<int EPI, int OBF, int BM>
__global__ __launch_bounds__(256) void gemm_bf16(
    const short* __restrict__ A, const short* __restrict__ BT,
    const float* __restrict__ bias, const float* __restrict__ add1,
    const short* __restrict__ add2, void* __restrict__ C,
    int M, int N, int K, int NS)
{
  constexpr int MF = BM / 32;   // per-wave M fragments (wave tile = BM/2 x 64)
  constexpr int AR = BM / 32;   // A staging rounds (32 rows per round)
  __shared__ __align__(16) short As[BM * 64];
  __shared__ __align__(16) short Bs[128 * 64];
  const int tid = threadIdx.x;
  const int wave = tid >> 6, lane = tid & 63;
  const int wr = wave >> 1, wc = wave & 1;
  const int bm = blockIdx.y * BM, bn = blockIdx.x * 128;

  const int srow = tid >> 3;                 // row within 32-row round
  const int dpiece = tid & 7;                // dest 16B unit
  const int spiece = dpiece ^ (srow & 7);    // pre-swizzled source unit

  const short* sA[AR]; const short* sB[4];
  int ldsA[AR], ldsB[4];
#pragma unroll
  for (int r = 0; r < AR; ++r) {
    const int row = r * 32 + srow;
    sA[r] = A + (size_t)(bm + row) * K + spiece * 8;
    ldsA[r] = row * 128 + dpiece * 16;
  }
#pragma unroll
  for (int r = 0; r < 4; ++r) {
    const int row = r * 32 + srow;
    sB[r] = BT + (size_t)(bn + row) * K + spiece * 8;
    ldsB[r] = row * 128 + dpiece * 16;
  }

  const int xr = (lane & 7) << 4;            // frag-read XOR (lane-constant)
  f32x4 acc[MF][4] = {};

  for (int k0 = 0; k0 < K; k0 += 64) {
#pragma unroll
    for (int r = 0; r < AR; ++r) {
      __builtin_amdgcn_global_load_lds(AS1(sA[r]), AS3((char*)As + ldsA[r]), 16, 0, 0);
      sA[r] += 64;
    }
#pragma unroll
    for (int r = 0; r < 4; ++r) {
      __builtin_amdgcn_global_load_lds(AS1(sB[r]), AS3((char*)Bs + ldsB[r]), 16, 0, 0);
      sB[r] += 64;
    }
    __syncthreads();
    short8 af[MF][2], bf[4][2];
#pragma unroll
    for (int m = 0; m < MF; ++m)
#pragma unroll
      for (int kk = 0; kk < 2; ++kk) {
        const int row = wr * (BM / 2) + m * 16 + (lane & 15);
        af[m][kk] = *(const short8*)((char*)As + ((row * 128 + kk * 64 + (lane >> 4) * 16) ^ xr));
      }
#pragma unroll
    for (int n = 0; n < 4; ++n)
#pragma unroll
      for (int kk = 0; kk < 2; ++kk) {
        const int row = wc * 64 + n * 16 + (lane & 15);
        bf[n][kk] = *(const short8*)((char*)Bs + ((row * 128 + kk * 64 + (lane >> 4) * 16) ^ xr));
      }
#pragma unroll
    for (int kk = 0; kk < 2; ++kk)
#pragma unroll
      for (int m = 0; m < MF; ++m)
#pragma unroll
        for (int n = 0; n < 4; ++n)
          acc[m][n] = __builtin_amdgcn_mfma_f32_16x16x32_bf16(af[m][kk], bf[n][kk], acc[m][n], 0, 0, 0);
    __syncthreads();
  }

#pragma unroll
  for (int m = 0; m < MF; ++m) {
#pragma unroll
    for (int n = 0; n < 4; ++n) {
      const int col = bn + wc * 64 + n * 16 + (lane & 15);
      const float bb = (EPI == 1 || EPI == 3) ? bias[col] : (bias ? bias[col] : 0.f);
#pragma unroll
      for (int r = 0; r < 4; ++r) {
        const int row = bm + wr * (BM / 2) + m * 16 + (lane >> 4) * 4 + r;
        const size_t idx = (size_t)row * N + col;
        float v = acc[m][n][r] + bb;
        if (EPI == 1) v = gelu_tanh(v);
        if (EPI == 2 || EPI == 3) v += add1[idx];
        if (EPI == 3) v += b2f(add2[idx]);
        if (OBF == 1) ((short*)C)[(size_t)row * NS + col] = f2b(v);
        else ((float*)C)[idx] = v;
      }
    }
  }
}

// ---------------- Sliding-window attention (bf16 qkv in, bf16 out) ----------
__global__ __launch_bounds__(256) void swa_kernel(
    const unsigned short* __restrict__ qkv, short* __restrict__ out)
{
  __shared__ __align__(16) short ks[128 * 72];
  __shared__ __align__(16) short vt[64 * 136];
  __shared__ __align__(16) short ps[4][16 * 136];
  __shared__ float lsum[64];

  const int tid = threadIdx.x;
  const int w = tid >> 6, l = tid & 63;
  const int tile = blockIdx.x & 31;
  const int h = (blockIdx.x >> 5) & 7;
  const int b = blockIdx.x >> 8;
  const int s0 = tile * 64;
  const size_t base = (size_t)b * SS;

#pragma unroll
  for (int u = 0; u < 16; ++u) {
    const int id = u * 256 + tid;
    const int row = id >> 5, dp = id & 31;
    int jp = s0 - 32 + row;
    jp = min(max(jp, 0), SS - 1);
    const size_t g = (base + jp) * 1536 + h * 64 + dp * 2;
    *(unsigned*)&ks[row * 72 + dp * 2] = *(const unsigned*)&qkv[g + 512];
    const unsigned vv = *(const unsigned*)&qkv[g + 1024];
    vt[(dp * 2) * 136 + row] = (short)(vv & 0xFFFF);
    vt[(dp * 2 + 1) * 136 + row] = (short)(vv >> 16);
  }

  const int qi = w * 16 + (l & 15);
  short8 qf[2];
#pragma unroll
  for (int kf = 0; kf < 2; ++kf)
    qf[kf] = *(const short8*)&qkv[(base + s0 + qi) * 1536 + h * 64 + kf * 32 + (l >> 4) * 8];
  __syncthreads();

  f32x4 sa[8] = {};
#pragma unroll
  for (int mf = 0; mf < 8; ++mf)
#pragma unroll
    for (int kf = 0; kf < 2; ++kf) {
      const short8 af = *(const short8*)&ks[(mf * 16 + (l & 15)) * 72 + kf * 32 + (l >> 4) * 8];
      sa[mf] = __builtin_amdgcn_mfma_f32_16x16x32_bf16(af, qf[kf], sa[mf], 0, 0, 0);
    }

  float sv[8][4];
  float mx = -INFINITY;
#pragma unroll
  for (int mf = 0; mf < 8; ++mf)
#pragma unroll
    for (int r = 0; r < 4; ++r) {
      const int j = mf * 16 + (l >> 4) * 4 + r;
      const int jpos = s0 - 32 + j;
      const bool ok = (j >= qi) && (j <= qi + 64) && (jpos >= 0) && (jpos < SS);
      const float s = ok ? sa[mf][r] * 0.125f : -INFINITY;
      sv[mf][r] = s;
      mx = fmaxf(mx, s);
    }
  mx = fmaxf(mx, __shfl_xor(mx, 16));
  mx = fmaxf(mx, __shfl_xor(mx, 32));
  float ls = 0.f;
#pragma unroll
  for (int mf = 0; mf < 8; ++mf)
#pragma unroll
    for (int r = 0; r < 4; ++r) {
      const float p = __expf(sv[mf][r] - mx);
      sv[mf][r] = p;
      ls += p;
    }
  ls += __shfl_xor(ls, 16);
  ls += __shfl_xor(ls, 32);
  if (l < 16) lsum[w * 16 + l] = ls;

#pragma unroll
  for (int mf = 0; mf < 8; ++mf) {
    short4v p4;
    p4.x = f2b(sv[mf][0]); p4.y = f2b(sv[mf][1]);
    p4.z = f2b(sv[mf][2]); p4.w = f2b(sv[mf][3]);
    *(short4v*)&ps[w][(l & 15) * 136 + mf * 16 + (l >> 4) * 4] = p4;
  }

  f32x4 oa[4] = {};
#pragma unroll
  for (int kf = 0; kf < 4; ++kf) {
    const short8 pf = *(const short8*)&ps[w][(l & 15) * 136 + kf * 32 + (l >> 4) * 8];
#pragma unroll
    for (int nf = 0; nf < 4; ++nf) {
      const short8 vf = *(const short8*)&vt[(nf * 16 + (l & 15)) * 136 + kf * 32 + (l >> 4) * 8];
      oa[nf] = __builtin_amdgcn_mfma_f32_16x16x32_bf16(pf, vf, oa[nf], 0, 0, 0);
    }
  }

  float rl[4];
#pragma unroll
  for (int r = 0; r < 4; ++r) rl[r] = 1.f / lsum[w * 16 + (l >> 4) * 4 + r];
#pragma unroll
  for (int nf = 0; nf < 4; ++nf)
#pragma unroll
    for (int r = 0; r < 4; ++r) {
      const int q = (l >> 4) * 4 + r;
      const int d = nf * 16 + (l & 15);
      out[(base + s0 + w * 16 + q) * 512 + h * 64 + d] = f2b(oa[nf][r] * rl[r]);
    }
}

// ========== Neural memory, linear-scan formulation ==========
// grad_c = A_c M_{c-1} - B_c,  A_c = k^T k/64 (bf16, XOR-swizzled, via symmetry),
// B_c = k^T v/64 (bf16, stored TRANSPOSED [e][d])

// ---- P1: per (chain, chunk) compute A_c, B_c via MFMA (bf16 k,v inputs) ----
__global__ __launch_bounds__(256) void mem_prep(
    const short* __restrict__ kb, const short* __restrict__ vb,
    short* __restrict__ Aq, short* __restrict__ Bq)
{
  __shared__ __align__(16) short kn[64 * 136];
  __shared__ __align__(16) char kT[128 * 128];
  __shared__ __align__(16) char vT[128 * 128];
  const int bid = blockIdx.x;
  const int chain = bid >> 5, c = bid & 31;
  const int b = chain >> 2, mh = chain & 3;
  const size_t rowbase = (size_t)(b * SS + c * 64);
  const int tid = threadIdx.x, w = tid >> 6, l = tid & 63;
  const int td = tid & 127, rh = tid >> 7;

#pragma unroll
  for (int pass = 0; pass < 2; ++pass) {
    const short* src = pass ? vb : kb;
    char* dT = pass ? vT : kT;
#pragma unroll
    for (int j = 0; j < 4; ++j) {
      const int i4 = tid + 256 * j;
      const int r = i4 >> 4, d8 = (i4 & 15) * 8;
      *(short8*)&kn[r * 136 + d8] = *(const short8*)&src[(rowbase + r) * 1536 + mh * 128 + d8];
    }
    __syncthreads();
#pragma unroll
    for (int j = 0; j < 4; ++j) {
      const int r0 = rh * 8 + 16 * j;
      short8 g8;
#pragma unroll
      for (int t = 0; t < 8; ++t) g8[t] = kn[(r0 + t) * 136 + td];
      *(short8*)&dT[(td * 128 + r0 * 2) ^ ((td & 7) << 4)] = g8;
    }
    __syncthreads();
  }

  const int wr = w >> 1, wc = w & 1;
  {
    f32x4 acc[4][4] = {};
#pragma unroll
    for (int kf = 0; kf < 2; ++kf) {
      short8 af[4];
#pragma unroll
      for (int m = 0; m < 4; ++m) {
        const int d = wr * 64 + m * 16 + (l & 15);
        af[m] = *(const short8*)&kT[(d * 128 + kf * 64 + (l >> 4) * 16) ^ ((d & 7) << 4)];
      }
#pragma unroll
      for (int n = 0; n < 4; ++n) {
        const int dp = wc * 64 + n * 16 + (l & 15);
        const short8 bf = *(const short8*)&kT[(dp * 128 + kf * 64 + (l >> 4) * 16) ^ ((dp & 7) << 4)];
#pragma unroll
        for (int m = 0; m < 4; ++m)
          acc[m][n] = __builtin_amdgcn_mfma_f32_16x16x32_bf16(af[m], bf, acc[m][n], 0, 0, 0);
      }
    }
    char* Ad = (char*)(Aq + (size_t)bid * 16384);
#pragma unroll
    for (int m = 0; m < 4; ++m)
#pragma unroll
      for (int n = 0; n < 4; ++n) {
        const int dp = wc * 64 + n * 16 + (l & 15);
        const int d0 = wr * 64 + m * 16 + (l >> 4) * 4;
        short4v s4;
#pragma unroll
        for (int i = 0; i < 4; ++i) s4[i] = f2b(acc[m][n][i] * 0.015625f);
        *(short4v*)&Ad[(dp * 256 + d0 * 2) ^ ((dp & 7) << 4)] = s4;
      }
  }
  {
    f32x4 acc[4][4] = {};
#pragma unroll
    for (int kf = 0; kf < 2; ++kf) {
      short8 af[4];
#pragma unroll
      for (int m = 0; m < 4; ++m) {
        const int d = wr * 64 + m * 16 + (l & 15);
        af[m] = *(const short8*)&kT[(d * 128 + kf * 64 + (l >> 4) * 16) ^ ((d & 7) << 4)];
      }
#pragma unroll
      for (int n = 0; n < 4; ++n) {
        const int e = wc * 64 + n * 16 + (l & 15);
        const short8 bf = *(const short8*)&vT[(e * 128 + kf * 64 + (l >> 4) * 16) ^ ((e & 7) << 4)];
#pragma unroll
        for (int m = 0; m < 4; ++m)
          acc[m][n] = __builtin_amdgcn_mfma_f32_16x16x32_bf16(af[m], bf, acc[m][n], 0, 0, 0);
      }
    }
    short* Bd = Bq + (size_t)bid * 16384;
#pragma unroll
    for (int m = 0; m < 4; ++m)
#pragma unroll
      for (int n = 0; n < 4; ++n) {
        const int e = wc * 64 + n * 16 + (l & 15);
        const int d0 = wr * 64 + m * 16 + (l >> 4) * 4;
        short4v s4;
#pragma unroll
        for (int i = 0; i < 4; ++i) s4[i] = f2b(acc[m][n][i] * 0.015625f);
        *(short4v*)&Bd[e * 128 + d0] = s4;
      }
  }
}

// ---- P2: serial scan — raw s_barrier + counted vmcnt, depth-2 A prefetch ----
__global__ __launch_bounds__(256) void mem_scan2(
    const short* __restrict__ Aq, const short* __restrict__ Bq,
    short* __restrict__ MTg)
{
  __shared__ __align__(16) char AcL[3][32768];
  __shared__ __align__(16) char MT[2][8192];
  const int bid = blockIdx.x;
  const int chain = bid >> 2, ch = bid & 3;
  const int tid = threadIdx.x;
  const int w = tid >> 6, l = tid & 63;
  const int wr = w >> 1, wc = w & 1;
  const int e = wc * 16 + (l & 15);

  const short* Ab = Aq + (size_t)chain * 32 * 16384;
  const short* Bb = Bq + (size_t)chain * 32 * 16384;
  short* MTb = MTg + (size_t)chain * 32 * 16384 + (size_t)ch * 32 * 128;
  const int brow = (ch * 32 + e) * 128;

  // prologue: zero MT[0]; stage A(0),A(1); load B(0),B(1); full sync
  {
    const short8 z = {0, 0, 0, 0, 0, 0, 0, 0};
    for (int i = tid; i < 512; i += 256) *(short8*)(MT[0] + i * 16) = z;
  }
#pragma unroll
  for (int cc = 0; cc < 2; ++cc) {
    const char* srcA = (const char*)(Ab + (size_t)cc * 16384);
#pragma unroll
    for (int j = 0; j < 8; ++j) {
      const int byte = tid * 16 + j * 4096;
      __builtin_amdgcn_global_load_lds(AS1(srcA + byte), AS3(AcL[cc] + byte), 16, 0, 0);
    }
  }
  short4v b0[4], b1[4], b2[4];
#pragma unroll
  for (int m = 0; m < 4; ++m) {
    b0[m] = *(const short4v*)&Bb[brow + wr * 64 + m * 16 + (l >> 4) * 4];
    b1[m] = *(const short4v*)&Bb[16384 + brow + wr * 64 + m * 16 + (l >> 4) * 4];
  }
  float Mreg[16] = {}, Momreg[16] = {};
  __syncthreads();

#define SCHUNK(C, AB, MR, BC, BN, DOI, WN)                                     \
  {                                                                            \
    short* slot = MTb + (size_t)(C) * 16384;                                   \
    _Pragma("unroll") for (int m = 0; m < 4; ++m) {                            \
      const int d0 = wr * 64 + m * 16 + (l >> 4) * 4;                          \
      short4v s4;                                                              \
      _Pragma("unroll") for (int i = 0; i < 4; ++i) s4[i] = f2b(Mreg[m * 4 + i]); \
      *(short4v*)&slot[e * 128 + d0] = s4;                                     \
    }                                                                          \
    if (DOI) {                                                                 \
      const char* srcA = (const char*)(Ab + (size_t)((C) + 2) * 16384);        \
      _Pragma("unroll") for (int j = 0; j < 8; ++j) {                          \
        const int byte = tid * 16 + j * 4096;                                  \
        __builtin_amdgcn_global_load_lds(AS1(srcA + byte),                     \
            AS3(AcL[((C) + 2) % 3] + byte), 16, 0, 0);                         \
      }                                                                        \
      const short* Bn = Bb + (size_t)((C) + 2) * 16384;                        \
      _Pragma("unroll") for (int m = 0; m < 4; ++m)                            \
        BN[m] = *(const short4v*)&Bn[brow + wr * 64 + m * 16 + (l >> 4) * 4];  \
    }                                                                          \
    {                                                                          \
      f32x4 acc[4] = {};                                                       \
      _Pragma("unroll") for (int kf = 0; kf < 4; ++kf) {                       \
        const short8 bf = *(const short8*)&MT[MR][(e * 256 + kf * 64 + (l >> 4) * 16) ^ ((e & 7) << 4)]; \
        _Pragma("unroll") for (int m = 0; m < 4; ++m) {                        \
          const int d = wr * 64 + m * 16 + (l & 15);                           \
          const short8 af = *(const short8*)&AcL[AB][(d * 256 + kf * 64 + (l >> 4) * 16) ^ ((d & 7) << 4)]; \
          acc[m] = __builtin_amdgcn_mfma_f32_16x16x32_bf16(af, bf, acc[m], 0, 0, 0); \
        }                                                                      \
      }                                                                        \
      _Pragma("unroll") for (int m = 0; m < 4; ++m) {                          \
        const int d0 = wr * 64 + m * 16 + (l >> 4) * 4;                        \
        short4v s4;                                                            \
        _Pragma("unroll") for (int i = 0; i < 4; ++i) {                        \
          const int idx = m * 4 + i;                                           \
          const float g = acc[m][i] - b2f(BC[m][i]);                           \
          Momreg[idx] = 0.9f * Momreg[idx] - 0.1f * g;                         \
          Mreg[idx] = 0.99f * Mreg[idx] + Momreg[idx];                         \
          s4[i] = f2b(Mreg[idx]);                                              \
        }                                                                      \
        *(short4v*)&MT[(MR) ^ 1][(e * 256 + d0 * 2) ^ ((e & 7) << 4)] = s4;    \
      }                                                                        \
    }                                                                          \
    asm volatile("s_waitcnt lgkmcnt(0) vmcnt(" #WN ")" ::: "memory");          \
    __builtin_amdgcn_sched_barrier(0);                                         \
    __builtin_amdgcn_s_barrier();                                              \
    __builtin_amdgcn_sched_barrier(0);                                         \
  }

  SCHUNK(0, 0, 0, b0, b2, 1, 20)  SCHUNK(1, 1, 1, b1, b0, 1, 20)
  SCHUNK(2, 2, 0, b2, b1, 1, 20)  SCHUNK(3, 0, 1, b0, b2, 1, 20)
  SCHUNK(4, 1, 0, b1, b0, 1, 20)  SCHUNK(5, 2, 1, b2, b1, 1, 20)
  SCHUNK(6, 0, 0, b0, b2, 1, 20)  SCHUNK(7, 1, 1, b1, b0, 1, 20)
  SCHUNK(8, 2, 0, b2, b1, 1, 20)  SCHUNK(9, 0, 1, b0, b2, 1, 20)
  SCHUNK(10, 1, 0, b1, b0, 1, 20) SCHUNK(11, 2, 1, b2, b1, 1, 20)
  SCHUNK(12, 0, 0, b0, b2, 1, 20) SCHUNK(13, 1, 1, b1, b0, 1, 20)
  SCHUNK(14, 2, 0, b2, b1, 1, 20) SCHUNK(15, 0, 1, b0, b2, 1, 20)
  SCHUNK(16, 1, 0, b1, b0, 1, 20) SCHUNK(17, 2, 1, b2, b1, 1, 20)
  SCHUNK(18, 0, 0, b0, b2, 1, 20) SCHUNK(19, 1, 1, b1, b0, 1, 20)
  SCHUNK(20, 2, 0, b2, b1, 1, 20) SCHUNK(21, 0, 1, b0, b2, 1, 20)
  SCHUNK(22, 1, 0, b1, b0, 1, 20) SCHUNK(23, 2, 1, b2, b1, 1, 20)
  SCHUNK(24, 0, 0, b0, b2, 1, 20) SCHUNK(25, 1, 1, b1, b0, 1, 20)
  SCHUNK(26, 2, 0, b2, b1, 1, 20) SCHUNK(27, 0, 1, b0, b2, 1, 20)
  SCHUNK(28, 1, 0, b1, b0, 1, 20) SCHUNK(29, 2, 1, b2, b1, 0, 8)
  SCHUNK(30, 0, 0, b0, b2, 0, 8)
#undef SCHUNK

  // epilogue: slot 31 = M_30
  {
    short* slot = MTb + (size_t)31 * 16384;
#pragma unroll
    for (int m = 0; m < 4; ++m) {
      const int d0 = wr * 64 + m * 16 + (l >> 4) * 4;
      short4v s4;
#pragma unroll
      for (int i = 0; i < 4; ++i) s4[i] = f2b(Mreg[m * 4 + i]);
      *(short4v*)&slot[e * 128 + d0] = s4;
    }
  }
}

// ---- P3: out_c = q_c @ M_{c-1} (bf16 q input) ----
__global__ __launch_bounds__(256) void mem_out(
    const short* __restrict__ qb, const short* __restrict__ MTg,
    short* __restrict__ mem)
{
  const int bid = blockIdx.x;
  const int chain = bid >> 5, c = bid & 31;
  const int b = chain >> 2, mh = chain & 3;
  const size_t rowbase = (size_t)(b * SS + c * 64);
  const int tid = threadIdx.x, w = tid >> 6, l = tid & 63;
  const int wr = w >> 1, wc = w & 1;
  const short* MTc = MTg + (size_t)chain * 32 * 16384 + (size_t)c * 16384;

  f32x4 acc[2][4] = {};
#pragma unroll
  for (int kf = 0; kf < 4; ++kf) {
    short8 af[2];
#pragma unroll
    for (int m = 0; m < 2; ++m) {
      const int r = wr * 32 + m * 16 + (l & 15);
      af[m] = *(const short8*)&qb[(rowbase + r) * 1536 + mh * 128 + kf * 32 + (l >> 4) * 8];
    }
#pragma unroll
    for (int n = 0; n < 4; ++n) {
      const int e = wc * 64 + n * 16 + (l & 15);
      const short8 bf = *(const short8*)&MTc[e * 128 + kf * 32 + (l >> 4) * 8];
#pragma unroll
      for (int m = 0; m < 2; ++m)
        acc[m][n] = __builtin_amdgcn_mfma_f32_16x16x32_bf16(af[m], bf, acc[m][n], 0, 0, 0);
    }
  }
#pragma unroll
  for (int m = 0; m < 2; ++m)
#pragma unroll
    for (int n = 0; n < 4; ++n)
#pragma unroll
      for (int i = 0; i < 4; ++i) {
        const int r = wr * 32 + m * 16 + (l >> 4) * 4 + i;
        const int e = wc * 64 + n * 16 + (l & 15);
        mem[(rowbase + r) * 512 + mh * 128 + e] = f2b(acc[m][n][i]);
      }
}

// ---------------- merged weight transpose+convert (all matrices, 1 launch) ---
struct TcvtJob { const float* src; short* dst; int K; int N; int blks; };
struct TcvtArgs { TcvtJob j[10]; };

__global__ __launch_bounds__(256) void tcvt_all(TcvtArgs a)
{
  int bid = blockIdx.x;
  const float* src = nullptr; short* dst = nullptr; int K = 0, N = 0;
#pragma unroll
  for (int i = 0; i < 10; ++i) {
    if (!src) {
      if (bid < a.j[i].blks) { src = a.j[i].src; dst = a.j[i].dst; K = a.j[i].K; N = a.j[i].N; }
      else bid -= a.j[i].blks;
    }
  }
  const int nt = N >> 5, kt = K >> 5;
  const int z = bid / (nt * kt);
  const int rem = bid % (nt * kt);
  const int k0 = (rem / nt) * 32, n0 = (rem % nt) * 32;
  const size_t zoff = (size_t)z * K * N;
  src += zoff; dst += zoff;

  __shared__ float t[32][33];
  const int tx = threadIdx.x & 31, ty = threadIdx.x >> 5;
#pragma unroll
  for (int i = 0; i < 4; ++i)
    t[ty + i * 8][tx] = src[(size_t)(k0 + ty + i * 8) * N + n0 + tx];
  __syncthreads();
#pragma unroll
  for (int i = 0; i < 4; ++i)
    dst[(size_t)(n0 + ty + i * 8) * K + k0 + tx] = f2b(t[tx][ty + i * 8]);
}

// ---------------- persistent path: 1 block, 512 threads -------------------
__global__ __launch_bounds__(512) void persist_kernel(
    const float* __restrict__ pm, const float* __restrict__ pmw,
    const float* __restrict__ pmb, const float* __restrict__ fw2,
    const float* __restrict__ fb, float* __restrict__ t2)
{
  __shared__ float t0[512], t1[512];
  const int e = threadIdx.x;
  float s = 0.f;
#pragma unroll
  for (int t = 0; t < 16; ++t) s += pm[t * 512 + e];
  t0[e] = s * (1.f / 16.f);
  __syncthreads();
  float p = pmb[e];
  for (int d = 0; d < 512; ++d) p += t0[d] * pmw[d * 512 + e];
  t1[e] = p;
  __syncthreads();
  float q = fb[e];
  for (int d = 0; d < 512; ++d) q += t1[d] * fw2[d * 512 + e];
  t2[e] = q;
}

// ---------------- host side ----------------
extern "C" void kernel_launch(void* const* d_in, const int* in_sizes, int n_in,
                              void* d_out, int out_size, void* d_ws, size_t ws_size,
                              hipStream_t stream)
{
  const float* x         = (const float*)d_in[0];
  const float* n1w       = (const float*)d_in[1];
  const float* n1b       = (const float*)d_in[2];
  const float* qkvw      = (const float*)d_in[3];
  const float* qkvb      = (const float*)d_in[4];
  const float* projw     = (const float*)d_in[5];
  const float* projb     = (const float*)d_in[6];
  const float* n2w       = (const float*)d_in[7];
  const float* n2b       = (const float*)d_in[8];
  const float* fc1w      = (const float*)d_in[9];
  const float* fc1b      = (const float*)d_in[10];
  const float* fc2w      = (const float*)d_in[11];
  const float* fc2b      = (const float*)d_in[12];
  const float* mlnw      = (const float*)d_in[13];
  const float* mlnb      = (const float*)d_in[14];
  const float* mwq       = (const float*)d_in[15];
  const float* mwk       = (const float*)d_in[16];
  const float* mwv       = (const float*)d_in[17];
  const float* mprojw    = (const float*)d_in[18];
  const float* mprojb    = (const float*)d_in[19];
  const float* pm_tokens = (const float*)d_in[20];
  const float* pmw       = (const float*)d_in[21];
  const float* pmb       = (const float*)d_in[22];
  const float* fw        = (const float*)d_in[23];
  const float* fb        = (const float*)d_in[24];
  float* out = (float*)d_out;

  char* p = (char*)d_ws;
  auto alloc = [&](size_t bytes) {
    char* r = p;
    p += (bytes + 255) & ~(size_t)255;
    return r;
  };
  short* qkvwT  = (short*)alloc(6ull * 1536 * 512 * 2);
  short* projwT = (short*)alloc(6ull * 512 * 512 * 2);
  short* fc1wT  = (short*)alloc(6ull * 2048 * 512 * 2);
  short* fc2wT  = (short*)alloc(6ull * 512 * 2048 * 2);
  short* mqkvT  = (short*)alloc(3ull * 512 * 512 * 2);
  short* mprojT = (short*)alloc(512ull * 512 * 2);
  short* fwT    = (short*)alloc(512ull * 1024 * 2);
  short* bigb   = (short*)alloc((size_t)BS * 1536 * 2);
  float* hbuf   = (float*)alloc((size_t)BS * 512 * 4);
  float* t2     = (float*)alloc(512 * 4);
  short* actA   = (short*)alloc((size_t)BS * 512 * 2);
  short* ln0b   = (short*)alloc((size_t)BS * 512 * 2);
  short* attnb  = (short*)alloc((size_t)BS * 512 * 2);
  short* ff1b   = (short*)alloc((size_t)BS * 2048 * 2);
  short* stlt   = (short*)alloc((size_t)BS * 1024 * 2);
  short* Aq     = (short*)alloc(256ull * 16384 * 2);
  short* Bq     = (short*)alloc(256ull * 16384 * 2);
  short* MTg    = (short*)alloc(256ull * 16384 * 2);

  // ---- all weight transposes in one launch ----
  TcvtArgs ta;
  ta.j[0] = {qkvw,  qkvwT,  512, 1536, 48 * 16 * 6};
  ta.j[1] = {projw, projwT, 512, 512,  16 * 16 * 6};
  ta.j[2] = {fc1w,  fc1wT,  512, 2048, 64 * 16 * 6};
  ta.j[3] = {fc2w,  fc2wT,  2048, 512, 16 * 64 * 6};
  ta.j[4] = {mwq, mqkvT,                 512, 512, 256};
  ta.j[5] = {mwk, mqkvT + 512 * 512,     512, 512, 256};
  ta.j[6] = {mwv, mqkvT + 2 * 512 * 512, 512, 512, 256};
  ta.j[7] = {mprojw, mprojT, 512, 512, 256};
  ta.j[8] = {fw, fwT, 1024, 512, 512};
  ta.j[9] = {nullptr, nullptr, 32, 32, 0};
  int total_blks = 0;
  for (int i = 0; i < 10; ++i) total_blks += ta.j[i].blks;
  tcvt_all<<<total_blks, 256, 0, stream>>>(ta);

  persist_kernel<<<1, 512, 0, stream>>>(pm_tokens, pmw, pmb,
                                        fw + (size_t)1024 * 512, fb, t2);

  // ---- neural memory path ----
  ln_dual_kernel<<<BS / 4, 256, 0, stream>>>(x, mlnw, mlnb, actA, n1w, n1b, ln0b);
  gemm_bf16<0, 1, 128><<<dim3(12, 32), 256, 0, stream>>>(
      actA, mqkvT, nullptr, nullptr, nullptr, bigb, BS, 1536, 512, 1536);
  mem_prep<<<256, 256, 0, stream>>>(bigb + 512, bigb + 1024, Aq, Bq);
  mem_scan2<<<32, 256, 0, stream>>>(Aq, Bq, MTg);
  mem_out<<<256, 256, 0, stream>>>(bigb, MTg, ff1b);
  gemm_bf16<2, 1, 64><<<dim3(4, 64), 256, 0, stream>>>(
      ff1b, mprojT, mprojb, x, nullptr, stlt + 512, BS, 512, 512, 1024);

  // ---- layer stack ----
  for (int l = 0; l < LL; ++l) {
    const short* lnin = (l == 0) ? ln0b : actA;
    if (l > 0)
      ln_kernel<<<BS / 4, 256, 0, stream>>>(hbuf, n1w + l * 512, n1b + l * 512, actA);
    gemm_bf16<0, 1, 128><<<dim3(12, 32), 256, 0, stream>>>(
        lnin, qkvwT + (size_t)l * 1536 * 512, qkvb + l * 1536,
        nullptr, nullptr, bigb, BS, 1536, 512, 1536);
    swa_kernel<<<512, 256, 0, stream>>>((const unsigned short*)bigb, attnb);
    gemm_bf16<2, 0, 64><<<dim3(4, 64), 256, 0, stream>>>(
        attnb, projwT + (size_t)l * 512 * 512, projb + l * 512,
        (l == 0) ? x : hbuf, nullptr, hbuf, BS, 512, 512, 512);
    ln_kernel<<<BS / 4, 256, 0, stream>>>(hbuf, n2w + l * 512, n2b + l * 512, actA);
    gemm_bf16<1, 1, 128><<<dim3(16, 32), 256, 0, stream>>>(
        actA, fc1wT + (size_t)l * 2048 * 512, fc1b + l * 2048,
        nullptr, nullptr, ff1b, BS, 2048, 512, 2048);
    if (l < LL - 1)
      gemm_bf16<3, 0, 64><<<dim3(4, 64), 256, 0, stream>>>(
          ff1b, fc2wT + (size_t)l * 512 * 2048, fc2b + l * 512,
          hbuf, actA, hbuf, BS, 512, 2048, 512);
    else
      gemm_bf16<3, 1, 64><<<dim3(4, 64), 256, 0, stream>>>(
          ff1b, fc2wT + (size_t)l * 512 * 2048, fc2b + l * 512,
          hbuf, actA, stlt, BS, 512, 2048, 1024);   // ST -> stlt[:, 0:512]
  }

  // ---- fusion: out = [ST | LT] @ fwT + (persistent + fusion bias) ----
  gemm_bf16<0, 0, 64><<<dim3(4, 64), 256, 0, stream>>>(
      stlt, fwT, t2, nullptr, nullptr, out, BS, 512, 1024, 512);
}

// Round 11
// 764.694 us; speedup vs baseline: 5.0380x; 1.0241x over previous
//
#include <hip/hip_runtime.h>
#include <math.h>

// Problem constants
#define BB 2
#define SS 2048
#define DD 512
#define HH 8
#define LL 6
#define WW 64
#define CHH 64
#define NCC 32
#define BS (BB*SS)   // 4096 rows

typedef __attribute__((ext_vector_type(8))) short short8;
typedef __attribute__((ext_vector_type(4))) short short4v;
typedef __attribute__((ext_vector_type(4))) float f32x4;

__device__ inline float b2f(short s) {
  unsigned u = ((unsigned)(unsigned short)s) << 16;
  float f; __builtin_memcpy(&f, &u, 4); return f;
}
__device__ inline short f2b(float f) {
  unsigned u; __builtin_memcpy(&u, &f, 4);
  unsigned r = (u + 0x7FFFu + ((u >> 16) & 1u)) >> 16;
  return (short)r;
}
__device__ inline float gelu_tanh(float v) {
  float u = 0.7978845608f * (v + 0.044715f * v * v * v);
  u = fminf(fmaxf(u, -20.f), 20.f);
  float e2 = __expf(2.f * u);
  return 0.5f * v * (1.f + (e2 - 1.f) / (e2 + 1.f));
}

#define AS1(p) ((const __attribute__((address_space(1))) void*)(p))
#define AS3(p) ((__attribute__((address_space(3))) void*)(p))

// ---------------- LayerNorm: wave-per-row, 4 rows/block ----------------
__global__ __launch_bounds__(256) void ln_kernel(
    const float* __restrict__ x, const float* __restrict__ w,
    const float* __restrict__ b, short* __restrict__ y)
{
  const int row = blockIdx.x * 4 + (threadIdx.x >> 6);
  const int l = threadIdx.x & 63;
  const float* xr = x + (size_t)row * DD + l * 8;
  const float4 a = *(const float4*)xr;
  const float4 c = *(const float4*)(xr + 4);
  float s = a.x + a.y + a.z + a.w + c.x + c.y + c.z + c.w;
  float sq = a.x * a.x + a.y * a.y + a.z * a.z + a.w * a.w
           + c.x * c.x + c.y * c.y + c.z * c.z + c.w * c.w;
#pragma unroll
  for (int off = 1; off < 64; off <<= 1) {
    s += __shfl_xor(s, off);
    sq += __shfl_xor(sq, off);
  }
  const float mean = s * (1.f / DD);
  const float var = sq * (1.f / DD) - mean * mean;
  const float inv = rsqrtf(var + 1e-5f);
  const float4 w0 = *(const float4*)(w + l * 8);
  const float4 w1 = *(const float4*)(w + l * 8 + 4);
  const float4 b0 = *(const float4*)(b + l * 8);
  const float4 b1 = *(const float4*)(b + l * 8 + 4);
  short8 o;
  o[0] = f2b((a.x - mean) * inv * w0.x + b0.x);
  o[1] = f2b((a.y - mean) * inv * w0.y + b0.y);
  o[2] = f2b((a.z - mean) * inv * w0.z + b0.z);
  o[3] = f2b((a.w - mean) * inv * w0.w + b0.w);
  o[4] = f2b((c.x - mean) * inv * w1.x + b1.x);
  o[5] = f2b((c.y - mean) * inv * w1.y + b1.y);
  o[6] = f2b((c.z - mean) * inv * w1.z + b1.z);
  o[7] = f2b((c.w - mean) * inv * w1.w + b1.w);
  *(short8*)(y + (size_t)row * DD + l * 8) = o;
}

// ---------------- Dual LayerNorm: one read of x, two (w,b,y) ----------------
__global__ __launch_bounds__(256) void ln_dual_kernel(
    const float* __restrict__ x,
    const float* __restrict__ w1, const float* __restrict__ b1v, short* __restrict__ y1,
    const float* __restrict__ w2, const float* __restrict__ b2v, short* __restrict__ y2)
{
  const int row = blockIdx.x * 4 + (threadIdx.x >> 6);
  const int l = threadIdx.x & 63;
  const float* xr = x + (size_t)row * DD + l * 8;
  const float4 a = *(const float4*)xr;
  const float4 c = *(const float4*)(xr + 4);
  float s = a.x + a.y + a.z + a.w + c.x + c.y + c.z + c.w;
  float sq = a.x * a.x + a.y * a.y + a.z * a.z + a.w * a.w
           + c.x * c.x + c.y * c.y + c.z * c.z + c.w * c.w;
#pragma unroll
  for (int off = 1; off < 64; off <<= 1) {
    s += __shfl_xor(s, off);
    sq += __shfl_xor(sq, off);
  }
  const float mean = s * (1.f / DD);
  const float var = sq * (1.f / DD) - mean * mean;
  const float inv = rsqrtf(var + 1e-5f);
  const float n0 = (a.x - mean) * inv, n1 = (a.y - mean) * inv,
              n2 = (a.z - mean) * inv, n3 = (a.w - mean) * inv,
              n4 = (c.x - mean) * inv, n5 = (c.y - mean) * inv,
              n6 = (c.z - mean) * inv, n7 = (c.w - mean) * inv;
#pragma unroll
  for (int pass = 0; pass < 2; ++pass) {
    const float* w = pass ? w2 : w1;
    const float* b = pass ? b2v : b1v;
    short* y = pass ? y2 : y1;
    const float4 w0 = *(const float4*)(w + l * 8);
    const float4 w1_ = *(const float4*)(w + l * 8 + 4);
    const float4 bb0 = *(const float4*)(b + l * 8);
    const float4 bb1 = *(const float4*)(b + l * 8 + 4);
    short8 o;
    o[0] = f2b(n0 * w0.x + bb0.x);
    o[1] = f2b(n1 * w0.y + bb0.y);
    o[2] = f2b(n2 * w0.z + bb0.z);
    o[3] = f2b(n3 * w0.w + bb0.w);
    o[4] = f2b(n4 * w1_.x + bb1.x);
    o[5] = f2b(n5 * w1_.y + bb1.y);
    o[6] = f2b(n6 * w1_.z + bb1.z);
    o[7] = f2b(n7 * w1_.w + bb1.w);
    *(short8*)(y + (size_t)row * DD + l * 8) = o;
  }
}

// ---------------- bf16 MFMA GEMM, BK=64, XOR-swizzled LDS ----------------
// EPI: 0=+bias(opt); 1=gelu(+bias); 2=+bias(opt)+add1(f32); 3=+bias+add1(f32)+add2(bf16)
// OBF: 0=f32 out (stride N); 1=bf16 out (stride NS)
template<int EPI, int OBF, int BM>
__global__ __launch_bounds__(256) void gemm_bf16(
    const short* __restrict__ A, const short* __restrict__ BT,
    const float* __restrict__ bias, const float* __restrict__ add1,
    const short* __restrict__ add2, void* __restrict__ C,
    int M, int N, int K, int NS)
{
  constexpr int MF = BM / 32;
  constexpr int AR = BM / 32;
  __shared__ __align__(16) short As[BM * 64];
  __shared__ __align__(16) short Bs[128 * 64];
  const int tid = threadIdx.x;
  const int wave = tid >> 6, lane = tid & 63;
  const int wr = wave >> 1, wc = wave & 1;
  const int bm = blockIdx.y * BM, bn = blockIdx.x * 128;

  const int srow = tid >> 3;
  const int dpiece = tid & 7;
  const int spiece = dpiece ^ (srow & 7);

  const short* sA[AR]; const short* sB[4];
  int ldsA[AR], ldsB[4];
#pragma unroll
  for (int r = 0; r < AR; ++r) {
    const int row = r * 32 + srow;
    sA[r] = A + (size_t)(bm + row) * K + spiece * 8;
    ldsA[r] = row * 128 + dpiece * 16;
  }
#pragma unroll
  for (int r = 0; r < 4; ++r) {
    const int row = r * 32 + srow;
    sB[r] = BT + (size_t)(bn + row) * K + spiece * 8;
    ldsB[r] = row * 128 + dpiece * 16;
  }

  const int xr = (lane & 7) << 4;
  f32x4 acc[MF][4] = {};

  for (int k0 = 0; k0 < K; k0 += 64) {
#pragma unroll
    for (int r = 0; r < AR; ++r) {
      __builtin_amdgcn_global_load_lds(AS1(sA[r]), AS3((char*)As + ldsA[r]), 16, 0, 0);
      sA[r] += 64;
    }
#pragma unroll
    for (int r = 0; r < 4; ++r) {
      __builtin_amdgcn_global_load_lds(AS1(sB[r]), AS3((char*)Bs + ldsB[r]), 16, 0, 0);
      sB[r] += 64;
    }
    __syncthreads();
    short8 af[MF][2], bf[4][2];
#pragma unroll
    for (int m = 0; m < MF; ++m)
#pragma unroll
      for (int kk = 0; kk < 2; ++kk) {
        const int row = wr * (BM / 2) + m * 16 + (lane & 15);
        af[m][kk] = *(const short8*)((char*)As + ((row * 128 + kk * 64 + (lane >> 4) * 16) ^ xr));
      }
#pragma unroll
    for (int n = 0; n < 4; ++n)
#pragma unroll
      for (int kk = 0; kk < 2; ++kk) {
        const int row = wc * 64 + n * 16 + (lane & 15);
        bf[n][kk] = *(const short8*)((char*)Bs + ((row * 128 + kk * 64 + (lane >> 4) * 16) ^ xr));
      }
#pragma unroll
    for (int kk = 0; kk < 2; ++kk)
#pragma unroll
      for (int m = 0; m < MF; ++m)
#pragma unroll
        for (int n = 0; n < 4; ++n)
          acc[m][n] = __builtin_amdgcn_mfma_f32_16x16x32_bf16(af[m][kk], bf[n][kk], acc[m][n], 0, 0, 0);
    __syncthreads();
  }

#pragma unroll
  for (int m = 0; m < MF; ++m) {
#pragma unroll
    for (int n = 0; n < 4; ++n) {
      const int col = bn + wc * 64 + n * 16 + (lane & 15);
      const float bb = (EPI == 1 || EPI == 3) ? bias[col] : (bias ? bias[col] : 0.f);
#pragma unroll
      for (int r = 0; r < 4; ++r) {
        const int row = bm + wr * (BM / 2) + m * 16 + (lane >> 4) * 4 + r;
        const size_t idx = (size_t)row * N + col;
        float v = acc[m][n][r] + bb;
        if (EPI == 1) v = gelu_tanh(v);
        if (EPI == 2 || EPI == 3) v += add1[idx];
        if (EPI == 3) v += b2f(add2[idx]);
        if (OBF == 1) ((short*)C)[(size_t)row * NS + col] = f2b(v);
        else ((float*)C)[idx] = v;
      }
    }
  }
}

// ---------------- Sliding-window attention (bf16 qkv in, bf16 out) ----------
__global__ __launch_bounds__(256) void swa_kernel(
    const unsigned short* __restrict__ qkv, short* __restrict__ out)
{
  __shared__ __align__(16) short ks[128 * 72];
  __shared__ __align__(16) short vt[64 * 136];
  __shared__ __align__(16) short ps[4][16 * 136];
  __shared__ float lsum[64];

  const int tid = threadIdx.x;
  const int w = tid >> 6, l = tid & 63;
  const int tile = blockIdx.x & 31;
  const int h = (blockIdx.x >> 5) & 7;
  const int b = blockIdx.x >> 8;
  const int s0 = tile * 64;
  const size_t base = (size_t)b * SS;

#pragma unroll
  for (int u = 0; u < 16; ++u) {
    const int id = u * 256 + tid;
    const int row = id >> 5, dp = id & 31;
    int jp = s0 - 32 + row;
    jp = min(max(jp, 0), SS - 1);
    const size_t g = (base + jp) * 1536 + h * 64 + dp * 2;
    *(unsigned*)&ks[row * 72 + dp * 2] = *(const unsigned*)&qkv[g + 512];
    const unsigned vv = *(const unsigned*)&qkv[g + 1024];
    vt[(dp * 2) * 136 + row] = (short)(vv & 0xFFFF);
    vt[(dp * 2 + 1) * 136 + row] = (short)(vv >> 16);
  }

  const int qi = w * 16 + (l & 15);
  short8 qf[2];
#pragma unroll
  for (int kf = 0; kf < 2; ++kf)
    qf[kf] = *(const short8*)&qkv[(base + s0 + qi) * 1536 + h * 64 + kf * 32 + (l >> 4) * 8];
  __syncthreads();

  f32x4 sa[8] = {};
#pragma unroll
  for (int mf = 0; mf < 8; ++mf)
#pragma unroll
    for (int kf = 0; kf < 2; ++kf) {
      const short8 af = *(const short8*)&ks[(mf * 16 + (l & 15)) * 72 + kf * 32 + (l >> 4) * 8];
      sa[mf] = __builtin_amdgcn_mfma_f32_16x16x32_bf16(af, qf[kf], sa[mf], 0, 0, 0);
    }

  float sv[8][4];
  float mx = -INFINITY;
#pragma unroll
  for (int mf = 0; mf < 8; ++mf)
#pragma unroll
    for (int r = 0; r < 4; ++r) {
      const int j = mf * 16 + (l >> 4) * 4 + r;
      const int jpos = s0 - 32 + j;
      const bool ok = (j >= qi) && (j <= qi + 64) && (jpos >= 0) && (jpos < SS);
      const float s = ok ? sa[mf][r] * 0.125f : -INFINITY;
      sv[mf][r] = s;
      mx = fmaxf(mx, s);
    }
  mx = fmaxf(mx, __shfl_xor(mx, 16));
  mx = fmaxf(mx, __shfl_xor(mx, 32));
  float ls = 0.f;
#pragma unroll
  for (int mf = 0; mf < 8; ++mf)
#pragma unroll
    for (int r = 0; r < 4; ++r) {
      const float p = __expf(sv[mf][r] - mx);
      sv[mf][r] = p;
      ls += p;
    }
  ls += __shfl_xor(ls, 16);
  ls += __shfl_xor(ls, 32);
  if (l < 16) lsum[w * 16 + l] = ls;

#pragma unroll
  for (int mf = 0; mf < 8; ++mf) {
    short4v p4;
    p4.x = f2b(sv[mf][0]); p4.y = f2b(sv[mf][1]);
    p4.z = f2b(sv[mf][2]); p4.w = f2b(sv[mf][3]);
    *(short4v*)&ps[w][(l & 15) * 136 + mf * 16 + (l >> 4) * 4] = p4;
  }

  f32x4 oa[4] = {};
#pragma unroll
  for (int kf = 0; kf < 4; ++kf) {
    const short8 pf = *(const short8*)&ps[w][(l & 15) * 136 + kf * 32 + (l >> 4) * 8];
#pragma unroll
    for (int nf = 0; nf < 4; ++nf) {
      const short8 vf = *(const short8*)&vt[(nf * 16 + (l & 15)) * 136 + kf * 32 + (l >> 4) * 8];
      oa[nf] = __builtin_amdgcn_mfma_f32_16x16x32_bf16(pf, vf, oa[nf], 0, 0, 0);
    }
  }

  float rl[4];
#pragma unroll
  for (int r = 0; r < 4; ++r) rl[r] = 1.f / lsum[w * 16 + (l >> 4) * 4 + r];
#pragma unroll
  for (int nf = 0; nf < 4; ++nf)
#pragma unroll
    for (int r = 0; r < 4; ++r) {
      const int q = (l >> 4) * 4 + r;
      const int d = nf * 16 + (l & 15);
      out[(base + s0 + w * 16 + q) * 512 + h * 64 + d] = f2b(oa[nf][r] * rl[r]);
    }
}

// ========== Neural memory, linear-scan formulation ==========

// ---- P1: per (chain, chunk) compute A_c, B_c via MFMA (bf16 k,v inputs) ----
__global__ __launch_bounds__(256) void mem_prep(
    const short* __restrict__ kb, const short* __restrict__ vb,
    short* __restrict__ Aq, short* __restrict__ Bq)
{
  __shared__ __align__(16) short kn[64 * 136];
  __shared__ __align__(16) char kT[128 * 128];
  __shared__ __align__(16) char vT[128 * 128];
  const int bid = blockIdx.x;
  const int chain = bid >> 5, c = bid & 31;
  const int b = chain >> 2, mh = chain & 3;
  const size_t rowbase = (size_t)(b * SS + c * 64);
  const int tid = threadIdx.x, w = tid >> 6, l = tid & 63;
  const int td = tid & 127, rh = tid >> 7;

#pragma unroll
  for (int pass = 0; pass < 2; ++pass) {
    const short* src = pass ? vb : kb;
    char* dT = pass ? vT : kT;
#pragma unroll
    for (int j = 0; j < 4; ++j) {
      const int i4 = tid + 256 * j;
      const int r = i4 >> 4, d8 = (i4 & 15) * 8;
      *(short8*)&kn[r * 136 + d8] = *(const short8*)&src[(rowbase + r) * 1536 + mh * 128 + d8];
    }
    __syncthreads();
#pragma unroll
    for (int j = 0; j < 4; ++j) {
      const int r0 = rh * 8 + 16 * j;
      short8 g8;
#pragma unroll
      for (int t = 0; t < 8; ++t) g8[t] = kn[(r0 + t) * 136 + td];
      *(short8*)&dT[(td * 128 + r0 * 2) ^ ((td & 7) << 4)] = g8;
    }
    __syncthreads();
  }

  const int wr = w >> 1, wc = w & 1;
  {
    f32x4 acc[4][4] = {};
#pragma unroll
    for (int kf = 0; kf < 2; ++kf) {
      short8 af[4];
#pragma unroll
      for (int m = 0; m < 4; ++m) {
        const int d = wr * 64 + m * 16 + (l & 15);
        af[m] = *(const short8*)&kT[(d * 128 + kf * 64 + (l >> 4) * 16) ^ ((d & 7) << 4)];
      }
#pragma unroll
      for (int n = 0; n < 4; ++n) {
        const int dp = wc * 64 + n * 16 + (l & 15);
        const short8 bf = *(const short8*)&kT[(dp * 128 + kf * 64 + (l >> 4) * 16) ^ ((dp & 7) << 4)];
#pragma unroll
        for (int m = 0; m < 4; ++m)
          acc[m][n] = __builtin_amdgcn_mfma_f32_16x16x32_bf16(af[m], bf, acc[m][n], 0, 0, 0);
      }
    }
    char* Ad = (char*)(Aq + (size_t)bid * 16384);
#pragma unroll
    for (int m = 0; m < 4; ++m)
#pragma unroll
      for (int n = 0; n < 4; ++n) {
        const int dp = wc * 64 + n * 16 + (l & 15);
        const int d0 = wr * 64 + m * 16 + (l >> 4) * 4;
        short4v s4;
#pragma unroll
        for (int i = 0; i < 4; ++i) s4[i] = f2b(acc[m][n][i] * 0.015625f);
        *(short4v*)&Ad[(dp * 256 + d0 * 2) ^ ((dp & 7) << 4)] = s4;
      }
  }
  {
    f32x4 acc[4][4] = {};
#pragma unroll
    for (int kf = 0; kf < 2; ++kf) {
      short8 af[4];
#pragma unroll
      for (int m = 0; m < 4; ++m) {
        const int d = wr * 64 + m * 16 + (l & 15);
        af[m] = *(const short8*)&kT[(d * 128 + kf * 64 + (l >> 4) * 16) ^ ((d & 7) << 4)];
      }
#pragma unroll
      for (int n = 0; n < 4; ++n) {
        const int e = wc * 64 + n * 16 + (l & 15);
        const short8 bf = *(const short8*)&vT[(e * 128 + kf * 64 + (l >> 4) * 16) ^ ((e & 7) << 4)];
#pragma unroll
        for (int m = 0; m < 4; ++m)
          acc[m][n] = __builtin_amdgcn_mfma_f32_16x16x32_bf16(af[m], bf, acc[m][n], 0, 0, 0);
      }
    }
    short* Bd = Bq + (size_t)bid * 16384;
#pragma unroll
    for (int m = 0; m < 4; ++m)
#pragma unroll
      for (int n = 0; n < 4; ++n) {
        const int e = wc * 64 + n * 16 + (l & 15);
        const int d0 = wr * 64 + m * 16 + (l >> 4) * 4;
        short4v s4;
#pragma unroll
        for (int i = 0; i < 4; ++i) s4[i] = f2b(acc[m][n][i] * 0.015625f);
        *(short4v*)&Bd[e * 128 + d0] = s4;
      }
  }
}

// ---- P2: serial scan — raw s_barrier + counted vmcnt, depth-2 A prefetch ----
__global__ __launch_bounds__(256) void mem_scan2(
    const short* __restrict__ Aq, const short* __restrict__ Bq,
    short* __restrict__ MTg)
{
  __shared__ __align__(16) char AcL[3][32768];
  __shared__ __align__(16) char MT[2][8192];
  const int bid = blockIdx.x;
  const int chain = bid >> 2, ch = bid & 3;
  const int tid = threadIdx.x;
  const int w = tid >> 6, l = tid & 63;
  const int wr = w >> 1, wc = w & 1;
  const int e = wc * 16 + (l & 15);

  const short* Ab = Aq + (size_t)chain * 32 * 16384;
  const short* Bb = Bq + (size_t)chain * 32 * 16384;
  short* MTb = MTg + (size_t)chain * 32 * 16384 + (size_t)ch * 32 * 128;
  const int brow = (ch * 32 + e) * 128;

  {
    const short8 z = {0, 0, 0, 0, 0, 0, 0, 0};
    for (int i = tid; i < 512; i += 256) *(short8*)(MT[0] + i * 16) = z;
  }
#pragma unroll
  for (int cc = 0; cc < 2; ++cc) {
    const char* srcA = (const char*)(Ab + (size_t)cc * 16384);
#pragma unroll
    for (int j = 0; j < 8; ++j) {
      const int byte = tid * 16 + j * 4096;
      __builtin_amdgcn_global_load_lds(AS1(srcA + byte), AS3(AcL[cc] + byte), 16, 0, 0);
    }
  }
  short4v b0[4], b1[4], b2[4];
#pragma unroll
  for (int m = 0; m < 4; ++m) {
    b0[m] = *(const short4v*)&Bb[brow + wr * 64 + m * 16 + (l >> 4) * 4];
    b1[m] = *(const short4v*)&Bb[16384 + brow + wr * 64 + m * 16 + (l >> 4) * 4];
  }
  float Mreg[16] = {}, Momreg[16] = {};
  __syncthreads();

#define SCHUNK(C, AB, MR, BC, BN, DOI, WN)                                     \
  {                                                                            \
    short* slot = MTb + (size_t)(C) * 16384;                                   \
    _Pragma("unroll") for (int m = 0; m < 4; ++m) {                            \
      const int d0 = wr * 64 + m * 16 + (l >> 4) * 4;                          \
      short4v s4;                                                              \
      _Pragma("unroll") for (int i = 0; i < 4; ++i) s4[i] = f2b(Mreg[m * 4 + i]); \
      *(short4v*)&slot[e * 128 + d0] = s4;                                     \
    }                                                                          \
    if (DOI) {                                                                 \
      const char* srcA = (const char*)(Ab + (size_t)((C) + 2) * 16384);        \
      _Pragma("unroll") for (int j = 0; j < 8; ++j) {                          \
        const int byte = tid * 16 + j * 4096;                                  \
        __builtin_amdgcn_global_load_lds(AS1(srcA + byte),                     \
            AS3(AcL[((C) + 2) % 3] + byte), 16, 0, 0);                         \
      }                                                                        \
      const short* Bn = Bb + (size_t)((C) + 2) * 16384;                        \
      _Pragma("unroll") for (int m = 0; m < 4; ++m)                            \
        BN[m] = *(const short4v*)&Bn[brow + wr * 64 + m * 16 + (l >> 4) * 4];  \
    }                                                                          \
    {                                                                          \
      f32x4 acc[4] = {};                                                       \
      _Pragma("unroll") for (int kf = 0; kf < 4; ++kf) {                       \
        const short8 bf = *(const short8*)&MT[MR][(e * 256 + kf * 64 + (l >> 4) * 16) ^ ((e & 7) << 4)]; \
        _Pragma("unroll") for (int m = 0; m < 4; ++m) {                        \
          const int d = wr * 64 + m * 16 + (l & 15);                           \
          const short8 af = *(const short8*)&AcL[AB][(d * 256 + kf * 64 + (l >> 4) * 16) ^ ((d & 7) << 4)]; \
          acc[m] = __builtin_amdgcn_mfma_f32_16x16x32_bf16(af, bf, acc[m], 0, 0, 0); \
        }                                                                      \
      }                                                                        \
      _Pragma("unroll") for (int m = 0; m < 4; ++m) {                          \
        const int d0 = wr * 64 + m * 16 + (l >> 4) * 4;                        \
        short4v s4;                                                            \
        _Pragma("unroll") for (int i = 0; i < 4; ++i) {                        \
          const int idx = m * 4 + i;                                           \
          const float g = acc[m][i] - b2f(BC[m][i]);                           \
          Momreg[idx] = 0.9f * Momreg[idx] - 0.1f * g;                         \
          Mreg[idx] = 0.99f * Mreg[idx] + Momreg[idx];                         \
          s4[i] = f2b(Mreg[idx]);                                              \
        }                                                                      \
        *(short4v*)&MT[(MR) ^ 1][(e * 256 + d0 * 2) ^ ((e & 7) << 4)] = s4;    \
      }                                                                        \
    }                                                                          \
    asm volatile("s_waitcnt lgkmcnt(0) vmcnt(" #WN ")" ::: "memory");          \
    __builtin_amdgcn_sched_barrier(0);                                         \
    __builtin_amdgcn_s_barrier();                                              \
    __builtin_amdgcn_sched_barrier(0);                                         \
  }

  SCHUNK(0, 0, 0, b0, b2, 1, 20)  SCHUNK(1, 1, 1, b1, b0, 1, 20)
  SCHUNK(2, 2, 0, b2, b1, 1, 20)  SCHUNK(3, 0, 1, b0, b2, 1, 20)
  SCHUNK(4, 1, 0, b1, b0, 1, 20)  SCHUNK(5, 2, 1, b2, b1, 1, 20)
  SCHUNK(6, 0, 0, b0, b2, 1, 20)  SCHUNK(7, 1, 1, b1, b0, 1, 20)
  SCHUNK(8, 2, 0, b2, b1, 1, 20)  SCHUNK(9, 0, 1, b0, b2, 1, 20)
  SCHUNK(10, 1, 0, b1, b0, 1, 20) SCHUNK(11, 2, 1, b2, b1, 1, 20)
  SCHUNK(12, 0, 0, b0, b2, 1, 20) SCHUNK(13, 1, 1, b1, b0, 1, 20)
  SCHUNK(14, 2, 0, b2, b1, 1, 20) SCHUNK(15, 0, 1, b0, b2, 1, 20)
  SCHUNK(16, 1, 0, b1, b0, 1, 20) SCHUNK(17, 2, 1, b2, b1, 1, 20)
  SCHUNK(18, 0, 0, b0, b2, 1, 20) SCHUNK(19, 1, 1, b1, b0, 1, 20)
  SCHUNK(20, 2, 0, b2, b1, 1, 20) SCHUNK(21, 0, 1, b0, b2, 1, 20)
  SCHUNK(22, 1, 0, b1, b0, 1, 20) SCHUNK(23, 2, 1, b2, b1, 1, 20)
  SCHUNK(24, 0, 0, b0, b2, 1, 20) SCHUNK(25, 1, 1, b1, b0, 1, 20)
  SCHUNK(26, 2, 0, b2, b1, 1, 20) SCHUNK(27, 0, 1, b0, b2, 1, 20)
  SCHUNK(28, 1, 0, b1, b0, 1, 20) SCHUNK(29, 2, 1, b2, b1, 0, 8)
  SCHUNK(30, 0, 0, b0, b2, 0, 8)
#undef SCHUNK

  // epilogue: slot 31 = M_30
  {
    short* slot = MTb + (size_t)31 * 16384;
#pragma unroll
    for (int m = 0; m < 4; ++m) {
      const int d0 = wr * 64 + m * 16 + (l >> 4) * 4;
      short4v s4;
#pragma unroll
      for (int i = 0; i < 4; ++i) s4[i] = f2b(Mreg[m * 4 + i]);
      *(short4v*)&slot[e * 128 + d0] = s4;
    }
  }
}

// ---- P3: out_c = q_c @ M_{c-1} (bf16 q input) ----
__global__ __launch_bounds__(256) void mem_out(
    const short* __restrict__ qb, const short* __restrict__ MTg,
    short* __restrict__ mem)
{
  const int bid = blockIdx.x;
  const int chain = bid >> 5, c = bid & 31;
  const int b = chain >> 2, mh = chain & 3;
  const size_t rowbase = (size_t)(b * SS + c * 64);
  const int tid = threadIdx.x, w = tid >> 6, l = tid & 63;
  const int wr = w >> 1, wc = w & 1;
  const short* MTc = MTg + (size_t)chain * 32 * 16384 + (size_t)c * 16384;

  f32x4 acc[2][4] = {};
#pragma unroll
  for (int kf = 0; kf < 4; ++kf) {
    short8 af[2];
#pragma unroll
    for (int m = 0; m < 2; ++m) {
      const int r = wr * 32 + m * 16 + (l & 15);
      af[m] = *(const short8*)&qb[(rowbase + r) * 1536 + mh * 128 + kf * 32 + (l >> 4) * 8];
    }
#pragma unroll
    for (int n = 0; n < 4; ++n) {
      const int e = wc * 64 + n * 16 + (l & 15);
      const short8 bf = *(const short8*)&MTc[e * 128 + kf * 32 + (l >> 4) * 8];
#pragma unroll
      for (int m = 0; m < 2; ++m)
        acc[m][n] = __builtin_amdgcn_mfma_f32_16x16x32_bf16(af[m], bf, acc[m][n], 0, 0, 0);
    }
  }
#pragma unroll
  for (int m = 0; m < 2; ++m)
#pragma unroll
    for (int n = 0; n < 4; ++n)
#pragma unroll
      for (int i = 0; i < 4; ++i) {
        const int r = wr * 32 + m * 16 + (l >> 4) * 4 + i;
        const int e = wc * 64 + n * 16 + (l & 15);
        mem[(rowbase + r) * 512 + mh * 128 + e] = f2b(acc[m][n][i]);
      }
}

// ---------------- merged weight transpose+convert (all matrices, 1 launch) ---
struct TcvtJob { const float* src; short* dst; int K; int N; int blks; };
struct TcvtArgs { TcvtJob j[10]; };

__global__ __launch_bounds__(256) void tcvt_all(TcvtArgs a)
{
  int bid = blockIdx.x;
  const float* src = nullptr; short* dst = nullptr; int K = 0, N = 0;
#pragma unroll
  for (int i = 0; i < 10; ++i) {
    if (!src) {
      if (bid < a.j[i].blks) { src = a.j[i].src; dst = a.j[i].dst; K = a.j[i].K; N = a.j[i].N; }
      else bid -= a.j[i].blks;
    }
  }
  const int nt = N >> 5, kt = K >> 5;
  const int z = bid / (nt * kt);
  const int rem = bid % (nt * kt);
  const int k0 = (rem / nt) * 32, n0 = (rem % nt) * 32;
  const size_t zoff = (size_t)z * K * N;
  src += zoff; dst += zoff;

  __shared__ float t[32][33];
  const int tx = threadIdx.x & 31, ty = threadIdx.x >> 5;
#pragma unroll
  for (int i = 0; i < 4; ++i)
    t[ty + i * 8][tx] = src[(size_t)(k0 + ty + i * 8) * N + n0 + tx];
  __syncthreads();
#pragma unroll
  for (int i = 0; i < 4; ++i)
    dst[(size_t)(n0 + ty + i * 8) * K + k0 + tx] = f2b(t[tx][ty + i * 8]);
}

// ---------------- persistent path: wide parallel kernels -------------------
__global__ __launch_bounds__(256) void mean_tokens_kernel(
    const float* __restrict__ pm, float* __restrict__ mvec)
{
  const int d = blockIdx.x * 256 + threadIdx.x;
  if (d < 512) {
    float s = 0.f;
#pragma unroll
    for (int t = 0; t < 16; ++t) s += pm[t * 512 + d];
    mvec[d] = s * (1.f / 16.f);
  }
}

// out[e] = bias[e] + sum_d a[d]*W[d*512+e]; grid 32 x 256 (16 outputs/block)
__global__ __launch_bounds__(256) void matvec512_kernel(
    const float* __restrict__ a, const float* __restrict__ W,
    const float* __restrict__ bias, float* __restrict__ out)
{
  __shared__ float red[16][17];
  const int eo = threadIdx.x & 15;
  const int g = threadIdx.x >> 4;
  const int e = blockIdx.x * 16 + eo;
  float s = 0.f;
#pragma unroll 8
  for (int j = 0; j < 32; ++j) {
    const int d = g * 32 + j;
    s += a[d] * W[d * 512 + e];
  }
  red[g][eo] = s;
  __syncthreads();
  if (threadIdx.x < 16) {
    float t = bias[blockIdx.x * 16 + threadIdx.x];
#pragma unroll
    for (int gg = 0; gg < 16; ++gg) t += red[gg][threadIdx.x];
    out[blockIdx.x * 16 + threadIdx.x] = t;
  }
}

// ---------------- host side ----------------
extern "C" void kernel_launch(void* const* d_in, const int* in_sizes, int n_in,
                              void* d_out, int out_size, void* d_ws, size_t ws_size,
                              hipStream_t stream)
{
  const float* x         = (const float*)d_in[0];
  const float* n1w       = (const float*)d_in[1];
  const float* n1b       = (const float*)d_in[2];
  const float* qkvw      = (const float*)d_in[3];
  const float* qkvb      = (const float*)d_in[4];
  const float* projw     = (const float*)d_in[5];
  const float* projb     = (const float*)d_in[6];
  const float* n2w       = (const float*)d_in[7];
  const float* n2b       = (const float*)d_in[8];
  const float* fc1w      = (const float*)d_in[9];
  const float* fc1b      = (const float*)d_in[10];
  const float* fc2w      = (const float*)d_in[11];
  const float* fc2b      = (const float*)d_in[12];
  const float* mlnw      = (const float*)d_in[13];
  const float* mlnb      = (const float*)d_in[14];
  const float* mwq       = (const float*)d_in[15];
  const float* mwk       = (const float*)d_in[16];
  const float* mwv       = (const float*)d_in[17];
  const float* mprojw    = (const float*)d_in[18];
  const float* mprojb    = (const float*)d_in[19];
  const float* pm_tokens = (const float*)d_in[20];
  const float* pmw       = (const float*)d_in[21];
  const float* pmb       = (const float*)d_in[22];
  const float* fw        = (const float*)d_in[23];
  const float* fb        = (const float*)d_in[24];
  float* out = (float*)d_out;

  char* p = (char*)d_ws;
  auto alloc = [&](size_t bytes) {
    char* r = p;
    p += (bytes + 255) & ~(size_t)255;
    return r;
  };
  short* qkvwT  = (short*)alloc(6ull * 1536 * 512 * 2);
  short* projwT = (short*)alloc(6ull * 512 * 512 * 2);
  short* fc1wT  = (short*)alloc(6ull * 2048 * 512 * 2);
  short* fc2wT  = (short*)alloc(6ull * 512 * 2048 * 2);
  short* mqkvT  = (short*)alloc(3ull * 512 * 512 * 2);
  short* mprojT = (short*)alloc(512ull * 512 * 2);
  short* fwT    = (short*)alloc(512ull * 1024 * 2);
  short* bigb   = (short*)alloc((size_t)BS * 1536 * 2);
  float* hbuf   = (float*)alloc((size_t)BS * 512 * 4);
  float* t0     = (float*)alloc(3 * 512 * 4);
  float* t1 = t0 + 512; float* t2 = t1 + 512;
  short* actA   = (short*)alloc((size_t)BS * 512 * 2);
  short* ln0b   = (short*)alloc((size_t)BS * 512 * 2);
  short* attnb  = (short*)alloc((size_t)BS * 512 * 2);
  short* ff1b   = (short*)alloc((size_t)BS * 2048 * 2);
  short* stlt   = (short*)alloc((size_t)BS * 1024 * 2);
  short* Aq     = (short*)alloc(256ull * 16384 * 2);
  short* Bq     = (short*)alloc(256ull * 16384 * 2);
  short* MTg    = (short*)alloc(256ull * 16384 * 2);

  // ---- all weight transposes in one launch ----
  TcvtArgs ta;
  ta.j[0] = {qkvw,  qkvwT,  512, 1536, 48 * 16 * 6};
  ta.j[1] = {projw, projwT, 512, 512,  16 * 16 * 6};
  ta.j[2] = {fc1w,  fc1wT,  512, 2048, 64 * 16 * 6};
  ta.j[3] = {fc2w,  fc2wT,  2048, 512, 16 * 64 * 6};
  ta.j[4] = {mwq, mqkvT,                 512, 512, 256};
  ta.j[5] = {mwk, mqkvT + 512 * 512,     512, 512, 256};
  ta.j[6] = {mwv, mqkvT + 2 * 512 * 512, 512, 512, 256};
  ta.j[7] = {mprojw, mprojT, 512, 512, 256};
  ta.j[8] = {fw, fwT, 1024, 512, 512};
  ta.j[9] = {nullptr, nullptr, 32, 32, 0};
  int total_blks = 0;
  for (int i = 0; i < 10; ++i) total_blks += ta.j[i].blks;
  tcvt_all<<<total_blks, 256, 0, stream>>>(ta);

  // ---- persistent path (parallel) ----
  mean_tokens_kernel<<<2, 256, 0, stream>>>(pm_tokens, t0);
  matvec512_kernel<<<32, 256, 0, stream>>>(t0, pmw, pmb, t1);
  matvec512_kernel<<<32, 256, 0, stream>>>(t1, fw + (size_t)1024 * 512, fb, t2);

  // ---- neural memory path ----
  ln_dual_kernel<<<BS / 4, 256, 0, stream>>>(x, mlnw, mlnb, actA, n1w, n1b, ln0b);
  gemm_bf16<0, 1, 128><<<dim3(12, 32), 256, 0, stream>>>(
      actA, mqkvT, nullptr, nullptr, nullptr, bigb, BS, 1536, 512, 1536);
  mem_prep<<<256, 256, 0, stream>>>(bigb + 512, bigb + 1024, Aq, Bq);
  mem_scan2<<<32, 256, 0, stream>>>(Aq, Bq, MTg);
  mem_out<<<256, 256, 0, stream>>>(bigb, MTg, ff1b);
  gemm_bf16<2, 1, 64><<<dim3(4, 64), 256, 0, stream>>>(
      ff1b, mprojT, mprojb, x, nullptr, stlt + 512, BS, 512, 512, 1024);

  // ---- layer stack ----
  for (int l = 0; l < LL; ++l) {
    const short* lnin = (l == 0) ? ln0b : actA;
    if (l > 0)
      ln_kernel<<<BS / 4, 256, 0, stream>>>(hbuf, n1w + l * 512, n1b + l * 512, actA);
    gemm_bf16<0, 1, 128><<<dim3(12, 32), 256, 0, stream>>>(
        lnin, qkvwT + (size_t)l * 1536 * 512, qkvb + l * 1536,
        nullptr, nullptr, bigb, BS, 1536, 512, 1536);
    swa_kernel<<<512, 256, 0, stream>>>((const unsigned short*)bigb, attnb);
    gemm_bf16<2, 0, 64><<<dim3(4, 64), 256, 0, stream>>>(
        attnb, projwT + (size_t)l * 512 * 512, projb + l * 512,
        (l == 0) ? x : hbuf, nullptr, hbuf, BS, 512, 512, 512);
    ln_kernel<<<BS / 4, 256, 0, stream>>>(hbuf, n2w + l * 512, n2b + l * 512, actA);
    gemm_bf16<1, 1, 128><<<dim3(16, 32), 256, 0, stream>>>(
        actA, fc1wT + (size_t)l * 2048 * 512, fc1b + l * 2048,
        nullptr, nullptr, ff1b, BS, 2048, 512, 2048);
    if (l < LL - 1)
      gemm_bf16<3, 0, 64><<<dim3(4, 64), 256, 0, stream>>>(
          ff1b, fc2wT + (size_t)l * 512 * 2048, fc2b + l * 512,
          hbuf, actA, hbuf, BS, 512, 2048, 512);
    else
      gemm_bf16<3, 1, 64><<<dim3(4, 64), 256, 0, stream>>>(
          ff1b, fc2wT + (size_t)l * 512 * 2048, fc2b + l * 512,
          hbuf, actA, stlt, BS, 512, 2048, 1024);   // ST -> stlt[:, 0:512]
  }

  // ---- fusion: out = [ST | LT] @ fwT + (persistent + fusion bias) ----
  gemm_bf16<0, 0, 64><<<dim3(4, 64), 256, 0, stream>>>(
      stlt, fwT, t2, nullptr, nullptr, out, BS, 512, 1024, 512);
}

// Round 12
// 732.641 us; speedup vs baseline: 5.2585x; 1.0438x over previous
//
#include <hip/hip_runtime.h>
#include <math.h>

// Problem constants
#define BB 2
#define SS 2048
#define DD 512
#define HH 8
#define LL 6
#define WW 64
#define CHH 64
#define NCC 32
#define BS (BB*SS)   // 4096 rows

typedef __attribute__((ext_vector_type(8))) short short8;
typedef __attribute__((ext_vector_type(4))) short short4v;
typedef __attribute__((ext_vector_type(4))) float f32x4;

__device__ inline float b2f(short s) {
  unsigned u = ((unsigned)(unsigned short)s) << 16;
  float f; __builtin_memcpy(&f, &u, 4); return f;
}
__device__ inline short f2b(float f) {
  unsigned u; __builtin_memcpy(&u, &f, 4);
  unsigned r = (u + 0x7FFFu + ((u >> 16) & 1u)) >> 16;
  return (short)r;
}
__device__ inline float gelu_tanh(float v) {
  float u = 0.7978845608f * (v + 0.044715f * v * v * v);
  u = fminf(fmaxf(u, -20.f), 20.f);
  float e2 = __expf(2.f * u);
  return 0.5f * v * (1.f + (e2 - 1.f) / (e2 + 1.f));
}

#define AS1(p) ((const __attribute__((address_space(1))) void*)(p))
#define AS3(p) ((__attribute__((address_space(3))) void*)(p))

// ---------------- LayerNorm: wave-per-row, 4 rows/block ----------------
__global__ __launch_bounds__(256) void ln_kernel(
    const float* __restrict__ x, const float* __restrict__ w,
    const float* __restrict__ b, short* __restrict__ y)
{
  const int row = blockIdx.x * 4 + (threadIdx.x >> 6);
  const int l = threadIdx.x & 63;
  const float* xr = x + (size_t)row * DD + l * 8;
  const float4 a = *(const float4*)xr;
  const float4 c = *(const float4*)(xr + 4);
  float s = a.x + a.y + a.z + a.w + c.x + c.y + c.z + c.w;
  float sq = a.x * a.x + a.y * a.y + a.z * a.z + a.w * a.w
           + c.x * c.x + c.y * c.y + c.z * c.z + c.w * c.w;
#pragma unroll
  for (int off = 1; off < 64; off <<= 1) {
    s += __shfl_xor(s, off);
    sq += __shfl_xor(sq, off);
  }
  const float mean = s * (1.f / DD);
  const float var = sq * (1.f / DD) - mean * mean;
  const float inv = rsqrtf(var + 1e-5f);
  const float4 w0 = *(const float4*)(w + l * 8);
  const float4 w1 = *(const float4*)(w + l * 8 + 4);
  const float4 b0 = *(const float4*)(b + l * 8);
  const float4 b1 = *(const float4*)(b + l * 8 + 4);
  short8 o;
  o[0] = f2b((a.x - mean) * inv * w0.x + b0.x);
  o[1] = f2b((a.y - mean) * inv * w0.y + b0.y);
  o[2] = f2b((a.z - mean) * inv * w0.z + b0.z);
  o[3] = f2b((a.w - mean) * inv * w0.w + b0.w);
  o[4] = f2b((c.x - mean) * inv * w1.x + b1.x);
  o[5] = f2b((c.y - mean) * inv * w1.y + b1.y);
  o[6] = f2b((c.z - mean) * inv * w1.z + b1.z);
  o[7] = f2b((c.w - mean) * inv * w1.w + b1.w);
  *(short8*)(y + (size_t)row * DD + l * 8) = o;
}

// ---------------- Dual LayerNorm: one read of x, two (w,b,y) ----------------
__global__ __launch_bounds__(256) void ln_dual_kernel(
    const float* __restrict__ x,
    const float* __restrict__ w1, const float* __restrict__ b1v, short* __restrict__ y1,
    const float* __restrict__ w2, const float* __restrict__ b2v, short* __restrict__ y2)
{
  const int row = blockIdx.x * 4 + (threadIdx.x >> 6);
  const int l = threadIdx.x & 63;
  const float* xr = x + (size_t)row * DD + l * 8;
  const float4 a = *(const float4*)xr;
  const float4 c = *(const float4*)(xr + 4);
  float s = a.x + a.y + a.z + a.w + c.x + c.y + c.z + c.w;
  float sq = a.x * a.x + a.y * a.y + a.z * a.z + a.w * a.w
           + c.x * c.x + c.y * c.y + c.z * c.z + c.w * c.w;
#pragma unroll
  for (int off = 1; off < 64; off <<= 1) {
    s += __shfl_xor(s, off);
    sq += __shfl_xor(sq, off);
  }
  const float mean = s * (1.f / DD);
  const float var = sq * (1.f / DD) - mean * mean;
  const float inv = rsqrtf(var + 1e-5f);
  const float n0 = (a.x - mean) * inv, n1 = (a.y - mean) * inv,
              n2 = (a.z - mean) * inv, n3 = (a.w - mean) * inv,
              n4 = (c.x - mean) * inv, n5 = (c.y - mean) * inv,
              n6 = (c.z - mean) * inv, n7 = (c.w - mean) * inv;
#pragma unroll
  for (int pass = 0; pass < 2; ++pass) {
    const float* w = pass ? w2 : w1;
    const float* b = pass ? b2v : b1v;
    short* y = pass ? y2 : y1;
    const float4 w0 = *(const float4*)(w + l * 8);
    const float4 w1_ = *(const float4*)(w + l * 8 + 4);
    const float4 bb0 = *(const float4*)(b + l * 8);
    const float4 bb1 = *(const float4*)(b + l * 8 + 4);
    short8 o;
    o[0] = f2b(n0 * w0.x + bb0.x);
    o[1] = f2b(n1 * w0.y + bb0.y);
    o[2] = f2b(n2 * w0.z + bb0.z);
    o[3] = f2b(n3 * w0.w + bb0.w);
    o[4] = f2b(n4 * w1_.x + bb1.x);
    o[5] = f2b(n5 * w1_.y + bb1.y);
    o[6] = f2b(n6 * w1_.z + bb1.z);
    o[7] = f2b(n7 * w1_.w + bb1.w);
    *(short8*)(y + (size_t)row * DD + l * 8) = o;
  }
}

// ------- bf16 MFMA GEMM, BK=64, XOR-swizzled LDS, 2-phase double-buffer ------
// EPI: 0=+bias(opt); 1=gelu(+bias); 2=+bias(opt)+add1(f32); 3=+bias+add1(f32)+add2(bf16)
// OBF: 0=f32 out (stride N); 1=bf16 out (stride NS)
template<int EPI, int OBF, int BM>
__global__ __launch_bounds__(256) void gemm_bf16(
    const short* __restrict__ A, const short* __restrict__ BT,
    const float* __restrict__ bias, const float* __restrict__ add1,
    const short* __restrict__ add2, void* __restrict__ C,
    int M, int N, int K, int NS)
{
  constexpr int MF = BM / 32;
  constexpr int AR = BM / 32;
  __shared__ __align__(16) short As[2][BM * 64];
  __shared__ __align__(16) short Bs[2][128 * 64];
  const int tid = threadIdx.x;
  const int wave = tid >> 6, lane = tid & 63;
  const int wr = wave >> 1, wc = wave & 1;
  const int bm = blockIdx.y * BM, bn = blockIdx.x * 128;

  const int srow = tid >> 3;
  const int dpiece = tid & 7;
  const int spiece = dpiece ^ (srow & 7);

  const short* sA[AR]; const short* sB[4];
  int ldsA[AR], ldsB[4];
#pragma unroll
  for (int r = 0; r < AR; ++r) {
    const int row = r * 32 + srow;
    sA[r] = A + (size_t)(bm + row) * K + spiece * 8;
    ldsA[r] = row * 128 + dpiece * 16;
  }
#pragma unroll
  for (int r = 0; r < 4; ++r) {
    const int row = r * 32 + srow;
    sB[r] = BT + (size_t)(bn + row) * K + spiece * 8;
    ldsB[r] = row * 128 + dpiece * 16;
  }

  const int xr = (lane & 7) << 4;
  f32x4 acc[MF][4] = {};

  // prologue: stage tile 0 into buf 0
#pragma unroll
  for (int r = 0; r < AR; ++r) {
    __builtin_amdgcn_global_load_lds(AS1(sA[r]), AS3((char*)As[0] + ldsA[r]), 16, 0, 0);
    sA[r] += 64;
  }
#pragma unroll
  for (int r = 0; r < 4; ++r) {
    __builtin_amdgcn_global_load_lds(AS1(sB[r]), AS3((char*)Bs[0] + ldsB[r]), 16, 0, 0);
    sB[r] += 64;
  }
  __syncthreads();

  int cur = 0;
  for (int k0 = 0; k0 < K; k0 += 64) {
    // issue prefetch of next tile into buf^1 (overlaps with MFMA below)
    if (k0 + 64 < K) {
#pragma unroll
      for (int r = 0; r < AR; ++r) {
        __builtin_amdgcn_global_load_lds(AS1(sA[r]), AS3((char*)As[cur ^ 1] + ldsA[r]), 16, 0, 0);
        sA[r] += 64;
      }
#pragma unroll
      for (int r = 0; r < 4; ++r) {
        __builtin_amdgcn_global_load_lds(AS1(sB[r]), AS3((char*)Bs[cur ^ 1] + ldsB[r]), 16, 0, 0);
        sB[r] += 64;
      }
    }
    short8 af[MF][2], bf[4][2];
#pragma unroll
    for (int m = 0; m < MF; ++m)
#pragma unroll
      for (int kk = 0; kk < 2; ++kk) {
        const int row = wr * (BM / 2) + m * 16 + (lane & 15);
        af[m][kk] = *(const short8*)((char*)As[cur] + ((row * 128 + kk * 64 + (lane >> 4) * 16) ^ xr));
      }
#pragma unroll
    for (int n = 0; n < 4; ++n)
#pragma unroll
      for (int kk = 0; kk < 2; ++kk) {
        const int row = wc * 64 + n * 16 + (lane & 15);
        bf[n][kk] = *(const short8*)((char*)Bs[cur] + ((row * 128 + kk * 64 + (lane >> 4) * 16) ^ xr));
      }
#pragma unroll
    for (int kk = 0; kk < 2; ++kk)
#pragma unroll
      for (int m = 0; m < MF; ++m)
#pragma unroll
        for (int n = 0; n < 4; ++n)
          acc[m][n] = __builtin_amdgcn_mfma_f32_16x16x32_bf16(af[m][kk], bf[n][kk], acc[m][n], 0, 0, 0);
    __syncthreads();   // drains prefetch (vm) + frag reads (lgkm); 1 barrier/step
    cur ^= 1;
  }

#pragma unroll
  for (int m = 0; m < MF; ++m) {
#pragma unroll
    for (int n = 0; n < 4; ++n) {
      const int col = bn + wc * 64 + n * 16 + (lane & 15);
      const float bb = (EPI == 1 || EPI == 3) ? bias[col] : (bias ? bias[col] : 0.f);
#pragma unroll
      for (int r = 0; r < 4; ++r) {
        const int row = bm + wr * (BM / 2) + m * 16 + (lane >> 4) * 4 + r;
        const size_t idx = (size_t)row * N + col;
        float v = acc[m][n][r] + bb;
        if (EPI == 1) v = gelu_tanh(v);
        if (EPI == 2 || EPI == 3) v += add1[idx];
        if (EPI == 3) v += b2f(add2[idx]);
        if (OBF == 1) ((short*)C)[(size_t)row * NS + col] = f2b(v);
        else ((float*)C)[idx] = v;
      }
    }
  }
}

// ---------------- Sliding-window attention (bf16 qkv in, bf16 out) ----------
__global__ __launch_bounds__(256) void swa_kernel(
    const unsigned short* __restrict__ qkv, short* __restrict__ out)
{
  __shared__ __align__(16) short ks[128 * 72];
  __shared__ __align__(16) short vt[64 * 136];
  __shared__ __align__(16) short ps[4][16 * 136];
  __shared__ float lsum[64];

  const int tid = threadIdx.x;
  const int w = tid >> 6, l = tid & 63;
  const int tile = blockIdx.x & 31;
  const int h = (blockIdx.x >> 5) & 7;
  const int b = blockIdx.x >> 8;
  const int s0 = tile * 64;
  const size_t base = (size_t)b * SS;

#pragma unroll
  for (int u = 0; u < 16; ++u) {
    const int id = u * 256 + tid;
    const int row = id >> 5, dp = id & 31;
    int jp = s0 - 32 + row;
    jp = min(max(jp, 0), SS - 1);
    const size_t g = (base + jp) * 1536 + h * 64 + dp * 2;
    *(unsigned*)&ks[row * 72 + dp * 2] = *(const unsigned*)&qkv[g + 512];
    const unsigned vv = *(const unsigned*)&qkv[g + 1024];
    vt[(dp * 2) * 136 + row] = (short)(vv & 0xFFFF);
    vt[(dp * 2 + 1) * 136 + row] = (short)(vv >> 16);
  }

  const int qi = w * 16 + (l & 15);
  short8 qf[2];
#pragma unroll
  for (int kf = 0; kf < 2; ++kf)
    qf[kf] = *(const short8*)&qkv[(base + s0 + qi) * 1536 + h * 64 + kf * 32 + (l >> 4) * 8];
  __syncthreads();

  f32x4 sa[8] = {};
#pragma unroll
  for (int mf = 0; mf < 8; ++mf)
#pragma unroll
    for (int kf = 0; kf < 2; ++kf) {
      const short8 af = *(const short8*)&ks[(mf * 16 + (l & 15)) * 72 + kf * 32 + (l >> 4) * 8];
      sa[mf] = __builtin_amdgcn_mfma_f32_16x16x32_bf16(af, qf[kf], sa[mf], 0, 0, 0);
    }

  float sv[8][4];
  float mx = -INFINITY;
#pragma unroll
  for (int mf = 0; mf < 8; ++mf)
#pragma unroll
    for (int r = 0; r < 4; ++r) {
      const int j = mf * 16 + (l >> 4) * 4 + r;
      const int jpos = s0 - 32 + j;
      const bool ok = (j >= qi) && (j <= qi + 64) && (jpos >= 0) && (jpos < SS);
      const float s = ok ? sa[mf][r] * 0.125f : -INFINITY;
      sv[mf][r] = s;
      mx = fmaxf(mx, s);
    }
  mx = fmaxf(mx, __shfl_xor(mx, 16));
  mx = fmaxf(mx, __shfl_xor(mx, 32));
  float ls = 0.f;
#pragma unroll
  for (int mf = 0; mf < 8; ++mf)
#pragma unroll
    for (int r = 0; r < 4; ++r) {
      const float p = __expf(sv[mf][r] - mx);
      sv[mf][r] = p;
      ls += p;
    }
  ls += __shfl_xor(ls, 16);
  ls += __shfl_xor(ls, 32);
  if (l < 16) lsum[w * 16 + l] = ls;

#pragma unroll
  for (int mf = 0; mf < 8; ++mf) {
    short4v p4;
    p4.x = f2b(sv[mf][0]); p4.y = f2b(sv[mf][1]);
    p4.z = f2b(sv[mf][2]); p4.w = f2b(sv[mf][3]);
    *(short4v*)&ps[w][(l & 15) * 136 + mf * 16 + (l >> 4) * 4] = p4;
  }

  f32x4 oa[4] = {};
#pragma unroll
  for (int kf = 0; kf < 4; ++kf) {
    const short8 pf = *(const short8*)&ps[w][(l & 15) * 136 + kf * 32 + (l >> 4) * 8];
#pragma unroll
    for (int nf = 0; nf < 4; ++nf) {
      const short8 vf = *(const short8*)&vt[(nf * 16 + (l & 15)) * 136 + kf * 32 + (l >> 4) * 8];
      oa[nf] = __builtin_amdgcn_mfma_f32_16x16x32_bf16(pf, vf, oa[nf], 0, 0, 0);
    }
  }

  float rl[4];
#pragma unroll
  for (int r = 0; r < 4; ++r) rl[r] = 1.f / lsum[w * 16 + (l >> 4) * 4 + r];
#pragma unroll
  for (int nf = 0; nf < 4; ++nf)
#pragma unroll
    for (int r = 0; r < 4; ++r) {
      const int q = (l >> 4) * 4 + r;
      const int d = nf * 16 + (l & 15);
      out[(base + s0 + w * 16 + q) * 512 + h * 64 + d] = f2b(oa[nf][r] * rl[r]);
    }
}

// ========== Neural memory, linear-scan formulation ==========

// ---- P1: per (chain, chunk) compute A_c, B_c via MFMA (bf16 k,v inputs) ----
__global__ __launch_bounds__(256) void mem_prep(
    const short* __restrict__ kb, const short* __restrict__ vb,
    short* __restrict__ Aq, short* __restrict__ Bq)
{
  __shared__ __align__(16) short kn[64 * 136];
  __shared__ __align__(16) char kT[128 * 128];
  __shared__ __align__(16) char vT[128 * 128];
  const int bid = blockIdx.x;
  const int chain = bid >> 5, c = bid & 31;
  const int b = chain >> 2, mh = chain & 3;
  const size_t rowbase = (size_t)(b * SS + c * 64);
  const int tid = threadIdx.x, w = tid >> 6, l = tid & 63;
  const int td = tid & 127, rh = tid >> 7;

#pragma unroll
  for (int pass = 0; pass < 2; ++pass) {
    const short* src = pass ? vb : kb;
    char* dT = pass ? vT : kT;
#pragma unroll
    for (int j = 0; j < 4; ++j) {
      const int i4 = tid + 256 * j;
      const int r = i4 >> 4, d8 = (i4 & 15) * 8;
      *(short8*)&kn[r * 136 + d8] = *(const short8*)&src[(rowbase + r) * 1536 + mh * 128 + d8];
    }
    __syncthreads();
#pragma unroll
    for (int j = 0; j < 4; ++j) {
      const int r0 = rh * 8 + 16 * j;
      short8 g8;
#pragma unroll
      for (int t = 0; t < 8; ++t) g8[t] = kn[(r0 + t) * 136 + td];
      *(short8*)&dT[(td * 128 + r0 * 2) ^ ((td & 7) << 4)] = g8;
    }
    __syncthreads();
  }

  const int wr = w >> 1, wc = w & 1;
  {
    f32x4 acc[4][4] = {};
#pragma unroll
    for (int kf = 0; kf < 2; ++kf) {
      short8 af[4];
#pragma unroll
      for (int m = 0; m < 4; ++m) {
        const int d = wr * 64 + m * 16 + (l & 15);
        af[m] = *(const short8*)&kT[(d * 128 + kf * 64 + (l >> 4) * 16) ^ ((d & 7) << 4)];
      }
#pragma unroll
      for (int n = 0; n < 4; ++n) {
        const int dp = wc * 64 + n * 16 + (l & 15);
        const short8 bf = *(const short8*)&kT[(dp * 128 + kf * 64 + (l >> 4) * 16) ^ ((dp & 7) << 4)];
#pragma unroll
        for (int m = 0; m < 4; ++m)
          acc[m][n] = __builtin_amdgcn_mfma_f32_16x16x32_bf16(af[m], bf, acc[m][n], 0, 0, 0);
      }
    }
    char* Ad = (char*)(Aq + (size_t)bid * 16384);
#pragma unroll
    for (int m = 0; m < 4; ++m)
#pragma unroll
      for (int n = 0; n < 4; ++n) {
        const int dp = wc * 64 + n * 16 + (l & 15);
        const int d0 = wr * 64 + m * 16 + (l >> 4) * 4;
        short4v s4;
#pragma unroll
        for (int i = 0; i < 4; ++i) s4[i] = f2b(acc[m][n][i] * 0.015625f);
        *(short4v*)&Ad[(dp * 256 + d0 * 2) ^ ((dp & 7) << 4)] = s4;
      }
  }
  {
    f32x4 acc[4][4] = {};
#pragma unroll
    for (int kf = 0; kf < 2; ++kf) {
      short8 af[4];
#pragma unroll
      for (int m = 0; m < 4; ++m) {
        const int d = wr * 64 + m * 16 + (l & 15);
        af[m] = *(const short8*)&kT[(d * 128 + kf * 64 + (l >> 4) * 16) ^ ((d & 7) << 4)];
      }
#pragma unroll
      for (int n = 0; n < 4; ++n) {
        const int e = wc * 64 + n * 16 + (l & 15);
        const short8 bf = *(const short8*)&vT[(e * 128 + kf * 64 + (l >> 4) * 16) ^ ((e & 7) << 4)];
#pragma unroll
        for (int m = 0; m < 4; ++m)
          acc[m][n] = __builtin_amdgcn_mfma_f32_16x16x32_bf16(af[m], bf, acc[m][n], 0, 0, 0);
      }
    }
    short* Bd = Bq + (size_t)bid * 16384;
#pragma unroll
    for (int m = 0; m < 4; ++m)
#pragma unroll
      for (int n = 0; n < 4; ++n) {
        const int e = wc * 64 + n * 16 + (l & 15);
        const int d0 = wr * 64 + m * 16 + (l >> 4) * 4;
        short4v s4;
#pragma unroll
        for (int i = 0; i < 4; ++i) s4[i] = f2b(acc[m][n][i] * 0.015625f);
        *(short4v*)&Bd[e * 128 + d0] = s4;
      }
  }
}

// ---- P2: serial scan — raw s_barrier + counted vmcnt, depth-2 A prefetch ----
__global__ __launch_bounds__(256) void mem_scan2(
    const short* __restrict__ Aq, const short* __restrict__ Bq,
    short* __restrict__ MTg)
{
  __shared__ __align__(16) char AcL[3][32768];
  __shared__ __align__(16) char MT[2][8192];
  const int bid = blockIdx.x;
  const int chain = bid >> 2, ch = bid & 3;
  const int tid = threadIdx.x;
  const int w = tid >> 6, l = tid & 63;
  const int wr = w >> 1, wc = w & 1;
  const int e = wc * 16 + (l & 15);

  const short* Ab = Aq + (size_t)chain * 32 * 16384;
  const short* Bb = Bq + (size_t)chain * 32 * 16384;
  short* MTb = MTg + (size_t)chain * 32 * 16384 + (size_t)ch * 32 * 128;
  const int brow = (ch * 32 + e) * 128;

  {
    const short8 z = {0, 0, 0, 0, 0, 0, 0, 0};
    for (int i = tid; i < 512; i += 256) *(short8*)(MT[0] + i * 16) = z;
  }
#pragma unroll
  for (int cc = 0; cc < 2; ++cc) {
    const char* srcA = (const char*)(Ab + (size_t)cc * 16384);
#pragma unroll
    for (int j = 0; j < 8; ++j) {
      const int byte = tid * 16 + j * 4096;
      __builtin_amdgcn_global_load_lds(AS1(srcA + byte), AS3(AcL[cc] + byte), 16, 0, 0);
    }
  }
  short4v b0[4], b1[4], b2[4];
#pragma unroll
  for (int m = 0; m < 4; ++m) {
    b0[m] = *(const short4v*)&Bb[brow + wr * 64 + m * 16 + (l >> 4) * 4];
    b1[m] = *(const short4v*)&Bb[16384 + brow + wr * 64 + m * 16 + (l >> 4) * 4];
  }
  float Mreg[16] = {}, Momreg[16] = {};
  __syncthreads();

#define SCHUNK(C, AB, MR, BC, BN, DOI, WN)                                     \
  {                                                                            \
    short* slot = MTb + (size_t)(C) * 16384;                                   \
    _Pragma("unroll") for (int m = 0; m < 4; ++m) {                            \
      const int d0 = wr * 64 + m * 16 + (l >> 4) * 4;                          \
      short4v s4;                                                              \
      _Pragma("unroll") for (int i = 0; i < 4; ++i) s4[i] = f2b(Mreg[m * 4 + i]); \
      *(short4v*)&slot[e * 128 + d0] = s4;                                     \
    }                                                                          \
    if (DOI) {                                                                 \
      const char* srcA = (const char*)(Ab + (size_t)((C) + 2) * 16384);        \
      _Pragma("unroll") for (int j = 0; j < 8; ++j) {                          \
        const int byte = tid * 16 + j * 4096;                                  \
        __builtin_amdgcn_global_load_lds(AS1(srcA + byte),                     \
            AS3(AcL[((C) + 2) % 3] + byte), 16, 0, 0);                         \
      }                                                                        \
      const short* Bn = Bb + (size_t)((C) + 2) * 16384;                        \
      _Pragma("unroll") for (int m = 0; m < 4; ++m)                            \
        BN[m] = *(const short4v*)&Bn[brow + wr * 64 + m * 16 + (l >> 4) * 4];  \
    }                                                                          \
    {                                                                          \
      f32x4 acc[4] = {};                                                       \
      _Pragma("unroll") for (int kf = 0; kf < 4; ++kf) {                       \
        const short8 bf = *(const short8*)&MT[MR][(e * 256 + kf * 64 + (l >> 4) * 16) ^ ((e & 7) << 4)]; \
        _Pragma("unroll") for (int m = 0; m < 4; ++m) {                        \
          const int d = wr * 64 + m * 16 + (l & 15);                           \
          const short8 af = *(const short8*)&AcL[AB][(d * 256 + kf * 64 + (l >> 4) * 16) ^ ((d & 7) << 4)]; \
          acc[m] = __builtin_amdgcn_mfma_f32_16x16x32_bf16(af, bf, acc[m], 0, 0, 0); \
        }                                                                      \
      }                                                                        \
      _Pragma("unroll") for (int m = 0; m < 4; ++m) {                          \
        const int d0 = wr * 64 + m * 16 + (l >> 4) * 4;                        \
        short4v s4;                                                            \
        _Pragma("unroll") for (int i = 0; i < 4; ++i) {                        \
          const int idx = m * 4 + i;                                           \
          const float g = acc[m][i] - b2f(BC[m][i]);                           \
          Momreg[idx] = 0.9f * Momreg[idx] - 0.1f * g;                         \
          Mreg[idx] = 0.99f * Mreg[idx] + Momreg[idx];                         \
          s4[i] = f2b(Mreg[idx]);                                              \
        }                                                                      \
        *(short4v*)&MT[(MR) ^ 1][(e * 256 + d0 * 2) ^ ((e & 7) << 4)] = s4;    \
      }                                                                        \
    }                                                                          \
    asm volatile("s_waitcnt lgkmcnt(0) vmcnt(" #WN ")" ::: "memory");          \
    __builtin_amdgcn_sched_barrier(0);                                         \
    __builtin_amdgcn_s_barrier();                                              \
    __builtin_amdgcn_sched_barrier(0);                                         \
  }

  SCHUNK(0, 0, 0, b0, b2, 1, 20)  SCHUNK(1, 1, 1, b1, b0, 1, 20)
  SCHUNK(2, 2, 0, b2, b1, 1, 20)  SCHUNK(3, 0, 1, b0, b2, 1, 20)
  SCHUNK(4, 1, 0, b1, b0, 1, 20)  SCHUNK(5, 2, 1, b2, b1, 1, 20)
  SCHUNK(6, 0, 0, b0, b2, 1, 20)  SCHUNK(7, 1, 1, b1, b0, 1, 20)
  SCHUNK(8, 2, 0, b2, b1, 1, 20)  SCHUNK(9, 0, 1, b0, b2, 1, 20)
  SCHUNK(10, 1, 0, b1, b0, 1, 20) SCHUNK(11, 2, 1, b2, b1, 1, 20)
  SCHUNK(12, 0, 0, b0, b2, 1, 20) SCHUNK(13, 1, 1, b1, b0, 1, 20)
  SCHUNK(14, 2, 0, b2, b1, 1, 20) SCHUNK(15, 0, 1, b0, b2, 1, 20)
  SCHUNK(16, 1, 0, b1, b0, 1, 20) SCHUNK(17, 2, 1, b2, b1, 1, 20)
  SCHUNK(18, 0, 0, b0, b2, 1, 20) SCHUNK(19, 1, 1, b1, b0, 1, 20)
  SCHUNK(20, 2, 0, b2, b1, 1, 20) SCHUNK(21, 0, 1, b0, b2, 1, 20)
  SCHUNK(22, 1, 0, b1, b0, 1, 20) SCHUNK(23, 2, 1, b2, b1, 1, 20)
  SCHUNK(24, 0, 0, b0, b2, 1, 20) SCHUNK(25, 1, 1, b1, b0, 1, 20)
  SCHUNK(26, 2, 0, b2, b1, 1, 20) SCHUNK(27, 0, 1, b0, b2, 1, 20)
  SCHUNK(28, 1, 0, b1, b0, 1, 20) SCHUNK(29, 2, 1, b2, b1, 0, 8)
  SCHUNK(30, 0, 0, b0, b2, 0, 8)
#undef SCHUNK

  // epilogue: slot 31 = M_30
  {
    short* slot = MTb + (size_t)31 * 16384;
#pragma unroll
    for (int m = 0; m < 4; ++m) {
      const int d0 = wr * 64 + m * 16 + (l >> 4) * 4;
      short4v s4;
#pragma unroll
      for (int i = 0; i < 4; ++i) s4[i] = f2b(Mreg[m * 4 + i]);
      *(short4v*)&slot[e * 128 + d0] = s4;
    }
  }
}

// ---- P3: out_c = q_c @ M_{c-1} (bf16 q input) ----
__global__ __launch_bounds__(256) void mem_out(
    const short* __restrict__ qb, const short* __restrict__ MTg,
    short* __restrict__ mem)
{
  const int bid = blockIdx.x;
  const int chain = bid >> 5, c = bid & 31;
  const int b = chain >> 2, mh = chain & 3;
  const size_t rowbase = (size_t)(b * SS + c * 64);
  const int tid = threadIdx.x, w = tid >> 6, l = tid & 63;
  const int wr = w >> 1, wc = w & 1;
  const short* MTc = MTg + (size_t)chain * 32 * 16384 + (size_t)c * 16384;

  f32x4 acc[2][4] = {};
#pragma unroll
  for (int kf = 0; kf < 4; ++kf) {
    short8 af[2];
#pragma unroll
    for (int m = 0; m < 2; ++m) {
      const int r = wr * 32 + m * 16 + (l & 15);
      af[m] = *(const short8*)&qb[(rowbase + r) * 1536 + mh * 128 + kf * 32 + (l >> 4) * 8];
    }
#pragma unroll
    for (int n = 0; n < 4; ++n) {
      const int e = wc * 64 + n * 16 + (l & 15);
      const short8 bf = *(const short8*)&MTc[e * 128 + kf * 32 + (l >> 4) * 8];
#pragma unroll
      for (int m = 0; m < 2; ++m)
        acc[m][n] = __builtin_amdgcn_mfma_f32_16x16x32_bf16(af[m], bf, acc[m][n], 0, 0, 0);
    }
  }
#pragma unroll
  for (int m = 0; m < 2; ++m)
#pragma unroll
    for (int n = 0; n < 4; ++n)
#pragma unroll
      for (int i = 0; i < 4; ++i) {
        const int r = wr * 32 + m * 16 + (l >> 4) * 4 + i;
        const int e = wc * 64 + n * 16 + (l & 15);
        mem[(rowbase + r) * 512 + mh * 128 + e] = f2b(acc[m][n][i]);
      }
}

// ---------------- merged weight transpose+convert (all matrices, 1 launch) ---
struct TcvtJob { const float* src; short* dst; int K; int N; int blks; };
struct TcvtArgs { TcvtJob j[10]; };

__global__ __launch_bounds__(256) void tcvt_all(TcvtArgs a)
{
  int bid = blockIdx.x;
  const float* src = nullptr; short* dst = nullptr; int K = 0, N = 0;
#pragma unroll
  for (int i = 0; i < 10; ++i) {
    if (!src) {
      if (bid < a.j[i].blks) { src = a.j[i].src; dst = a.j[i].dst; K = a.j[i].K; N = a.j[i].N; }
      else bid -= a.j[i].blks;
    }
  }
  const int nt = N >> 5, kt = K >> 5;
  const int z = bid / (nt * kt);
  const int rem = bid % (nt * kt);
  const int k0 = (rem / nt) * 32, n0 = (rem % nt) * 32;
  const size_t zoff = (size_t)z * K * N;
  src += zoff; dst += zoff;

  __shared__ float t[32][33];
  const int tx = threadIdx.x & 31, ty = threadIdx.x >> 5;
#pragma unroll
  for (int i = 0; i < 4; ++i)
    t[ty + i * 8][tx] = src[(size_t)(k0 + ty + i * 8) * N + n0 + tx];
  __syncthreads();
#pragma unroll
  for (int i = 0; i < 4; ++i)
    dst[(size_t)(n0 + ty + i * 8) * K + k0 + tx] = f2b(t[tx][ty + i * 8]);
}

// ---------------- persistent path: wide parallel kernels -------------------
__global__ __launch_bounds__(256) void mean_tokens_kernel(
    const float* __restrict__ pm, float* __restrict__ mvec)
{
  const int d = blockIdx.x * 256 + threadIdx.x;
  if (d < 512) {
    float s = 0.f;
#pragma unroll
    for (int t = 0; t < 16; ++t) s += pm[t * 512 + d];
    mvec[d] = s * (1.f / 16.f);
  }
}

// out[e] = bias[e] + sum_d a[d]*W[d*512+e]; grid 32 x 256 (16 outputs/block)
__global__ __launch_bounds__(256) void matvec512_kernel(
    const float* __restrict__ a, const float* __restrict__ W,
    const float* __restrict__ bias, float* __restrict__ out)
{
  __shared__ float red[16][17];
  const int eo = threadIdx.x & 15;
  const int g = threadIdx.x >> 4;
  const int e = blockIdx.x * 16 + eo;
  float s = 0.f;
#pragma unroll 8
  for (int j = 0; j < 32; ++j) {
    const int d = g * 32 + j;
    s += a[d] * W[d * 512 + e];
  }
  red[g][eo] = s;
  __syncthreads();
  if (threadIdx.x < 16) {
    float t = bias[blockIdx.x * 16 + threadIdx.x];
#pragma unroll
    for (int gg = 0; gg < 16; ++gg) t += red[gg][threadIdx.x];
    out[blockIdx.x * 16 + threadIdx.x] = t;
  }
}

// ---------------- host side ----------------
extern "C" void kernel_launch(void* const* d_in, const int* in_sizes, int n_in,
                              void* d_out, int out_size, void* d_ws, size_t ws_size,
                              hipStream_t stream)
{
  const float* x         = (const float*)d_in[0];
  const float* n1w       = (const float*)d_in[1];
  const float* n1b       = (const float*)d_in[2];
  const float* qkvw      = (const float*)d_in[3];
  const float* qkvb      = (const float*)d_in[4];
  const float* projw     = (const float*)d_in[5];
  const float* projb     = (const float*)d_in[6];
  const float* n2w       = (const float*)d_in[7];
  const float* n2b       = (const float*)d_in[8];
  const float* fc1w      = (const float*)d_in[9];
  const float* fc1b      = (const float*)d_in[10];
  const float* fc2w      = (const float*)d_in[11];
  const float* fc2b      = (const float*)d_in[12];
  const float* mlnw      = (const float*)d_in[13];
  const float* mlnb      = (const float*)d_in[14];
  const float* mwq       = (const float*)d_in[15];
  const float* mwk       = (const float*)d_in[16];
  const float* mwv       = (const float*)d_in[17];
  const float* mprojw    = (const float*)d_in[18];
  const float* mprojb    = (const float*)d_in[19];
  const float* pm_tokens = (const float*)d_in[20];
  const float* pmw       = (const float*)d_in[21];
  const float* pmb       = (const float*)d_in[22];
  const float* fw        = (const float*)d_in[23];
  const float* fb        = (const float*)d_in[24];
  float* out = (float*)d_out;

  char* p = (char*)d_ws;
  auto alloc = [&](size_t bytes) {
    char* r = p;
    p += (bytes + 255) & ~(size_t)255;
    return r;
  };
  short* qkvwT  = (short*)alloc(6ull * 1536 * 512 * 2);
  short* projwT = (short*)alloc(6ull * 512 * 512 * 2);
  short* fc1wT  = (short*)alloc(6ull * 2048 * 512 * 2);
  short* fc2wT  = (short*)alloc(6ull * 512 * 2048 * 2);
  short* mqkvT  = (short*)alloc(3ull * 512 * 512 * 2);
  short* mprojT = (short*)alloc(512ull * 512 * 2);
  short* fwT    = (short*)alloc(512ull * 1024 * 2);
  short* bigb   = (short*)alloc((size_t)BS * 1536 * 2);
  float* hbuf   = (float*)alloc((size_t)BS * 512 * 4);
  float* t0     = (float*)alloc(3 * 512 * 4);
  float* t1 = t0 + 512; float* t2 = t1 + 512;
  short* actA   = (short*)alloc((size_t)BS * 512 * 2);
  short* ln0b   = (short*)alloc((size_t)BS * 512 * 2);
  short* attnb  = (short*)alloc((size_t)BS * 512 * 2);
  short* ff1b   = (short*)alloc((size_t)BS * 2048 * 2);
  short* stlt   = (short*)alloc((size_t)BS * 1024 * 2);
  short* Aq     = (short*)alloc(256ull * 16384 * 2);
  short* Bq     = (short*)alloc(256ull * 16384 * 2);
  short* MTg    = (short*)alloc(256ull * 16384 * 2);

  // ---- all weight transposes in one launch ----
  TcvtArgs ta;
  ta.j[0] = {qkvw,  qkvwT,  512, 1536, 48 * 16 * 6};
  ta.j[1] = {projw, projwT, 512, 512,  16 * 16 * 6};
  ta.j[2] = {fc1w,  fc1wT,  512, 2048, 64 * 16 * 6};
  ta.j[3] = {fc2w,  fc2wT,  2048, 512, 16 * 64 * 6};
  ta.j[4] = {mwq, mqkvT,                 512, 512, 256};
  ta.j[5] = {mwk, mqkvT + 512 * 512,     512, 512, 256};
  ta.j[6] = {mwv, mqkvT + 2 * 512 * 512, 512, 512, 256};
  ta.j[7] = {mprojw, mprojT, 512, 512, 256};
  ta.j[8] = {fw, fwT, 1024, 512, 512};
  ta.j[9] = {nullptr, nullptr, 32, 32, 0};
  int total_blks = 0;
  for (int i = 0; i < 10; ++i) total_blks += ta.j[i].blks;
  tcvt_all<<<total_blks, 256, 0, stream>>>(ta);

  // ---- persistent path (parallel) ----
  mean_tokens_kernel<<<2, 256, 0, stream>>>(pm_tokens, t0);
  matvec512_kernel<<<32, 256, 0, stream>>>(t0, pmw, pmb, t1);
  matvec512_kernel<<<32, 256, 0, stream>>>(t1, fw + (size_t)1024 * 512, fb, t2);

  // ---- neural memory path ----
  ln_dual_kernel<<<BS / 4, 256, 0, stream>>>(x, mlnw, mlnb, actA, n1w, n1b, ln0b);
  gemm_bf16<0, 1, 128><<<dim3(12, 32), 256, 0, stream>>>(
      actA, mqkvT, nullptr, nullptr, nullptr, bigb, BS, 1536, 512, 1536);
  mem_prep<<<256, 256, 0, stream>>>(bigb + 512, bigb + 1024, Aq, Bq);
  mem_scan2<<<32, 256, 0, stream>>>(Aq, Bq, MTg);
  mem_out<<<256, 256, 0, stream>>>(bigb, MTg, ff1b);
  gemm_bf16<2, 1, 64><<<dim3(4, 64), 256, 0, stream>>>(
      ff1b, mprojT, mprojb, x, nullptr, stlt + 512, BS, 512, 512, 1024);

  // ---- layer stack ----
  for (int l = 0; l < LL; ++l) {
    const short* lnin = (l == 0) ? ln0b : actA;
    if (l > 0)
      ln_kernel<<<BS / 4, 256, 0, stream>>>(hbuf, n1w + l * 512, n1b + l * 512, actA);
    gemm_bf16<0, 1, 128><<<dim3(12, 32), 256, 0, stream>>>(
        lnin, qkvwT + (size_t)l * 1536 * 512, qkvb + l * 1536,
        nullptr, nullptr, bigb, BS, 1536, 512, 1536);
    swa_kernel<<<512, 256, 0, stream>>>((const unsigned short*)bigb, attnb);
    gemm_bf16<2, 0, 64><<<dim3(4, 64), 256, 0, stream>>>(
        attnb, projwT + (size_t)l * 512 * 512, projb + l * 512,
        (l == 0) ? x : hbuf, nullptr, hbuf, BS, 512, 512, 512);
    ln_kernel<<<BS / 4, 256, 0, stream>>>(hbuf, n2w + l * 512, n2b + l * 512, actA);
    gemm_bf16<1, 1, 128><<<dim3(16, 32), 256, 0, stream>>>(
        actA, fc1wT + (size_t)l * 2048 * 512, fc1b + l * 2048,
        nullptr, nullptr, ff1b, BS, 2048, 512, 2048);
    if (l < LL - 1)
      gemm_bf16<3, 0, 64><<<dim3(4, 64), 256, 0, stream>>>(
          ff1b, fc2wT + (size_t)l * 512 * 2048, fc2b + l * 512,
          hbuf, actA, hbuf, BS, 512, 2048, 512);
    else
      gemm_bf16<3, 1, 64><<<dim3(4, 64), 256, 0, stream>>>(
          ff1b, fc2wT + (size_t)l * 512 * 2048, fc2b + l * 512,
          hbuf, actA, stlt, BS, 512, 2048, 1024);   // ST -> stlt[:, 0:512]
  }

  // ---- fusion: out = [ST | LT] @ fwT + (persistent + fusion bias) ----
  gemm_bf16<0, 0, 64><<<dim3(4, 64), 256, 0, stream>>>(
      stlt, fwT, t2, nullptr, nullptr, out, BS, 512, 1024, 512);
}

// Round 13
// 647.515 us; speedup vs baseline: 5.9498x; 1.1315x over previous
//
#include <hip/hip_runtime.h>
#include <math.h>

// Problem constants
#define BB 2
#define SS 2048
#define DD 512
#define HH 8
#define LL 6
#define WW 64
#define CHH 64
#define NCC 32
#define BS (BB*SS)   // 4096 rows

typedef __attribute__((ext_vector_type(8))) short short8;
typedef __attribute__((ext_vector_type(4))) short short4v;
typedef __attribute__((ext_vector_type(4))) float f32x4;

__device__ inline float b2f(short s) {
  unsigned u = ((unsigned)(unsigned short)s) << 16;
  float f; __builtin_memcpy(&f, &u, 4); return f;
}
__device__ inline short f2b(float f) {
  unsigned u; __builtin_memcpy(&u, &f, 4);
  unsigned r = (u + 0x7FFFu + ((u >> 16) & 1u)) >> 16;
  return (short)r;
}
__device__ inline float gelu_tanh(float v) {
  float u = 0.7978845608f * (v + 0.044715f * v * v * v);
  u = fminf(fmaxf(u, -20.f), 20.f);
  float e2 = __expf(2.f * u);
  return 0.5f * v * (1.f + (e2 - 1.f) / (e2 + 1.f));
}

#define AS1(p) ((const __attribute__((address_space(1))) void*)(p))
#define AS3(p) ((__attribute__((address_space(3))) void*)(p))

// ---------------- LayerNorm: wave-per-row, 4 rows/block ----------------
__global__ __launch_bounds__(256) void ln_kernel(
    const float* __restrict__ x, const float* __restrict__ w,
    const float* __restrict__ b, short* __restrict__ y)
{
  const int row = blockIdx.x * 4 + (threadIdx.x >> 6);
  const int l = threadIdx.x & 63;
  const float* xr = x + (size_t)row * DD + l * 8;
  const float4 a = *(const float4*)xr;
  const float4 c = *(const float4*)(xr + 4);
  float s = a.x + a.y + a.z + a.w + c.x + c.y + c.z + c.w;
  float sq = a.x * a.x + a.y * a.y + a.z * a.z + a.w * a.w
           + c.x * c.x + c.y * c.y + c.z * c.z + c.w * c.w;
#pragma unroll
  for (int off = 1; off < 64; off <<= 1) {
    s += __shfl_xor(s, off);
    sq += __shfl_xor(sq, off);
  }
  const float mean = s * (1.f / DD);
  const float var = sq * (1.f / DD) - mean * mean;
  const float inv = rsqrtf(var + 1e-5f);
  const float4 w0 = *(const float4*)(w + l * 8);
  const float4 w1 = *(const float4*)(w + l * 8 + 4);
  const float4 b0 = *(const float4*)(b + l * 8);
  const float4 b1 = *(const float4*)(b + l * 8 + 4);
  short8 o;
  o[0] = f2b((a.x - mean) * inv * w0.x + b0.x);
  o[1] = f2b((a.y - mean) * inv * w0.y + b0.y);
  o[2] = f2b((a.z - mean) * inv * w0.z + b0.z);
  o[3] = f2b((a.w - mean) * inv * w0.w + b0.w);
  o[4] = f2b((c.x - mean) * inv * w1.x + b1.x);
  o[5] = f2b((c.y - mean) * inv * w1.y + b1.y);
  o[6] = f2b((c.z - mean) * inv * w1.z + b1.z);
  o[7] = f2b((c.w - mean) * inv * w1.w + b1.w);
  *(short8*)(y + (size_t)row * DD + l * 8) = o;
}

// ---------------- Dual LayerNorm: one read of x, two (w,b,y) ----------------
__global__ __launch_bounds__(256) void ln_dual_kernel(
    const float* __restrict__ x,
    const float* __restrict__ w1, const float* __restrict__ b1v, short* __restrict__ y1,
    const float* __restrict__ w2, const float* __restrict__ b2v, short* __restrict__ y2)
{
  const int row = blockIdx.x * 4 + (threadIdx.x >> 6);
  const int l = threadIdx.x & 63;
  const float* xr = x + (size_t)row * DD + l * 8;
  const float4 a = *(const float4*)xr;
  const float4 c = *(const float4*)(xr + 4);
  float s = a.x + a.y + a.z + a.w + c.x + c.y + c.z + c.w;
  float sq = a.x * a.x + a.y * a.y + a.z * a.z + a.w * a.w
           + c.x * c.x + c.y * c.y + c.z * c.z + c.w * c.w;
#pragma unroll
  for (int off = 1; off < 64; off <<= 1) {
    s += __shfl_xor(s, off);
    sq += __shfl_xor(sq, off);
  }
  const float mean = s * (1.f / DD);
  const float var = sq * (1.f / DD) - mean * mean;
  const float inv = rsqrtf(var + 1e-5f);
  const float n0 = (a.x - mean) * inv, n1 = (a.y - mean) * inv,
              n2 = (a.z - mean) * inv, n3 = (a.w - mean) * inv,
              n4 = (c.x - mean) * inv, n5 = (c.y - mean) * inv,
              n6 = (c.z - mean) * inv, n7 = (c.w - mean) * inv;
#pragma unroll
  for (int pass = 0; pass < 2; ++pass) {
    const float* w = pass ? w2 : w1;
    const float* b = pass ? b2v : b1v;
    short* y = pass ? y2 : y1;
    const float4 w0 = *(const float4*)(w + l * 8);
    const float4 w1_ = *(const float4*)(w + l * 8 + 4);
    const float4 bb0 = *(const float4*)(b + l * 8);
    const float4 bb1 = *(const float4*)(b + l * 8 + 4);
    short8 o;
    o[0] = f2b(n0 * w0.x + bb0.x);
    o[1] = f2b(n1 * w0.y + bb0.y);
    o[2] = f2b(n2 * w0.z + bb0.z);
    o[3] = f2b(n3 * w0.w + bb0.w);
    o[4] = f2b(n4 * w1_.x + bb1.x);
    o[5] = f2b(n5 * w1_.y + bb1.y);
    o[6] = f2b(n6 * w1_.z + bb1.z);
    o[7] = f2b(n7 * w1_.w + bb1.w);
    *(short8*)(y + (size_t)row * DD + l * 8) = o;
  }
}

// --- bf16 MFMA GEMM, BK=64, XOR-swizzled LDS, 2-phase dbuf, BM x BN tiles ---
// EPI: 0=+bias(opt); 1=gelu(+bias); 2=+bias(opt)+add1(f32); 3=+bias+add1(f32)+add2(bf16)
// OBF: 0=f32 out (stride N); 1=bf16 out (stride NS)
// Waves 2x2; wave tile (BM/2) x (BN/2).
template<int EPI, int OBF, int BM, int BN>
__global__ __launch_bounds__(256) void gemm_bf16(
    const short* __restrict__ A, const short* __restrict__ BT,
    const float* __restrict__ bias, const float* __restrict__ add1,
    const short* __restrict__ add2, void* __restrict__ C,
    int M, int N, int K, int NS)
{
  constexpr int MF = BM / 32;       // A frags per wave
  constexpr int NF = BN / 32;       // B frags per wave
  constexpr int AR = BM / 32;       // A staging rounds
  constexpr int BR = BN / 32;       // B staging rounds
  __shared__ __align__(16) short As[2][BM * 64];
  __shared__ __align__(16) short Bs[2][BN * 64];
  const int tid = threadIdx.x;
  const int wave = tid >> 6, lane = tid & 63;
  const int wr = wave >> 1, wc = wave & 1;
  const int bm = blockIdx.y * BM, bn = blockIdx.x * BN;

  const int srow = tid >> 3;
  const int dpiece = tid & 7;
  const int spiece = dpiece ^ (srow & 7);

  const short* sA[AR]; const short* sB[BR];
  int ldsA[AR], ldsB[BR];
#pragma unroll
  for (int r = 0; r < AR; ++r) {
    const int row = r * 32 + srow;
    sA[r] = A + (size_t)(bm + row) * K + spiece * 8;
    ldsA[r] = row * 128 + dpiece * 16;
  }
#pragma unroll
  for (int r = 0; r < BR; ++r) {
    const int row = r * 32 + srow;
    sB[r] = BT + (size_t)(bn + row) * K + spiece * 8;
    ldsB[r] = row * 128 + dpiece * 16;
  }

  const int xr = (lane & 7) << 4;
  f32x4 acc[MF][NF] = {};

  // prologue: stage tile 0 into buf 0
#pragma unroll
  for (int r = 0; r < AR; ++r) {
    __builtin_amdgcn_global_load_lds(AS1(sA[r]), AS3((char*)As[0] + ldsA[r]), 16, 0, 0);
    sA[r] += 64;
  }
#pragma unroll
  for (int r = 0; r < BR; ++r) {
    __builtin_amdgcn_global_load_lds(AS1(sB[r]), AS3((char*)Bs[0] + ldsB[r]), 16, 0, 0);
    sB[r] += 64;
  }
  __syncthreads();

  int cur = 0;
  for (int k0 = 0; k0 < K; k0 += 64) {
    if (k0 + 64 < K) {
#pragma unroll
      for (int r = 0; r < AR; ++r) {
        __builtin_amdgcn_global_load_lds(AS1(sA[r]), AS3((char*)As[cur ^ 1] + ldsA[r]), 16, 0, 0);
        sA[r] += 64;
      }
#pragma unroll
      for (int r = 0; r < BR; ++r) {
        __builtin_amdgcn_global_load_lds(AS1(sB[r]), AS3((char*)Bs[cur ^ 1] + ldsB[r]), 16, 0, 0);
        sB[r] += 64;
      }
    }
    short8 af[MF][2], bf[NF][2];
#pragma unroll
    for (int m = 0; m < MF; ++m)
#pragma unroll
      for (int kk = 0; kk < 2; ++kk) {
        const int row = wr * (BM / 2) + m * 16 + (lane & 15);
        af[m][kk] = *(const short8*)((char*)As[cur] + ((row * 128 + kk * 64 + (lane >> 4) * 16) ^ xr));
      }
#pragma unroll
    for (int n = 0; n < NF; ++n)
#pragma unroll
      for (int kk = 0; kk < 2; ++kk) {
        const int row = wc * (BN / 2) + n * 16 + (lane & 15);
        bf[n][kk] = *(const short8*)((char*)Bs[cur] + ((row * 128 + kk * 64 + (lane >> 4) * 16) ^ xr));
      }
#pragma unroll
    for (int kk = 0; kk < 2; ++kk)
#pragma unroll
      for (int m = 0; m < MF; ++m)
#pragma unroll
        for (int n = 0; n < NF; ++n)
          acc[m][n] = __builtin_amdgcn_mfma_f32_16x16x32_bf16(af[m][kk], bf[n][kk], acc[m][n], 0, 0, 0);
    __syncthreads();
    cur ^= 1;
  }

#pragma unroll
  for (int m = 0; m < MF; ++m) {
#pragma unroll
    for (int n = 0; n < NF; ++n) {
      const int col = bn + wc * (BN / 2) + n * 16 + (lane & 15);
      const float bb = (EPI == 1 || EPI == 3) ? bias[col] : (bias ? bias[col] : 0.f);
#pragma unroll
      for (int r = 0; r < 4; ++r) {
        const int row = bm + wr * (BM / 2) + m * 16 + (lane >> 4) * 4 + r;
        const size_t idx = (size_t)row * N + col;
        float v = acc[m][n][r] + bb;
        if (EPI == 1) v = gelu_tanh(v);
        if (EPI == 2 || EPI == 3) v += add1[idx];
        if (EPI == 3) v += b2f(add2[idx]);
        if (OBF == 1) ((short*)C)[(size_t)row * NS + col] = f2b(v);
        else ((float*)C)[idx] = v;
      }
    }
  }
}

// ---------------- Sliding-window attention (bf16 qkv in, bf16 out) ----------
__global__ __launch_bounds__(256) void swa_kernel(
    const unsigned short* __restrict__ qkv, short* __restrict__ out)
{
  __shared__ __align__(16) short ks[128 * 72];
  __shared__ __align__(16) short vt[64 * 136];
  __shared__ __align__(16) short ps[4][16 * 136];
  __shared__ float lsum[64];

  const int tid = threadIdx.x;
  const int w = tid >> 6, l = tid & 63;
  const int tile = blockIdx.x & 31;
  const int h = (blockIdx.x >> 5) & 7;
  const int b = blockIdx.x >> 8;
  const int s0 = tile * 64;
  const size_t base = (size_t)b * SS;

#pragma unroll
  for (int u = 0; u < 16; ++u) {
    const int id = u * 256 + tid;
    const int row = id >> 5, dp = id & 31;
    int jp = s0 - 32 + row;
    jp = min(max(jp, 0), SS - 1);
    const size_t g = (base + jp) * 1536 + h * 64 + dp * 2;
    *(unsigned*)&ks[row * 72 + dp * 2] = *(const unsigned*)&qkv[g + 512];
    const unsigned vv = *(const unsigned*)&qkv[g + 1024];
    vt[(dp * 2) * 136 + row] = (short)(vv & 0xFFFF);
    vt[(dp * 2 + 1) * 136 + row] = (short)(vv >> 16);
  }

  const int qi = w * 16 + (l & 15);
  short8 qf[2];
#pragma unroll
  for (int kf = 0; kf < 2; ++kf)
    qf[kf] = *(const short8*)&qkv[(base + s0 + qi) * 1536 + h * 64 + kf * 32 + (l >> 4) * 8];
  __syncthreads();

  f32x4 sa[8] = {};
#pragma unroll
  for (int mf = 0; mf < 8; ++mf)
#pragma unroll
    for (int kf = 0; kf < 2; ++kf) {
      const short8 af = *(const short8*)&ks[(mf * 16 + (l & 15)) * 72 + kf * 32 + (l >> 4) * 8];
      sa[mf] = __builtin_amdgcn_mfma_f32_16x16x32_bf16(af, qf[kf], sa[mf], 0, 0, 0);
    }

  float sv[8][4];
  float mx = -INFINITY;
#pragma unroll
  for (int mf = 0; mf < 8; ++mf)
#pragma unroll
    for (int r = 0; r < 4; ++r) {
      const int j = mf * 16 + (l >> 4) * 4 + r;
      const int jpos = s0 - 32 + j;
      const bool ok = (j >= qi) && (j <= qi + 64) && (jpos >= 0) && (jpos < SS);
      const float s = ok ? sa[mf][r] * 0.125f : -INFINITY;
      sv[mf][r] = s;
      mx = fmaxf(mx, s);
    }
  mx = fmaxf(mx, __shfl_xor(mx, 16));
  mx = fmaxf(mx, __shfl_xor(mx, 32));
  float ls = 0.f;
#pragma unroll
  for (int mf = 0; mf < 8; ++mf)
#pragma unroll
    for (int r = 0; r < 4; ++r) {
      const float p = __expf(sv[mf][r] - mx);
      sv[mf][r] = p;
      ls += p;
    }
  ls += __shfl_xor(ls, 16);
  ls += __shfl_xor(ls, 32);
  if (l < 16) lsum[w * 16 + l] = ls;

#pragma unroll
  for (int mf = 0; mf < 8; ++mf) {
    short4v p4;
    p4.x = f2b(sv[mf][0]); p4.y = f2b(sv[mf][1]);
    p4.z = f2b(sv[mf][2]); p4.w = f2b(sv[mf][3]);
    *(short4v*)&ps[w][(l & 15) * 136 + mf * 16 + (l >> 4) * 4] = p4;
  }

  f32x4 oa[4] = {};
#pragma unroll
  for (int kf = 0; kf < 4; ++kf) {
    const short8 pf = *(const short8*)&ps[w][(l & 15) * 136 + kf * 32 + (l >> 4) * 8];
#pragma unroll
    for (int nf = 0; nf < 4; ++nf) {
      const short8 vf = *(const short8*)&vt[(nf * 16 + (l & 15)) * 136 + kf * 32 + (l >> 4) * 8];
      oa[nf] = __builtin_amdgcn_mfma_f32_16x16x32_bf16(pf, vf, oa[nf], 0, 0, 0);
    }
  }

  float rl[4];
#pragma unroll
  for (int r = 0; r < 4; ++r) rl[r] = 1.f / lsum[w * 16 + (l >> 4) * 4 + r];
#pragma unroll
  for (int nf = 0; nf < 4; ++nf)
#pragma unroll
    for (int r = 0; r < 4; ++r) {
      const int q = (l >> 4) * 4 + r;
      const int d = nf * 16 + (l & 15);
      out[(base + s0 + w * 16 + q) * 512 + h * 64 + d] = f2b(oa[nf][r] * rl[r]);
    }
}

// ========== Neural memory, linear-scan formulation ==========

// ---- P1: per (chain, chunk) compute A_c, B_c via MFMA (bf16 k,v inputs) ----
__global__ __launch_bounds__(256) void mem_prep(
    const short* __restrict__ kb, const short* __restrict__ vb,
    short* __restrict__ Aq, short* __restrict__ Bq)
{
  __shared__ __align__(16) short kn[64 * 136];
  __shared__ __align__(16) char kT[128 * 128];
  __shared__ __align__(16) char vT[128 * 128];
  const int bid = blockIdx.x;
  const int chain = bid >> 5, c = bid & 31;
  const int b = chain >> 2, mh = chain & 3;
  const size_t rowbase = (size_t)(b * SS + c * 64);
  const int tid = threadIdx.x, w = tid >> 6, l = tid & 63;
  const int td = tid & 127, rh = tid >> 7;

#pragma unroll
  for (int pass = 0; pass < 2; ++pass) {
    const short* src = pass ? vb : kb;
    char* dT = pass ? vT : kT;
#pragma unroll
    for (int j = 0; j < 4; ++j) {
      const int i4 = tid + 256 * j;
      const int r = i4 >> 4, d8 = (i4 & 15) * 8;
      *(short8*)&kn[r * 136 + d8] = *(const short8*)&src[(rowbase + r) * 1536 + mh * 128 + d8];
    }
    __syncthreads();
#pragma unroll
    for (int j = 0; j < 4; ++j) {
      const int r0 = rh * 8 + 16 * j;
      short8 g8;
#pragma unroll
      for (int t = 0; t < 8; ++t) g8[t] = kn[(r0 + t) * 136 + td];
      *(short8*)&dT[(td * 128 + r0 * 2) ^ ((td & 7) << 4)] = g8;
    }
    __syncthreads();
  }

  const int wr = w >> 1, wc = w & 1;
  {
    f32x4 acc[4][4] = {};
#pragma unroll
    for (int kf = 0; kf < 2; ++kf) {
      short8 af[4];
#pragma unroll
      for (int m = 0; m < 4; ++m) {
        const int d = wr * 64 + m * 16 + (l & 15);
        af[m] = *(const short8*)&kT[(d * 128 + kf * 64 + (l >> 4) * 16) ^ ((d & 7) << 4)];
      }
#pragma unroll
      for (int n = 0; n < 4; ++n) {
        const int dp = wc * 64 + n * 16 + (l & 15);
        const short8 bf = *(const short8*)&kT[(dp * 128 + kf * 64 + (l >> 4) * 16) ^ ((dp & 7) << 4)];
#pragma unroll
        for (int m = 0; m < 4; ++m)
          acc[m][n] = __builtin_amdgcn_mfma_f32_16x16x32_bf16(af[m], bf, acc[m][n], 0, 0, 0);
      }
    }
    char* Ad = (char*)(Aq + (size_t)bid * 16384);
#pragma unroll
    for (int m = 0; m < 4; ++m)
#pragma unroll
      for (int n = 0; n < 4; ++n) {
        const int dp = wc * 64 + n * 16 + (l & 15);
        const int d0 = wr * 64 + m * 16 + (l >> 4) * 4;
        short4v s4;
#pragma unroll
        for (int i = 0; i < 4; ++i) s4[i] = f2b(acc[m][n][i] * 0.015625f);
        *(short4v*)&Ad[(dp * 256 + d0 * 2) ^ ((dp & 7) << 4)] = s4;
      }
  }
  {
    f32x4 acc[4][4] = {};
#pragma unroll
    for (int kf = 0; kf < 2; ++kf) {
      short8 af[4];
#pragma unroll
      for (int m = 0; m < 4; ++m) {
        const int d = wr * 64 + m * 16 + (l & 15);
        af[m] = *(const short8*)&kT[(d * 128 + kf * 64 + (l >> 4) * 16) ^ ((d & 7) << 4)];
      }
#pragma unroll
      for (int n = 0; n < 4; ++n) {
        const int e = wc * 64 + n * 16 + (l & 15);
        const short8 bf = *(const short8*)&vT[(e * 128 + kf * 64 + (l >> 4) * 16) ^ ((e & 7) << 4)];
#pragma unroll
        for (int m = 0; m < 4; ++m)
          acc[m][n] = __builtin_amdgcn_mfma_f32_16x16x32_bf16(af[m], bf, acc[m][n], 0, 0, 0);
      }
    }
    short* Bd = Bq + (size_t)bid * 16384;
#pragma unroll
    for (int m = 0; m < 4; ++m)
#pragma unroll
      for (int n = 0; n < 4; ++n) {
        const int e = wc * 64 + n * 16 + (l & 15);
        const int d0 = wr * 64 + m * 16 + (l >> 4) * 4;
        short4v s4;
#pragma unroll
        for (int i = 0; i < 4; ++i) s4[i] = f2b(acc[m][n][i] * 0.015625f);
        *(short4v*)&Bd[e * 128 + d0] = s4;
      }
  }
}

// ---- P2: serial scan — raw s_barrier + counted vmcnt, depth-2 A prefetch ----
__global__ __launch_bounds__(256) void mem_scan2(
    const short* __restrict__ Aq, const short* __restrict__ Bq,
    short* __restrict__ MTg)
{
  __shared__ __align__(16) char AcL[3][32768];
  __shared__ __align__(16) char MT[2][8192];
  const int bid = blockIdx.x;
  const int chain = bid >> 2, ch = bid & 3;
  const int tid = threadIdx.x;
  const int w = tid >> 6, l = tid & 63;
  const int wr = w >> 1, wc = w & 1;
  const int e = wc * 16 + (l & 15);

  const short* Ab = Aq + (size_t)chain * 32 * 16384;
  const short* Bb = Bq + (size_t)chain * 32 * 16384;
  short* MTb = MTg + (size_t)chain * 32 * 16384 + (size_t)ch * 32 * 128;
  const int brow = (ch * 32 + e) * 128;

  {
    const short8 z = {0, 0, 0, 0, 0, 0, 0, 0};
    for (int i = tid; i < 512; i += 256) *(short8*)(MT[0] + i * 16) = z;
  }
#pragma unroll
  for (int cc = 0; cc < 2; ++cc) {
    const char* srcA = (const char*)(Ab + (size_t)cc * 16384);
#pragma unroll
    for (int j = 0; j < 8; ++j) {
      const int byte = tid * 16 + j * 4096;
      __builtin_amdgcn_global_load_lds(AS1(srcA + byte), AS3(AcL[cc] + byte), 16, 0, 0);
    }
  }
  short4v b0[4], b1[4], b2[4];
#pragma unroll
  for (int m = 0; m < 4; ++m) {
    b0[m] = *(const short4v*)&Bb[brow + wr * 64 + m * 16 + (l >> 4) * 4];
    b1[m] = *(const short4v*)&Bb[16384 + brow + wr * 64 + m * 16 + (l >> 4) * 4];
  }
  float Mreg[16] = {}, Momreg[16] = {};
  __syncthreads();

#define SCHUNK(C, AB, MR, BC, BN_, DOI, WN)                                    \
  {                                                                            \
    short* slot = MTb + (size_t)(C) * 16384;                                   \
    _Pragma("unroll") for (int m = 0; m < 4; ++m) {                            \
      const int d0 = wr * 64 + m * 16 + (l >> 4) * 4;                          \
      short4v s4;                                                              \
      _Pragma("unroll") for (int i = 0; i < 4; ++i) s4[i] = f2b(Mreg[m * 4 + i]); \
      *(short4v*)&slot[e * 128 + d0] = s4;                                     \
    }                                                                          \
    if (DOI) {                                                                 \
      const char* srcA = (const char*)(Ab + (size_t)((C) + 2) * 16384);        \
      _Pragma("unroll") for (int j = 0; j < 8; ++j) {                          \
        const int byte = tid * 16 + j * 4096;                                  \
        __builtin_amdgcn_global_load_lds(AS1(srcA + byte),                     \
            AS3(AcL[((C) + 2) % 3] + byte), 16, 0, 0);                         \
      }                                                                        \
      const short* Bn = Bb + (size_t)((C) + 2) * 16384;                        \
      _Pragma("unroll") for (int m = 0; m < 4; ++m)                            \
        BN_[m] = *(const short4v*)&Bn[brow + wr * 64 + m * 16 + (l >> 4) * 4]; \
    }                                                                          \
    {                                                                          \
      f32x4 acc[4] = {};                                                       \
      _Pragma("unroll") for (int kf = 0; kf < 4; ++kf) {                       \
        const short8 bf = *(const short8*)&MT[MR][(e * 256 + kf * 64 + (l >> 4) * 16) ^ ((e & 7) << 4)]; \
        _Pragma("unroll") for (int m = 0; m < 4; ++m) {                        \
          const int d = wr * 64 + m * 16 + (l & 15);                           \
          const short8 af = *(const short8*)&AcL[AB][(d * 256 + kf * 64 + (l >> 4) * 16) ^ ((d & 7) << 4)]; \
          acc[m] = __builtin_amdgcn_mfma_f32_16x16x32_bf16(af, bf, acc[m], 0, 0, 0); \
        }                                                                      \
      }                                                                        \
      _Pragma("unroll") for (int m = 0; m < 4; ++m) {                          \
        const int d0 = wr * 64 + m * 16 + (l >> 4) * 4;                        \
        short4v s4;                                                            \
        _Pragma("unroll") for (int i = 0; i < 4; ++i) {                        \
          const int idx = m * 4 + i;                                           \
          const float g = acc[m][i] - b2f(BC[m][i]);                           \
          Momreg[idx] = 0.9f * Momreg[idx] - 0.1f * g;                         \
          Mreg[idx] = 0.99f * Mreg[idx] + Momreg[idx];                         \
          s4[i] = f2b(Mreg[idx]);                                              \
        }                                                                      \
        *(short4v*)&MT[(MR) ^ 1][(e * 256 + d0 * 2) ^ ((e & 7) << 4)] = s4;    \
      }                                                                        \
    }                                                                          \
    asm volatile("s_waitcnt lgkmcnt(0) vmcnt(" #WN ")" ::: "memory");          \
    __builtin_amdgcn_sched_barrier(0);                                         \
    __builtin_amdgcn_s_barrier();                                              \
    __builtin_amdgcn_sched_barrier(0);                                         \
  }

  SCHUNK(0, 0, 0, b0, b2, 1, 20)  SCHUNK(1, 1, 1, b1, b0, 1, 20)
  SCHUNK(2, 2, 0, b2, b1, 1, 20)  SCHUNK(3, 0, 1, b0, b2, 1, 20)
  SCHUNK(4, 1, 0, b1, b0, 1, 20)  SCHUNK(5, 2, 1, b2, b1, 1, 20)
  SCHUNK(6, 0, 0, b0, b2, 1, 20)  SCHUNK(7, 1, 1, b1, b0, 1, 20)
  SCHUNK(8, 2, 0, b2, b1, 1, 20)  SCHUNK(9, 0, 1, b0, b2, 1, 20)
  SCHUNK(10, 1, 0, b1, b0, 1, 20) SCHUNK(11, 2, 1, b2, b1, 1, 20)
  SCHUNK(12, 0, 0, b0, b2, 1, 20) SCHUNK(13, 1, 1, b1, b0, 1, 20)
  SCHUNK(14, 2, 0, b2, b1, 1, 20) SCHUNK(15, 0, 1, b0, b2, 1, 20)
  SCHUNK(16, 1, 0, b1, b0, 1, 20) SCHUNK(17, 2, 1, b2, b1, 1, 20)
  SCHUNK(18, 0, 0, b0, b2, 1, 20) SCHUNK(19, 1, 1, b1, b0, 1, 20)
  SCHUNK(20, 2, 0, b2, b1, 1, 20) SCHUNK(21, 0, 1, b0, b2, 1, 20)
  SCHUNK(22, 1, 0, b1, b0, 1, 20) SCHUNK(23, 2, 1, b2, b1, 1, 20)
  SCHUNK(24, 0, 0, b0, b2, 1, 20) SCHUNK(25, 1, 1, b1, b0, 1, 20)
  SCHUNK(26, 2, 0, b2, b1, 1, 20) SCHUNK(27, 0, 1, b0, b2, 1, 20)
  SCHUNK(28, 1, 0, b1, b0, 1, 20) SCHUNK(29, 2, 1, b2, b1, 0, 8)
  SCHUNK(30, 0, 0, b0, b2, 0, 8)
#undef SCHUNK

  // epilogue: slot 31 = M_30
  {
    short* slot = MTb + (size_t)31 * 16384;
#pragma unroll
    for (int m = 0; m < 4; ++m) {
      const int d0 = wr * 64 + m * 16 + (l >> 4) * 4;
      short4v s4;
#pragma unroll
      for (int i = 0; i < 4; ++i) s4[i] = f2b(Mreg[m * 4 + i]);
      *(short4v*)&slot[e * 128 + d0] = s4;
    }
  }
}

// ---- P3: out_c = q_c @ M_{c-1} (bf16 q input) ----
__global__ __launch_bounds__(256) void mem_out(
    const short* __restrict__ qb, const short* __restrict__ MTg,
    short* __restrict__ mem)
{
  const int bid = blockIdx.x;
  const int chain = bid >> 5, c = bid & 31;
  const int b = chain >> 2, mh = chain & 3;
  const size_t rowbase = (size_t)(b * SS + c * 64);
  const int tid = threadIdx.x, w = tid >> 6, l = tid & 63;
  const int wr = w >> 1, wc = w & 1;
  const short* MTc = MTg + (size_t)chain * 32 * 16384 + (size_t)c * 16384;

  f32x4 acc[2][4] = {};
#pragma unroll
  for (int kf = 0; kf < 4; ++kf) {
    short8 af[2];
#pragma unroll
    for (int m = 0; m < 2; ++m) {
      const int r = wr * 32 + m * 16 + (l & 15);
      af[m] = *(const short8*)&qb[(rowbase + r) * 1536 + mh * 128 + kf * 32 + (l >> 4) * 8];
    }
#pragma unroll
    for (int n = 0; n < 4; ++n) {
      const int e = wc * 64 + n * 16 + (l & 15);
      const short8 bf = *(const short8*)&MTc[e * 128 + kf * 32 + (l >> 4) * 8];
#pragma unroll
      for (int m = 0; m < 2; ++m)
        acc[m][n] = __builtin_amdgcn_mfma_f32_16x16x32_bf16(af[m], bf, acc[m][n], 0, 0, 0);
    }
  }
#pragma unroll
  for (int m = 0; m < 2; ++m)
#pragma unroll
    for (int n = 0; n < 4; ++n)
#pragma unroll
      for (int i = 0; i < 4; ++i) {
        const int r = wr * 32 + m * 16 + (l >> 4) * 4 + i;
        const int e = wc * 64 + n * 16 + (l & 15);
        mem[(rowbase + r) * 512 + mh * 128 + e] = f2b(acc[m][n][i]);
      }
}

// ---------------- merged weight transpose+convert (all matrices, 1 launch) ---
struct TcvtJob { const float* src; short* dst; int K; int N; int blks; };
struct TcvtArgs { TcvtJob j[10]; };

__global__ __launch_bounds__(256) void tcvt_all(TcvtArgs a)
{
  int bid = blockIdx.x;
  const float* src = nullptr; short* dst = nullptr; int K = 0, N = 0;
#pragma unroll
  for (int i = 0; i < 10; ++i) {
    if (!src) {
      if (bid < a.j[i].blks) { src = a.j[i].src; dst = a.j[i].dst; K = a.j[i].K; N = a.j[i].N; }
      else bid -= a.j[i].blks;
    }
  }
  const int nt = N >> 5, kt = K >> 5;
  const int z = bid / (nt * kt);
  const int rem = bid % (nt * kt);
  const int k0 = (rem / nt) * 32, n0 = (rem % nt) * 32;
  const size_t zoff = (size_t)z * K * N;
  src += zoff; dst += zoff;

  __shared__ float t[32][33];
  const int tx = threadIdx.x & 31, ty = threadIdx.x >> 5;
#pragma unroll
  for (int i = 0; i < 4; ++i)
    t[ty + i * 8][tx] = src[(size_t)(k0 + ty + i * 8) * N + n0 + tx];
  __syncthreads();
#pragma unroll
  for (int i = 0; i < 4; ++i)
    dst[(size_t)(n0 + ty + i * 8) * K + k0 + tx] = f2b(t[tx][ty + i * 8]);
}

// ---------------- persistent path: wide parallel kernels -------------------
__global__ __launch_bounds__(256) void mean_tokens_kernel(
    const float* __restrict__ pm, float* __restrict__ mvec)
{
  const int d = blockIdx.x * 256 + threadIdx.x;
  if (d < 512) {
    float s = 0.f;
#pragma unroll
    for (int t = 0; t < 16; ++t) s += pm[t * 512 + d];
    mvec[d] = s * (1.f / 16.f);
  }
}

// out[e] = bias[e] + sum_d a[d]*W[d*512+e]; grid 32 x 256 (16 outputs/block)
__global__ __launch_bounds__(256) void matvec512_kernel(
    const float* __restrict__ a, const float* __restrict__ W,
    const float* __restrict__ bias, float* __restrict__ out)
{
  __shared__ float red[16][17];
  const int eo = threadIdx.x & 15;
  const int g = threadIdx.x >> 4;
  const int e = blockIdx.x * 16 + eo;
  float s = 0.f;
#pragma unroll 8
  for (int j = 0; j < 32; ++j) {
    const int d = g * 32 + j;
    s += a[d] * W[d * 512 + e];
  }
  red[g][eo] = s;
  __syncthreads();
  if (threadIdx.x < 16) {
    float t = bias[blockIdx.x * 16 + threadIdx.x];
#pragma unroll
    for (int gg = 0; gg < 16; ++gg) t += red[gg][threadIdx.x];
    out[blockIdx.x * 16 + threadIdx.x] = t;
  }
}

// ---------------- host side ----------------
extern "C" void kernel_launch(void* const* d_in, const int* in_sizes, int n_in,
                              void* d_out, int out_size, void* d_ws, size_t ws_size,
                              hipStream_t stream)
{
  const float* x         = (const float*)d_in[0];
  const float* n1w       = (const float*)d_in[1];
  const float* n1b       = (const float*)d_in[2];
  const float* qkvw      = (const float*)d_in[3];
  const float* qkvb      = (const float*)d_in[4];
  const float* projw     = (const float*)d_in[5];
  const float* projb     = (const float*)d_in[6];
  const float* n2w       = (const float*)d_in[7];
  const float* n2b       = (const float*)d_in[8];
  const float* fc1w      = (const float*)d_in[9];
  const float* fc1b      = (const float*)d_in[10];
  const float* fc2w      = (const float*)d_in[11];
  const float* fc2b      = (const float*)d_in[12];
  const float* mlnw      = (const float*)d_in[13];
  const float* mlnb      = (const float*)d_in[14];
  const float* mwq       = (const float*)d_in[15];
  const float* mwk       = (const float*)d_in[16];
  const float* mwv       = (const float*)d_in[17];
  const float* mprojw    = (const float*)d_in[18];
  const float* mprojb    = (const float*)d_in[19];
  const float* pm_tokens = (const float*)d_in[20];
  const float* pmw       = (const float*)d_in[21];
  const float* pmb       = (const float*)d_in[22];
  const float* fw        = (const float*)d_in[23];
  const float* fb        = (const float*)d_in[24];
  float* out = (float*)d_out;

  char* p = (char*)d_ws;
  auto alloc = [&](size_t bytes) {
    char* r = p;
    p += (bytes + 255) & ~(size_t)255;
    return r;
  };
  short* qkvwT  = (short*)alloc(6ull * 1536 * 512 * 2);
  short* projwT = (short*)alloc(6ull * 512 * 512 * 2);
  short* fc1wT  = (short*)alloc(6ull * 2048 * 512 * 2);
  short* fc2wT  = (short*)alloc(6ull * 512 * 2048 * 2);
  short* mqkvT  = (short*)alloc(3ull * 512 * 512 * 2);
  short* mprojT = (short*)alloc(512ull * 512 * 2);
  short* fwT    = (short*)alloc(512ull * 1024 * 2);
  short* bigb   = (short*)alloc((size_t)BS * 1536 * 2);
  float* hbuf   = (float*)alloc((size_t)BS * 512 * 4);
  float* t0     = (float*)alloc(3 * 512 * 4);
  float* t1 = t0 + 512; float* t2 = t1 + 512;
  short* actA   = (short*)alloc((size_t)BS * 512 * 2);
  short* ln0b   = (short*)alloc((size_t)BS * 512 * 2);
  short* attnb  = (short*)alloc((size_t)BS * 512 * 2);
  short* ff1b   = (short*)alloc((size_t)BS * 2048 * 2);
  short* stlt   = (short*)alloc((size_t)BS * 1024 * 2);
  short* Aq     = (short*)alloc(256ull * 16384 * 2);
  short* Bq     = (short*)alloc(256ull * 16384 * 2);
  short* MTg    = (short*)alloc(256ull * 16384 * 2);

  // ---- all weight transposes in one launch ----
  TcvtArgs ta;
  ta.j[0] = {qkvw,  qkvwT,  512, 1536, 48 * 16 * 6};
  ta.j[1] = {projw, projwT, 512, 512,  16 * 16 * 6};
  ta.j[2] = {fc1w,  fc1wT,  512, 2048, 64 * 16 * 6};
  ta.j[3] = {fc2w,  fc2wT,  2048, 512, 16 * 64 * 6};
  ta.j[4] = {mwq, mqkvT,                 512, 512, 256};
  ta.j[5] = {mwk, mqkvT + 512 * 512,     512, 512, 256};
  ta.j[6] = {mwv, mqkvT + 2 * 512 * 512, 512, 512, 256};
  ta.j[7] = {mprojw, mprojT, 512, 512, 256};
  ta.j[8] = {fw, fwT, 1024, 512, 512};
  ta.j[9] = {nullptr, nullptr, 32, 32, 0};
  int total_blks = 0;
  for (int i = 0; i < 10; ++i) total_blks += ta.j[i].blks;
  tcvt_all<<<total_blks, 256, 0, stream>>>(ta);

  // ---- persistent path (parallel) ----
  mean_tokens_kernel<<<2, 256, 0, stream>>>(pm_tokens, t0);
  matvec512_kernel<<<32, 256, 0, stream>>>(t0, pmw, pmb, t1);
  matvec512_kernel<<<32, 256, 0, stream>>>(t1, fw + (size_t)1024 * 512, fb, t2);

  // ---- neural memory path ----
  ln_dual_kernel<<<BS / 4, 256, 0, stream>>>(x, mlnw, mlnb, actA, n1w, n1b, ln0b);
  gemm_bf16<0, 1, 128, 128><<<dim3(12, 32), 256, 0, stream>>>(
      actA, mqkvT, nullptr, nullptr, nullptr, bigb, BS, 1536, 512, 1536);
  mem_prep<<<256, 256, 0, stream>>>(bigb + 512, bigb + 1024, Aq, Bq);
  mem_scan2<<<32, 256, 0, stream>>>(Aq, Bq, MTg);
  mem_out<<<256, 256, 0, stream>>>(bigb, MTg, ff1b);
  gemm_bf16<2, 1, 64, 64><<<dim3(8, 64), 256, 0, stream>>>(
      ff1b, mprojT, mprojb, x, nullptr, stlt + 512, BS, 512, 512, 1024);

  // ---- layer stack ----
  for (int l = 0; l < LL; ++l) {
    const short* lnin = (l == 0) ? ln0b : actA;
    if (l > 0)
      ln_kernel<<<BS / 4, 256, 0, stream>>>(hbuf, n1w + l * 512, n1b + l * 512, actA);
    gemm_bf16<0, 1, 128, 128><<<dim3(12, 32), 256, 0, stream>>>(
        lnin, qkvwT + (size_t)l * 1536 * 512, qkvb + l * 1536,
        nullptr, nullptr, bigb, BS, 1536, 512, 1536);
    swa_kernel<<<512, 256, 0, stream>>>((const unsigned short*)bigb, attnb);
    gemm_bf16<2, 0, 64, 64><<<dim3(8, 64), 256, 0, stream>>>(
        attnb, projwT + (size_t)l * 512 * 512, projb + l * 512,
        (l == 0) ? x : hbuf, nullptr, hbuf, BS, 512, 512, 512);
    ln_kernel<<<BS / 4, 256, 0, stream>>>(hbuf, n2w + l * 512, n2b + l * 512, actA);
    gemm_bf16<1, 1, 128, 128><<<dim3(16, 32), 256, 0, stream>>>(
        actA, fc1wT + (size_t)l * 2048 * 512, fc1b + l * 2048,
        nullptr, nullptr, ff1b, BS, 2048, 512, 2048);
    if (l < LL - 1)
      gemm_bf16<3, 0, 64, 64><<<dim3(8, 64), 256, 0, stream>>>(
          ff1b, fc2wT + (size_t)l * 512 * 2048, fc2b + l * 512,
          hbuf, actA, hbuf, BS, 512, 2048, 512);
    else
      gemm_bf16<3, 1, 64, 64><<<dim3(8, 64), 256, 0, stream>>>(
          ff1b, fc2wT + (size_t)l * 512 * 2048, fc2b + l * 512,
          hbuf, actA, stlt, BS, 512, 2048, 1024);   // ST -> stlt[:, 0:512]
  }

  // ---- fusion: out = [ST | LT] @ fwT + (persistent + fusion bias) ----
  gemm_bf16<0, 0, 64, 64><<<dim3(8, 64), 256, 0, stream>>>(
      stlt, fwT, t2, nullptr, nullptr, out, BS, 512, 1024, 512);
}

// Round 14
// 639.964 us; speedup vs baseline: 6.0200x; 1.0118x over previous
//
#include <hip/hip_runtime.h>
#include <math.h>

// Problem constants
#define BB 2
#define SS 2048
#define DD 512
#define HH 8
#define LL 6
#define WW 64
#define CHH 64
#define NCC 32
#define BS (BB*SS)   // 4096 rows

typedef __attribute__((ext_vector_type(8))) short short8;
typedef __attribute__((ext_vector_type(4))) short short4v;
typedef __attribute__((ext_vector_type(4))) float f32x4;

__device__ inline float b2f(short s) {
  unsigned u = ((unsigned)(unsigned short)s) << 16;
  float f; __builtin_memcpy(&f, &u, 4); return f;
}
__device__ inline short f2b(float f) {
  unsigned u; __builtin_memcpy(&u, &f, 4);
  unsigned r = (u + 0x7FFFu + ((u >> 16) & 1u)) >> 16;
  return (short)r;
}
__device__ inline float gelu_tanh(float v) {
  float u = 0.7978845608f * (v + 0.044715f * v * v * v);
  u = fminf(fmaxf(u, -20.f), 20.f);
  float e2 = __expf(2.f * u);
  return 0.5f * v * (1.f + (e2 - 1.f) / (e2 + 1.f));
}

#define AS1(p) ((const __attribute__((address_space(1))) void*)(p))
#define AS3(p) ((__attribute__((address_space(3))) void*)(p))

// ---------------- LayerNorm: wave-per-row, 4 rows/block ----------------
__global__ __launch_bounds__(256) void ln_kernel(
    const float* __restrict__ x, const float* __restrict__ w,
    const float* __restrict__ b, short* __restrict__ y)
{
  const int row = blockIdx.x * 4 + (threadIdx.x >> 6);
  const int l = threadIdx.x & 63;
  const float* xr = x + (size_t)row * DD + l * 8;
  const float4 a = *(const float4*)xr;
  const float4 c = *(const float4*)(xr + 4);
  float s = a.x + a.y + a.z + a.w + c.x + c.y + c.z + c.w;
  float sq = a.x * a.x + a.y * a.y + a.z * a.z + a.w * a.w
           + c.x * c.x + c.y * c.y + c.z * c.z + c.w * c.w;
#pragma unroll
  for (int off = 1; off < 64; off <<= 1) {
    s += __shfl_xor(s, off);
    sq += __shfl_xor(sq, off);
  }
  const float mean = s * (1.f / DD);
  const float var = sq * (1.f / DD) - mean * mean;
  const float inv = rsqrtf(var + 1e-5f);
  const float4 w0 = *(const float4*)(w + l * 8);
  const float4 w1 = *(const float4*)(w + l * 8 + 4);
  const float4 b0 = *(const float4*)(b + l * 8);
  const float4 b1 = *(const float4*)(b + l * 8 + 4);
  short8 o;
  o[0] = f2b((a.x - mean) * inv * w0.x + b0.x);
  o[1] = f2b((a.y - mean) * inv * w0.y + b0.y);
  o[2] = f2b((a.z - mean) * inv * w0.z + b0.z);
  o[3] = f2b((a.w - mean) * inv * w0.w + b0.w);
  o[4] = f2b((c.x - mean) * inv * w1.x + b1.x);
  o[5] = f2b((c.y - mean) * inv * w1.y + b1.y);
  o[6] = f2b((c.z - mean) * inv * w1.z + b1.z);
  o[7] = f2b((c.w - mean) * inv * w1.w + b1.w);
  *(short8*)(y + (size_t)row * DD + l * 8) = o;
}

// ---------------- Dual LayerNorm: one read of x, two (w,b,y) ----------------
__global__ __launch_bounds__(256) void ln_dual_kernel(
    const float* __restrict__ x,
    const float* __restrict__ w1, const float* __restrict__ b1v, short* __restrict__ y1,
    const float* __restrict__ w2, const float* __restrict__ b2v, short* __restrict__ y2)
{
  const int row = blockIdx.x * 4 + (threadIdx.x >> 6);
  const int l = threadIdx.x & 63;
  const float* xr = x + (size_t)row * DD + l * 8;
  const float4 a = *(const float4*)xr;
  const float4 c = *(const float4*)(xr + 4);
  float s = a.x + a.y + a.z + a.w + c.x + c.y + c.z + c.w;
  float sq = a.x * a.x + a.y * a.y + a.z * a.z + a.w * a.w
           + c.x * c.x + c.y * c.y + c.z * c.z + c.w * c.w;
#pragma unroll
  for (int off = 1; off < 64; off <<= 1) {
    s += __shfl_xor(s, off);
    sq += __shfl_xor(sq, off);
  }
  const float mean = s * (1.f / DD);
  const float var = sq * (1.f / DD) - mean * mean;
  const float inv = rsqrtf(var + 1e-5f);
  const float n0 = (a.x - mean) * inv, n1 = (a.y - mean) * inv,
              n2 = (a.z - mean) * inv, n3 = (a.w - mean) * inv,
              n4 = (c.x - mean) * inv, n5 = (c.y - mean) * inv,
              n6 = (c.z - mean) * inv, n7 = (c.w - mean) * inv;
#pragma unroll
  for (int pass = 0; pass < 2; ++pass) {
    const float* w = pass ? w2 : w1;
    const float* b = pass ? b2v : b1v;
    short* y = pass ? y2 : y1;
    const float4 w0 = *(const float4*)(w + l * 8);
    const float4 w1_ = *(const float4*)(w + l * 8 + 4);
    const float4 bb0 = *(const float4*)(b + l * 8);
    const float4 bb1 = *(const float4*)(b + l * 8 + 4);
    short8 o;
    o[0] = f2b(n0 * w0.x + bb0.x);
    o[1] = f2b(n1 * w0.y + bb0.y);
    o[2] = f2b(n2 * w0.z + bb0.z);
    o[3] = f2b(n3 * w0.w + bb0.w);
    o[4] = f2b(n4 * w1_.x + bb1.x);
    o[5] = f2b(n5 * w1_.y + bb1.y);
    o[6] = f2b(n6 * w1_.z + bb1.z);
    o[7] = f2b(n7 * w1_.w + bb1.w);
    *(short8*)(y + (size_t)row * DD + l * 8) = o;
  }
}

// --- bf16 MFMA GEMM, BK=64, XOR-swizzled LDS, 2-phase dbuf, BM x BN tiles ---
// EPI: 0=+bias(opt); 1=gelu(+bias); 2=+bias(opt)+add1(f32); 3=+bias+add1(f32)+add2(bf16)
// OBF: 0=f32 out (stride N); 1=bf16 out (stride NS)
// Waves 2x2; wave tile (BM/2) x (BN/2).
template<int EPI, int OBF, int BM, int BN>
__global__ __launch_bounds__(256) void gemm_bf16(
    const short* __restrict__ A, const short* __restrict__ BT,
    const float* __restrict__ bias, const float* __restrict__ add1,
    const short* __restrict__ add2, void* __restrict__ C,
    int M, int N, int K, int NS)
{
  constexpr int MF = BM / 32;       // A frags per wave
  constexpr int NF = BN / 32;       // B frags per wave
  constexpr int AR = BM / 32;       // A staging rounds
  constexpr int BR = BN / 32;       // B staging rounds
  __shared__ __align__(16) short As[2][BM * 64];
  __shared__ __align__(16) short Bs[2][BN * 64];
  const int tid = threadIdx.x;
  const int wave = tid >> 6, lane = tid & 63;
  const int wr = wave >> 1, wc = wave & 1;
  const int bm = blockIdx.y * BM, bn = blockIdx.x * BN;

  const int srow = tid >> 3;
  const int dpiece = tid & 7;
  const int spiece = dpiece ^ (srow & 7);

  const short* sA[AR]; const short* sB[BR];
  int ldsA[AR], ldsB[BR];
#pragma unroll
  for (int r = 0; r < AR; ++r) {
    const int row = r * 32 + srow;
    sA[r] = A + (size_t)(bm + row) * K + spiece * 8;
    ldsA[r] = row * 128 + dpiece * 16;
  }
#pragma unroll
  for (int r = 0; r < BR; ++r) {
    const int row = r * 32 + srow;
    sB[r] = BT + (size_t)(bn + row) * K + spiece * 8;
    ldsB[r] = row * 128 + dpiece * 16;
  }

  const int xr = (lane & 7) << 4;
  f32x4 acc[MF][NF] = {};

  // prologue: stage tile 0 into buf 0
#pragma unroll
  for (int r = 0; r < AR; ++r) {
    __builtin_amdgcn_global_load_lds(AS1(sA[r]), AS3((char*)As[0] + ldsA[r]), 16, 0, 0);
    sA[r] += 64;
  }
#pragma unroll
  for (int r = 0; r < BR; ++r) {
    __builtin_amdgcn_global_load_lds(AS1(sB[r]), AS3((char*)Bs[0] + ldsB[r]), 16, 0, 0);
    sB[r] += 64;
  }
  __syncthreads();

  int cur = 0;
  for (int k0 = 0; k0 < K; k0 += 64) {
    if (k0 + 64 < K) {
#pragma unroll
      for (int r = 0; r < AR; ++r) {
        __builtin_amdgcn_global_load_lds(AS1(sA[r]), AS3((char*)As[cur ^ 1] + ldsA[r]), 16, 0, 0);
        sA[r] += 64;
      }
#pragma unroll
      for (int r = 0; r < BR; ++r) {
        __builtin_amdgcn_global_load_lds(AS1(sB[r]), AS3((char*)Bs[cur ^ 1] + ldsB[r]), 16, 0, 0);
        sB[r] += 64;
      }
    }
    short8 af[MF][2], bf[NF][2];
#pragma unroll
    for (int m = 0; m < MF; ++m)
#pragma unroll
      for (int kk = 0; kk < 2; ++kk) {
        const int row = wr * (BM / 2) + m * 16 + (lane & 15);
        af[m][kk] = *(const short8*)((char*)As[cur] + ((row * 128 + kk * 64 + (lane >> 4) * 16) ^ xr));
      }
#pragma unroll
    for (int n = 0; n < NF; ++n)
#pragma unroll
      for (int kk = 0; kk < 2; ++kk) {
        const int row = wc * (BN / 2) + n * 16 + (lane & 15);
        bf[n][kk] = *(const short8*)((char*)Bs[cur] + ((row * 128 + kk * 64 + (lane >> 4) * 16) ^ xr));
      }
#pragma unroll
    for (int kk = 0; kk < 2; ++kk)
#pragma unroll
      for (int m = 0; m < MF; ++m)
#pragma unroll
        for (int n = 0; n < NF; ++n)
          acc[m][n] = __builtin_amdgcn_mfma_f32_16x16x32_bf16(af[m][kk], bf[n][kk], acc[m][n], 0, 0, 0);
    __syncthreads();
    cur ^= 1;
  }

#pragma unroll
  for (int m = 0; m < MF; ++m) {
#pragma unroll
    for (int n = 0; n < NF; ++n) {
      const int col = bn + wc * (BN / 2) + n * 16 + (lane & 15);
      const float bb = (EPI == 1 || EPI == 3) ? bias[col] : (bias ? bias[col] : 0.f);
#pragma unroll
      for (int r = 0; r < 4; ++r) {
        const int row = bm + wr * (BM / 2) + m * 16 + (lane >> 4) * 4 + r;
        const size_t idx = (size_t)row * N + col;
        float v = acc[m][n][r] + bb;
        if (EPI == 1) v = gelu_tanh(v);
        if (EPI == 2 || EPI == 3) v += add1[idx];
        if (EPI == 3) v += b2f(add2[idx]);
        if (OBF == 1) ((short*)C)[(size_t)row * NS + col] = f2b(v);
        else ((float*)C)[idx] = v;
      }
    }
  }
}

// ---------------- Sliding-window attention (bf16 qkv in, bf16 out) ----------
__global__ __launch_bounds__(256) void swa_kernel(
    const unsigned short* __restrict__ qkv, short* __restrict__ out)
{
  __shared__ __align__(16) short ks[128 * 72];
  __shared__ __align__(16) short vt[64 * 136];
  __shared__ __align__(16) short ps[4][16 * 136];
  __shared__ float lsum[64];

  const int tid = threadIdx.x;
  const int w = tid >> 6, l = tid & 63;
  const int tile = blockIdx.x & 31;
  const int h = (blockIdx.x >> 5) & 7;
  const int b = blockIdx.x >> 8;
  const int s0 = tile * 64;
  const size_t base = (size_t)b * SS;

#pragma unroll
  for (int u = 0; u < 16; ++u) {
    const int id = u * 256 + tid;
    const int row = id >> 5, dp = id & 31;
    int jp = s0 - 32 + row;
    jp = min(max(jp, 0), SS - 1);
    const size_t g = (base + jp) * 1536 + h * 64 + dp * 2;
    *(unsigned*)&ks[row * 72 + dp * 2] = *(const unsigned*)&qkv[g + 512];
    const unsigned vv = *(const unsigned*)&qkv[g + 1024];
    vt[(dp * 2) * 136 + row] = (short)(vv & 0xFFFF);
    vt[(dp * 2 + 1) * 136 + row] = (short)(vv >> 16);
  }

  const int qi = w * 16 + (l & 15);
  short8 qf[2];
#pragma unroll
  for (int kf = 0; kf < 2; ++kf)
    qf[kf] = *(const short8*)&qkv[(base + s0 + qi) * 1536 + h * 64 + kf * 32 + (l >> 4) * 8];
  __syncthreads();

  f32x4 sa[8] = {};
#pragma unroll
  for (int mf = 0; mf < 8; ++mf)
#pragma unroll
    for (int kf = 0; kf < 2; ++kf) {
      const short8 af = *(const short8*)&ks[(mf * 16 + (l & 15)) * 72 + kf * 32 + (l >> 4) * 8];
      sa[mf] = __builtin_amdgcn_mfma_f32_16x16x32_bf16(af, qf[kf], sa[mf], 0, 0, 0);
    }

  float sv[8][4];
  float mx = -INFINITY;
#pragma unroll
  for (int mf = 0; mf < 8; ++mf)
#pragma unroll
    for (int r = 0; r < 4; ++r) {
      const int j = mf * 16 + (l >> 4) * 4 + r;
      const int jpos = s0 - 32 + j;
      const bool ok = (j >= qi) && (j <= qi + 64) && (jpos >= 0) && (jpos < SS);
      const float s = ok ? sa[mf][r] * 0.125f : -INFINITY;
      sv[mf][r] = s;
      mx = fmaxf(mx, s);
    }
  mx = fmaxf(mx, __shfl_xor(mx, 16));
  mx = fmaxf(mx, __shfl_xor(mx, 32));
  float ls = 0.f;
#pragma unroll
  for (int mf = 0; mf < 8; ++mf)
#pragma unroll
    for (int r = 0; r < 4; ++r) {
      const float p = __expf(sv[mf][r] - mx);
      sv[mf][r] = p;
      ls += p;
    }
  ls += __shfl_xor(ls, 16);
  ls += __shfl_xor(ls, 32);
  if (l < 16) lsum[w * 16 + l] = ls;

#pragma unroll
  for (int mf = 0; mf < 8; ++mf) {
    short4v p4;
    p4.x = f2b(sv[mf][0]); p4.y = f2b(sv[mf][1]);
    p4.z = f2b(sv[mf][2]); p4.w = f2b(sv[mf][3]);
    *(short4v*)&ps[w][(l & 15) * 136 + mf * 16 + (l >> 4) * 4] = p4;
  }

  f32x4 oa[4] = {};
#pragma unroll
  for (int kf = 0; kf < 4; ++kf) {
    const short8 pf = *(const short8*)&ps[w][(l & 15) * 136 + kf * 32 + (l >> 4) * 8];
#pragma unroll
    for (int nf = 0; nf < 4; ++nf) {
      const short8 vf = *(const short8*)&vt[(nf * 16 + (l & 15)) * 136 + kf * 32 + (l >> 4) * 8];
      oa[nf] = __builtin_amdgcn_mfma_f32_16x16x32_bf16(pf, vf, oa[nf], 0, 0, 0);
    }
  }

  float rl[4];
#pragma unroll
  for (int r = 0; r < 4; ++r) rl[r] = 1.f / lsum[w * 16 + (l >> 4) * 4 + r];
#pragma unroll
  for (int nf = 0; nf < 4; ++nf)
#pragma unroll
    for (int r = 0; r < 4; ++r) {
      const int q = (l >> 4) * 4 + r;
      const int d = nf * 16 + (l & 15);
      out[(base + s0 + w * 16 + q) * 512 + h * 64 + d] = f2b(oa[nf][r] * rl[r]);
    }
}

// ========== Neural memory, linear-scan formulation ==========

// ---- P1: per (chain, chunk) compute A_c, B_c via MFMA (bf16 k,v inputs) ----
__global__ __launch_bounds__(256) void mem_prep(
    const short* __restrict__ kb, const short* __restrict__ vb,
    short* __restrict__ Aq, short* __restrict__ Bq)
{
  __shared__ __align__(16) short kn[64 * 136];
  __shared__ __align__(16) char kT[128 * 128];
  __shared__ __align__(16) char vT[128 * 128];
  const int bid = blockIdx.x;
  const int chain = bid >> 5, c = bid & 31;
  const int b = chain >> 2, mh = chain & 3;
  const size_t rowbase = (size_t)(b * SS + c * 64);
  const int tid = threadIdx.x, w = tid >> 6, l = tid & 63;
  const int td = tid & 127, rh = tid >> 7;

#pragma unroll
  for (int pass = 0; pass < 2; ++pass) {
    const short* src = pass ? vb : kb;
    char* dT = pass ? vT : kT;
#pragma unroll
    for (int j = 0; j < 4; ++j) {
      const int i4 = tid + 256 * j;
      const int r = i4 >> 4, d8 = (i4 & 15) * 8;
      *(short8*)&kn[r * 136 + d8] = *(const short8*)&src[(rowbase + r) * 1536 + mh * 128 + d8];
    }
    __syncthreads();
#pragma unroll
    for (int j = 0; j < 4; ++j) {
      const int r0 = rh * 8 + 16 * j;
      short8 g8;
#pragma unroll
      for (int t = 0; t < 8; ++t) g8[t] = kn[(r0 + t) * 136 + td];
      *(short8*)&dT[(td * 128 + r0 * 2) ^ ((td & 7) << 4)] = g8;
    }
    __syncthreads();
  }

  const int wr = w >> 1, wc = w & 1;
  {
    f32x4 acc[4][4] = {};
#pragma unroll
    for (int kf = 0; kf < 2; ++kf) {
      short8 af[4];
#pragma unroll
      for (int m = 0; m < 4; ++m) {
        const int d = wr * 64 + m * 16 + (l & 15);
        af[m] = *(const short8*)&kT[(d * 128 + kf * 64 + (l >> 4) * 16) ^ ((d & 7) << 4)];
      }
#pragma unroll
      for (int n = 0; n < 4; ++n) {
        const int dp = wc * 64 + n * 16 + (l & 15);
        const short8 bf = *(const short8*)&kT[(dp * 128 + kf * 64 + (l >> 4) * 16) ^ ((dp & 7) << 4)];
#pragma unroll
        for (int m = 0; m < 4; ++m)
          acc[m][n] = __builtin_amdgcn_mfma_f32_16x16x32_bf16(af[m], bf, acc[m][n], 0, 0, 0);
      }
    }
    char* Ad = (char*)(Aq + (size_t)bid * 16384);
#pragma unroll
    for (int m = 0; m < 4; ++m)
#pragma unroll
      for (int n = 0; n < 4; ++n) {
        const int dp = wc * 64 + n * 16 + (l & 15);
        const int d0 = wr * 64 + m * 16 + (l >> 4) * 4;
        short4v s4;
#pragma unroll
        for (int i = 0; i < 4; ++i) s4[i] = f2b(acc[m][n][i] * 0.015625f);
        *(short4v*)&Ad[(dp * 256 + d0 * 2) ^ ((dp & 7) << 4)] = s4;
      }
  }
  {
    f32x4 acc[4][4] = {};
#pragma unroll
    for (int kf = 0; kf < 2; ++kf) {
      short8 af[4];
#pragma unroll
      for (int m = 0; m < 4; ++m) {
        const int d = wr * 64 + m * 16 + (l & 15);
        af[m] = *(const short8*)&kT[(d * 128 + kf * 64 + (l >> 4) * 16) ^ ((d & 7) << 4)];
      }
#pragma unroll
      for (int n = 0; n < 4; ++n) {
        const int e = wc * 64 + n * 16 + (l & 15);
        const short8 bf = *(const short8*)&vT[(e * 128 + kf * 64 + (l >> 4) * 16) ^ ((e & 7) << 4)];
#pragma unroll
        for (int m = 0; m < 4; ++m)
          acc[m][n] = __builtin_amdgcn_mfma_f32_16x16x32_bf16(af[m], bf, acc[m][n], 0, 0, 0);
      }
    }
    short* Bd = Bq + (size_t)bid * 16384;
#pragma unroll
    for (int m = 0; m < 4; ++m)
#pragma unroll
      for (int n = 0; n < 4; ++n) {
        const int e = wc * 64 + n * 16 + (l & 15);
        const int d0 = wr * 64 + m * 16 + (l >> 4) * 4;
        short4v s4;
#pragma unroll
        for (int i = 0; i < 4; ++i) s4[i] = f2b(acc[m][n][i] * 0.015625f);
        *(short4v*)&Bd[e * 128 + d0] = s4;
      }
  }
}

// ---- P2: serial scan — raw s_barrier + counted vmcnt, depth-2 A prefetch ----
__global__ __launch_bounds__(256) void mem_scan2(
    const short* __restrict__ Aq, const short* __restrict__ Bq,
    short* __restrict__ MTg)
{
  __shared__ __align__(16) char AcL[3][32768];
  __shared__ __align__(16) char MT[2][8192];
  const int bid = blockIdx.x;
  const int chain = bid >> 2, ch = bid & 3;
  const int tid = threadIdx.x;
  const int w = tid >> 6, l = tid & 63;
  const int wr = w >> 1, wc = w & 1;
  const int e = wc * 16 + (l & 15);

  const short* Ab = Aq + (size_t)chain * 32 * 16384;
  const short* Bb = Bq + (size_t)chain * 32 * 16384;
  short* MTb = MTg + (size_t)chain * 32 * 16384 + (size_t)ch * 32 * 128;
  const int brow = (ch * 32 + e) * 128;

  {
    const short8 z = {0, 0, 0, 0, 0, 0, 0, 0};
    for (int i = tid; i < 512; i += 256) *(short8*)(MT[0] + i * 16) = z;
  }
#pragma unroll
  for (int cc = 0; cc < 2; ++cc) {
    const char* srcA = (const char*)(Ab + (size_t)cc * 16384);
#pragma unroll
    for (int j = 0; j < 8; ++j) {
      const int byte = tid * 16 + j * 4096;
      __builtin_amdgcn_global_load_lds(AS1(srcA + byte), AS3(AcL[cc] + byte), 16, 0, 0);
    }
  }
  short4v b0[4], b1[4], b2[4];
#pragma unroll
  for (int m = 0; m < 4; ++m) {
    b0[m] = *(const short4v*)&Bb[brow + wr * 64 + m * 16 + (l >> 4) * 4];
    b1[m] = *(const short4v*)&Bb[16384 + brow + wr * 64 + m * 16 + (l >> 4) * 4];
  }
  float Mreg[16] = {}, Momreg[16] = {};
  __syncthreads();

#define SCHUNK(C, AB, MR, BC, BN_, DOI, WN)                                    \
  {                                                                            \
    short* slot = MTb + (size_t)(C) * 16384;                                   \
    _Pragma("unroll") for (int m = 0; m < 4; ++m) {                            \
      const int d0 = wr * 64 + m * 16 + (l >> 4) * 4;                          \
      short4v s4;                                                              \
      _Pragma("unroll") for (int i = 0; i < 4; ++i) s4[i] = f2b(Mreg[m * 4 + i]); \
      *(short4v*)&slot[e * 128 + d0] = s4;                                     \
    }                                                                          \
    if (DOI) {                                                                 \
      const char* srcA = (const char*)(Ab + (size_t)((C) + 2) * 16384);        \
      _Pragma("unroll") for (int j = 0; j < 8; ++j) {                          \
        const int byte = tid * 16 + j * 4096;                                  \
        __builtin_amdgcn_global_load_lds(AS1(srcA + byte),                     \
            AS3(AcL[((C) + 2) % 3] + byte), 16, 0, 0);                         \
      }                                                                        \
      const short* Bn = Bb + (size_t)((C) + 2) * 16384;                        \
      _Pragma("unroll") for (int m = 0; m < 4; ++m)                            \
        BN_[m] = *(const short4v*)&Bn[brow + wr * 64 + m * 16 + (l >> 4) * 4]; \
    }                                                                          \
    {                                                                          \
      f32x4 acc[4] = {};                                                       \
      _Pragma("unroll") for (int kf = 0; kf < 4; ++kf) {                       \
        const short8 bf = *(const short8*)&MT[MR][(e * 256 + kf * 64 + (l >> 4) * 16) ^ ((e & 7) << 4)]; \
        _Pragma("unroll") for (int m = 0; m < 4; ++m) {                        \
          const int d = wr * 64 + m * 16 + (l & 15);                           \
          const short8 af = *(const short8*)&AcL[AB][(d * 256 + kf * 64 + (l >> 4) * 16) ^ ((d & 7) << 4)]; \
          acc[m] = __builtin_amdgcn_mfma_f32_16x16x32_bf16(af, bf, acc[m], 0, 0, 0); \
        }                                                                      \
      }                                                                        \
      _Pragma("unroll") for (int m = 0; m < 4; ++m) {                          \
        const int d0 = wr * 64 + m * 16 + (l >> 4) * 4;                        \
        short4v s4;                                                            \
        _Pragma("unroll") for (int i = 0; i < 4; ++i) {                        \
          const int idx = m * 4 + i;                                           \
          const float g = acc[m][i] - b2f(BC[m][i]);                           \
          Momreg[idx] = 0.9f * Momreg[idx] - 0.1f * g;                         \
          Mreg[idx] = 0.99f * Mreg[idx] + Momreg[idx];                         \
          s4[i] = f2b(Mreg[idx]);                                              \
        }                                                                      \
        *(short4v*)&MT[(MR) ^ 1][(e * 256 + d0 * 2) ^ ((e & 7) << 4)] = s4;    \
      }                                                                        \
    }                                                                          \
    asm volatile("s_waitcnt lgkmcnt(0) vmcnt(" #WN ")" ::: "memory");          \
    __builtin_amdgcn_sched_barrier(0);                                         \
    __builtin_amdgcn_s_barrier();                                              \
    __builtin_amdgcn_sched_barrier(0);                                         \
  }

  SCHUNK(0, 0, 0, b0, b2, 1, 20)  SCHUNK(1, 1, 1, b1, b0, 1, 20)
  SCHUNK(2, 2, 0, b2, b1, 1, 20)  SCHUNK(3, 0, 1, b0, b2, 1, 20)
  SCHUNK(4, 1, 0, b1, b0, 1, 20)  SCHUNK(5, 2, 1, b2, b1, 1, 20)
  SCHUNK(6, 0, 0, b0, b2, 1, 20)  SCHUNK(7, 1, 1, b1, b0, 1, 20)
  SCHUNK(8, 2, 0, b2, b1, 1, 20)  SCHUNK(9, 0, 1, b0, b2, 1, 20)
  SCHUNK(10, 1, 0, b1, b0, 1, 20) SCHUNK(11, 2, 1, b2, b1, 1, 20)
  SCHUNK(12, 0, 0, b0, b2, 1, 20) SCHUNK(13, 1, 1, b1, b0, 1, 20)
  SCHUNK(14, 2, 0, b2, b1, 1, 20) SCHUNK(15, 0, 1, b0, b2, 1, 20)
  SCHUNK(16, 1, 0, b1, b0, 1, 20) SCHUNK(17, 2, 1, b2, b1, 1, 20)
  SCHUNK(18, 0, 0, b0, b2, 1, 20) SCHUNK(19, 1, 1, b1, b0, 1, 20)
  SCHUNK(20, 2, 0, b2, b1, 1, 20) SCHUNK(21, 0, 1, b0, b2, 1, 20)
  SCHUNK(22, 1, 0, b1, b0, 1, 20) SCHUNK(23, 2, 1, b2, b1, 1, 20)
  SCHUNK(24, 0, 0, b0, b2, 1, 20) SCHUNK(25, 1, 1, b1, b0, 1, 20)
  SCHUNK(26, 2, 0, b2, b1, 1, 20) SCHUNK(27, 0, 1, b0, b2, 1, 20)
  SCHUNK(28, 1, 0, b1, b0, 1, 20) SCHUNK(29, 2, 1, b2, b1, 0, 8)
  SCHUNK(30, 0, 0, b0, b2, 0, 8)
#undef SCHUNK

  // epilogue: slot 31 = M_30
  {
    short* slot = MTb + (size_t)31 * 16384;
#pragma unroll
    for (int m = 0; m < 4; ++m) {
      const int d0 = wr * 64 + m * 16 + (l >> 4) * 4;
      short4v s4;
#pragma unroll
      for (int i = 0; i < 4; ++i) s4[i] = f2b(Mreg[m * 4 + i]);
      *(short4v*)&slot[e * 128 + d0] = s4;
    }
  }
}

// ---- P3: out_c = q_c @ M_{c-1} (bf16 q input) ----
__global__ __launch_bounds__(256) void mem_out(
    const short* __restrict__ qb, const short* __restrict__ MTg,
    short* __restrict__ mem)
{
  const int bid = blockIdx.x;
  const int chain = bid >> 5, c = bid & 31;
  const int b = chain >> 2, mh = chain & 3;
  const size_t rowbase = (size_t)(b * SS + c * 64);
  const int tid = threadIdx.x, w = tid >> 6, l = tid & 63;
  const int wr = w >> 1, wc = w & 1;
  const short* MTc = MTg + (size_t)chain * 32 * 16384 + (size_t)c * 16384;

  f32x4 acc[2][4] = {};
#pragma unroll
  for (int kf = 0; kf < 4; ++kf) {
    short8 af[2];
#pragma unroll
    for (int m = 0; m < 2; ++m) {
      const int r = wr * 32 + m * 16 + (l & 15);
      af[m] = *(const short8*)&qb[(rowbase + r) * 1536 + mh * 128 + kf * 32 + (l >> 4) * 8];
    }
#pragma unroll
    for (int n = 0; n < 4; ++n) {
      const int e = wc * 64 + n * 16 + (l & 15);
      const short8 bf = *(const short8*)&MTc[e * 128 + kf * 32 + (l >> 4) * 8];
#pragma unroll
      for (int m = 0; m < 2; ++m)
        acc[m][n] = __builtin_amdgcn_mfma_f32_16x16x32_bf16(af[m], bf, acc[m][n], 0, 0, 0);
    }
  }
#pragma unroll
  for (int m = 0; m < 2; ++m)
#pragma unroll
    for (int n = 0; n < 4; ++n)
#pragma unroll
      for (int i = 0; i < 4; ++i) {
        const int r = wr * 32 + m * 16 + (l >> 4) * 4 + i;
        const int e = wc * 64 + n * 16 + (l & 15);
        mem[(rowbase + r) * 512 + mh * 128 + e] = f2b(acc[m][n][i]);
      }
}

// ---------------- merged weight transpose+convert (all matrices, 1 launch) ---
struct TcvtJob { const float* src; short* dst; int K; int N; int blks; };
struct TcvtArgs { TcvtJob j[10]; };

__global__ __launch_bounds__(256) void tcvt_all(TcvtArgs a)
{
  int bid = blockIdx.x;
  const float* src = nullptr; short* dst = nullptr; int K = 0, N = 0;
#pragma unroll
  for (int i = 0; i < 10; ++i) {
    if (!src) {
      if (bid < a.j[i].blks) { src = a.j[i].src; dst = a.j[i].dst; K = a.j[i].K; N = a.j[i].N; }
      else bid -= a.j[i].blks;
    }
  }
  const int nt = N >> 5, kt = K >> 5;
  const int z = bid / (nt * kt);
  const int rem = bid % (nt * kt);
  const int k0 = (rem / nt) * 32, n0 = (rem % nt) * 32;
  const size_t zoff = (size_t)z * K * N;
  src += zoff; dst += zoff;

  __shared__ float t[32][33];
  const int tx = threadIdx.x & 31, ty = threadIdx.x >> 5;
#pragma unroll
  for (int i = 0; i < 4; ++i)
    t[ty + i * 8][tx] = src[(size_t)(k0 + ty + i * 8) * N + n0 + tx];
  __syncthreads();
#pragma unroll
  for (int i = 0; i < 4; ++i)
    dst[(size_t)(n0 + ty + i * 8) * K + k0 + tx] = f2b(t[tx][ty + i * 8]);
}

// ---------------- persistent path: wide parallel kernels -------------------
__global__ __launch_bounds__(256) void mean_tokens_kernel(
    const float* __restrict__ pm, float* __restrict__ mvec)
{
  const int d = blockIdx.x * 256 + threadIdx.x;
  if (d < 512) {
    float s = 0.f;
#pragma unroll
    for (int t = 0; t < 16; ++t) s += pm[t * 512 + d];
    mvec[d] = s * (1.f / 16.f);
  }
}

// out[e] = bias[e] + sum_d a[d]*W[d*512+e]; grid 32 x 256 (16 outputs/block)
__global__ __launch_bounds__(256) void matvec512_kernel(
    const float* __restrict__ a, const float* __restrict__ W,
    const float* __restrict__ bias, float* __restrict__ out)
{
  __shared__ float red[16][17];
  const int eo = threadIdx.x & 15;
  const int g = threadIdx.x >> 4;
  const int e = blockIdx.x * 16 + eo;
  float s = 0.f;
#pragma unroll 8
  for (int j = 0; j < 32; ++j) {
    const int d = g * 32 + j;
    s += a[d] * W[d * 512 + e];
  }
  red[g][eo] = s;
  __syncthreads();
  if (threadIdx.x < 16) {
    float t = bias[blockIdx.x * 16 + threadIdx.x];
#pragma unroll
    for (int gg = 0; gg < 16; ++gg) t += red[gg][threadIdx.x];
    out[blockIdx.x * 16 + threadIdx.x] = t;
  }
}

// ---------------- host side ----------------
extern "C" void kernel_launch(void* const* d_in, const int* in_sizes, int n_in,
                              void* d_out, int out_size, void* d_ws, size_t ws_size,
                              hipStream_t stream)
{
  const float* x         = (const float*)d_in[0];
  const float* n1w       = (const float*)d_in[1];
  const float* n1b       = (const float*)d_in[2];
  const float* qkvw      = (const float*)d_in[3];
  const float* qkvb      = (const float*)d_in[4];
  const float* projw     = (const float*)d_in[5];
  const float* projb     = (const float*)d_in[6];
  const float* n2w       = (const float*)d_in[7];
  const float* n2b       = (const float*)d_in[8];
  const float* fc1w      = (const float*)d_in[9];
  const float* fc1b      = (const float*)d_in[10];
  const float* fc2w      = (const float*)d_in[11];
  const float* fc2b      = (const float*)d_in[12];
  const float* mlnw      = (const float*)d_in[13];
  const float* mlnb      = (const float*)d_in[14];
  const float* mwq       = (const float*)d_in[15];
  const float* mwk       = (const float*)d_in[16];
  const float* mwv       = (const float*)d_in[17];
  const float* mprojw    = (const float*)d_in[18];
  const float* mprojb    = (const float*)d_in[19];
  const float* pm_tokens = (const float*)d_in[20];
  const float* pmw       = (const float*)d_in[21];
  const float* pmb       = (const float*)d_in[22];
  const float* fw        = (const float*)d_in[23];
  const float* fb        = (const float*)d_in[24];
  float* out = (float*)d_out;

  char* p = (char*)d_ws;
  auto alloc = [&](size_t bytes) {
    char* r = p;
    p += (bytes + 255) & ~(size_t)255;
    return r;
  };
  short* qkvwT  = (short*)alloc(6ull * 1536 * 512 * 2);
  short* projwT = (short*)alloc(6ull * 512 * 512 * 2);
  short* fc1wT  = (short*)alloc(6ull * 2048 * 512 * 2);
  short* fc2wT  = (short*)alloc(6ull * 512 * 2048 * 2);
  short* mqkvT  = (short*)alloc(3ull * 512 * 512 * 2);
  short* mprojT = (short*)alloc(512ull * 512 * 2);
  short* fwT    = (short*)alloc(512ull * 1024 * 2);
  short* bigb   = (short*)alloc((size_t)BS * 1536 * 2);
  float* hbuf   = (float*)alloc((size_t)BS * 512 * 4);
  float* t0     = (float*)alloc(3 * 512 * 4);
  float* t1 = t0 + 512; float* t2 = t1 + 512;
  short* actA   = (short*)alloc((size_t)BS * 512 * 2);
  short* ln0b   = (short*)alloc((size_t)BS * 512 * 2);
  short* attnb  = (short*)alloc((size_t)BS * 512 * 2);
  short* ff1b   = (short*)alloc((size_t)BS * 2048 * 2);
  short* stlt   = (short*)alloc((size_t)BS * 1024 * 2);
  short* Aq     = (short*)alloc(256ull * 16384 * 2);
  short* Bq     = (short*)alloc(256ull * 16384 * 2);
  short* MTg    = (short*)alloc(256ull * 16384 * 2);

  // ---- all weight transposes in one launch ----
  TcvtArgs ta;
  ta.j[0] = {qkvw,  qkvwT,  512, 1536, 48 * 16 * 6};
  ta.j[1] = {projw, projwT, 512, 512,  16 * 16 * 6};
  ta.j[2] = {fc1w,  fc1wT,  512, 2048, 64 * 16 * 6};
  ta.j[3] = {fc2w,  fc2wT,  2048, 512, 16 * 64 * 6};
  ta.j[4] = {mwq, mqkvT,                 512, 512, 256};
  ta.j[5] = {mwk, mqkvT + 512 * 512,     512, 512, 256};
  ta.j[6] = {mwv, mqkvT + 2 * 512 * 512, 512, 512, 256};
  ta.j[7] = {mprojw, mprojT, 512, 512, 256};
  ta.j[8] = {fw, fwT, 1024, 512, 512};
  ta.j[9] = {nullptr, nullptr, 32, 32, 0};
  int total_blks = 0;
  for (int i = 0; i < 10; ++i) total_blks += ta.j[i].blks;
  tcvt_all<<<total_blks, 256, 0, stream>>>(ta);

  // ---- persistent path (parallel) ----
  mean_tokens_kernel<<<2, 256, 0, stream>>>(pm_tokens, t0);
  matvec512_kernel<<<32, 256, 0, stream>>>(t0, pmw, pmb, t1);
  matvec512_kernel<<<32, 256, 0, stream>>>(t1, fw + (size_t)1024 * 512, fb, t2);

  // ---- neural memory path ----
  ln_dual_kernel<<<BS / 4, 256, 0, stream>>>(x, mlnw, mlnb, actA, n1w, n1b, ln0b);
  gemm_bf16<0, 1, 64, 128><<<dim3(12, 64), 256, 0, stream>>>(
      actA, mqkvT, nullptr, nullptr, nullptr, bigb, BS, 1536, 512, 1536);
  mem_prep<<<256, 256, 0, stream>>>(bigb + 512, bigb + 1024, Aq, Bq);
  mem_scan2<<<32, 256, 0, stream>>>(Aq, Bq, MTg);
  mem_out<<<256, 256, 0, stream>>>(bigb, MTg, ff1b);
  gemm_bf16<2, 1, 64, 64><<<dim3(8, 64), 256, 0, stream>>>(
      ff1b, mprojT, mprojb, x, nullptr, stlt + 512, BS, 512, 512, 1024);

  // ---- layer stack ----
  for (int l = 0; l < LL; ++l) {
    const short* lnin = (l == 0) ? ln0b : actA;
    if (l > 0)
      ln_kernel<<<BS / 4, 256, 0, stream>>>(hbuf, n1w + l * 512, n1b + l * 512, actA);
    gemm_bf16<0, 1, 64, 128><<<dim3(12, 64), 256, 0, stream>>>(
        lnin, qkvwT + (size_t)l * 1536 * 512, qkvb + l * 1536,
        nullptr, nullptr, bigb, BS, 1536, 512, 1536);
    swa_kernel<<<512, 256, 0, stream>>>((const unsigned short*)bigb, attnb);
    gemm_bf16<2, 0, 64, 64><<<dim3(8, 64), 256, 0, stream>>>(
        attnb, projwT + (size_t)l * 512 * 512, projb + l * 512,
        (l == 0) ? x : hbuf, nullptr, hbuf, BS, 512, 512, 512);
    ln_kernel<<<BS / 4, 256, 0, stream>>>(hbuf, n2w + l * 512, n2b + l * 512, actA);
    gemm_bf16<1, 1, 64, 128><<<dim3(16, 64), 256, 0, stream>>>(
        actA, fc1wT + (size_t)l * 2048 * 512, fc1b + l * 2048,
        nullptr, nullptr, ff1b, BS, 2048, 512, 2048);
    if (l < LL - 1)
      gemm_bf16<3, 0, 64, 64><<<dim3(8, 64), 256, 0, stream>>>(
          ff1b, fc2wT + (size_t)l * 512 * 2048, fc2b + l * 512,
          hbuf, actA, hbuf, BS, 512, 2048, 512);
    else
      gemm_bf16<3, 1, 64, 64><<<dim3(8, 64), 256, 0, stream>>>(
          ff1b, fc2wT + (size_t)l * 512 * 2048, fc2b + l * 512,
          hbuf, actA, stlt, BS, 512, 2048, 1024);   // ST -> stlt[:, 0:512]
  }

  // ---- fusion: out = [ST | LT] @ fwT + (persistent + fusion bias) ----
  gemm_bf16<0, 0, 64, 64><<<dim3(8, 64), 256, 0, stream>>>(
      stlt, fwT, t2, nullptr, nullptr, out, BS, 512, 1024, 512);
}

// Round 15
// 632.460 us; speedup vs baseline: 6.0914x; 1.0119x over previous
//
#include <hip/hip_runtime.h>
#include <math.h>

// Problem constants
#define BB 2
#define SS 2048
#define DD 512
#define HH 8
#define LL 6
#define WW 64
#define CHH 64
#define NCC 32
#define BS (BB*SS)   // 4096 rows

typedef __attribute__((ext_vector_type(8))) short short8;
typedef __attribute__((ext_vector_type(4))) short short4v;
typedef __attribute__((ext_vector_type(4))) float f32x4;

__device__ inline float b2f(short s) {
  unsigned u = ((unsigned)(unsigned short)s) << 16;
  float f; __builtin_memcpy(&f, &u, 4); return f;
}
__device__ inline short f2b(float f) {
  unsigned u; __builtin_memcpy(&u, &f, 4);
  unsigned r = (u + 0x7FFFu + ((u >> 16) & 1u)) >> 16;
  return (short)r;
}
__device__ inline float gelu_tanh(float v) {
  float u = 0.7978845608f * (v + 0.044715f * v * v * v);
  u = fminf(fmaxf(u, -20.f), 20.f);
  float e2 = __expf(2.f * u);
  return 0.5f * v * (1.f + (e2 - 1.f) / (e2 + 1.f));
}

#define AS1(p) ((const __attribute__((address_space(1))) void*)(p))
#define AS3(p) ((__attribute__((address_space(3))) void*)(p))

// ---------------- LayerNorm (bf16 in): wave-per-row, 4 rows/block -----------
__global__ __launch_bounds__(256) void ln_kernel(
    const short* __restrict__ x, const float* __restrict__ w,
    const float* __restrict__ b, short* __restrict__ y)
{
  const int row = blockIdx.x * 4 + (threadIdx.x >> 6);
  const int l = threadIdx.x & 63;
  const short8 v = *(const short8*)(x + (size_t)row * DD + l * 8);
  float e[8];
#pragma unroll
  for (int i = 0; i < 8; ++i) e[i] = b2f(v[i]);
  float s = 0.f, sq = 0.f;
#pragma unroll
  for (int i = 0; i < 8; ++i) { s += e[i]; sq += e[i] * e[i]; }
#pragma unroll
  for (int off = 1; off < 64; off <<= 1) {
    s += __shfl_xor(s, off);
    sq += __shfl_xor(sq, off);
  }
  const float mean = s * (1.f / DD);
  const float var = sq * (1.f / DD) - mean * mean;
  const float inv = rsqrtf(var + 1e-5f);
  const float4 w0 = *(const float4*)(w + l * 8);
  const float4 w1 = *(const float4*)(w + l * 8 + 4);
  const float4 b0 = *(const float4*)(b + l * 8);
  const float4 b1 = *(const float4*)(b + l * 8 + 4);
  const float wv[8] = {w0.x, w0.y, w0.z, w0.w, w1.x, w1.y, w1.z, w1.w};
  const float bv[8] = {b0.x, b0.y, b0.z, b0.w, b1.x, b1.y, b1.z, b1.w};
  short8 o;
#pragma unroll
  for (int i = 0; i < 8; ++i) o[i] = f2b((e[i] - mean) * inv * wv[i] + bv[i]);
  *(short8*)(y + (size_t)row * DD + l * 8) = o;
}

// ---- Dual LayerNorm (f32 in): two (w,b,y) + bf16 copy of x ----
__global__ __launch_bounds__(256) void ln_dual_kernel(
    const float* __restrict__ x,
    const float* __restrict__ w1, const float* __restrict__ b1v, short* __restrict__ y1,
    const float* __restrict__ w2, const float* __restrict__ b2v, short* __restrict__ y2,
    short* __restrict__ xb)
{
  const int row = blockIdx.x * 4 + (threadIdx.x >> 6);
  const int l = threadIdx.x & 63;
  const float* xr = x + (size_t)row * DD + l * 8;
  const float4 a = *(const float4*)xr;
  const float4 c = *(const float4*)(xr + 4);
  const float e[8] = {a.x, a.y, a.z, a.w, c.x, c.y, c.z, c.w};
  float s = 0.f, sq = 0.f;
#pragma unroll
  for (int i = 0; i < 8; ++i) { s += e[i]; sq += e[i] * e[i]; }
#pragma unroll
  for (int off = 1; off < 64; off <<= 1) {
    s += __shfl_xor(s, off);
    sq += __shfl_xor(sq, off);
  }
  const float mean = s * (1.f / DD);
  const float var = sq * (1.f / DD) - mean * mean;
  const float inv = rsqrtf(var + 1e-5f);
  // bf16 copy of x
  short8 xo;
#pragma unroll
  for (int i = 0; i < 8; ++i) xo[i] = f2b(e[i]);
  *(short8*)(xb + (size_t)row * DD + l * 8) = xo;
#pragma unroll
  for (int pass = 0; pass < 2; ++pass) {
    const float* w = pass ? w2 : w1;
    const float* b = pass ? b2v : b1v;
    short* y = pass ? y2 : y1;
    const float4 w0 = *(const float4*)(w + l * 8);
    const float4 w1_ = *(const float4*)(w + l * 8 + 4);
    const float4 bb0 = *(const float4*)(b + l * 8);
    const float4 bb1 = *(const float4*)(b + l * 8 + 4);
    const float wv[8] = {w0.x, w0.y, w0.z, w0.w, w1_.x, w1_.y, w1_.z, w1_.w};
    const float bv[8] = {bb0.x, bb0.y, bb0.z, bb0.w, bb1.x, bb1.y, bb1.z, bb1.w};
    short8 o;
#pragma unroll
    for (int i = 0; i < 8; ++i) o[i] = f2b((e[i] - mean) * inv * wv[i] + bv[i]);
    *(short8*)(y + (size_t)row * DD + l * 8) = o;
  }
}

// --- bf16 MFMA GEMM, BK=64, XOR-swizzled LDS, 2-phase dbuf, BM x BN tiles ---
// EPI: 0=+bias(opt); 1=gelu(+bias); 2=+bias(opt)+add1(bf16); 3=+bias+add1(bf16)+add2(bf16)
// OBF: 0=f32 out (stride N); 1=bf16 out (stride NS)
template<int EPI, int OBF, int BM, int BN>
__global__ __launch_bounds__(256) void gemm_bf16(
    const short* __restrict__ A, const short* __restrict__ BT,
    const float* __restrict__ bias, const short* __restrict__ add1,
    const short* __restrict__ add2, void* __restrict__ C,
    int M, int N, int K, int NS)
{
  constexpr int MF = BM / 32;
  constexpr int NF = BN / 32;
  constexpr int AR = BM / 32;
  constexpr int BR = BN / 32;
  __shared__ __align__(16) short As[2][BM * 64];
  __shared__ __align__(16) short Bs[2][BN * 64];
  const int tid = threadIdx.x;
  const int wave = tid >> 6, lane = tid & 63;
  const int wr = wave >> 1, wc = wave & 1;
  const int bm = blockIdx.y * BM, bn = blockIdx.x * BN;

  const int srow = tid >> 3;
  const int dpiece = tid & 7;
  const int spiece = dpiece ^ (srow & 7);

  const short* sA[AR]; const short* sB[BR];
  int ldsA[AR], ldsB[BR];
#pragma unroll
  for (int r = 0; r < AR; ++r) {
    const int row = r * 32 + srow;
    sA[r] = A + (size_t)(bm + row) * K + spiece * 8;
    ldsA[r] = row * 128 + dpiece * 16;
  }
#pragma unroll
  for (int r = 0; r < BR; ++r) {
    const int row = r * 32 + srow;
    sB[r] = BT + (size_t)(bn + row) * K + spiece * 8;
    ldsB[r] = row * 128 + dpiece * 16;
  }

  const int xr = (lane & 7) << 4;
  f32x4 acc[MF][NF] = {};

#pragma unroll
  for (int r = 0; r < AR; ++r) {
    __builtin_amdgcn_global_load_lds(AS1(sA[r]), AS3((char*)As[0] + ldsA[r]), 16, 0, 0);
    sA[r] += 64;
  }
#pragma unroll
  for (int r = 0; r < BR; ++r) {
    __builtin_amdgcn_global_load_lds(AS1(sB[r]), AS3((char*)Bs[0] + ldsB[r]), 16, 0, 0);
    sB[r] += 64;
  }
  __syncthreads();

  int cur = 0;
  for (int k0 = 0; k0 < K; k0 += 64) {
    if (k0 + 64 < K) {
#pragma unroll
      for (int r = 0; r < AR; ++r) {
        __builtin_amdgcn_global_load_lds(AS1(sA[r]), AS3((char*)As[cur ^ 1] + ldsA[r]), 16, 0, 0);
        sA[r] += 64;
      }
#pragma unroll
      for (int r = 0; r < BR; ++r) {
        __builtin_amdgcn_global_load_lds(AS1(sB[r]), AS3((char*)Bs[cur ^ 1] + ldsB[r]), 16, 0, 0);
        sB[r] += 64;
      }
    }
    short8 af[MF][2], bf[NF][2];
#pragma unroll
    for (int m = 0; m < MF; ++m)
#pragma unroll
      for (int kk = 0; kk < 2; ++kk) {
        const int row = wr * (BM / 2) + m * 16 + (lane & 15);
        af[m][kk] = *(const short8*)((char*)As[cur] + ((row * 128 + kk * 64 + (lane >> 4) * 16) ^ xr));
      }
#pragma unroll
    for (int n = 0; n < NF; ++n)
#pragma unroll
      for (int kk = 0; kk < 2; ++kk) {
        const int row = wc * (BN / 2) + n * 16 + (lane & 15);
        bf[n][kk] = *(const short8*)((char*)Bs[cur] + ((row * 128 + kk * 64 + (lane >> 4) * 16) ^ xr));
      }
#pragma unroll
    for (int kk = 0; kk < 2; ++kk)
#pragma unroll
      for (int m = 0; m < MF; ++m)
#pragma unroll
        for (int n = 0; n < NF; ++n)
          acc[m][n] = __builtin_amdgcn_mfma_f32_16x16x32_bf16(af[m][kk], bf[n][kk], acc[m][n], 0, 0, 0);
    __syncthreads();
    cur ^= 1;
  }

#pragma unroll
  for (int m = 0; m < MF; ++m) {
#pragma unroll
    for (int n = 0; n < NF; ++n) {
      const int col = bn + wc * (BN / 2) + n * 16 + (lane & 15);
      const float bb = (EPI == 1 || EPI == 3) ? bias[col] : (bias ? bias[col] : 0.f);
#pragma unroll
      for (int r = 0; r < 4; ++r) {
        const int row = bm + wr * (BM / 2) + m * 16 + (lane >> 4) * 4 + r;
        const size_t idx = (size_t)row * N + col;
        float v = acc[m][n][r] + bb;
        if (EPI == 1) v = gelu_tanh(v);
        if (EPI == 2 || EPI == 3) v += b2f(add1[idx]);
        if (EPI == 3) v += b2f(add2[idx]);
        if (OBF == 1) ((short*)C)[(size_t)row * NS + col] = f2b(v);
        else ((float*)C)[idx] = v;
      }
    }
  }
}

// ---------------- Sliding-window attention (bf16 qkv in, bf16 out) ----------
__global__ __launch_bounds__(256) void swa_kernel(
    const unsigned short* __restrict__ qkv, short* __restrict__ out)
{
  __shared__ __align__(16) short ks[128 * 72];
  __shared__ __align__(16) short vt[64 * 136];
  __shared__ __align__(16) short ps[4][16 * 136];
  __shared__ float lsum[64];

  const int tid = threadIdx.x;
  const int w = tid >> 6, l = tid & 63;
  const int tile = blockIdx.x & 31;
  const int h = (blockIdx.x >> 5) & 7;
  const int b = blockIdx.x >> 8;
  const int s0 = tile * 64;
  const size_t base = (size_t)b * SS;

#pragma unroll
  for (int u = 0; u < 16; ++u) {
    const int id = u * 256 + tid;
    const int row = id >> 5, dp = id & 31;
    int jp = s0 - 32 + row;
    jp = min(max(jp, 0), SS - 1);
    const size_t g = (base + jp) * 1536 + h * 64 + dp * 2;
    *(unsigned*)&ks[row * 72 + dp * 2] = *(const unsigned*)&qkv[g + 512];
    const unsigned vv = *(const unsigned*)&qkv[g + 1024];
    vt[(dp * 2) * 136 + row] = (short)(vv & 0xFFFF);
    vt[(dp * 2 + 1) * 136 + row] = (short)(vv >> 16);
  }

  const int qi = w * 16 + (l & 15);
  short8 qf[2];
#pragma unroll
  for (int kf = 0; kf < 2; ++kf)
    qf[kf] = *(const short8*)&qkv[(base + s0 + qi) * 1536 + h * 64 + kf * 32 + (l >> 4) * 8];
  __syncthreads();

  f32x4 sa[8] = {};
#pragma unroll
  for (int mf = 0; mf < 8; ++mf)
#pragma unroll
    for (int kf = 0; kf < 2; ++kf) {
      const short8 af = *(const short8*)&ks[(mf * 16 + (l & 15)) * 72 + kf * 32 + (l >> 4) * 8];
      sa[mf] = __builtin_amdgcn_mfma_f32_16x16x32_bf16(af, qf[kf], sa[mf], 0, 0, 0);
    }

  float sv[8][4];
  float mx = -INFINITY;
#pragma unroll
  for (int mf = 0; mf < 8; ++mf)
#pragma unroll
    for (int r = 0; r < 4; ++r) {
      const int j = mf * 16 + (l >> 4) * 4 + r;
      const int jpos = s0 - 32 + j;
      const bool ok = (j >= qi) && (j <= qi + 64) && (jpos >= 0) && (jpos < SS);
      const float s = ok ? sa[mf][r] * 0.125f : -INFINITY;
      sv[mf][r] = s;
      mx = fmaxf(mx, s);
    }
  mx = fmaxf(mx, __shfl_xor(mx, 16));
  mx = fmaxf(mx, __shfl_xor(mx, 32));
  float ls = 0.f;
#pragma unroll
  for (int mf = 0; mf < 8; ++mf)
#pragma unroll
    for (int r = 0; r < 4; ++r) {
      const float p = __expf(sv[mf][r] - mx);
      sv[mf][r] = p;
      ls += p;
    }
  ls += __shfl_xor(ls, 16);
  ls += __shfl_xor(ls, 32);
  if (l < 16) lsum[w * 16 + l] = ls;

#pragma unroll
  for (int mf = 0; mf < 8; ++mf) {
    short4v p4;
    p4.x = f2b(sv[mf][0]); p4.y = f2b(sv[mf][1]);
    p4.z = f2b(sv[mf][2]); p4.w = f2b(sv[mf][3]);
    *(short4v*)&ps[w][(l & 15) * 136 + mf * 16 + (l >> 4) * 4] = p4;
  }

  f32x4 oa[4] = {};
#pragma unroll
  for (int kf = 0; kf < 4; ++kf) {
    const short8 pf = *(const short8*)&ps[w][(l & 15) * 136 + kf * 32 + (l >> 4) * 8];
#pragma unroll
    for (int nf = 0; nf < 4; ++nf) {
      const short8 vf = *(const short8*)&vt[(nf * 16 + (l & 15)) * 136 + kf * 32 + (l >> 4) * 8];
      oa[nf] = __builtin_amdgcn_mfma_f32_16x16x32_bf16(pf, vf, oa[nf], 0, 0, 0);
    }
  }

  float rl[4];
#pragma unroll
  for (int r = 0; r < 4; ++r) rl[r] = 1.f / lsum[w * 16 + (l >> 4) * 4 + r];
#pragma unroll
  for (int nf = 0; nf < 4; ++nf)
#pragma unroll
    for (int r = 0; r < 4; ++r) {
      const int q = (l >> 4) * 4 + r;
      const int d = nf * 16 + (l & 15);
      out[(base + s0 + w * 16 + q) * 512 + h * 64 + d] = f2b(oa[nf][r] * rl[r]);
    }
}

// ========== Neural memory, linear-scan formulation ==========

// ---- P1: per (chain, chunk) compute A_c, B_c via MFMA (bf16 k,v inputs) ----
__global__ __launch_bounds__(256) void mem_prep(
    const short* __restrict__ kb, const short* __restrict__ vb,
    short* __restrict__ Aq, short* __restrict__ Bq)
{
  __shared__ __align__(16) short kn[64 * 136];
  __shared__ __align__(16) char kT[128 * 128];
  __shared__ __align__(16) char vT[128 * 128];
  const int bid = blockIdx.x;
  const int chain = bid >> 5, c = bid & 31;
  const int b = chain >> 2, mh = chain & 3;
  const size_t rowbase = (size_t)(b * SS + c * 64);
  const int tid = threadIdx.x, w = tid >> 6, l = tid & 63;
  const int td = tid & 127, rh = tid >> 7;

#pragma unroll
  for (int pass = 0; pass < 2; ++pass) {
    const short* src = pass ? vb : kb;
    char* dT = pass ? vT : kT;
#pragma unroll
    for (int j = 0; j < 4; ++j) {
      const int i4 = tid + 256 * j;
      const int r = i4 >> 4, d8 = (i4 & 15) * 8;
      *(short8*)&kn[r * 136 + d8] = *(const short8*)&src[(rowbase + r) * 1536 + mh * 128 + d8];
    }
    __syncthreads();
#pragma unroll
    for (int j = 0; j < 4; ++j) {
      const int r0 = rh * 8 + 16 * j;
      short8 g8;
#pragma unroll
      for (int t = 0; t < 8; ++t) g8[t] = kn[(r0 + t) * 136 + td];
      *(short8*)&dT[(td * 128 + r0 * 2) ^ ((td & 7) << 4)] = g8;
    }
    __syncthreads();
  }

  const int wr = w >> 1, wc = w & 1;
  {
    f32x4 acc[4][4] = {};
#pragma unroll
    for (int kf = 0; kf < 2; ++kf) {
      short8 af[4];
#pragma unroll
      for (int m = 0; m < 4; ++m) {
        const int d = wr * 64 + m * 16 + (l & 15);
        af[m] = *(const short8*)&kT[(d * 128 + kf * 64 + (l >> 4) * 16) ^ ((d & 7) << 4)];
      }
#pragma unroll
      for (int n = 0; n < 4; ++n) {
        const int dp = wc * 64 + n * 16 + (l & 15);
        const short8 bf = *(const short8*)&kT[(dp * 128 + kf * 64 + (l >> 4) * 16) ^ ((dp & 7) << 4)];
#pragma unroll
        for (int m = 0; m < 4; ++m)
          acc[m][n] = __builtin_amdgcn_mfma_f32_16x16x32_bf16(af[m], bf, acc[m][n], 0, 0, 0);
      }
    }
    char* Ad = (char*)(Aq + (size_t)bid * 16384);
#pragma unroll
    for (int m = 0; m < 4; ++m)
#pragma unroll
      for (int n = 0; n < 4; ++n) {
        const int dp = wc * 64 + n * 16 + (l & 15);
        const int d0 = wr * 64 + m * 16 + (l >> 4) * 4;
        short4v s4;
#pragma unroll
        for (int i = 0; i < 4; ++i) s4[i] = f2b(acc[m][n][i] * 0.015625f);
        *(short4v*)&Ad[(dp * 256 + d0 * 2) ^ ((dp & 7) << 4)] = s4;
      }
  }
  {
    f32x4 acc[4][4] = {};
#pragma unroll
    for (int kf = 0; kf < 2; ++kf) {
      short8 af[4];
#pragma unroll
      for (int m = 0; m < 4; ++m) {
        const int d = wr * 64 + m * 16 + (l & 15);
        af[m] = *(const short8*)&kT[(d * 128 + kf * 64 + (l >> 4) * 16) ^ ((d & 7) << 4)];
      }
#pragma unroll
      for (int n = 0; n < 4; ++n) {
        const int e = wc * 64 + n * 16 + (l & 15);
        const short8 bf = *(const short8*)&vT[(e * 128 + kf * 64 + (l >> 4) * 16) ^ ((e & 7) << 4)];
#pragma unroll
        for (int m = 0; m < 4; ++m)
          acc[m][n] = __builtin_amdgcn_mfma_f32_16x16x32_bf16(af[m], bf, acc[m][n], 0, 0, 0);
      }
    }
    short* Bd = Bq + (size_t)bid * 16384;
#pragma unroll
    for (int m = 0; m < 4; ++m)
#pragma unroll
      for (int n = 0; n < 4; ++n) {
        const int e = wc * 64 + n * 16 + (l & 15);
        const int d0 = wr * 64 + m * 16 + (l >> 4) * 4;
        short4v s4;
#pragma unroll
        for (int i = 0; i < 4; ++i) s4[i] = f2b(acc[m][n][i] * 0.015625f);
        *(short4v*)&Bd[e * 128 + d0] = s4;
      }
  }
}

// ---- P2: serial scan — raw s_barrier + counted vmcnt, depth-2 A prefetch ----
__global__ __launch_bounds__(256) void mem_scan2(
    const short* __restrict__ Aq, const short* __restrict__ Bq,
    short* __restrict__ MTg)
{
  __shared__ __align__(16) char AcL[3][32768];
  __shared__ __align__(16) char MT[2][8192];
  const int bid = blockIdx.x;
  const int chain = bid >> 2, ch = bid & 3;
  const int tid = threadIdx.x;
  const int w = tid >> 6, l = tid & 63;
  const int wr = w >> 1, wc = w & 1;
  const int e = wc * 16 + (l & 15);

  const short* Ab = Aq + (size_t)chain * 32 * 16384;
  const short* Bb = Bq + (size_t)chain * 32 * 16384;
  short* MTb = MTg + (size_t)chain * 32 * 16384 + (size_t)ch * 32 * 128;
  const int brow = (ch * 32 + e) * 128;

  {
    const short8 z = {0, 0, 0, 0, 0, 0, 0, 0};
    for (int i = tid; i < 512; i += 256) *(short8*)(MT[0] + i * 16) = z;
  }
#pragma unroll
  for (int cc = 0; cc < 2; ++cc) {
    const char* srcA = (const char*)(Ab + (size_t)cc * 16384);
#pragma unroll
    for (int j = 0; j < 8; ++j) {
      const int byte = tid * 16 + j * 4096;
      __builtin_amdgcn_global_load_lds(AS1(srcA + byte), AS3(AcL[cc] + byte), 16, 0, 0);
    }
  }
  short4v b0[4], b1[4], b2[4];
#pragma unroll
  for (int m = 0; m < 4; ++m) {
    b0[m] = *(const short4v*)&Bb[brow + wr * 64 + m * 16 + (l >> 4) * 4];
    b1[m] = *(const short4v*)&Bb[16384 + brow + wr * 64 + m * 16 + (l >> 4) * 4];
  }
  float Mreg[16] = {}, Momreg[16] = {};
  __syncthreads();

#define SCHUNK(C, AB, MR, BC, BN_, DOI, WN)                                    \
  {                                                                            \
    short* slot = MTb + (size_t)(C) * 16384;                                   \
    _Pragma("unroll") for (int m = 0; m < 4; ++m) {                            \
      const int d0 = wr * 64 + m * 16 + (l >> 4) * 4;                          \
      short4v s4;                                                              \
      _Pragma("unroll") for (int i = 0; i < 4; ++i) s4[i] = f2b(Mreg[m * 4 + i]); \
      *(short4v*)&slot[e * 128 + d0] = s4;                                     \
    }                                                                          \
    if (DOI) {                                                                 \
      const char* srcA = (const char*)(Ab + (size_t)((C) + 2) * 16384);        \
      _Pragma("unroll") for (int j = 0; j < 8; ++j) {                          \
        const int byte = tid * 16 + j * 4096;                                  \
        __builtin_amdgcn_global_load_lds(AS1(srcA + byte),                     \
            AS3(AcL[((C) + 2) % 3] + byte), 16, 0, 0);                         \
      }                                                                        \
      const short* Bn = Bb + (size_t)((C) + 2) * 16384;                        \
      _Pragma("unroll") for (int m = 0; m < 4; ++m)                            \
        BN_[m] = *(const short4v*)&Bn[brow + wr * 64 + m * 16 + (l >> 4) * 4]; \
    }                                                                          \
    {                                                                          \
      f32x4 acc[4] = {};                                                       \
      _Pragma("unroll") for (int kf = 0; kf < 4; ++kf) {                       \
        const short8 bf = *(const short8*)&MT[MR][(e * 256 + kf * 64 + (l >> 4) * 16) ^ ((e & 7) << 4)]; \
        _Pragma("unroll") for (int m = 0; m < 4; ++m) {                        \
          const int d = wr * 64 + m * 16 + (l & 15);                           \
          const short8 af = *(const short8*)&AcL[AB][(d * 256 + kf * 64 + (l >> 4) * 16) ^ ((d & 7) << 4)]; \
          acc[m] = __builtin_amdgcn_mfma_f32_16x16x32_bf16(af, bf, acc[m], 0, 0, 0); \
        }                                                                      \
      }                                                                        \
      _Pragma("unroll") for (int m = 0; m < 4; ++m) {                          \
        const int d0 = wr * 64 + m * 16 + (l >> 4) * 4;                        \
        short4v s4;                                                            \
        _Pragma("unroll") for (int i = 0; i < 4; ++i) {                        \
          const int idx = m * 4 + i;                                           \
          const float g = acc[m][i] - b2f(BC[m][i]);                           \
          Momreg[idx] = 0.9f * Momreg[idx] - 0.1f * g;                         \
          Mreg[idx] = 0.99f * Mreg[idx] + Momreg[idx];                         \
          s4[i] = f2b(Mreg[idx]);                                              \
        }                                                                      \
        *(short4v*)&MT[(MR) ^ 1][(e * 256 + d0 * 2) ^ ((e & 7) << 4)] = s4;    \
      }                                                                        \
    }                                                                          \
    asm volatile("s_waitcnt lgkmcnt(0) vmcnt(" #WN ")" ::: "memory");          \
    __builtin_amdgcn_sched_barrier(0);                                         \
    __builtin_amdgcn_s_barrier();                                              \
    __builtin_amdgcn_sched_barrier(0);                                         \
  }

  SCHUNK(0, 0, 0, b0, b2, 1, 20)  SCHUNK(1, 1, 1, b1, b0, 1, 20)
  SCHUNK(2, 2, 0, b2, b1, 1, 20)  SCHUNK(3, 0, 1, b0, b2, 1, 20)
  SCHUNK(4, 1, 0, b1, b0, 1, 20)  SCHUNK(5, 2, 1, b2, b1, 1, 20)
  SCHUNK(6, 0, 0, b0, b2, 1, 20)  SCHUNK(7, 1, 1, b1, b0, 1, 20)
  SCHUNK(8, 2, 0, b2, b1, 1, 20)  SCHUNK(9, 0, 1, b0, b2, 1, 20)
  SCHUNK(10, 1, 0, b1, b0, 1, 20) SCHUNK(11, 2, 1, b2, b1, 1, 20)
  SCHUNK(12, 0, 0, b0, b2, 1, 20) SCHUNK(13, 1, 1, b1, b0, 1, 20)
  SCHUNK(14, 2, 0, b2, b1, 1, 20) SCHUNK(15, 0, 1, b0, b2, 1, 20)
  SCHUNK(16, 1, 0, b1, b0, 1, 20) SCHUNK(17, 2, 1, b2, b1, 1, 20)
  SCHUNK(18, 0, 0, b0, b2, 1, 20) SCHUNK(19, 1, 1, b1, b0, 1, 20)
  SCHUNK(20, 2, 0, b2, b1, 1, 20) SCHUNK(21, 0, 1, b0, b2, 1, 20)
  SCHUNK(22, 1, 0, b1, b0, 1, 20) SCHUNK(23, 2, 1, b2, b1, 1, 20)
  SCHUNK(24, 0, 0, b0, b2, 1, 20) SCHUNK(25, 1, 1, b1, b0, 1, 20)
  SCHUNK(26, 2, 0, b2, b1, 1, 20) SCHUNK(27, 0, 1, b0, b2, 1, 20)
  SCHUNK(28, 1, 0, b1, b0, 1, 20) SCHUNK(29, 2, 1, b2, b1, 0, 8)
  SCHUNK(30, 0, 0, b0, b2, 0, 8)
#undef SCHUNK

  // epilogue: slot 31 = M_30
  {
    short* slot = MTb + (size_t)31 * 16384;
#pragma unroll
    for (int m = 0; m < 4; ++m) {
      const int d0 = wr * 64 + m * 16 + (l >> 4) * 4;
      short4v s4;
#pragma unroll
      for (int i = 0; i < 4; ++i) s4[i] = f2b(Mreg[m * 4 + i]);
      *(short4v*)&slot[e * 128 + d0] = s4;
    }
  }
}

// ---- P3: out_c = q_c @ M_{c-1} (bf16 q input) ----
__global__ __launch_bounds__(256) void mem_out(
    const short* __restrict__ qb, const short* __restrict__ MTg,
    short* __restrict__ mem)
{
  const int bid = blockIdx.x;
  const int chain = bid >> 5, c = bid & 31;
  const int b = chain >> 2, mh = chain & 3;
  const size_t rowbase = (size_t)(b * SS + c * 64);
  const int tid = threadIdx.x, w = tid >> 6, l = tid & 63;
  const int wr = w >> 1, wc = w & 1;
  const short* MTc = MTg + (size_t)chain * 32 * 16384 + (size_t)c * 16384;

  f32x4 acc[2][4] = {};
#pragma unroll
  for (int kf = 0; kf < 4; ++kf) {
    short8 af[2];
#pragma unroll
    for (int m = 0; m < 2; ++m) {
      const int r = wr * 32 + m * 16 + (l & 15);
      af[m] = *(const short8*)&qb[(rowbase + r) * 1536 + mh * 128 + kf * 32 + (l >> 4) * 8];
    }
#pragma unroll
    for (int n = 0; n < 4; ++n) {
      const int e = wc * 64 + n * 16 + (l & 15);
      const short8 bf = *(const short8*)&MTc[e * 128 + kf * 32 + (l >> 4) * 8];
#pragma unroll
      for (int m = 0; m < 2; ++m)
        acc[m][n] = __builtin_amdgcn_mfma_f32_16x16x32_bf16(af[m], bf, acc[m][n], 0, 0, 0);
    }
  }
#pragma unroll
  for (int m = 0; m < 2; ++m)
#pragma unroll
    for (int n = 0; n < 4; ++n)
#pragma unroll
      for (int i = 0; i < 4; ++i) {
        const int r = wr * 32 + m * 16 + (l >> 4) * 4 + i;
        const int e = wc * 64 + n * 16 + (l & 15);
        mem[(rowbase + r) * 512 + mh * 128 + e] = f2b(acc[m][n][i]);
      }
}

// ---------------- merged weight transpose+convert (all matrices, 1 launch) ---
struct TcvtJob { const float* src; short* dst; int K; int N; int blks; };
struct TcvtArgs { TcvtJob j[10]; };

__global__ __launch_bounds__(256) void tcvt_all(TcvtArgs a)
{
  int bid = blockIdx.x;
  const float* src = nullptr; short* dst = nullptr; int K = 0, N = 0;
#pragma unroll
  for (int i = 0; i < 10; ++i) {
    if (!src) {
      if (bid < a.j[i].blks) { src = a.j[i].src; dst = a.j[i].dst; K = a.j[i].K; N = a.j[i].N; }
      else bid -= a.j[i].blks;
    }
  }
  const int nt = N >> 5, kt = K >> 5;
  const int z = bid / (nt * kt);
  const int rem = bid % (nt * kt);
  const int k0 = (rem / nt) * 32, n0 = (rem % nt) * 32;
  const size_t zoff = (size_t)z * K * N;
  src += zoff; dst += zoff;

  __shared__ float t[32][33];
  const int tx = threadIdx.x & 31, ty = threadIdx.x >> 5;
#pragma unroll
  for (int i = 0; i < 4; ++i)
    t[ty + i * 8][tx] = src[(size_t)(k0 + ty + i * 8) * N + n0 + tx];
  __syncthreads();
#pragma unroll
  for (int i = 0; i < 4; ++i)
    dst[(size_t)(n0 + ty + i * 8) * K + k0 + tx] = f2b(t[tx][ty + i * 8]);
}

// ---------------- persistent path: wide parallel kernels -------------------
__global__ __launch_bounds__(256) void mean_tokens_kernel(
    const float* __restrict__ pm, float* __restrict__ mvec)
{
  const int d = blockIdx.x * 256 + threadIdx.x;
  if (d < 512) {
    float s = 0.f;
#pragma unroll
    for (int t = 0; t < 16; ++t) s += pm[t * 512 + d];
    mvec[d] = s * (1.f / 16.f);
  }
}

// out[e] = bias[e] + sum_d a[d]*W[d*512+e]; grid 32 x 256 (16 outputs/block)
__global__ __launch_bounds__(256) void matvec512_kernel(
    const float* __restrict__ a, const float* __restrict__ W,
    const float* __restrict__ bias, float* __restrict__ out)
{
  __shared__ float red[16][17];
  const int eo = threadIdx.x & 15;
  const int g = threadIdx.x >> 4;
  const int e = blockIdx.x * 16 + eo;
  float s = 0.f;
#pragma unroll 8
  for (int j = 0; j < 32; ++j) {
    const int d = g * 32 + j;
    s += a[d] * W[d * 512 + e];
  }
  red[g][eo] = s;
  __syncthreads();
  if (threadIdx.x < 16) {
    float t = bias[blockIdx.x * 16 + threadIdx.x];
#pragma unroll
    for (int gg = 0; gg < 16; ++gg) t += red[gg][threadIdx.x];
    out[blockIdx.x * 16 + threadIdx.x] = t;
  }
}

// ---------------- host side ----------------
extern "C" void kernel_launch(void* const* d_in, const int* in_sizes, int n_in,
                              void* d_out, int out_size, void* d_ws, size_t ws_size,
                              hipStream_t stream)
{
  const float* x         = (const float*)d_in[0];
  const float* n1w       = (const float*)d_in[1];
  const float* n1b       = (const float*)d_in[2];
  const float* qkvw      = (const float*)d_in[3];
  const float* qkvb      = (const float*)d_in[4];
  const float* projw     = (const float*)d_in[5];
  const float* projb     = (const float*)d_in[6];
  const float* n2w       = (const float*)d_in[7];
  const float* n2b       = (const float*)d_in[8];
  const float* fc1w      = (const float*)d_in[9];
  const float* fc1b      = (const float*)d_in[10];
  const float* fc2w      = (const float*)d_in[11];
  const float* fc2b      = (const float*)d_in[12];
  const float* mlnw      = (const float*)d_in[13];
  const float* mlnb      = (const float*)d_in[14];
  const float* mwq       = (const float*)d_in[15];
  const float* mwk       = (const float*)d_in[16];
  const float* mwv       = (const float*)d_in[17];
  const float* mprojw    = (const float*)d_in[18];
  const float* mprojb    = (const float*)d_in[19];
  const float* pm_tokens = (const float*)d_in[20];
  const float* pmw       = (const float*)d_in[21];
  const float* pmb       = (const float*)d_in[22];
  const float* fw        = (const float*)d_in[23];
  const float* fb        = (const float*)d_in[24];
  float* out = (float*)d_out;

  char* p = (char*)d_ws;
  auto alloc = [&](size_t bytes) {
    char* r = p;
    p += (bytes + 255) & ~(size_t)255;
    return r;
  };
  short* qkvwT  = (short*)alloc(6ull * 1536 * 512 * 2);
  short* projwT = (short*)alloc(6ull * 512 * 512 * 2);
  short* fc1wT  = (short*)alloc(6ull * 2048 * 512 * 2);
  short* fc2wT  = (short*)alloc(6ull * 512 * 2048 * 2);
  short* mqkvT  = (short*)alloc(3ull * 512 * 512 * 2);
  short* mprojT = (short*)alloc(512ull * 512 * 2);
  short* fwT    = (short*)alloc(512ull * 1024 * 2);
  short* bigb   = (short*)alloc((size_t)BS * 1536 * 2);
  short* hbuf   = (short*)alloc((size_t)BS * 512 * 2);   // bf16 residual stream
  short* xb     = (short*)alloc((size_t)BS * 512 * 2);   // bf16 copy of x
  float* t0     = (float*)alloc(3 * 512 * 4);
  float* t1 = t0 + 512; float* t2 = t1 + 512;
  short* actA   = (short*)alloc((size_t)BS * 512 * 2);
  short* ln0b   = (short*)alloc((size_t)BS * 512 * 2);
  short* attnb  = (short*)alloc((size_t)BS * 512 * 2);
  short* ff1b   = (short*)alloc((size_t)BS * 2048 * 2);
  short* stlt   = (short*)alloc((size_t)BS * 1024 * 2);
  short* Aq     = (short*)alloc(256ull * 16384 * 2);
  short* Bq     = (short*)alloc(256ull * 16384 * 2);
  short* MTg    = (short*)alloc(256ull * 16384 * 2);

  // ---- all weight transposes in one launch ----
  TcvtArgs ta;
  ta.j[0] = {qkvw,  qkvwT,  512, 1536, 48 * 16 * 6};
  ta.j[1] = {projw, projwT, 512, 512,  16 * 16 * 6};
  ta.j[2] = {fc1w,  fc1wT,  512, 2048, 64 * 16 * 6};
  ta.j[3] = {fc2w,  fc2wT,  2048, 512, 16 * 64 * 6};
  ta.j[4] = {mwq, mqkvT,                 512, 512, 256};
  ta.j[5] = {mwk, mqkvT + 512 * 512,     512, 512, 256};
  ta.j[6] = {mwv, mqkvT + 2 * 512 * 512, 512, 512, 256};
  ta.j[7] = {mprojw, mprojT, 512, 512, 256};
  ta.j[8] = {fw, fwT, 1024, 512, 512};
  ta.j[9] = {nullptr, nullptr, 32, 32, 0};
  int total_blks = 0;
  for (int i = 0; i < 10; ++i) total_blks += ta.j[i].blks;
  tcvt_all<<<total_blks, 256, 0, stream>>>(ta);

  // ---- persistent path (parallel) ----
  mean_tokens_kernel<<<2, 256, 0, stream>>>(pm_tokens, t0);
  matvec512_kernel<<<32, 256, 0, stream>>>(t0, pmw, pmb, t1);
  matvec512_kernel<<<32, 256, 0, stream>>>(t1, fw + (size_t)1024 * 512, fb, t2);

  // ---- neural memory path ----
  ln_dual_kernel<<<BS / 4, 256, 0, stream>>>(x, mlnw, mlnb, actA, n1w, n1b, ln0b, xb);
  gemm_bf16<0, 1, 64, 128><<<dim3(12, 64), 256, 0, stream>>>(
      actA, mqkvT, nullptr, nullptr, nullptr, bigb, BS, 1536, 512, 1536);
  mem_prep<<<256, 256, 0, stream>>>(bigb + 512, bigb + 1024, Aq, Bq);
  mem_scan2<<<32, 256, 0, stream>>>(Aq, Bq, MTg);
  mem_out<<<256, 256, 0, stream>>>(bigb, MTg, ff1b);
  gemm_bf16<2, 1, 64, 64><<<dim3(8, 64), 256, 0, stream>>>(
      ff1b, mprojT, mprojb, xb, nullptr, stlt + 512, BS, 512, 512, 1024);

  // ---- layer stack (bf16 residual stream hbuf) ----
  for (int l = 0; l < LL; ++l) {
    const short* lnin = (l == 0) ? ln0b : actA;
    if (l > 0)
      ln_kernel<<<BS / 4, 256, 0, stream>>>(hbuf, n1w + l * 512, n1b + l * 512, actA);
    gemm_bf16<0, 1, 64, 128><<<dim3(12, 64), 256, 0, stream>>>(
        lnin, qkvwT + (size_t)l * 1536 * 512, qkvb + l * 1536,
        nullptr, nullptr, bigb, BS, 1536, 512, 1536);
    swa_kernel<<<512, 256, 0, stream>>>((const unsigned short*)bigb, attnb);
    gemm_bf16<2, 1, 64, 64><<<dim3(8, 64), 256, 0, stream>>>(
        attnb, projwT + (size_t)l * 512 * 512, projb + l * 512,
        (l == 0) ? xb : hbuf, nullptr, hbuf, BS, 512, 512, 512);
    ln_kernel<<<BS / 4, 256, 0, stream>>>(hbuf, n2w + l * 512, n2b + l * 512, actA);
    gemm_bf16<1, 1, 64, 128><<<dim3(16, 64), 256, 0, stream>>>(
        actA, fc1wT + (size_t)l * 2048 * 512, fc1b + l * 2048,
        nullptr, nullptr, ff1b, BS, 2048, 512, 2048);
    if (l < LL - 1)
      gemm_bf16<3, 1, 64, 64><<<dim3(8, 64), 256, 0, stream>>>(
          ff1b, fc2wT + (size_t)l * 512 * 2048, fc2b + l * 512,
          hbuf, actA, hbuf, BS, 512, 2048, 512);
    else
      gemm_bf16<3, 1, 64, 64><<<dim3(8, 64), 256, 0, stream>>>(
          ff1b, fc2wT + (size_t)l * 512 * 2048, fc2b + l * 512,
          hbuf, actA, stlt, BS, 512, 2048, 1024);   // ST -> stlt[:, 0:512]
  }

  // ---- fusion: out = [ST | LT] @ fwT + (persistent + fusion bias) ----
  gemm_bf16<0, 0, 64, 64><<<dim3(8, 64), 256, 0, stream>>>(
      stlt, fwT, t2, nullptr, nullptr, out, BS, 512, 1024, 512);
}